// Round 6
// baseline (2409.559 us; speedup 1.0000x reference)
//
#include <hip/hip_runtime.h>
#include <math.h>

#define PI_D 3.14159265358979323846
#define TPB 256
typedef unsigned short ushortT;
typedef unsigned int uintT;

__device__ __forceinline__ float2 cxmul(float2 a, float2 b){
  return make_float2(a.x*b.x - a.y*b.y, a.x*b.y + a.y*b.x);
}
__device__ __forceinline__ float bf2f(ushortT u){
  uintT x = ((uintT)u) << 16;
  return __uint_as_float(x);
}
__device__ __forceinline__ ushortT f2bf(float f){
  uintT x = __float_as_uint(f);
  x = x + 0x7FFFu + ((x >> 16) & 1u);
  return (ushortT)(x >> 16);
}

// ---------------- tables ----------------
__global__ void k_tables(double* lf, double* qw){
  if (threadIdx.x == 0){
    lf[0] = 0.0;
    for (int i = 1; i <= 64; ++i) lf[i] = lf[i-1] + log((double)i);
  }
  int j = threadIdx.x;
  if (j < 64){
    double s1 = sin(PI_D*(2*j+1)/128.0);
    double inner = 0.0;
    for (int k = 0; k < 32; ++k)
      inner += (1.0/(double)(2*k+1)) * sin((double)(2*j+1)*(double)(2*k+1)*PI_D/128.0);
    qw[j] = (2.0/32.0) * s1 * inner;
  }
}

__device__ double wigd(const double* lfs, int l, int mp, int m, double lc, double ls){
  if (mp < -l || mp > l || m < -l || m > l) return 0.0;
  int k0 = (m - mp > 0) ? (m - mp) : 0;
  int k1 = (l + m < l - mp) ? (l + m) : (l - mp);
  double base = 0.5*(lfs[l+mp] + lfs[l-mp] + lfs[l+m] + lfs[l-m]);
  double val = 0.0;
  for (int k = k0; k <= k1; ++k){
    double t = base - lfs[l+m-k] - lfs[k] - lfs[mp-m+k] - lfs[l-mp-k]
             + (double)(2*l + m - mp - 2*k)*lc + (double)(mp - m + 2*k)*ls;
    double e = exp(t);
    val += ((mp - m + k) & 1) ? -e : e;
  }
  return val;
}

// Dz[z][l][mi'][n], Deq[l][r][c]
__global__ __launch_bounds__(TPB) void k_wigner(const double* __restrict__ lf,
                                                float* __restrict__ Dz, float* __restrict__ Deq){
  __shared__ double lfs[65];
  if (threadIdx.x < 65) lfs[threadIdx.x] = lf[threadIdx.x];
  __syncthreads();
  int zs = blockIdx.x, l = blockIdx.y;
  double beta = (zs < 64) ? ((double)zs + 0.5)*PI_D/64.0 : PI_D*0.5;
  double ch = cos(beta*0.5), sh = sin(beta*0.5);
  double lc = log(ch), ls = log(sh);
  if (zs < 64){
    for (int idx = threadIdx.x; idx < 2016; idx += TPB){
      int mi = idx/63, c = idx%63;
      Dz[((size_t)(zs*32 + l)*32 + mi)*63 + c] = (float)wigd(lfs, l, mi, c-31, lc, ls);
    }
  } else {
    for (int idx = threadIdx.x; idx < 3969; idx += TPB){
      int r = idx/63, c = idx%63;
      Deq[((size_t)l*63 + r)*63 + c] = (float)wigd(lfs, l, r-31, c-31, lc, ls);
    }
  }
}

// Kh[o][i][n] = scale * sum_p K[i,o,p] * exp(-i*2pi*p*(n-31)/64)
__global__ void k_kh(const float* __restrict__ K, float2* __restrict__ Kh, int I, int O, float scale){
  int idx = blockIdx.x*blockDim.x + threadIdx.x;
  if (idx >= I*O*63) return;
  int n = idx % 63, i = (idx/63) % I, o = idx/(63*I);
  float sr = 0.f, si = 0.f;
  for (int p = 0; p < 64; ++p){
    int t = (p * (n - 31)) & 63;
    float s, c;
    sincosf(-(float)PI_D/32.f * (float)t, &s, &c);
    float kv = K[(i*O + o)*64 + p];
    sr += kv * c; si += kv * s;
  }
  Kh[((size_t)o*I + i)*63 + n] = make_float2(sr*scale, si*scale);
}

// ---------------- S2 front ----------------
__global__ void k_s2_fft(const float* __restrict__ x, float2* __restrict__ XH2){
  int idx = blockIdx.x*blockDim.x + threadIdx.x;
  if (idx >= 2*3*64*63) return;
  int mi = idx % 63; int z = (idx/63) & 63; int bc = idx / (63*64);
  int f = (mi + 33) & 63;
  const float* row = x + ((size_t)bc*64 + z)*64;
  float sr = 0.f, si = 0.f;
  for (int a = 0; a < 64; ++a){
    int t = (f*a) & 63;
    float s, c;
    sincosf(-(float)PI_D/32.f * (float)t, &s, &c);
    sr += row[a]*c; si += row[a]*s;
  }
  XH2[idx] = make_float2(sr, si);
}

__global__ void k_s2_F(const float* __restrict__ Dz, const double* __restrict__ qw,
                       const float2* __restrict__ XH2, float2* __restrict__ F2){
  int idx = blockIdx.x*blockDim.x + threadIdx.x;
  if (idx >= 2*3*32*63) return;
  int r = idx % 63; int l = (idx/63) & 31; int bc = idx / (63*32);
  float2 acc = make_float2(0,0);
  for (int z = 0; z < 64; ++z){
    float d;
    if (r >= 31) d = Dz[((size_t)(z*32 + l)*32 + (r-31))*63 + 31];
    else {
      d = Dz[((size_t)(z*32 + l)*32 + (31-r))*63 + 31];
      if ((31-r) & 1) d = -d;
    }
    float wv = (float)qw[z] * d;
    float2 v = XH2[((size_t)bc*64 + z)*63 + r];
    acc.x += wv*v.x; acc.y += wv*v.y;
  }
  F2[idx] = acc;
}

__global__ void k_s2_zhat(const float* __restrict__ Deq, const float2* __restrict__ F2,
                          const float2* __restrict__ Kh, float2* __restrict__ Z){
  int idx = blockIdx.x*blockDim.x + threadIdx.x;
  if (idx >= 2*25*32*2016) return;
  int n = idx % 63; int mi = (idx/63) & 31; int l = (idx/2016) & 31;
  int o = (idx/(2016*32)) % 25; int b = idx/(2016*32*25);
  float deq0 = Deq[((size_t)l*63 + n)*63 + 31];
  float2 acc = make_float2(0,0);
  for (int i = 0; i < 3; ++i){
    float2 f = F2[((size_t)(b*3 + i)*32 + l)*63 + (mi+31)];
    float2 kh = Kh[((size_t)(o*3 + i))*63 + n];
    float2 p = cxmul(f, kh);
    acc.x += p.x; acc.y += p.y;
  }
  Z[((size_t)((b*25+o)*32) + l)*2016 + mi*63 + n] = make_float2(acc.x*deq0, acc.y*deq0);
}

// ---------------- BN stats over bf16 X buffers ----------------
__global__ __launch_bounds__(TPB) void k_bnstats(const ushortT* __restrict__ src, int slotBase,
                                                 double* __restrict__ part){
  int c = blockIdx.x, blk = blockIdx.y;
  const uint2* s4 = (const uint2*)src;
  double s = 0.0, q = 0.0;
  for (int k = 0; k < 8; ++k){
    int g4 = blk*2048 + k*256 + threadIdx.x;
    int b = g4 >> 16, pos4 = g4 & 65535;
    uint2 u = s4[((size_t)(b*25 + c))*65536 + pos4];
    float v0 = bf2f((ushortT)(u.x & 0xffff)), v1 = bf2f((ushortT)(u.x >> 16));
    float v2 = bf2f((ushortT)(u.y & 0xffff)), v3 = bf2f((ushortT)(u.y >> 16));
    s += (double)v0 + v1 + v2 + v3;
    q += (double)v0*v0 + (double)v1*v1 + (double)v2*v2 + (double)v3*v3;
  }
  __shared__ double sh[TPB], sh2[TPB];
  sh[threadIdx.x] = s; sh2[threadIdx.x] = q;
  __syncthreads();
  for (int o = 128; o > 0; o >>= 1){
    if (threadIdx.x < o){ sh[threadIdx.x] += sh[threadIdx.x+o]; sh2[threadIdx.x] += sh2[threadIdx.x+o]; }
    __syncthreads();
  }
  if (threadIdx.x == 0){
    part[((size_t)(slotBase + c)*64 + blk)*2 + 0] = sh[0];
    part[((size_t)(slotBase + c)*64 + blk)*2 + 1] = sh2[0];
  }
}

__global__ void k_bnfinal(const double* __restrict__ part, const float* __restrict__ g,
                          const float* __restrict__ b, float2* __restrict__ ss, int C){
  int c = blockIdx.x*blockDim.x + threadIdx.x;
  if (c >= C) return;
  double s = 0.0, q = 0.0;
  for (int k = 0; k < 64; ++k){
    s += part[((size_t)c*64 + k)*2 + 0];
    q += part[((size_t)c*64 + k)*2 + 1];
  }
  double N = 524288.0;
  double mu = s / N;
  double var = q / N - mu*mu;
  double sc = (double)g[c] / sqrt(var + 1e-5);
  ss[c] = make_float2((float)sc, (float)((double)b[c] - mu*sc));
}

// ---------------- 64-pt FFT across lanes (radix-2 DIF, shfl) ----------------
__device__ __forceinline__ float2 fft64_lane(float2 x, const float2* __restrict__ Wt, int lane){
  #pragma unroll
  for (int st = 0; st < 6; ++st){
    int h = 32 >> st;
    float2 p;
    p.x = __shfl_xor(x.x, h, 64);
    p.y = __shfl_xor(x.y, h, 64);
    if (lane & h){
      float2 s = make_float2(p.x - x.x, p.y - x.y);
      x = cxmul(s, Wt[(lane & (h-1)) << st]);
    } else {
      x = make_float2(x.x + p.x, x.y + p.y);
    }
  }
  return x;
}
__device__ __forceinline__ void init_W(float2* W, float sign){
  if (threadIdx.x < 64){
    float s, c;
    sincosf(sign*(float)(2.0*PI_D/64.0)*(float)threadIdx.x, &s, &c);
    W[threadIdx.x] = make_float2(c, s);
  }
}

// ---------------- fused BN+ReLU + fft2 + reduced centered extraction ----------------
__global__ __launch_bounds__(TPB) void k_fft2_fwd(const ushortT* __restrict__ X1, const ushortT* __restrict__ X2,
                                                  const ushortT* __restrict__ X3, const float2* __restrict__ ss,
                                                  float2* __restrict__ XH, int Cin, int z0){
  __shared__ float2 W[64];
  __shared__ __attribute__((aligned(16))) float2 buf[64*65];
  int bc = blockIdx.x, zz = blockIdx.y, z = z0 + zz;
  int b = bc / Cin, ci = bc % Cin;
  const ushortT* src; int cl;
  if (ci < 25){ src = X1; cl = ci; }
  else if (ci < 50){ src = X2; cl = ci - 25; }
  else { src = X3; cl = ci - 50; }
  src += ((size_t)(b*25 + cl)*64 + z)*4096;
  float2 sc = ss[ci];
  init_W(W, -1.f);
  int tid = threadIdx.x, lane = tid & 63, wid = tid >> 6;
  int rl = (int)(__brev((uintT)lane) >> 26);
  const uintT* s32 = (const uintT*)src;
  for (int i = tid; i < 2048; i += TPB){
    uintT u = s32[i];
    float v0 = fmaxf(bf2f((ushortT)(u & 0xffff))*sc.x + sc.y, 0.f);
    float v1 = fmaxf(bf2f((ushortT)(u >> 16))*sc.x + sc.y, 0.f);
    int row = i >> 5, col = (i << 1) & 63;
    buf[row*65 + col]     = make_float2(v0, 0.f);
    buf[row*65 + col + 1] = make_float2(v1, 0.f);
  }
  __syncthreads();
  #pragma unroll 4
  for (int i = 0; i < 16; ++i){
    int r = wid*16 + i;
    float2 x = buf[r*65 + lane];
    x = fft64_lane(x, W, lane);
    buf[r*65 + rl] = x;
  }
  __syncthreads();
  #pragma unroll 4
  for (int i = 0; i < 16; ++i){
    int c = wid*16 + i;
    float2 x = buf[lane*65 + c];
    x = fft64_lane(x, W, lane);
    buf[rl*65 + c] = x;
  }
  __syncthreads();
  float2* dst = XH + ((size_t)bc*32 + zz)*2016;
  for (int idx = tid; idx < 2016; idx += TPB){
    int mi = idx / 63, n = idx % 63;
    dst[idx] = buf[mi*65 + ((n+33)&63)];
  }
}

// ---------------- F[bc,l,mi,n] (+)= sum_z qw*Dz*XH — register-tiled ----------------
// grid (32 mi, 8 nt, ceil(BC/16)); block 256
__global__ __launch_bounds__(TPB) void k_wig_F(const float* __restrict__ Dz, const double* __restrict__ qw,
                                               const float2* __restrict__ XH, float2* __restrict__ F,
                                               int BC, int z0, int accum){
  __shared__ __attribute__((aligned(16))) float sm[9088];
  float* Dt = sm;                          // [z16][nn8][l 36pad]
  float2* Xt = (float2*)(sm + 4608);       // [bc16][130]
  int mi = blockIdx.x, nt = blockIdx.y, bcBase = blockIdx.z*16;
  int tid = threadIdx.x;
  int bg = tid & 3, lg = (tid>>2)&7, ng = tid>>5;
  float2 acc[4][4];
  #pragma unroll
  for (int a = 0; a < 4; ++a)
    #pragma unroll
    for (int j = 0; j < 4; ++j) acc[a][j] = make_float2(0,0);
  for (int zq = 0; zq < 32; zq += 16){
    __syncthreads();
    for (int idx = tid; idx < 4096; idx += TPB){
      int z = idx >> 8, l = (idx>>3)&31, nn = idx&7;
      int n = nt*8 + nn;
      float v = 0.f;
      if (n < 63) v = Dz[(((size_t)(z0+zq+z)*32 + l)*32 + mi)*63 + n] * (float)qw[z0+zq+z];
      Dt[(z*8+nn)*36 + l] = v;
    }
    for (int idx = tid; idx < 2048; idx += TPB){
      int bc = idx >> 7, z = (idx>>3)&15, nn = idx&7;
      int gbc = bcBase + bc, n = nt*8 + nn;
      float2 v = make_float2(0,0);
      if (gbc < BC && n < 63) v = XH[((size_t)gbc*32 + zq + z)*2016 + mi*63 + n];
      Xt[bc*130 + z*8 + nn] = v;
    }
    __syncthreads();
    #pragma unroll 4
    for (int z = 0; z < 16; ++z){
      const float4 d = *(const float4*)&Dt[(z*8+ng)*36 + lg*4];
      float dd[4] = {d.x, d.y, d.z, d.w};
      float2 xv[4];
      #pragma unroll
      for (int j = 0; j < 4; ++j) xv[j] = Xt[(bg + 4*j)*130 + z*8 + ng];
      #pragma unroll
      for (int j = 0; j < 4; ++j)
        #pragma unroll
        for (int dl = 0; dl < 4; ++dl){
          acc[j][dl].x += dd[dl]*xv[j].x;
          acc[j][dl].y += dd[dl]*xv[j].y;
        }
    }
  }
  __syncthreads();
  float2* St = (float2*)sm;                // [bc16][l32][nn8]
  #pragma unroll
  for (int j = 0; j < 4; ++j)
    #pragma unroll
    for (int dl = 0; dl < 4; ++dl)
      St[(((bg + 4*j)*32) + lg*4 + dl)*8 + ng] = acc[j][dl];
  __syncthreads();
  for (int idx = tid; idx < 4096; idx += TPB){
    int bc = idx >> 8, l = (idx>>3)&31, nn = idx&7;
    int gbc = bcBase + bc, n = nt*8 + nn;
    if (gbc < BC && n < 63){
      size_t a = ((size_t)(gbc*32 + l))*2016 + mi*63 + n;
      float2 v = St[idx];
      if (accum){ float2 o = F[a]; v.x += o.x; v.y += o.y; }
      F[a] = v;
    }
  }
}

// ---------------- C[bi,l,mi,n] = sum_k F[bi,l,mi,k]*Deq[l,n,k] — register-tiled ----------------
// grid (32 l, 32 mi, ceil(BC/64)); block 256
__global__ __launch_bounds__(TPB) void k_deq_C(const float* __restrict__ Deq, const float2* __restrict__ F,
                                               float2* __restrict__ C, int BC){
  __shared__ __attribute__((aligned(16))) float sm[12604];
  float2* Fb = (float2*)sm;                // [bi64][65pad]
  float* DeqT = sm + 8320;                 // [k63][68pad n]
  int l = blockIdx.x, mi = blockIdx.y, biBase = blockIdx.z*64;
  int tid = threadIdx.x;
  int ngr = tid & 15, big = tid >> 4;
  for (int idx = tid; idx < 3969; idx += TPB){
    int n = idx/63, k = idx - n*63;
    DeqT[k*68 + n] = Deq[((size_t)l*63 + n)*63 + k];
  }
  for (int idx = tid; idx < 4032; idx += TPB){
    int bi = idx/63, k = idx - bi*63;
    int gbi = biBase + bi;
    Fb[bi*65 + k] = (gbi < BC) ? F[((size_t)(gbi*32 + l))*2016 + mi*63 + k] : make_float2(0,0);
  }
  __syncthreads();
  float2 acc[4][4];
  #pragma unroll
  for (int a = 0; a < 4; ++a)
    #pragma unroll
    for (int j = 0; j < 4; ++j) acc[a][j] = make_float2(0,0);
  #pragma unroll 3
  for (int k = 0; k < 63; ++k){
    const float4 d = *(const float4*)&DeqT[k*68 + ngr*4];
    float dd[4] = {d.x, d.y, d.z, d.w};
    float2 fv[4];
    #pragma unroll
    for (int j = 0; j < 4; ++j) fv[j] = Fb[(big + 16*j)*65 + k];
    #pragma unroll
    for (int j = 0; j < 4; ++j)
      #pragma unroll
      for (int dn = 0; dn < 4; ++dn){
        acc[j][dn].x += dd[dn]*fv[j].x;
        acc[j][dn].y += dd[dn]*fv[j].y;
      }
  }
  __syncthreads();
  float2* St = (float2*)sm;                // [bi64][n63]
  #pragma unroll
  for (int j = 0; j < 4; ++j)
    #pragma unroll
    for (int dn = 0; dn < 4; ++dn){
      int n = ngr*4 + dn;
      if (n < 63) St[(big + 16*j)*63 + n] = acc[j][dn];
    }
  __syncthreads();
  for (int idx = tid; idx < 4032; idx += TPB){
    int bi = idx/63, n = idx - bi*63;
    int gbi = biBase + bi;
    if (gbi < BC) C[((size_t)(gbi*32 + l))*2016 + mi*63 + n] = St[idx];
  }
}

// ---------------- Z[b,o,l,mi,n] = sum_i Kh[o,i,n]*C[b,i,l,mi,n] — register-only ----------------
// grid (32 l, 8 mic, 3 oc); block 256 = 4 waves (one mi each); lane = n (63 active)
__global__ __launch_bounds__(TPB) void k_kh_z(const float2* __restrict__ C, const float2* __restrict__ Kh,
                                              float2* __restrict__ Z, int I, int O, int oChunk){
  int l = blockIdx.x, mic = blockIdx.y, oc = blockIdx.z;
  int lane = threadIdx.x & 63, wid = threadIdx.x >> 6;
  if (lane >= 63) return;
  int mi = mic*4 + wid;
  int n = lane;
  int o0 = oc*oChunk;
  int oCnt = O - o0; if (oCnt > oChunk) oCnt = oChunk;
  float2 acc[2][12];
  #pragma unroll
  for (int b = 0; b < 2; ++b)
    #pragma unroll
    for (int oo = 0; oo < 12; ++oo) acc[b][oo] = make_float2(0,0);
  size_t cBase = ((size_t)l)*2016 + mi*63 + n;
  for (int i = 0; i < I; ++i){
    float2 c0 = C[cBase + (size_t)i*64512];             // (0*I+i)*32*2016
    float2 c1 = C[cBase + (size_t)(I + i)*64512];
    #pragma unroll
    for (int oo = 0; oo < 12; ++oo){
      if (oo < oCnt){
        float2 kh = Kh[((size_t)(o0+oo)*I + i)*63 + n];
        acc[0][oo].x += kh.x*c0.x - kh.y*c0.y;
        acc[0][oo].y += kh.x*c0.y + kh.y*c0.x;
        acc[1][oo].x += kh.x*c1.x - kh.y*c1.y;
        acc[1][oo].y += kh.x*c1.y + kh.y*c1.x;
      }
    }
  }
  size_t zBase = ((size_t)l)*2016 + mi*63 + n;
  #pragma unroll
  for (int oo = 0; oo < 12; ++oo){
    if (oo < oCnt){
      int o = o0 + oo;
      Z[zBase + (size_t)(0*O + o)*64512] = acc[0][oo];
      Z[zBase + (size_t)(1*O + o)*64512] = acc[1][oo];
    }
  }
}

// ---------------- Xt[bo,z,mi,n] = sum_l wl*Dz*Z — register-tiled ----------------
// grid (32 mi, 8 nt, 2*ceil(BO/16)); block 256
__global__ __launch_bounds__(TPB) void k_wig_synth(const float* __restrict__ Dz, const float2* __restrict__ Z,
                                                   float2* __restrict__ Xt_g, int BO){
  __shared__ __attribute__((aligned(16))) float sm[9088];
  float* Dt = sm;                          // [l16][nn8][z 36pad]
  float2* Zt = (float2*)(sm + 4608);       // [bo16][130]
  int mi = blockIdx.x, nt = blockIdx.y;
  int z0 = (blockIdx.z & 1)*32;
  int boBase = (blockIdx.z >> 1)*16;
  int tid = threadIdx.x;
  int bg = tid & 3, zg = (tid>>2)&7, ng = tid>>5;
  float2 acc[4][4];
  #pragma unroll
  for (int a = 0; a < 4; ++a)
    #pragma unroll
    for (int j = 0; j < 4; ++j) acc[a][j] = make_float2(0,0);
  for (int lq = 0; lq < 32; lq += 16){
    __syncthreads();
    for (int idx = tid; idx < 4096; idx += TPB){
      int ll = idx >> 8, z = (idx>>3)&31, nn = idx&7;
      int n = nt*8 + nn, lG = lq + ll;
      float v = 0.f;
      if (n < 63) v = Dz[(((size_t)(z0+z)*32 + lG)*32 + mi)*63 + n] * (0.5f*(float)(2*lG+1));
      Dt[(ll*8+nn)*36 + z] = v;
    }
    for (int idx = tid; idx < 2048; idx += TPB){
      int bo = idx >> 7, ll = (idx>>3)&15, nn = idx&7;
      int gbo = boBase + bo, n = nt*8 + nn;
      float2 v = make_float2(0,0);
      if (gbo < BO && n < 63) v = Z[((size_t)(gbo*32 + lq + ll))*2016 + mi*63 + n];
      Zt[bo*130 + ll*8 + nn] = v;
    }
    __syncthreads();
    #pragma unroll 4
    for (int ll = 0; ll < 16; ++ll){
      const float4 d = *(const float4*)&Dt[(ll*8+ng)*36 + zg*4];
      float dd[4] = {d.x, d.y, d.z, d.w};
      float2 zv[4];
      #pragma unroll
      for (int j = 0; j < 4; ++j) zv[j] = Zt[(bg + 4*j)*130 + ll*8 + ng];
      #pragma unroll
      for (int j = 0; j < 4; ++j)
        #pragma unroll
        for (int dz = 0; dz < 4; ++dz){
          acc[j][dz].x += dd[dz]*zv[j].x;
          acc[j][dz].y += dd[dz]*zv[j].y;
        }
    }
  }
  __syncthreads();
  float2* St = (float2*)sm;                // [bo16][z32][nn8]
  #pragma unroll
  for (int j = 0; j < 4; ++j)
    #pragma unroll
    for (int dz = 0; dz < 4; ++dz)
      St[(((bg + 4*j)*32) + zg*4 + dz)*8 + ng] = acc[j][dz];
  __syncthreads();
  for (int idx = tid; idx < 4096; idx += TPB){
    int bo = idx >> 8, z = (idx>>3)&31, nn = idx&7;
    int gbo = boBase + bo, n = nt*8 + nn;
    if (gbo < BO && n < 63)
      Xt_g[((size_t)gbo*64 + z0 + z)*2016 + mi*63 + n] = St[idx];
  }
}

// ---------------- coalesced Hermitian build ----------------
__device__ __forceinline__ void build_plane_c(const float2* __restrict__ src, float2* buf){
  int tid = threadIdx.x;
  if (tid < 128){
    int k = tid & 63;
    if (tid < 64) buf[32*65 + k] = make_float2(0,0);
    else          buf[k*65 + 32] = make_float2(0,0);
  }
  for (int idx = tid; idx < 2016; idx += TPB){
    float2 v = src[idx];
    int mi = idx / 63, ni = idx - mi*63;
    buf[mi*65 + ((ni+33)&63)] = v;
    if (mi > 0) buf[(64-mi)*65 + ((31-ni)&63)] = make_float2(v.x, -v.y);
  }
}

// ---------------- ifft2 + real + bias -> bf16 X ----------------
__global__ __launch_bounds__(TPB) void k_ifft2_sym(const float2* __restrict__ Xt, ushortT* __restrict__ Xo,
                                                   const float* __restrict__ bias, int O){
  __shared__ float2 W[64];
  __shared__ __attribute__((aligned(16))) float2 buf[64*65];
  int bo = blockIdx.x >> 6;
  int o = bo % O;
  init_W(W, 1.f);
  int tid = threadIdx.x, lane = tid & 63, wid = tid >> 6;
  int rl = (int)(__brev((uintT)lane) >> 26);
  const float2* src = Xt + (size_t)blockIdx.x*2016;
  build_plane_c(src, buf);
  __syncthreads();
  #pragma unroll 4
  for (int i = 0; i < 16; ++i){
    int r = wid*16 + i;
    float2 x = buf[r*65 + lane];
    x = fft64_lane(x, W, lane);
    buf[r*65 + rl] = x;
  }
  __syncthreads();
  #pragma unroll 4
  for (int i = 0; i < 16; ++i){
    int c = wid*16 + i;
    float2 x = buf[lane*65 + c];
    x = fft64_lane(x, W, lane);
    buf[rl*65 + c] = x;
  }
  __syncthreads();
  float bb = bias[o];
  ushortT* dst = Xo + (size_t)blockIdx.x*4096;
  for (int idx = tid; idx < 4096; idx += TPB){
    dst[idx] = f2bf(buf[(idx>>6)*65 + (idx&63)].x * (1.f/4096.f) + bb);
  }
}

// ---------------- conv3 final stats from spectrum (Parseval) ----------------
__global__ __launch_bounds__(TPB) void k_stats3(const float2* __restrict__ Xt, double* __restrict__ part){
  int bo = blockIdx.x, zb = blockIdx.y;
  double s = 0.0, p = 0.0;
  for (int zz = 0; zz < 4; ++zz){
    const float2* pl = Xt + ((size_t)bo*64 + zb*4 + zz)*2016;
    for (int idx = threadIdx.x; idx < 2016; idx += TPB){
      float2 v = pl[idx];
      double q = (double)v.x*v.x + (double)v.y*v.y;
      p += (idx < 63) ? q : 2.0*q;
      if (idx == 31) s += v.x;
    }
  }
  __shared__ double sh[TPB], sh2[TPB];
  sh[threadIdx.x] = s; sh2[threadIdx.x] = p;
  __syncthreads();
  for (int o = 128; o > 0; o >>= 1){
    if (threadIdx.x < o){ sh[threadIdx.x] += sh[threadIdx.x+o]; sh2[threadIdx.x] += sh2[threadIdx.x+o]; }
    __syncthreads();
  }
  if (threadIdx.x == 0){
    part[((size_t)bo*16 + zb)*2 + 0] = sh[0];
    part[((size_t)bo*16 + zb)*2 + 1] = sh2[0];
  }
}

__global__ void k_fstat(const double* __restrict__ part, const float* __restrict__ bias,
                        const float* __restrict__ g, const float* __restrict__ bsh,
                        float2* __restrict__ ss, int O){
  int o = threadIdx.x;
  if (o >= O) return;
  double S = 0.0, P = 0.0;
  for (int b = 0; b < 2; ++b)
    for (int zb = 0; zb < 16; ++zb){
      size_t base = ((size_t)(b*O + o)*16 + zb)*2;
      S += part[base]; P += part[base+1];
    }
  P *= (1.0/4096.0);
  double N = 524288.0;
  double bi = bias[o];
  double mean = S/N + bi;
  double var = P/N + 2.0*bi*S/N + bi*bi - mean*mean;
  double sc = (double)g[o] / sqrt(var + 1e-5);
  ss[o] = make_float2((float)sc, (float)((bi - mean)*sc + (double)bsh[o]));
}

// ---------------- fused ifft2 + BN + ReLU + mean over gamma ----------------
__global__ __launch_bounds__(TPB) void k_final(const float2* __restrict__ Xt, const float2* __restrict__ ss,
                                               float* __restrict__ out, int O){
  __shared__ float2 W[64];
  __shared__ __attribute__((aligned(16))) float2 buf[64*65];
  __shared__ float s4[4*64];
  int bo = blockIdx.x >> 6;
  int o = bo % O;
  init_W(W, 1.f);
  int tid = threadIdx.x, lane = tid & 63, wid = tid >> 6;
  int rl = (int)(__brev((uintT)lane) >> 26);
  const float2* src = Xt + (size_t)blockIdx.x*2016;
  build_plane_c(src, buf);
  __syncthreads();
  #pragma unroll 4
  for (int i = 0; i < 16; ++i){
    int r = wid*16 + i;
    float2 x = buf[r*65 + lane];
    x = fft64_lane(x, W, lane);
    buf[r*65 + rl] = x;
  }
  __syncthreads();
  float2 sv = ss[o];
  float acc = 0.f;
  #pragma unroll 4
  for (int i = 0; i < 16; ++i){
    int c = wid*16 + i;
    float2 x = buf[lane*65 + c];
    x = fft64_lane(x, W, lane);
    acc += fmaxf(fmaf(x.x*(1.f/4096.f), sv.x, sv.y), 0.f);
  }
  s4[wid*64 + rl] = acc;
  __syncthreads();
  if (tid < 64)
    out[(size_t)blockIdx.x*64 + tid] = (s4[tid] + s4[64+tid] + s4[128+tid] + s4[192+tid]) * (1.f/64.f);
}

extern "C" void kernel_launch(void* const* d_in, const int* in_sizes, int n_in,
                              void* d_out, int out_size, void* d_ws, size_t ws_size,
                              hipStream_t stream){
  const float* x   = (const float*)d_in[0];
  const float* ks2 = (const float*)d_in[1];
  const float* bs2 = (const float*)d_in[2];
  const float* k1  = (const float*)d_in[3];
  const float* b1c = (const float*)d_in[4];
  const float* k2  = (const float*)d_in[5];
  const float* b2c = (const float*)d_in[6];
  const float* k3  = (const float*)d_in[7];
  const float* b3c = (const float*)d_in[8];
  const float* g1 = (const float*)d_in[9],  *bb1 = (const float*)d_in[10];
  const float* g2 = (const float*)d_in[11], *bb2 = (const float*)d_in[12];
  const float* g3 = (const float*)d_in[13], *bb3 = (const float*)d_in[14];
  const float* g4 = (const float*)d_in[15], *bb4 = (const float*)d_in[16];
  float* out = (float*)d_out;

  char* w = (char*)d_ws;
  size_t off = 0;
  auto take = [&](size_t bytes)->char*{
    char* p = w + off;
    off += (bytes + 255) & ~(size_t)255;
    return p;
  };
  float*  Dz   = (float*) take(64ull*32*32*63*4);
  float*  Deq  = (float*) take(32ull*63*63*4);
  double* lf   = (double*)take(65*8);
  double* qw   = (double*)take(64*8);
  double* part = (double*)take(75ull*64*2*8);
  float2* ss   = (float2*)take(75*8);
  float2* KhS2 = (float2*)take(63ull*25*3*8);
  float2* Kh1  = (float2*)take(63ull*25*25*8);
  float2* Kh2  = (float2*)take(63ull*25*50*8);
  float2* Kh3  = (float2*)take(63ull*36*75*8);
  float2* XH2  = (float2*)take(2ull*3*64*63*8);
  float2* F2   = (float2*)take(2ull*3*32*63*8);
  ushortT* X1  = (ushortT*)take(2ull*25*262144*2);
  ushortT* X2  = (ushortT*)take(2ull*25*262144*2);
  ushortT* X3  = (ushortT*)take(2ull*25*262144*2);
  float2* A    = (float2*)take(150ull*32*2016*8);
  float2* B    = (float2*)take(150ull*32*2016*8);
  if (off > ws_size) return;

  dim3 tpb(TPB);
  auto cdiv = [](long long a, long long b){ return (int)((a + b - 1) / b); };

  k_tables<<<1, 64, 0, stream>>>(lf, qw);
  k_wigner<<<dim3(65,32), tpb, 0, stream>>>(lf, Dz, Deq);
  k_kh<<<cdiv(3ll*25*63,TPB),  tpb, 0, stream>>>(ks2, KhS2, 3, 25,  (float)(1.0/sqrt(196608.0)));
  k_kh<<<cdiv(25ll*25*63,TPB), tpb, 0, stream>>>(k1,  Kh1, 25, 25, (float)(1.0/sqrt(1600.0)));
  k_kh<<<cdiv(50ll*25*63,TPB), tpb, 0, stream>>>(k2,  Kh2, 50, 25, (float)(1.0/sqrt(3200.0)));
  k_kh<<<cdiv(75ll*36*63,TPB), tpb, 0, stream>>>(k3,  Kh3, 75, 36, (float)(1.0/sqrt(4800.0)));

  // ---- S2 conv ----
  k_s2_fft<<<cdiv(2ll*3*64*63,TPB), tpb, 0, stream>>>(x, XH2);
  k_s2_F<<<cdiv(2ll*3*32*63,TPB), tpb, 0, stream>>>(Dz, qw, XH2, F2);
  k_s2_zhat<<<cdiv(2ll*25*32*2016,TPB), tpb, 0, stream>>>(Deq, F2, KhS2, B);
  k_wig_synth<<<dim3(32,8,2*cdiv(50,16)), tpb, 0, stream>>>(Dz, B, A, 50);
  k_ifft2_sym<<<50*64, tpb, 0, stream>>>(A, X1, bs2, 25);
  k_bnstats<<<dim3(25,64), tpb, 0, stream>>>(X1, 0, part);

  // ---- generic SO3 conv (stats slots already filled) ----
  auto so3 = [&](const ushortT* Xa, const ushortT* Xb, const ushortT* Xc, int Cin,
                 const float* g, const float* bb, const float2* Kh, int O,
                 const float* bias, ushortT* Xout, int isFinal){
    int BC = 2*Cin, BO = 2*O;
    k_bnfinal<<<1, 128, 0, stream>>>(part, g, bb, ss, Cin);
    for (int z0 = 0; z0 < 64; z0 += 32){
      k_fft2_fwd<<<dim3(BC,32), tpb, 0, stream>>>(Xa, Xb, Xc, ss, A, Cin, z0);
      k_wig_F<<<dim3(32,8,cdiv(BC,16)), tpb, 0, stream>>>(Dz, qw, A, B, BC, z0, z0 > 0 ? 1 : 0);
    }
    k_deq_C<<<dim3(32,32,cdiv(BC,64)), tpb, 0, stream>>>(Deq, B, A, BC);
    k_kh_z<<<dim3(32,8,3), tpb, 0, stream>>>(A, Kh, B, Cin, O, (O + 2)/3);
    k_wig_synth<<<dim3(32,8,2*cdiv(BO,16)), tpb, 0, stream>>>(Dz, B, A, BO);
    if (!isFinal){
      k_ifft2_sym<<<BO*64, tpb, 0, stream>>>(A, Xout, bias, O);
    } else {
      k_stats3<<<dim3(BO,16), tpb, 0, stream>>>(A, part);
      k_fstat<<<1, 64, 0, stream>>>(part, bias, g4, bb4, ss, O);
      k_final<<<BO*64, tpb, 0, stream>>>(A, ss, out, O);
    }
  };

  so3(X1, X1, X1, 25, g1, bb1, Kh1, 25, b1c, X2, 0);
  k_bnstats<<<dim3(25,64), tpb, 0, stream>>>(X2, 25, part);
  so3(X1, X2, X2, 50, g2, bb2, Kh2, 25, b2c, X3, 0);
  k_bnstats<<<dim3(25,64), tpb, 0, stream>>>(X3, 50, part);
  so3(X1, X2, X3, 75, g3, bb3, Kh3, 36, b3c, nullptr, 1);
}

// Round 7
// 2295.148 us; speedup vs baseline: 1.0498x; 1.0498x over previous
//
#include <hip/hip_runtime.h>
#include <math.h>

#define PI_D 3.14159265358979323846
#define TPB 256
typedef unsigned short ushortT;
typedef unsigned int uintT;

__device__ __forceinline__ float2 cxmul(float2 a, float2 b){
  return make_float2(a.x*b.x - a.y*b.y, a.x*b.y + a.y*b.x);
}
__device__ __forceinline__ float bf2f(ushortT u){
  uintT x = ((uintT)u) << 16;
  return __uint_as_float(x);
}
__device__ __forceinline__ ushortT f2bf(float f){
  uintT x = __float_as_uint(f);
  x = x + 0x7FFFu + ((x >> 16) & 1u);
  return (ushortT)(x >> 16);
}

// ---------------- tables ----------------
__global__ void k_tables(double* lf, double* qw){
  if (threadIdx.x == 0){
    lf[0] = 0.0;
    for (int i = 1; i <= 64; ++i) lf[i] = lf[i-1] + log((double)i);
  }
  int j = threadIdx.x;
  if (j < 64){
    double s1 = sin(PI_D*(2*j+1)/128.0);
    double inner = 0.0;
    for (int k = 0; k < 32; ++k)
      inner += (1.0/(double)(2*k+1)) * sin((double)(2*j+1)*(double)(2*k+1)*PI_D/128.0);
    qw[j] = (2.0/32.0) * s1 * inner;
  }
}

__device__ double wigd(const double* lfs, int l, int mp, int m, double lc, double ls){
  if (mp < -l || mp > l || m < -l || m > l) return 0.0;
  int k0 = (m - mp > 0) ? (m - mp) : 0;
  int k1 = (l + m < l - mp) ? (l + m) : (l - mp);
  double base = 0.5*(lfs[l+mp] + lfs[l-mp] + lfs[l+m] + lfs[l-m]);
  double val = 0.0;
  for (int k = k0; k <= k1; ++k){
    double t = base - lfs[l+m-k] - lfs[k] - lfs[mp-m+k] - lfs[l-mp-k]
             + (double)(2*l + m - mp - 2*k)*lc + (double)(mp - m + 2*k)*ls;
    double e = exp(t);
    val += ((mp - m + k) & 1) ? -e : e;
  }
  return val;
}

// Dz[z][l][mi'][n], Deq[l][r][c]
__global__ __launch_bounds__(TPB) void k_wigner(const double* __restrict__ lf,
                                                float* __restrict__ Dz, float* __restrict__ Deq){
  __shared__ double lfs[65];
  if (threadIdx.x < 65) lfs[threadIdx.x] = lf[threadIdx.x];
  __syncthreads();
  int zs = blockIdx.x, l = blockIdx.y;
  double beta = (zs < 64) ? ((double)zs + 0.5)*PI_D/64.0 : PI_D*0.5;
  double ch = cos(beta*0.5), sh = sin(beta*0.5);
  double lc = log(ch), ls = log(sh);
  if (zs < 64){
    for (int idx = threadIdx.x; idx < 2016; idx += TPB){
      int mi = idx/63, c = idx%63;
      Dz[((size_t)(zs*32 + l)*32 + mi)*63 + c] = (float)wigd(lfs, l, mi, c-31, lc, ls);
    }
  } else {
    for (int idx = threadIdx.x; idx < 3969; idx += TPB){
      int r = idx/63, c = idx%63;
      Deq[((size_t)l*63 + r)*63 + c] = (float)wigd(lfs, l, r-31, c-31, lc, ls);
    }
  }
}

// Kh[o][i][n] = scale * sum_p K[i,o,p] * exp(-i*2pi*p*(n-31)/64)
__global__ void k_kh(const float* __restrict__ K, float2* __restrict__ Kh, int I, int O, float scale){
  int idx = blockIdx.x*blockDim.x + threadIdx.x;
  if (idx >= I*O*63) return;
  int n = idx % 63, i = (idx/63) % I, o = idx/(63*I);
  float sr = 0.f, si = 0.f;
  for (int p = 0; p < 64; ++p){
    int t = (p * (n - 31)) & 63;
    float s, c;
    sincosf(-(float)PI_D/32.f * (float)t, &s, &c);
    float kv = K[(i*O + o)*64 + p];
    sr += kv * c; si += kv * s;
  }
  Kh[((size_t)o*I + i)*63 + n] = make_float2(sr*scale, si*scale);
}

// ---------------- S2 front ----------------
__global__ void k_s2_fft(const float* __restrict__ x, float2* __restrict__ XH2){
  int idx = blockIdx.x*blockDim.x + threadIdx.x;
  if (idx >= 2*3*64*63) return;
  int mi = idx % 63; int z = (idx/63) & 63; int bc = idx / (63*64);
  int f = (mi + 33) & 63;
  const float* row = x + ((size_t)bc*64 + z)*64;
  float sr = 0.f, si = 0.f;
  for (int a = 0; a < 64; ++a){
    int t = (f*a) & 63;
    float s, c;
    sincosf(-(float)PI_D/32.f * (float)t, &s, &c);
    sr += row[a]*c; si += row[a]*s;
  }
  XH2[idx] = make_float2(sr, si);
}

__global__ void k_s2_F(const float* __restrict__ Dz, const double* __restrict__ qw,
                       const float2* __restrict__ XH2, float2* __restrict__ F2){
  int idx = blockIdx.x*blockDim.x + threadIdx.x;
  if (idx >= 2*3*32*63) return;
  int r = idx % 63; int l = (idx/63) & 31; int bc = idx / (63*32);
  float2 acc = make_float2(0,0);
  for (int z = 0; z < 64; ++z){
    float d;
    if (r >= 31) d = Dz[((size_t)(z*32 + l)*32 + (r-31))*63 + 31];
    else {
      d = Dz[((size_t)(z*32 + l)*32 + (31-r))*63 + 31];
      if ((31-r) & 1) d = -d;
    }
    float wv = (float)qw[z] * d;
    float2 v = XH2[((size_t)bc*64 + z)*63 + r];
    acc.x += wv*v.x; acc.y += wv*v.y;
  }
  F2[idx] = acc;
}

__global__ void k_s2_zhat(const float* __restrict__ Deq, const float2* __restrict__ F2,
                          const float2* __restrict__ Kh, float2* __restrict__ Z){
  int idx = blockIdx.x*blockDim.x + threadIdx.x;
  if (idx >= 2*25*32*2016) return;
  int n = idx % 63; int mi = (idx/63) & 31; int l = (idx/2016) & 31;
  int o = (idx/(2016*32)) % 25; int b = idx/(2016*32*25);
  float deq0 = Deq[((size_t)l*63 + n)*63 + 31];
  float2 acc = make_float2(0,0);
  for (int i = 0; i < 3; ++i){
    float2 f = F2[((size_t)(b*3 + i)*32 + l)*63 + (mi+31)];
    float2 kh = Kh[((size_t)(o*3 + i))*63 + n];
    float2 p = cxmul(f, kh);
    acc.x += p.x; acc.y += p.y;
  }
  Z[((size_t)((b*25+o)*32) + l)*2016 + mi*63 + n] = make_float2(acc.x*deq0, acc.y*deq0);
}

// ---------------- BN stats over bf16 X buffers ----------------
__global__ __launch_bounds__(TPB) void k_bnstats(const ushortT* __restrict__ src, int slotBase,
                                                 double* __restrict__ part){
  int c = blockIdx.x, blk = blockIdx.y;
  const uint2* s4 = (const uint2*)src;
  double s = 0.0, q = 0.0;
  for (int k = 0; k < 8; ++k){
    int g4 = blk*2048 + k*256 + threadIdx.x;
    int b = g4 >> 16, pos4 = g4 & 65535;
    uint2 u = s4[((size_t)(b*25 + c))*65536 + pos4];
    float v0 = bf2f((ushortT)(u.x & 0xffff)), v1 = bf2f((ushortT)(u.x >> 16));
    float v2 = bf2f((ushortT)(u.y & 0xffff)), v3 = bf2f((ushortT)(u.y >> 16));
    s += (double)v0 + v1 + v2 + v3;
    q += (double)v0*v0 + (double)v1*v1 + (double)v2*v2 + (double)v3*v3;
  }
  __shared__ double sh[TPB], sh2[TPB];
  sh[threadIdx.x] = s; sh2[threadIdx.x] = q;
  __syncthreads();
  for (int o = 128; o > 0; o >>= 1){
    if (threadIdx.x < o){ sh[threadIdx.x] += sh[threadIdx.x+o]; sh2[threadIdx.x] += sh2[threadIdx.x+o]; }
    __syncthreads();
  }
  if (threadIdx.x == 0){
    part[((size_t)(slotBase + c)*64 + blk)*2 + 0] = sh[0];
    part[((size_t)(slotBase + c)*64 + blk)*2 + 1] = sh2[0];
  }
}

__global__ void k_bnfinal(const double* __restrict__ part, const float* __restrict__ g,
                          const float* __restrict__ b, float2* __restrict__ ss, int C){
  int c = blockIdx.x*blockDim.x + threadIdx.x;
  if (c >= C) return;
  double s = 0.0, q = 0.0;
  for (int k = 0; k < 64; ++k){
    s += part[((size_t)c*64 + k)*2 + 0];
    q += part[((size_t)c*64 + k)*2 + 1];
  }
  double N = 524288.0;
  double mu = s / N;
  double var = q / N - mu*mu;
  double sc = (double)g[c] / sqrt(var + 1e-5);
  ss[c] = make_float2((float)sc, (float)((double)b[c] - mu*sc));
}

// ---------------- 64-pt FFT across lanes (radix-2 DIF, shfl) ----------------
__device__ __forceinline__ float2 fft64_lane(float2 x, const float2* __restrict__ Wt, int lane){
  #pragma unroll
  for (int st = 0; st < 6; ++st){
    int h = 32 >> st;
    float2 p;
    p.x = __shfl_xor(x.x, h, 64);
    p.y = __shfl_xor(x.y, h, 64);
    if (lane & h){
      float2 s = make_float2(p.x - x.x, p.y - x.y);
      x = cxmul(s, Wt[(lane & (h-1)) << st]);
    } else {
      x = make_float2(x.x + p.x, x.y + p.y);
    }
  }
  return x;
}
__device__ __forceinline__ void init_W(float2* W, float sign){
  if (threadIdx.x < 64){
    float s, c;
    sincosf(sign*(float)(2.0*PI_D/64.0)*(float)threadIdx.x, &s, &c);
    W[threadIdx.x] = make_float2(c, s);
  }
}

// ---------------- fused BN+ReLU + fft2 + reduced centered extraction ----------------
__global__ __launch_bounds__(TPB) void k_fft2_fwd(const ushortT* __restrict__ X1, const ushortT* __restrict__ X2,
                                                  const ushortT* __restrict__ X3, const float2* __restrict__ ss,
                                                  float2* __restrict__ XH, int Cin, int z0){
  __shared__ float2 W[64];
  __shared__ __attribute__((aligned(16))) float2 buf[64*65];
  int bc = blockIdx.x, zz = blockIdx.y, z = z0 + zz;
  int b = bc / Cin, ci = bc % Cin;
  const ushortT* src; int cl;
  if (ci < 25){ src = X1; cl = ci; }
  else if (ci < 50){ src = X2; cl = ci - 25; }
  else { src = X3; cl = ci - 50; }
  src += ((size_t)(b*25 + cl)*64 + z)*4096;
  float2 sc = ss[ci];
  init_W(W, -1.f);
  int tid = threadIdx.x, lane = tid & 63, wid = tid >> 6;
  int rl = (int)(__brev((uintT)lane) >> 26);
  const uintT* s32 = (const uintT*)src;
  for (int i = tid; i < 2048; i += TPB){
    uintT u = s32[i];
    float v0 = fmaxf(bf2f((ushortT)(u & 0xffff))*sc.x + sc.y, 0.f);
    float v1 = fmaxf(bf2f((ushortT)(u >> 16))*sc.x + sc.y, 0.f);
    int row = i >> 5, col = (i << 1) & 63;
    buf[row*65 + col]     = make_float2(v0, 0.f);
    buf[row*65 + col + 1] = make_float2(v1, 0.f);
  }
  __syncthreads();
  #pragma unroll 4
  for (int i = 0; i < 16; ++i){
    int r = wid*16 + i;
    float2 x = buf[r*65 + lane];
    x = fft64_lane(x, W, lane);
    buf[r*65 + rl] = x;
  }
  __syncthreads();
  #pragma unroll 4
  for (int i = 0; i < 16; ++i){
    int c = wid*16 + i;
    float2 x = buf[lane*65 + c];
    x = fft64_lane(x, W, lane);
    buf[rl*65 + c] = x;
  }
  __syncthreads();
  float2* dst = XH + ((size_t)bc*32 + zz)*2016;
  for (int idx = tid; idx < 2016; idx += TPB){
    int mi = idx / 63, n = idx % 63;
    dst[idx] = buf[mi*65 + ((n+33)&63)];
  }
}

// ---------------- F[bc,l,mi,n] (+)= sum_z qw*Dz*XH — register-tiled ----------------
// grid (32 mi, 8 nt, ceil(BC/16)); block 256
__global__ __launch_bounds__(TPB) void k_wig_F(const float* __restrict__ Dz, const double* __restrict__ qw,
                                               const float2* __restrict__ XH, float2* __restrict__ F,
                                               int BC, int z0, int accum){
  __shared__ __attribute__((aligned(16))) float sm[9088];
  float* Dt = sm;                          // [z16][nn8][l 36pad]
  float2* Xt = (float2*)(sm + 4608);       // [bc16][130]
  int mi = blockIdx.x, nt = blockIdx.y, bcBase = blockIdx.z*16;
  int tid = threadIdx.x;
  int bg = tid & 3, lg = (tid>>2)&7, ng = tid>>5;
  float2 acc[4][4];
  #pragma unroll
  for (int a = 0; a < 4; ++a)
    #pragma unroll
    for (int j = 0; j < 4; ++j) acc[a][j] = make_float2(0,0);
  for (int zq = 0; zq < 32; zq += 16){
    __syncthreads();
    for (int idx = tid; idx < 4096; idx += TPB){
      int z = idx >> 8, l = (idx>>3)&31, nn = idx&7;
      int n = nt*8 + nn;
      float v = 0.f;
      if (n < 63) v = Dz[(((size_t)(z0+zq+z)*32 + l)*32 + mi)*63 + n] * (float)qw[z0+zq+z];
      Dt[(z*8+nn)*36 + l] = v;
    }
    for (int idx = tid; idx < 2048; idx += TPB){
      int bc = idx >> 7, z = (idx>>3)&15, nn = idx&7;
      int gbc = bcBase + bc, n = nt*8 + nn;
      float2 v = make_float2(0,0);
      if (gbc < BC && n < 63) v = XH[((size_t)gbc*32 + zq + z)*2016 + mi*63 + n];
      Xt[bc*130 + z*8 + nn] = v;
    }
    __syncthreads();
    #pragma unroll 4
    for (int z = 0; z < 16; ++z){
      const float4 d = *(const float4*)&Dt[(z*8+ng)*36 + lg*4];
      float dd[4] = {d.x, d.y, d.z, d.w};
      float2 xv[4];
      #pragma unroll
      for (int j = 0; j < 4; ++j) xv[j] = Xt[(bg + 4*j)*130 + z*8 + ng];
      #pragma unroll
      for (int j = 0; j < 4; ++j)
        #pragma unroll
        for (int dl = 0; dl < 4; ++dl){
          acc[j][dl].x += dd[dl]*xv[j].x;
          acc[j][dl].y += dd[dl]*xv[j].y;
        }
    }
  }
  __syncthreads();
  float2* St = (float2*)sm;                // [bc16][l32][nn8]
  #pragma unroll
  for (int j = 0; j < 4; ++j)
    #pragma unroll
    for (int dl = 0; dl < 4; ++dl)
      St[(((bg + 4*j)*32) + lg*4 + dl)*8 + ng] = acc[j][dl];
  __syncthreads();
  for (int idx = tid; idx < 4096; idx += TPB){
    int bc = idx >> 8, l = (idx>>3)&31, nn = idx&7;
    int gbc = bcBase + bc, n = nt*8 + nn;
    if (gbc < BC && n < 63){
      size_t a = ((size_t)(gbc*32 + l))*2016 + mi*63 + n;
      float2 v = St[idx];
      if (accum){ float2 o = F[a]; v.x += o.x; v.y += o.y; }
      F[a] = v;
    }
  }
}

// ---------------- C[bi,l,mi,n] = sum_k F[bi,l,mi,k]*Deq[l,n,k] — register-tiled ----------------
// grid (32 l, 32 mi, ceil(BC/64)); block 256
__global__ __launch_bounds__(TPB) void k_deq_C(const float* __restrict__ Deq, const float2* __restrict__ F,
                                               float2* __restrict__ C, int BC){
  __shared__ __attribute__((aligned(16))) float sm[12604];
  float2* Fb = (float2*)sm;                // [bi64][65pad]
  float* DeqT = sm + 8320;                 // [k63][68pad n]
  int l = blockIdx.x, mi = blockIdx.y, biBase = blockIdx.z*64;
  int tid = threadIdx.x;
  int ngr = tid & 15, big = tid >> 4;
  for (int idx = tid; idx < 3969; idx += TPB){
    int n = idx/63, k = idx - n*63;
    DeqT[k*68 + n] = Deq[((size_t)l*63 + n)*63 + k];
  }
  for (int idx = tid; idx < 4032; idx += TPB){
    int bi = idx/63, k = idx - bi*63;
    int gbi = biBase + bi;
    Fb[bi*65 + k] = (gbi < BC) ? F[((size_t)(gbi*32 + l))*2016 + mi*63 + k] : make_float2(0,0);
  }
  __syncthreads();
  float2 acc[4][4];
  #pragma unroll
  for (int a = 0; a < 4; ++a)
    #pragma unroll
    for (int j = 0; j < 4; ++j) acc[a][j] = make_float2(0,0);
  #pragma unroll 3
  for (int k = 0; k < 63; ++k){
    const float4 d = *(const float4*)&DeqT[k*68 + ngr*4];
    float dd[4] = {d.x, d.y, d.z, d.w};
    float2 fv[4];
    #pragma unroll
    for (int j = 0; j < 4; ++j) fv[j] = Fb[(big + 16*j)*65 + k];
    #pragma unroll
    for (int j = 0; j < 4; ++j)
      #pragma unroll
      for (int dn = 0; dn < 4; ++dn){
        acc[j][dn].x += dd[dn]*fv[j].x;
        acc[j][dn].y += dd[dn]*fv[j].y;
      }
  }
  __syncthreads();
  float2* St = (float2*)sm;                // [bi64][n63]
  #pragma unroll
  for (int j = 0; j < 4; ++j)
    #pragma unroll
    for (int dn = 0; dn < 4; ++dn){
      int n = ngr*4 + dn;
      if (n < 63) St[(big + 16*j)*63 + n] = acc[j][dn];
    }
  __syncthreads();
  for (int idx = tid; idx < 4032; idx += TPB){
    int bi = idx/63, n = idx - bi*63;
    int gbi = biBase + bi;
    if (gbi < BC) C[((size_t)(gbi*32 + l))*2016 + mi*63 + n] = St[idx];
  }
}

// ---------------- Z[b,o,l,mi,n] = sum_i Kh[o,i,n]*C[b,i,l,mi,n] — hybrid LDS-Kh ----------------
// grid (32 l, 8 mic, ceil(O/9)); block 256 = 4 waves (one mi each); lane = n
#define KOC 9
__global__ __launch_bounds__(TPB) void k_kh_z(const float2* __restrict__ C, const float2* __restrict__ Kh,
                                              float2* __restrict__ Z, int I, int O){
  __shared__ float2 Kt[KOC*5*64];          // [oo][ic5][n 64pad]
  int l = blockIdx.x, mic = blockIdx.y, oc = blockIdx.z;
  int lane = threadIdx.x & 63, wid = threadIdx.x >> 6;
  int mi = mic*4 + wid;
  int n = lane;
  int o0 = oc*KOC;
  float2 acc[2][KOC];
  #pragma unroll
  for (int b = 0; b < 2; ++b)
    #pragma unroll
    for (int oo = 0; oo < KOC; ++oo) acc[b][oo] = make_float2(0,0);
  size_t cBase = ((size_t)l)*2016 + mi*63 + n;
  for (int i0 = 0; i0 < I; i0 += 5){
    __syncthreads();
    for (int idx = threadIdx.x; idx < KOC*5*64; idx += TPB){
      int nn = idx & 63, rem = idx >> 6;
      int ic = rem % 5, oo = rem / 5;
      float2 v = make_float2(0,0);
      int o = o0 + oo;
      if (o < O && nn < 63) v = Kh[((size_t)o*I + (i0+ic))*63 + nn];
      Kt[(oo*5 + ic)*64 + nn] = v;
    }
    __syncthreads();
    if (n < 63){
      #pragma unroll
      for (int ic = 0; ic < 5; ++ic){
        int i = i0 + ic;
        float2 c0 = C[cBase + (size_t)i*64512];
        float2 c1 = C[cBase + (size_t)(I + i)*64512];
        #pragma unroll
        for (int oo = 0; oo < KOC; ++oo){
          float2 kh = Kt[(oo*5 + ic)*64 + n];
          acc[0][oo].x += kh.x*c0.x - kh.y*c0.y;
          acc[0][oo].y += kh.x*c0.y + kh.y*c0.x;
          acc[1][oo].x += kh.x*c1.x - kh.y*c1.y;
          acc[1][oo].y += kh.x*c1.y + kh.y*c1.x;
        }
      }
    }
  }
  if (n < 63){
    size_t zBase = ((size_t)l)*2016 + mi*63 + n;
    #pragma unroll
    for (int oo = 0; oo < KOC; ++oo){
      int o = o0 + oo;
      if (o < O){
        Z[zBase + (size_t)(0*O + o)*64512] = acc[0][oo];
        Z[zBase + (size_t)(1*O + o)*64512] = acc[1][oo];
      }
    }
  }
}

// ---------------- Xt[bo,z,mi,n] = sum_l wl*Dz*Z — register-tiled ----------------
// grid (32 mi, 8 nt, 2*ceil(BO/16)); block 256
__global__ __launch_bounds__(TPB) void k_wig_synth(const float* __restrict__ Dz, const float2* __restrict__ Z,
                                                   float2* __restrict__ Xt_g, int BO){
  __shared__ __attribute__((aligned(16))) float sm[9088];
  float* Dt = sm;                          // [l16][nn8][z 36pad]
  float2* Zt = (float2*)(sm + 4608);       // [bo16][130]
  int mi = blockIdx.x, nt = blockIdx.y;
  int z0 = (blockIdx.z & 1)*32;
  int boBase = (blockIdx.z >> 1)*16;
  int tid = threadIdx.x;
  int bg = tid & 3, zg = (tid>>2)&7, ng = tid>>5;
  float2 acc[4][4];
  #pragma unroll
  for (int a = 0; a < 4; ++a)
    #pragma unroll
    for (int j = 0; j < 4; ++j) acc[a][j] = make_float2(0,0);
  for (int lq = 0; lq < 32; lq += 16){
    __syncthreads();
    for (int idx = tid; idx < 4096; idx += TPB){
      int ll = idx >> 8, z = (idx>>3)&31, nn = idx&7;
      int n = nt*8 + nn, lG = lq + ll;
      float v = 0.f;
      if (n < 63) v = Dz[(((size_t)(z0+z)*32 + lG)*32 + mi)*63 + n] * (0.5f*(float)(2*lG+1));
      Dt[(ll*8+nn)*36 + z] = v;
    }
    for (int idx = tid; idx < 2048; idx += TPB){
      int bo = idx >> 7, ll = (idx>>3)&15, nn = idx&7;
      int gbo = boBase + bo, n = nt*8 + nn;
      float2 v = make_float2(0,0);
      if (gbo < BO && n < 63) v = Z[((size_t)(gbo*32 + lq + ll))*2016 + mi*63 + n];
      Zt[bo*130 + ll*8 + nn] = v;
    }
    __syncthreads();
    #pragma unroll 4
    for (int ll = 0; ll < 16; ++ll){
      const float4 d = *(const float4*)&Dt[(ll*8+ng)*36 + zg*4];
      float dd[4] = {d.x, d.y, d.z, d.w};
      float2 zv[4];
      #pragma unroll
      for (int j = 0; j < 4; ++j) zv[j] = Zt[(bg + 4*j)*130 + ll*8 + ng];
      #pragma unroll
      for (int j = 0; j < 4; ++j)
        #pragma unroll
        for (int dz = 0; dz < 4; ++dz){
          acc[j][dz].x += dd[dz]*zv[j].x;
          acc[j][dz].y += dd[dz]*zv[j].y;
        }
    }
  }
  __syncthreads();
  float2* St = (float2*)sm;                // [bo16][z32][nn8]
  #pragma unroll
  for (int j = 0; j < 4; ++j)
    #pragma unroll
    for (int dz = 0; dz < 4; ++dz)
      St[(((bg + 4*j)*32) + zg*4 + dz)*8 + ng] = acc[j][dz];
  __syncthreads();
  for (int idx = tid; idx < 4096; idx += TPB){
    int bo = idx >> 8, z = (idx>>3)&31, nn = idx&7;
    int gbo = boBase + bo, n = nt*8 + nn;
    if (gbo < BO && n < 63)
      Xt_g[((size_t)gbo*64 + z0 + z)*2016 + mi*63 + n] = St[idx];
  }
}

// ---------------- coalesced Hermitian build ----------------
__device__ __forceinline__ void build_plane_c(const float2* __restrict__ src, float2* buf){
  int tid = threadIdx.x;
  if (tid < 128){
    int k = tid & 63;
    if (tid < 64) buf[32*65 + k] = make_float2(0,0);
    else          buf[k*65 + 32] = make_float2(0,0);
  }
  for (int idx = tid; idx < 2016; idx += TPB){
    float2 v = src[idx];
    int mi = idx / 63, ni = idx - mi*63;
    buf[mi*65 + ((ni+33)&63)] = v;
    if (mi > 0) buf[(64-mi)*65 + ((31-ni)&63)] = make_float2(v.x, -v.y);
  }
}

// ---------------- ifft2 + real + bias -> bf16 X ----------------
__global__ __launch_bounds__(TPB) void k_ifft2_sym(const float2* __restrict__ Xt, ushortT* __restrict__ Xo,
                                                   const float* __restrict__ bias, int O){
  __shared__ float2 W[64];
  __shared__ __attribute__((aligned(16))) float2 buf[64*65];
  int bo = blockIdx.x >> 6;
  int o = bo % O;
  init_W(W, 1.f);
  int tid = threadIdx.x, lane = tid & 63, wid = tid >> 6;
  int rl = (int)(__brev((uintT)lane) >> 26);
  const float2* src = Xt + (size_t)blockIdx.x*2016;
  build_plane_c(src, buf);
  __syncthreads();
  #pragma unroll 4
  for (int i = 0; i < 16; ++i){
    int r = wid*16 + i;
    float2 x = buf[r*65 + lane];
    x = fft64_lane(x, W, lane);
    buf[r*65 + rl] = x;
  }
  __syncthreads();
  #pragma unroll 4
  for (int i = 0; i < 16; ++i){
    int c = wid*16 + i;
    float2 x = buf[lane*65 + c];
    x = fft64_lane(x, W, lane);
    buf[rl*65 + c] = x;
  }
  __syncthreads();
  float bb = bias[o];
  ushortT* dst = Xo + (size_t)blockIdx.x*4096;
  for (int idx = tid; idx < 4096; idx += TPB){
    dst[idx] = f2bf(buf[(idx>>6)*65 + (idx&63)].x * (1.f/4096.f) + bb);
  }
}

// ---------------- conv3 final stats from spectrum (Parseval) ----------------
__global__ __launch_bounds__(TPB) void k_stats3(const float2* __restrict__ Xt, double* __restrict__ part){
  int bo = blockIdx.x, zb = blockIdx.y;
  double s = 0.0, p = 0.0;
  for (int zz = 0; zz < 4; ++zz){
    const float2* pl = Xt + ((size_t)bo*64 + zb*4 + zz)*2016;
    for (int idx = threadIdx.x; idx < 2016; idx += TPB){
      float2 v = pl[idx];
      double q = (double)v.x*v.x + (double)v.y*v.y;
      p += (idx < 63) ? q : 2.0*q;
      if (idx == 31) s += v.x;
    }
  }
  __shared__ double sh[TPB], sh2[TPB];
  sh[threadIdx.x] = s; sh2[threadIdx.x] = p;
  __syncthreads();
  for (int o = 128; o > 0; o >>= 1){
    if (threadIdx.x < o){ sh[threadIdx.x] += sh[threadIdx.x+o]; sh2[threadIdx.x] += sh2[threadIdx.x+o]; }
    __syncthreads();
  }
  if (threadIdx.x == 0){
    part[((size_t)bo*16 + zb)*2 + 0] = sh[0];
    part[((size_t)bo*16 + zb)*2 + 1] = sh2[0];
  }
}

__global__ void k_fstat(const double* __restrict__ part, const float* __restrict__ bias,
                        const float* __restrict__ g, const float* __restrict__ bsh,
                        float2* __restrict__ ss, int O){
  int o = threadIdx.x;
  if (o >= O) return;
  double S = 0.0, P = 0.0;
  for (int b = 0; b < 2; ++b)
    for (int zb = 0; zb < 16; ++zb){
      size_t base = ((size_t)(b*O + o)*16 + zb)*2;
      S += part[base]; P += part[base+1];
    }
  P *= (1.0/4096.0);
  double N = 524288.0;
  double bi = bias[o];
  double mean = S/N + bi;
  double var = P/N + 2.0*bi*S/N + bi*bi - mean*mean;
  double sc = (double)g[o] / sqrt(var + 1e-5);
  ss[o] = make_float2((float)sc, (float)((bi - mean)*sc + (double)bsh[o]));
}

// ---------------- fused ifft2 + BN + ReLU + mean over gamma ----------------
__global__ __launch_bounds__(TPB) void k_final(const float2* __restrict__ Xt, const float2* __restrict__ ss,
                                               float* __restrict__ out, int O){
  __shared__ float2 W[64];
  __shared__ __attribute__((aligned(16))) float2 buf[64*65];
  __shared__ float s4[4*64];
  int bo = blockIdx.x >> 6;
  int o = bo % O;
  init_W(W, 1.f);
  int tid = threadIdx.x, lane = tid & 63, wid = tid >> 6;
  int rl = (int)(__brev((uintT)lane) >> 26);
  const float2* src = Xt + (size_t)blockIdx.x*2016;
  build_plane_c(src, buf);
  __syncthreads();
  #pragma unroll 4
  for (int i = 0; i < 16; ++i){
    int r = wid*16 + i;
    float2 x = buf[r*65 + lane];
    x = fft64_lane(x, W, lane);
    buf[r*65 + rl] = x;
  }
  __syncthreads();
  float2 sv = ss[o];
  float acc = 0.f;
  #pragma unroll 4
  for (int i = 0; i < 16; ++i){
    int c = wid*16 + i;
    float2 x = buf[lane*65 + c];
    x = fft64_lane(x, W, lane);
    acc += fmaxf(fmaf(x.x*(1.f/4096.f), sv.x, sv.y), 0.f);
  }
  s4[wid*64 + rl] = acc;
  __syncthreads();
  if (tid < 64)
    out[(size_t)blockIdx.x*64 + tid] = (s4[tid] + s4[64+tid] + s4[128+tid] + s4[192+tid]) * (1.f/64.f);
}

extern "C" void kernel_launch(void* const* d_in, const int* in_sizes, int n_in,
                              void* d_out, int out_size, void* d_ws, size_t ws_size,
                              hipStream_t stream){
  const float* x   = (const float*)d_in[0];
  const float* ks2 = (const float*)d_in[1];
  const float* bs2 = (const float*)d_in[2];
  const float* k1  = (const float*)d_in[3];
  const float* b1c = (const float*)d_in[4];
  const float* k2  = (const float*)d_in[5];
  const float* b2c = (const float*)d_in[6];
  const float* k3  = (const float*)d_in[7];
  const float* b3c = (const float*)d_in[8];
  const float* g1 = (const float*)d_in[9],  *bb1 = (const float*)d_in[10];
  const float* g2 = (const float*)d_in[11], *bb2 = (const float*)d_in[12];
  const float* g3 = (const float*)d_in[13], *bb3 = (const float*)d_in[14];
  const float* g4 = (const float*)d_in[15], *bb4 = (const float*)d_in[16];
  float* out = (float*)d_out;

  char* w = (char*)d_ws;
  size_t off = 0;
  auto take = [&](size_t bytes)->char*{
    char* p = w + off;
    off += (bytes + 255) & ~(size_t)255;
    return p;
  };
  float*  Dz   = (float*) take(64ull*32*32*63*4);
  float*  Deq  = (float*) take(32ull*63*63*4);
  double* lf   = (double*)take(65*8);
  double* qw   = (double*)take(64*8);
  double* part = (double*)take(75ull*64*2*8);
  float2* ss   = (float2*)take(75*8);
  float2* KhS2 = (float2*)take(63ull*25*3*8);
  float2* Kh1  = (float2*)take(63ull*25*25*8);
  float2* Kh2  = (float2*)take(63ull*25*50*8);
  float2* Kh3  = (float2*)take(63ull*36*75*8);
  float2* XH2  = (float2*)take(2ull*3*64*63*8);
  float2* F2   = (float2*)take(2ull*3*32*63*8);
  ushortT* X1  = (ushortT*)take(2ull*25*262144*2);
  ushortT* X2  = (ushortT*)take(2ull*25*262144*2);
  ushortT* X3  = (ushortT*)take(2ull*25*262144*2);
  float2* A    = (float2*)take(150ull*32*2016*8);
  float2* B    = (float2*)take(150ull*32*2016*8);
  if (off > ws_size) return;

  dim3 tpb(TPB);
  auto cdiv = [](long long a, long long b){ return (int)((a + b - 1) / b); };

  k_tables<<<1, 64, 0, stream>>>(lf, qw);
  k_wigner<<<dim3(65,32), tpb, 0, stream>>>(lf, Dz, Deq);
  k_kh<<<cdiv(3ll*25*63,TPB),  tpb, 0, stream>>>(ks2, KhS2, 3, 25,  (float)(1.0/sqrt(196608.0)));
  k_kh<<<cdiv(25ll*25*63,TPB), tpb, 0, stream>>>(k1,  Kh1, 25, 25, (float)(1.0/sqrt(1600.0)));
  k_kh<<<cdiv(50ll*25*63,TPB), tpb, 0, stream>>>(k2,  Kh2, 50, 25, (float)(1.0/sqrt(3200.0)));
  k_kh<<<cdiv(75ll*36*63,TPB), tpb, 0, stream>>>(k3,  Kh3, 75, 36, (float)(1.0/sqrt(4800.0)));

  // ---- S2 conv ----
  k_s2_fft<<<cdiv(2ll*3*64*63,TPB), tpb, 0, stream>>>(x, XH2);
  k_s2_F<<<cdiv(2ll*3*32*63,TPB), tpb, 0, stream>>>(Dz, qw, XH2, F2);
  k_s2_zhat<<<cdiv(2ll*25*32*2016,TPB), tpb, 0, stream>>>(Deq, F2, KhS2, B);
  k_wig_synth<<<dim3(32,8,2*cdiv(50,16)), tpb, 0, stream>>>(Dz, B, A, 50);
  k_ifft2_sym<<<50*64, tpb, 0, stream>>>(A, X1, bs2, 25);
  k_bnstats<<<dim3(25,64), tpb, 0, stream>>>(X1, 0, part);

  // ---- generic SO3 conv (stats slots already filled) ----
  auto so3 = [&](const ushortT* Xa, const ushortT* Xb, const ushortT* Xc, int Cin,
                 const float* g, const float* bb, const float2* Kh, int O,
                 const float* bias, ushortT* Xout, int isFinal){
    int BC = 2*Cin, BO = 2*O;
    k_bnfinal<<<1, 128, 0, stream>>>(part, g, bb, ss, Cin);
    for (int z0 = 0; z0 < 64; z0 += 32){
      k_fft2_fwd<<<dim3(BC,32), tpb, 0, stream>>>(Xa, Xb, Xc, ss, A, Cin, z0);
      k_wig_F<<<dim3(32,8,cdiv(BC,16)), tpb, 0, stream>>>(Dz, qw, A, B, BC, z0, z0 > 0 ? 1 : 0);
    }
    k_deq_C<<<dim3(32,32,cdiv(BC,64)), tpb, 0, stream>>>(Deq, B, A, BC);
    k_kh_z<<<dim3(32,8,cdiv(O,KOC)), tpb, 0, stream>>>(A, Kh, B, Cin, O);
    k_wig_synth<<<dim3(32,8,2*cdiv(BO,16)), tpb, 0, stream>>>(Dz, B, A, BO);
    if (!isFinal){
      k_ifft2_sym<<<BO*64, tpb, 0, stream>>>(A, Xout, bias, O);
    } else {
      k_stats3<<<dim3(BO,16), tpb, 0, stream>>>(A, part);
      k_fstat<<<1, 64, 0, stream>>>(part, bias, g4, bb4, ss, O);
      k_final<<<BO*64, tpb, 0, stream>>>(A, ss, out, O);
    }
  };

  so3(X1, X1, X1, 25, g1, bb1, Kh1, 25, b1c, X2, 0);
  k_bnstats<<<dim3(25,64), tpb, 0, stream>>>(X2, 25, part);
  so3(X1, X2, X2, 50, g2, bb2, Kh2, 25, b2c, X3, 0);
  k_bnstats<<<dim3(25,64), tpb, 0, stream>>>(X3, 50, part);
  so3(X1, X2, X3, 75, g3, bb3, Kh3, 36, b3c, nullptr, 1);
}

// Round 8
// 2166.902 us; speedup vs baseline: 1.1120x; 1.0592x over previous
//
#include <hip/hip_runtime.h>
#include <math.h>

#define PI_D 3.14159265358979323846
#define TPB 256
typedef unsigned short ushortT;
typedef unsigned int uintT;

__device__ __forceinline__ float2 cxmul(float2 a, float2 b){
  return make_float2(a.x*b.x - a.y*b.y, a.x*b.y + a.y*b.x);
}
__device__ __forceinline__ float bf2f(ushortT u){
  uintT x = ((uintT)u) << 16;
  return __uint_as_float(x);
}
__device__ __forceinline__ ushortT f2bf(float f){
  uintT x = __float_as_uint(f);
  x = x + 0x7FFFu + ((x >> 16) & 1u);
  return (ushortT)(x >> 16);
}

// ---------------- tables ----------------
__global__ void k_tables(double* lf, double* qw){
  if (threadIdx.x == 0){
    lf[0] = 0.0;
    for (int i = 1; i <= 64; ++i) lf[i] = lf[i-1] + log((double)i);
  }
  int j = threadIdx.x;
  if (j < 64){
    double s1 = sin(PI_D*(2*j+1)/128.0);
    double inner = 0.0;
    for (int k = 0; k < 32; ++k)
      inner += (1.0/(double)(2*k+1)) * sin((double)(2*j+1)*(double)(2*k+1)*PI_D/128.0);
    qw[j] = (2.0/32.0) * s1 * inner;
  }
}

__device__ double wigd(const double* lfs, int l, int mp, int m, double lc, double ls){
  if (mp < -l || mp > l || m < -l || m > l) return 0.0;
  int k0 = (m - mp > 0) ? (m - mp) : 0;
  int k1 = (l + m < l - mp) ? (l + m) : (l - mp);
  double base = 0.5*(lfs[l+mp] + lfs[l-mp] + lfs[l+m] + lfs[l-m]);
  double val = 0.0;
  for (int k = k0; k <= k1; ++k){
    double t = base - lfs[l+m-k] - lfs[k] - lfs[mp-m+k] - lfs[l-mp-k]
             + (double)(2*l + m - mp - 2*k)*lc + (double)(mp - m + 2*k)*ls;
    double e = exp(t);
    val += ((mp - m + k) & 1) ? -e : e;
  }
  return val;
}

// Dz[z][l][mi'][n], Deq[l][r][c]
__global__ __launch_bounds__(TPB) void k_wigner(const double* __restrict__ lf,
                                                float* __restrict__ Dz, float* __restrict__ Deq){
  __shared__ double lfs[65];
  if (threadIdx.x < 65) lfs[threadIdx.x] = lf[threadIdx.x];
  __syncthreads();
  int zs = blockIdx.x, l = blockIdx.y;
  double beta = (zs < 64) ? ((double)zs + 0.5)*PI_D/64.0 : PI_D*0.5;
  double ch = cos(beta*0.5), sh = sin(beta*0.5);
  double lc = log(ch), ls = log(sh);
  if (zs < 64){
    for (int idx = threadIdx.x; idx < 2016; idx += TPB){
      int mi = idx/63, c = idx%63;
      Dz[((size_t)(zs*32 + l)*32 + mi)*63 + c] = (float)wigd(lfs, l, mi, c-31, lc, ls);
    }
  } else {
    for (int idx = threadIdx.x; idx < 3969; idx += TPB){
      int r = idx/63, c = idx%63;
      Deq[((size_t)l*63 + r)*63 + c] = (float)wigd(lfs, l, r-31, c-31, lc, ls);
    }
  }
}

// Kh[o][i][n] = scale * sum_p K[i,o,p] * exp(-i*2pi*p*(n-31)/64)
__global__ void k_kh(const float* __restrict__ K, float2* __restrict__ Kh, int I, int O, float scale){
  int idx = blockIdx.x*blockDim.x + threadIdx.x;
  if (idx >= I*O*63) return;
  int n = idx % 63, i = (idx/63) % I, o = idx/(63*I);
  float sr = 0.f, si = 0.f;
  for (int p = 0; p < 64; ++p){
    int t = (p * (n - 31)) & 63;
    float s, c;
    sincosf(-(float)PI_D/32.f * (float)t, &s, &c);
    float kv = K[(i*O + o)*64 + p];
    sr += kv * c; si += kv * s;
  }
  Kh[((size_t)o*I + i)*63 + n] = make_float2(sr*scale, si*scale);
}

// ---------------- S2 front ----------------
__global__ void k_s2_fft(const float* __restrict__ x, float2* __restrict__ XH2){
  int idx = blockIdx.x*blockDim.x + threadIdx.x;
  if (idx >= 2*3*64*63) return;
  int mi = idx % 63; int z = (idx/63) & 63; int bc = idx / (63*64);
  int f = (mi + 33) & 63;
  const float* row = x + ((size_t)bc*64 + z)*64;
  float sr = 0.f, si = 0.f;
  for (int a = 0; a < 64; ++a){
    int t = (f*a) & 63;
    float s, c;
    sincosf(-(float)PI_D/32.f * (float)t, &s, &c);
    sr += row[a]*c; si += row[a]*s;
  }
  XH2[idx] = make_float2(sr, si);
}

__global__ void k_s2_F(const float* __restrict__ Dz, const double* __restrict__ qw,
                       const float2* __restrict__ XH2, float2* __restrict__ F2){
  int idx = blockIdx.x*blockDim.x + threadIdx.x;
  if (idx >= 2*3*32*63) return;
  int r = idx % 63; int l = (idx/63) & 31; int bc = idx / (63*32);
  float2 acc = make_float2(0,0);
  for (int z = 0; z < 64; ++z){
    float d;
    if (r >= 31) d = Dz[((size_t)(z*32 + l)*32 + (r-31))*63 + 31];
    else {
      d = Dz[((size_t)(z*32 + l)*32 + (31-r))*63 + 31];
      if ((31-r) & 1) d = -d;
    }
    float wv = (float)qw[z] * d;
    float2 v = XH2[((size_t)bc*64 + z)*63 + r];
    acc.x += wv*v.x; acc.y += wv*v.y;
  }
  F2[idx] = acc;
}

__global__ void k_s2_zhat(const float* __restrict__ Deq, const float2* __restrict__ F2,
                          const float2* __restrict__ Kh, float2* __restrict__ Z){
  int idx = blockIdx.x*blockDim.x + threadIdx.x;
  if (idx >= 2*25*32*2016) return;
  int n = idx % 63; int mi = (idx/63) & 31; int l = (idx/2016) & 31;
  int o = (idx/(2016*32)) % 25; int b = idx/(2016*32*25);
  float deq0 = Deq[((size_t)l*63 + n)*63 + 31];
  float2 acc = make_float2(0,0);
  for (int i = 0; i < 3; ++i){
    float2 f = F2[((size_t)(b*3 + i)*32 + l)*63 + (mi+31)];
    float2 kh = Kh[((size_t)(o*3 + i))*63 + n];
    float2 p = cxmul(f, kh);
    acc.x += p.x; acc.y += p.y;
  }
  Z[((size_t)((b*25+o)*32) + l)*2016 + mi*63 + n] = make_float2(acc.x*deq0, acc.y*deq0);
}

// ---------------- BN stats over bf16 X buffers ----------------
__global__ __launch_bounds__(TPB) void k_bnstats(const ushortT* __restrict__ src, int slotBase,
                                                 double* __restrict__ part){
  int c = blockIdx.x, blk = blockIdx.y;
  const uint2* s4 = (const uint2*)src;
  double s = 0.0, q = 0.0;
  for (int k = 0; k < 8; ++k){
    int g4 = blk*2048 + k*256 + threadIdx.x;
    int b = g4 >> 16, pos4 = g4 & 65535;
    uint2 u = s4[((size_t)(b*25 + c))*65536 + pos4];
    float v0 = bf2f((ushortT)(u.x & 0xffff)), v1 = bf2f((ushortT)(u.x >> 16));
    float v2 = bf2f((ushortT)(u.y & 0xffff)), v3 = bf2f((ushortT)(u.y >> 16));
    s += (double)v0 + v1 + v2 + v3;
    q += (double)v0*v0 + (double)v1*v1 + (double)v2*v2 + (double)v3*v3;
  }
  __shared__ double sh[TPB], sh2[TPB];
  sh[threadIdx.x] = s; sh2[threadIdx.x] = q;
  __syncthreads();
  for (int o = 128; o > 0; o >>= 1){
    if (threadIdx.x < o){ sh[threadIdx.x] += sh[threadIdx.x+o]; sh2[threadIdx.x] += sh2[threadIdx.x+o]; }
    __syncthreads();
  }
  if (threadIdx.x == 0){
    part[((size_t)(slotBase + c)*64 + blk)*2 + 0] = sh[0];
    part[((size_t)(slotBase + c)*64 + blk)*2 + 1] = sh2[0];
  }
}

__global__ void k_bnfinal(const double* __restrict__ part, const float* __restrict__ g,
                          const float* __restrict__ b, float2* __restrict__ ss, int C){
  int c = blockIdx.x*blockDim.x + threadIdx.x;
  if (c >= C) return;
  double s = 0.0, q = 0.0;
  for (int k = 0; k < 64; ++k){
    s += part[((size_t)c*64 + k)*2 + 0];
    q += part[((size_t)c*64 + k)*2 + 1];
  }
  double N = 524288.0;
  double mu = s / N;
  double var = q / N - mu*mu;
  double sc = (double)g[c] / sqrt(var + 1e-5);
  ss[c] = make_float2((float)sc, (float)((double)b[c] - mu*sc));
}

// ---------------- 64-pt FFT across lanes (radix-2 DIF, shfl) ----------------
__device__ __forceinline__ float2 fft64_lane(float2 x, const float2* __restrict__ Wt, int lane){
  #pragma unroll
  for (int st = 0; st < 6; ++st){
    int h = 32 >> st;
    float2 p;
    p.x = __shfl_xor(x.x, h, 64);
    p.y = __shfl_xor(x.y, h, 64);
    if (lane & h){
      float2 s = make_float2(p.x - x.x, p.y - x.y);
      x = cxmul(s, Wt[(lane & (h-1)) << st]);
    } else {
      x = make_float2(x.x + p.x, x.y + p.y);
    }
  }
  return x;
}
__device__ __forceinline__ void init_W(float2* W, float sign){
  if (threadIdx.x < 64){
    float s, c;
    sincosf(sign*(float)(2.0*PI_D/64.0)*(float)threadIdx.x, &s, &c);
    W[threadIdx.x] = make_float2(c, s);
  }
}

// ---------------- fused BN+ReLU + fft2 + reduced centered extraction ----------------
__global__ __launch_bounds__(TPB) void k_fft2_fwd(const ushortT* __restrict__ X1, const ushortT* __restrict__ X2,
                                                  const ushortT* __restrict__ X3, const float2* __restrict__ ss,
                                                  float2* __restrict__ XH, int Cin, int z0){
  __shared__ float2 W[64];
  __shared__ __attribute__((aligned(16))) float2 buf[64*65];
  int bc = blockIdx.x, zz = blockIdx.y, z = z0 + zz;
  int b = bc / Cin, ci = bc % Cin;
  const ushortT* src; int cl;
  if (ci < 25){ src = X1; cl = ci; }
  else if (ci < 50){ src = X2; cl = ci - 25; }
  else { src = X3; cl = ci - 50; }
  src += ((size_t)(b*25 + cl)*64 + z)*4096;
  float2 sc = ss[ci];
  init_W(W, -1.f);
  int tid = threadIdx.x, lane = tid & 63, wid = tid >> 6;
  int rl = (int)(__brev((uintT)lane) >> 26);
  const uintT* s32 = (const uintT*)src;
  for (int i = tid; i < 2048; i += TPB){
    uintT u = s32[i];
    float v0 = fmaxf(bf2f((ushortT)(u & 0xffff))*sc.x + sc.y, 0.f);
    float v1 = fmaxf(bf2f((ushortT)(u >> 16))*sc.x + sc.y, 0.f);
    int row = i >> 5, col = (i << 1) & 63;
    buf[row*65 + col]     = make_float2(v0, 0.f);
    buf[row*65 + col + 1] = make_float2(v1, 0.f);
  }
  __syncthreads();
  #pragma unroll 4
  for (int i = 0; i < 16; ++i){
    int r = wid*16 + i;
    float2 x = buf[r*65 + lane];
    x = fft64_lane(x, W, lane);
    buf[r*65 + rl] = x;
  }
  __syncthreads();
  #pragma unroll 4
  for (int i = 0; i < 16; ++i){
    int c = wid*16 + i;
    float2 x = buf[lane*65 + c];
    x = fft64_lane(x, W, lane);
    buf[rl*65 + c] = x;
  }
  __syncthreads();
  float2* dst = XH + ((size_t)bc*32 + zz)*2016;
  for (int idx = tid; idx < 2016; idx += TPB){
    int mi = idx / 63, n = idx % 63;
    dst[idx] = buf[mi*65 + ((n+33)&63)];
  }
}

// ---------------- F[bc,l,mi,n] (+)= sum_z qw*Dz*XH — register-tiled ----------------
// grid (32 mi, 8 nt, ceil(BC/16)); block 256
__global__ __launch_bounds__(TPB) void k_wig_F(const float* __restrict__ Dz, const double* __restrict__ qw,
                                               const float2* __restrict__ XH, float2* __restrict__ F,
                                               int BC, int z0, int accum){
  __shared__ __attribute__((aligned(16))) float sm[9088];
  float* Dt = sm;                          // [z16][nn8][l 36pad]
  float2* Xt = (float2*)(sm + 4608);       // [bc16][130]
  int mi = blockIdx.x, nt = blockIdx.y, bcBase = blockIdx.z*16;
  int tid = threadIdx.x;
  int bg = tid & 3, lg = (tid>>2)&7, ng = tid>>5;
  float2 acc[4][4];
  #pragma unroll
  for (int a = 0; a < 4; ++a)
    #pragma unroll
    for (int j = 0; j < 4; ++j) acc[a][j] = make_float2(0,0);
  for (int zq = 0; zq < 32; zq += 16){
    __syncthreads();
    for (int idx = tid; idx < 4096; idx += TPB){
      int z = idx >> 8, l = (idx>>3)&31, nn = idx&7;
      int n = nt*8 + nn;
      float v = 0.f;
      if (n < 63) v = Dz[(((size_t)(z0+zq+z)*32 + l)*32 + mi)*63 + n] * (float)qw[z0+zq+z];
      Dt[(z*8+nn)*36 + l] = v;
    }
    for (int idx = tid; idx < 2048; idx += TPB){
      int bc = idx >> 7, z = (idx>>3)&15, nn = idx&7;
      int gbc = bcBase + bc, n = nt*8 + nn;
      float2 v = make_float2(0,0);
      if (gbc < BC && n < 63) v = XH[((size_t)gbc*32 + zq + z)*2016 + mi*63 + n];
      Xt[bc*130 + z*8 + nn] = v;
    }
    __syncthreads();
    #pragma unroll 4
    for (int z = 0; z < 16; ++z){
      const float4 d = *(const float4*)&Dt[(z*8+ng)*36 + lg*4];
      float dd[4] = {d.x, d.y, d.z, d.w};
      float2 xv[4];
      #pragma unroll
      for (int j = 0; j < 4; ++j) xv[j] = Xt[(bg + 4*j)*130 + z*8 + ng];
      #pragma unroll
      for (int j = 0; j < 4; ++j)
        #pragma unroll
        for (int dl = 0; dl < 4; ++dl){
          acc[j][dl].x += dd[dl]*xv[j].x;
          acc[j][dl].y += dd[dl]*xv[j].y;
        }
    }
  }
  __syncthreads();
  float2* St = (float2*)sm;                // [bc16][l32][nn8]
  #pragma unroll
  for (int j = 0; j < 4; ++j)
    #pragma unroll
    for (int dl = 0; dl < 4; ++dl)
      St[(((bg + 4*j)*32) + lg*4 + dl)*8 + ng] = acc[j][dl];
  __syncthreads();
  for (int idx = tid; idx < 4096; idx += TPB){
    int bc = idx >> 8, l = (idx>>3)&31, nn = idx&7;
    int gbc = bcBase + bc, n = nt*8 + nn;
    if (gbc < BC && n < 63){
      size_t a = ((size_t)(gbc*32 + l))*2016 + mi*63 + n;
      float2 v = St[idx];
      if (accum){ float2 o = F[a]; v.x += o.x; v.y += o.y; }
      F[a] = v;
    }
  }
}

// ---------------- C[bi,l,mi,n] = sum_k F[bi,l,mi,k]*Deq[l,n,k] — register-tiled ----------------
// grid (32 l, 32 mi, ceil(BC/64)); block 256
__global__ __launch_bounds__(TPB) void k_deq_C(const float* __restrict__ Deq, const float2* __restrict__ F,
                                               float2* __restrict__ C, int BC){
  __shared__ __attribute__((aligned(16))) float sm[12604];
  float2* Fb = (float2*)sm;                // [bi64][65pad]
  float* DeqT = sm + 8320;                 // [k63][68pad n]
  int l = blockIdx.x, mi = blockIdx.y, biBase = blockIdx.z*64;
  int tid = threadIdx.x;
  int ngr = tid & 15, big = tid >> 4;
  for (int idx = tid; idx < 3969; idx += TPB){
    int n = idx/63, k = idx - n*63;
    DeqT[k*68 + n] = Deq[((size_t)l*63 + n)*63 + k];
  }
  for (int idx = tid; idx < 4032; idx += TPB){
    int bi = idx/63, k = idx - bi*63;
    int gbi = biBase + bi;
    Fb[bi*65 + k] = (gbi < BC) ? F[((size_t)(gbi*32 + l))*2016 + mi*63 + k] : make_float2(0,0);
  }
  __syncthreads();
  float2 acc[4][4];
  #pragma unroll
  for (int a = 0; a < 4; ++a)
    #pragma unroll
    for (int j = 0; j < 4; ++j) acc[a][j] = make_float2(0,0);
  #pragma unroll 3
  for (int k = 0; k < 63; ++k){
    const float4 d = *(const float4*)&DeqT[k*68 + ngr*4];
    float dd[4] = {d.x, d.y, d.z, d.w};
    float2 fv[4];
    #pragma unroll
    for (int j = 0; j < 4; ++j) fv[j] = Fb[(big + 16*j)*65 + k];
    #pragma unroll
    for (int j = 0; j < 4; ++j)
      #pragma unroll
      for (int dn = 0; dn < 4; ++dn){
        acc[j][dn].x += dd[dn]*fv[j].x;
        acc[j][dn].y += dd[dn]*fv[j].y;
      }
  }
  __syncthreads();
  float2* St = (float2*)sm;                // [bi64][n63]
  #pragma unroll
  for (int j = 0; j < 4; ++j)
    #pragma unroll
    for (int dn = 0; dn < 4; ++dn){
      int n = ngr*4 + dn;
      if (n < 63) St[(big + 16*j)*63 + n] = acc[j][dn];
    }
  __syncthreads();
  for (int idx = tid; idx < 4032; idx += TPB){
    int bi = idx/63, n = idx - bi*63;
    int gbi = biBase + bi;
    if (gbi < BC) C[((size_t)(gbi*32 + l))*2016 + mi*63 + n] = St[idx];
  }
}

// ---------------- Z[b,o,l,mi,n] = sum_i Kh[o,i,n]*C[b,i,l,mi,n] — hybrid, 2 mi per wave ----------------
// grid (32 l, 4 mic, ceil(O/9)); block 256 = 4 waves (two mi each); lane = n
#define KOC 9
__global__ __launch_bounds__(TPB) void k_kh_z(const float2* __restrict__ C, const float2* __restrict__ Kh,
                                              float2* __restrict__ Z, int I, int O){
  __shared__ float2 Kt[KOC*5*64];          // [oo][ic5][n 64pad]
  int l = blockIdx.x, mic = blockIdx.y, oc = blockIdx.z;
  int lane = threadIdx.x & 63, wid = threadIdx.x >> 6;
  int mi0 = mic*8 + wid*2;
  int n = lane;
  int o0 = oc*KOC;
  float2 acc[2][2][KOC];                   // [mi_local][b][oo]
  #pragma unroll
  for (int ml = 0; ml < 2; ++ml)
    #pragma unroll
    for (int b = 0; b < 2; ++b)
      #pragma unroll
      for (int oo = 0; oo < KOC; ++oo) acc[ml][b][oo] = make_float2(0,0);
  size_t cBase0 = ((size_t)l)*2016 + mi0*63 + n;
  size_t cBase1 = cBase0 + 63;
  for (int i0 = 0; i0 < I; i0 += 5){
    __syncthreads();
    for (int idx = threadIdx.x; idx < KOC*5*64; idx += TPB){
      int nn = idx & 63, rem = idx >> 6;
      int ic = rem % 5, oo = rem / 5;
      float2 v = make_float2(0,0);
      int o = o0 + oo;
      if (o < O && nn < 63) v = Kh[((size_t)o*I + (i0+ic))*63 + nn];
      Kt[(oo*5 + ic)*64 + nn] = v;
    }
    __syncthreads();
    if (n < 63){
      #pragma unroll
      for (int ic = 0; ic < 5; ++ic){
        int i = i0 + ic;
        float2 c00 = C[cBase0 + (size_t)i*64512];
        float2 c01 = C[cBase0 + (size_t)(I + i)*64512];
        float2 c10 = C[cBase1 + (size_t)i*64512];
        float2 c11 = C[cBase1 + (size_t)(I + i)*64512];
        #pragma unroll
        for (int oo = 0; oo < KOC; ++oo){
          float2 kh = Kt[(oo*5 + ic)*64 + n];
          acc[0][0][oo].x += kh.x*c00.x - kh.y*c00.y;
          acc[0][0][oo].y += kh.x*c00.y + kh.y*c00.x;
          acc[0][1][oo].x += kh.x*c01.x - kh.y*c01.y;
          acc[0][1][oo].y += kh.x*c01.y + kh.y*c01.x;
          acc[1][0][oo].x += kh.x*c10.x - kh.y*c10.y;
          acc[1][0][oo].y += kh.x*c10.y + kh.y*c10.x;
          acc[1][1][oo].x += kh.x*c11.x - kh.y*c11.y;
          acc[1][1][oo].y += kh.x*c11.y + kh.y*c11.x;
        }
      }
    }
  }
  if (n < 63){
    #pragma unroll
    for (int ml = 0; ml < 2; ++ml){
      size_t zBase = ((size_t)l)*2016 + (mi0 + ml)*63 + n;
      #pragma unroll
      for (int oo = 0; oo < KOC; ++oo){
        int o = o0 + oo;
        if (o < O){
          Z[zBase + (size_t)(0*O + o)*64512] = acc[ml][0][oo];
          Z[zBase + (size_t)(1*O + o)*64512] = acc[ml][1][oo];
        }
      }
    }
  }
}

// ---------------- Xt[bo,z,mi,n] = sum_l wl*Dz*Z — register-tiled ----------------
// grid (32 mi, 8 nt, 2*ceil(BO/16)); block 256
__global__ __launch_bounds__(TPB) void k_wig_synth(const float* __restrict__ Dz, const float2* __restrict__ Z,
                                                   float2* __restrict__ Xt_g, int BO){
  __shared__ __attribute__((aligned(16))) float sm[9088];
  float* Dt = sm;                          // [l16][nn8][z 36pad]
  float2* Zt = (float2*)(sm + 4608);       // [bo16][130]
  int mi = blockIdx.x, nt = blockIdx.y;
  int z0 = (blockIdx.z & 1)*32;
  int boBase = (blockIdx.z >> 1)*16;
  int tid = threadIdx.x;
  int bg = tid & 3, zg = (tid>>2)&7, ng = tid>>5;
  float2 acc[4][4];
  #pragma unroll
  for (int a = 0; a < 4; ++a)
    #pragma unroll
    for (int j = 0; j < 4; ++j) acc[a][j] = make_float2(0,0);
  for (int lq = 0; lq < 32; lq += 16){
    __syncthreads();
    for (int idx = tid; idx < 4096; idx += TPB){
      int ll = idx >> 8, z = (idx>>3)&31, nn = idx&7;
      int n = nt*8 + nn, lG = lq + ll;
      float v = 0.f;
      if (n < 63) v = Dz[(((size_t)(z0+z)*32 + lG)*32 + mi)*63 + n] * (0.5f*(float)(2*lG+1));
      Dt[(ll*8+nn)*36 + z] = v;
    }
    for (int idx = tid; idx < 2048; idx += TPB){
      int bo = idx >> 7, ll = (idx>>3)&15, nn = idx&7;
      int gbo = boBase + bo, n = nt*8 + nn;
      float2 v = make_float2(0,0);
      if (gbo < BO && n < 63) v = Z[((size_t)(gbo*32 + lq + ll))*2016 + mi*63 + n];
      Zt[bo*130 + ll*8 + nn] = v;
    }
    __syncthreads();
    #pragma unroll 4
    for (int ll = 0; ll < 16; ++ll){
      const float4 d = *(const float4*)&Dt[(ll*8+ng)*36 + zg*4];
      float dd[4] = {d.x, d.y, d.z, d.w};
      float2 zv[4];
      #pragma unroll
      for (int j = 0; j < 4; ++j) zv[j] = Zt[(bg + 4*j)*130 + ll*8 + ng];
      #pragma unroll
      for (int j = 0; j < 4; ++j)
        #pragma unroll
        for (int dz = 0; dz < 4; ++dz){
          acc[j][dz].x += dd[dz]*zv[j].x;
          acc[j][dz].y += dd[dz]*zv[j].y;
        }
    }
  }
  __syncthreads();
  float2* St = (float2*)sm;                // [bo16][z32][nn8]
  #pragma unroll
  for (int j = 0; j < 4; ++j)
    #pragma unroll
    for (int dz = 0; dz < 4; ++dz)
      St[(((bg + 4*j)*32) + zg*4 + dz)*8 + ng] = acc[j][dz];
  __syncthreads();
  for (int idx = tid; idx < 4096; idx += TPB){
    int bo = idx >> 8, z = (idx>>3)&31, nn = idx&7;
    int gbo = boBase + bo, n = nt*8 + nn;
    if (gbo < BO && n < 63)
      Xt_g[((size_t)gbo*64 + z0 + z)*2016 + mi*63 + n] = St[idx];
  }
}

// ---------------- coalesced Hermitian build ----------------
__device__ __forceinline__ void build_plane_c(const float2* __restrict__ src, float2* buf){
  int tid = threadIdx.x;
  if (tid < 128){
    int k = tid & 63;
    if (tid < 64) buf[32*65 + k] = make_float2(0,0);
    else          buf[k*65 + 32] = make_float2(0,0);
  }
  for (int idx = tid; idx < 2016; idx += TPB){
    float2 v = src[idx];
    int mi = idx / 63, ni = idx - mi*63;
    buf[mi*65 + ((ni+33)&63)] = v;
    if (mi > 0) buf[(64-mi)*65 + ((31-ni)&63)] = make_float2(v.x, -v.y);
  }
}

// ---------------- ifft2 + real + bias -> bf16 X ----------------
__global__ __launch_bounds__(TPB) void k_ifft2_sym(const float2* __restrict__ Xt, ushortT* __restrict__ Xo,
                                                   const float* __restrict__ bias, int O){
  __shared__ float2 W[64];
  __shared__ __attribute__((aligned(16))) float2 buf[64*65];
  int bo = blockIdx.x >> 6;
  int o = bo % O;
  init_W(W, 1.f);
  int tid = threadIdx.x, lane = tid & 63, wid = tid >> 6;
  int rl = (int)(__brev((uintT)lane) >> 26);
  const float2* src = Xt + (size_t)blockIdx.x*2016;
  build_plane_c(src, buf);
  __syncthreads();
  #pragma unroll 4
  for (int i = 0; i < 16; ++i){
    int r = wid*16 + i;
    float2 x = buf[r*65 + lane];
    x = fft64_lane(x, W, lane);
    buf[r*65 + rl] = x;
  }
  __syncthreads();
  #pragma unroll 4
  for (int i = 0; i < 16; ++i){
    int c = wid*16 + i;
    float2 x = buf[lane*65 + c];
    x = fft64_lane(x, W, lane);
    buf[rl*65 + c] = x;
  }
  __syncthreads();
  float bb = bias[o];
  ushortT* dst = Xo + (size_t)blockIdx.x*4096;
  for (int idx = tid; idx < 4096; idx += TPB){
    dst[idx] = f2bf(buf[(idx>>6)*65 + (idx&63)].x * (1.f/4096.f) + bb);
  }
}

// ---------------- conv3 final stats from spectrum (Parseval) ----------------
__global__ __launch_bounds__(TPB) void k_stats3(const float2* __restrict__ Xt, double* __restrict__ part){
  int bo = blockIdx.x, zb = blockIdx.y;
  double s = 0.0, p = 0.0;
  for (int zz = 0; zz < 4; ++zz){
    const float2* pl = Xt + ((size_t)bo*64 + zb*4 + zz)*2016;
    for (int idx = threadIdx.x; idx < 2016; idx += TPB){
      float2 v = pl[idx];
      double q = (double)v.x*v.x + (double)v.y*v.y;
      p += (idx < 63) ? q : 2.0*q;
      if (idx == 31) s += v.x;
    }
  }
  __shared__ double sh[TPB], sh2[TPB];
  sh[threadIdx.x] = s; sh2[threadIdx.x] = p;
  __syncthreads();
  for (int o = 128; o > 0; o >>= 1){
    if (threadIdx.x < o){ sh[threadIdx.x] += sh[threadIdx.x+o]; sh2[threadIdx.x] += sh2[threadIdx.x+o]; }
    __syncthreads();
  }
  if (threadIdx.x == 0){
    part[((size_t)bo*16 + zb)*2 + 0] = sh[0];
    part[((size_t)bo*16 + zb)*2 + 1] = sh2[0];
  }
}

__global__ void k_fstat(const double* __restrict__ part, const float* __restrict__ bias,
                        const float* __restrict__ g, const float* __restrict__ bsh,
                        float2* __restrict__ ss, int O){
  int o = threadIdx.x;
  if (o >= O) return;
  double S = 0.0, P = 0.0;
  for (int b = 0; b < 2; ++b)
    for (int zb = 0; zb < 16; ++zb){
      size_t base = ((size_t)(b*O + o)*16 + zb)*2;
      S += part[base]; P += part[base+1];
    }
  P *= (1.0/4096.0);
  double N = 524288.0;
  double bi = bias[o];
  double mean = S/N + bi;
  double var = P/N + 2.0*bi*S/N + bi*bi - mean*mean;
  double sc = (double)g[o] / sqrt(var + 1e-5);
  ss[o] = make_float2((float)sc, (float)((bi - mean)*sc + (double)bsh[o]));
}

// ---------------- fused ifft2 + BN + ReLU + mean over gamma ----------------
__global__ __launch_bounds__(TPB) void k_final(const float2* __restrict__ Xt, const float2* __restrict__ ss,
                                               float* __restrict__ out, int O){
  __shared__ float2 W[64];
  __shared__ __attribute__((aligned(16))) float2 buf[64*65];
  __shared__ float s4[4*64];
  int bo = blockIdx.x >> 6;
  int o = bo % O;
  init_W(W, 1.f);
  int tid = threadIdx.x, lane = tid & 63, wid = tid >> 6;
  int rl = (int)(__brev((uintT)lane) >> 26);
  const float2* src = Xt + (size_t)blockIdx.x*2016;
  build_plane_c(src, buf);
  __syncthreads();
  #pragma unroll 4
  for (int i = 0; i < 16; ++i){
    int r = wid*16 + i;
    float2 x = buf[r*65 + lane];
    x = fft64_lane(x, W, lane);
    buf[r*65 + rl] = x;
  }
  __syncthreads();
  float2 sv = ss[o];
  float acc = 0.f;
  #pragma unroll 4
  for (int i = 0; i < 16; ++i){
    int c = wid*16 + i;
    float2 x = buf[lane*65 + c];
    x = fft64_lane(x, W, lane);
    acc += fmaxf(fmaf(x.x*(1.f/4096.f), sv.x, sv.y), 0.f);
  }
  s4[wid*64 + rl] = acc;
  __syncthreads();
  if (tid < 64)
    out[(size_t)blockIdx.x*64 + tid] = (s4[tid] + s4[64+tid] + s4[128+tid] + s4[192+tid]) * (1.f/64.f);
}

extern "C" void kernel_launch(void* const* d_in, const int* in_sizes, int n_in,
                              void* d_out, int out_size, void* d_ws, size_t ws_size,
                              hipStream_t stream){
  const float* x   = (const float*)d_in[0];
  const float* ks2 = (const float*)d_in[1];
  const float* bs2 = (const float*)d_in[2];
  const float* k1  = (const float*)d_in[3];
  const float* b1c = (const float*)d_in[4];
  const float* k2  = (const float*)d_in[5];
  const float* b2c = (const float*)d_in[6];
  const float* k3  = (const float*)d_in[7];
  const float* b3c = (const float*)d_in[8];
  const float* g1 = (const float*)d_in[9],  *bb1 = (const float*)d_in[10];
  const float* g2 = (const float*)d_in[11], *bb2 = (const float*)d_in[12];
  const float* g3 = (const float*)d_in[13], *bb3 = (const float*)d_in[14];
  const float* g4 = (const float*)d_in[15], *bb4 = (const float*)d_in[16];
  float* out = (float*)d_out;

  char* w = (char*)d_ws;
  size_t off = 0;
  auto take = [&](size_t bytes)->char*{
    char* p = w + off;
    off += (bytes + 255) & ~(size_t)255;
    return p;
  };
  float*  Dz   = (float*) take(64ull*32*32*63*4);
  float*  Deq  = (float*) take(32ull*63*63*4);
  double* lf   = (double*)take(65*8);
  double* qw   = (double*)take(64*8);
  double* part = (double*)take(75ull*64*2*8);
  float2* ss   = (float2*)take(75*8);
  float2* KhS2 = (float2*)take(63ull*25*3*8);
  float2* Kh1  = (float2*)take(63ull*25*25*8);
  float2* Kh2  = (float2*)take(63ull*25*50*8);
  float2* Kh3  = (float2*)take(63ull*36*75*8);
  float2* XH2  = (float2*)take(2ull*3*64*63*8);
  float2* F2   = (float2*)take(2ull*3*32*63*8);
  ushortT* X1  = (ushortT*)take(2ull*25*262144*2);
  ushortT* X2  = (ushortT*)take(2ull*25*262144*2);
  ushortT* X3  = (ushortT*)take(2ull*25*262144*2);
  float2* A    = (float2*)take(150ull*32*2016*8);
  float2* B    = (float2*)take(150ull*32*2016*8);
  if (off > ws_size) return;

  dim3 tpb(TPB);
  auto cdiv = [](long long a, long long b){ return (int)((a + b - 1) / b); };

  k_tables<<<1, 64, 0, stream>>>(lf, qw);
  k_wigner<<<dim3(65,32), tpb, 0, stream>>>(lf, Dz, Deq);
  k_kh<<<cdiv(3ll*25*63,TPB),  tpb, 0, stream>>>(ks2, KhS2, 3, 25,  (float)(1.0/sqrt(196608.0)));
  k_kh<<<cdiv(25ll*25*63,TPB), tpb, 0, stream>>>(k1,  Kh1, 25, 25, (float)(1.0/sqrt(1600.0)));
  k_kh<<<cdiv(50ll*25*63,TPB), tpb, 0, stream>>>(k2,  Kh2, 50, 25, (float)(1.0/sqrt(3200.0)));
  k_kh<<<cdiv(75ll*36*63,TPB), tpb, 0, stream>>>(k3,  Kh3, 75, 36, (float)(1.0/sqrt(4800.0)));

  // ---- S2 conv ----
  k_s2_fft<<<cdiv(2ll*3*64*63,TPB), tpb, 0, stream>>>(x, XH2);
  k_s2_F<<<cdiv(2ll*3*32*63,TPB), tpb, 0, stream>>>(Dz, qw, XH2, F2);
  k_s2_zhat<<<cdiv(2ll*25*32*2016,TPB), tpb, 0, stream>>>(Deq, F2, KhS2, B);
  k_wig_synth<<<dim3(32,8,2*cdiv(50,16)), tpb, 0, stream>>>(Dz, B, A, 50);
  k_ifft2_sym<<<50*64, tpb, 0, stream>>>(A, X1, bs2, 25);
  k_bnstats<<<dim3(25,64), tpb, 0, stream>>>(X1, 0, part);

  // ---- generic SO3 conv (stats slots already filled) ----
  auto so3 = [&](const ushortT* Xa, const ushortT* Xb, const ushortT* Xc, int Cin,
                 const float* g, const float* bb, const float2* Kh, int O,
                 const float* bias, ushortT* Xout, int isFinal){
    int BC = 2*Cin, BO = 2*O;
    k_bnfinal<<<1, 128, 0, stream>>>(part, g, bb, ss, Cin);
    for (int z0 = 0; z0 < 64; z0 += 32){
      k_fft2_fwd<<<dim3(BC,32), tpb, 0, stream>>>(Xa, Xb, Xc, ss, A, Cin, z0);
      k_wig_F<<<dim3(32,8,cdiv(BC,16)), tpb, 0, stream>>>(Dz, qw, A, B, BC, z0, z0 > 0 ? 1 : 0);
    }
    k_deq_C<<<dim3(32,32,cdiv(BC,64)), tpb, 0, stream>>>(Deq, B, A, BC);
    k_kh_z<<<dim3(32,4,cdiv(O,KOC)), tpb, 0, stream>>>(A, Kh, B, Cin, O);
    k_wig_synth<<<dim3(32,8,2*cdiv(BO,16)), tpb, 0, stream>>>(Dz, B, A, BO);
    if (!isFinal){
      k_ifft2_sym<<<BO*64, tpb, 0, stream>>>(A, Xout, bias, O);
    } else {
      k_stats3<<<dim3(BO,16), tpb, 0, stream>>>(A, part);
      k_fstat<<<1, 64, 0, stream>>>(part, bias, g4, bb4, ss, O);
      k_final<<<BO*64, tpb, 0, stream>>>(A, ss, out, O);
    }
  };

  so3(X1, X1, X1, 25, g1, bb1, Kh1, 25, b1c, X2, 0);
  k_bnstats<<<dim3(25,64), tpb, 0, stream>>>(X2, 25, part);
  so3(X1, X2, X2, 50, g2, bb2, Kh2, 25, b2c, X3, 0);
  k_bnstats<<<dim3(25,64), tpb, 0, stream>>>(X3, 50, part);
  so3(X1, X2, X3, 75, g3, bb3, Kh3, 36, b3c, nullptr, 1);
}

// Round 9
// 1787.622 us; speedup vs baseline: 1.3479x; 1.2122x over previous
//
#include <hip/hip_runtime.h>
#include <math.h>

#define PI_D 3.14159265358979323846
#define TPB 256
typedef unsigned short ushortT;
typedef unsigned int uintT;

__device__ __forceinline__ float2 cxmul(float2 a, float2 b){
  return make_float2(a.x*b.x - a.y*b.y, a.x*b.y + a.y*b.x);
}
__device__ __forceinline__ float bf2f(ushortT u){
  uintT x = ((uintT)u) << 16;
  return __uint_as_float(x);
}
__device__ __forceinline__ ushortT f2bf(float f){
  uintT x = __float_as_uint(f);
  x = x + 0x7FFFu + ((x >> 16) & 1u);
  return (ushortT)(x >> 16);
}

// ---------------- tables ----------------
__global__ void k_tables(double* lf, double* qw){
  if (threadIdx.x == 0){
    lf[0] = 0.0;
    for (int i = 1; i <= 64; ++i) lf[i] = lf[i-1] + log((double)i);
  }
  int j = threadIdx.x;
  if (j < 64){
    double s1 = sin(PI_D*(2*j+1)/128.0);
    double inner = 0.0;
    for (int k = 0; k < 32; ++k)
      inner += (1.0/(double)(2*k+1)) * sin((double)(2*j+1)*(double)(2*k+1)*PI_D/128.0);
    qw[j] = (2.0/32.0) * s1 * inner;
  }
}

__device__ double wigd(const double* lfs, int l, int mp, int m, double lc, double ls){
  if (mp < -l || mp > l || m < -l || m > l) return 0.0;
  int k0 = (m - mp > 0) ? (m - mp) : 0;
  int k1 = (l + m < l - mp) ? (l + m) : (l - mp);
  double base = 0.5*(lfs[l+mp] + lfs[l-mp] + lfs[l+m] + lfs[l-m]);
  double val = 0.0;
  for (int k = k0; k <= k1; ++k){
    double t = base - lfs[l+m-k] - lfs[k] - lfs[mp-m+k] - lfs[l-mp-k]
             + (double)(2*l + m - mp - 2*k)*lc + (double)(mp - m + 2*k)*ls;
    double e = exp(t);
    val += ((mp - m + k) & 1) ? -e : e;
  }
  return val;
}

// Dz[z][l][mi'][n], Deq[l][r][c]
__global__ __launch_bounds__(TPB) void k_wigner(const double* __restrict__ lf,
                                                float* __restrict__ Dz, float* __restrict__ Deq){
  __shared__ double lfs[65];
  if (threadIdx.x < 65) lfs[threadIdx.x] = lf[threadIdx.x];
  __syncthreads();
  int zs = blockIdx.x, l = blockIdx.y;
  double beta = (zs < 64) ? ((double)zs + 0.5)*PI_D/64.0 : PI_D*0.5;
  double ch = cos(beta*0.5), sh = sin(beta*0.5);
  double lc = log(ch), ls = log(sh);
  if (zs < 64){
    for (int idx = threadIdx.x; idx < 2016; idx += TPB){
      int mi = idx/63, c = idx%63;
      Dz[((size_t)(zs*32 + l)*32 + mi)*63 + c] = (float)wigd(lfs, l, mi, c-31, lc, ls);
    }
  } else {
    for (int idx = threadIdx.x; idx < 3969; idx += TPB){
      int r = idx/63, c = idx%63;
      Deq[((size_t)l*63 + r)*63 + c] = (float)wigd(lfs, l, r-31, c-31, lc, ls);
    }
  }
}

// Kh[o][i][n] = scale * sum_p K[i,o,p] * exp(-i*2pi*p*(n-31)/64)
__global__ void k_kh(const float* __restrict__ K, float2* __restrict__ Kh, int I, int O, float scale){
  int idx = blockIdx.x*blockDim.x + threadIdx.x;
  if (idx >= I*O*63) return;
  int n = idx % 63, i = (idx/63) % I, o = idx/(63*I);
  float sr = 0.f, si = 0.f;
  for (int p = 0; p < 64; ++p){
    int t = (p * (n - 31)) & 63;
    float s, c;
    sincosf(-(float)PI_D/32.f * (float)t, &s, &c);
    float kv = K[(i*O + o)*64 + p];
    sr += kv * c; si += kv * s;
  }
  Kh[((size_t)o*I + i)*63 + n] = make_float2(sr*scale, si*scale);
}

// ---------------- S2 front ----------------
__global__ void k_s2_fft(const float* __restrict__ x, float2* __restrict__ XH2){
  int idx = blockIdx.x*blockDim.x + threadIdx.x;
  if (idx >= 2*3*64*63) return;
  int mi = idx % 63; int z = (idx/63) & 63; int bc = idx / (63*64);
  int f = (mi + 33) & 63;
  const float* row = x + ((size_t)bc*64 + z)*64;
  float sr = 0.f, si = 0.f;
  for (int a = 0; a < 64; ++a){
    int t = (f*a) & 63;
    float s, c;
    sincosf(-(float)PI_D/32.f * (float)t, &s, &c);
    sr += row[a]*c; si += row[a]*s;
  }
  XH2[idx] = make_float2(sr, si);
}

__global__ void k_s2_F(const float* __restrict__ Dz, const double* __restrict__ qw,
                       const float2* __restrict__ XH2, float2* __restrict__ F2){
  int idx = blockIdx.x*blockDim.x + threadIdx.x;
  if (idx >= 2*3*32*63) return;
  int r = idx % 63; int l = (idx/63) & 31; int bc = idx / (63*32);
  float2 acc = make_float2(0,0);
  for (int z = 0; z < 64; ++z){
    float d;
    if (r >= 31) d = Dz[((size_t)(z*32 + l)*32 + (r-31))*63 + 31];
    else {
      d = Dz[((size_t)(z*32 + l)*32 + (31-r))*63 + 31];
      if ((31-r) & 1) d = -d;
    }
    float wv = (float)qw[z] * d;
    float2 v = XH2[((size_t)bc*64 + z)*63 + r];
    acc.x += wv*v.x; acc.y += wv*v.y;
  }
  F2[idx] = acc;
}

__global__ void k_s2_zhat(const float* __restrict__ Deq, const float2* __restrict__ F2,
                          const float2* __restrict__ Kh, float2* __restrict__ Z){
  int idx = blockIdx.x*blockDim.x + threadIdx.x;
  if (idx >= 2*25*32*2016) return;
  int n = idx % 63; int mi = (idx/63) & 31; int l = (idx/2016) & 31;
  int o = (idx/(2016*32)) % 25; int b = idx/(2016*32*25);
  float deq0 = Deq[((size_t)l*63 + n)*63 + 31];
  float2 acc = make_float2(0,0);
  for (int i = 0; i < 3; ++i){
    float2 f = F2[((size_t)(b*3 + i)*32 + l)*63 + (mi+31)];
    float2 kh = Kh[((size_t)(o*3 + i))*63 + n];
    float2 p = cxmul(f, kh);
    acc.x += p.x; acc.y += p.y;
  }
  Z[((size_t)((b*25+o)*32) + l)*2016 + mi*63 + n] = make_float2(acc.x*deq0, acc.y*deq0);
}

// ---------------- BN stats over bf16 X buffers ----------------
__global__ __launch_bounds__(TPB) void k_bnstats(const ushortT* __restrict__ src, int slotBase,
                                                 double* __restrict__ part){
  int c = blockIdx.x, blk = blockIdx.y;
  const uint2* s4 = (const uint2*)src;
  double s = 0.0, q = 0.0;
  for (int k = 0; k < 8; ++k){
    int g4 = blk*2048 + k*256 + threadIdx.x;
    int b = g4 >> 16, pos4 = g4 & 65535;
    uint2 u = s4[((size_t)(b*25 + c))*65536 + pos4];
    float v0 = bf2f((ushortT)(u.x & 0xffff)), v1 = bf2f((ushortT)(u.x >> 16));
    float v2 = bf2f((ushortT)(u.y & 0xffff)), v3 = bf2f((ushortT)(u.y >> 16));
    s += (double)v0 + v1 + v2 + v3;
    q += (double)v0*v0 + (double)v1*v1 + (double)v2*v2 + (double)v3*v3;
  }
  __shared__ double sh[TPB], sh2[TPB];
  sh[threadIdx.x] = s; sh2[threadIdx.x] = q;
  __syncthreads();
  for (int o = 128; o > 0; o >>= 1){
    if (threadIdx.x < o){ sh[threadIdx.x] += sh[threadIdx.x+o]; sh2[threadIdx.x] += sh2[threadIdx.x+o]; }
    __syncthreads();
  }
  if (threadIdx.x == 0){
    part[((size_t)(slotBase + c)*64 + blk)*2 + 0] = sh[0];
    part[((size_t)(slotBase + c)*64 + blk)*2 + 1] = sh2[0];
  }
}

__global__ void k_bnfinal(const double* __restrict__ part, const float* __restrict__ g,
                          const float* __restrict__ b, float2* __restrict__ ss, int C){
  int c = blockIdx.x*blockDim.x + threadIdx.x;
  if (c >= C) return;
  double s = 0.0, q = 0.0;
  for (int k = 0; k < 64; ++k){
    s += part[((size_t)c*64 + k)*2 + 0];
    q += part[((size_t)c*64 + k)*2 + 1];
  }
  double N = 524288.0;
  double mu = s / N;
  double var = q / N - mu*mu;
  double sc = (double)g[c] / sqrt(var + 1e-5);
  ss[c] = make_float2((float)sc, (float)((double)b[c] - mu*sc));
}

// ---------------- 64-pt FFT across lanes (radix-2 DIF, shfl) ----------------
__device__ __forceinline__ float2 fft64_lane(float2 x, const float2* __restrict__ Wt, int lane){
  #pragma unroll
  for (int st = 0; st < 6; ++st){
    int h = 32 >> st;
    float2 p;
    p.x = __shfl_xor(x.x, h, 64);
    p.y = __shfl_xor(x.y, h, 64);
    if (lane & h){
      float2 s = make_float2(p.x - x.x, p.y - x.y);
      x = cxmul(s, Wt[(lane & (h-1)) << st]);
    } else {
      x = make_float2(x.x + p.x, x.y + p.y);
    }
  }
  return x;
}
__device__ __forceinline__ void init_W(float2* W, float sign){
  if (threadIdx.x < 64){
    float s, c;
    sincosf(sign*(float)(2.0*PI_D/64.0)*(float)threadIdx.x, &s, &c);
    W[threadIdx.x] = make_float2(c, s);
  }
}

// ---------------- fused BN+ReLU + packed real fft2 + reduced extraction ----------------
// real input: pack col pairs -> 32 FFTs over a1, Hermitian unpack rows 0..31, 32 row FFTs
__global__ __launch_bounds__(TPB) void k_fft2_fwd(const ushortT* __restrict__ X1, const ushortT* __restrict__ X2,
                                                  const ushortT* __restrict__ X3, const float2* __restrict__ ss,
                                                  float2* __restrict__ XH, int Cin, int z0){
  __shared__ float2 W[64];
  __shared__ __attribute__((aligned(16))) float2 smem[4224];   // bufP[64*33] | bufW[64*33]
  float2* bufP = smem;          // packed input [a1][c33] ; reused as A rows [32][65]
  float2* bufW = smem + 2112;   // W[f1][c33]
  int bc = blockIdx.x, zz = blockIdx.y, z = z0 + zz;
  int b = bc / Cin, ci = bc % Cin;
  const ushortT* src; int cl;
  if (ci < 25){ src = X1; cl = ci; }
  else if (ci < 50){ src = X2; cl = ci - 25; }
  else { src = X3; cl = ci - 50; }
  src += ((size_t)(b*25 + cl)*64 + z)*4096;
  float2 sc = ss[ci];
  init_W(W, -1.f);
  int tid = threadIdx.x, lane = tid & 63, wid = tid >> 6;
  int rl = (int)(__brev((uintT)lane) >> 26);
  const uintT* s32 = (const uintT*)src;
  for (int i = tid; i < 2048; i += TPB){
    uintT u = s32[i];
    float v0 = fmaxf(bf2f((ushortT)(u & 0xffff))*sc.x + sc.y, 0.f);
    float v1 = fmaxf(bf2f((ushortT)(u >> 16))*sc.x + sc.y, 0.f);
    int a1 = i >> 5, c = i & 31;
    bufP[a1*33 + c] = make_float2(v0, v1);
  }
  __syncthreads();
  // step A: 32 packed FFTs over a1 (lane = a1)
  #pragma unroll 2
  for (int j = 0; j < 8; ++j){
    int c = wid*8 + j;
    float2 x = bufP[lane*33 + c];
    x = fft64_lane(x, W, lane);
    bufW[rl*33 + c] = x;             // W[f1][c]
  }
  __syncthreads();
  // Hermitian unpack: rows f1=0..31, cols 0..63 into bufA(=bufP) stride 65
  for (int i = tid; i < 1024; i += TPB){
    int f1 = i >> 5, c = i & 31;
    float2 Wv = bufW[f1*33 + c];
    float2 Wm = bufW[((64-f1)&63)*33 + c];
    bufP[f1*65 + 2*c]     = make_float2(0.5f*(Wv.x + Wm.x), 0.5f*(Wv.y - Wm.y));
    bufP[f1*65 + 2*c + 1] = make_float2(0.5f*(Wv.y + Wm.y), 0.5f*(Wm.x - Wv.x));
  }
  __syncthreads();
  // step B: 32 row FFTs over a2 (lane = a2)
  #pragma unroll 2
  for (int j = 0; j < 8; ++j){
    int r = wid*8 + j;
    float2 x = bufP[r*65 + lane];
    x = fft64_lane(x, W, lane);
    bufP[r*65 + rl] = x;
  }
  __syncthreads();
  float2* dst = XH + ((size_t)bc*32 + zz)*2016;
  for (int idx = tid; idx < 2016; idx += TPB){
    int mi = idx / 63, n = idx % 63;
    dst[idx] = bufP[mi*65 + ((n+33)&63)];
  }
}

// ---------------- F[bc,l,mi,n] (+)= sum_z qw*Dz*XH — register-tiled ----------------
__global__ __launch_bounds__(TPB) void k_wig_F(const float* __restrict__ Dz, const double* __restrict__ qw,
                                               const float2* __restrict__ XH, float2* __restrict__ F,
                                               int BC, int z0, int accum){
  __shared__ __attribute__((aligned(16))) float sm[9088];
  float* Dt = sm;                          // [z16][nn8][l 36pad]
  float2* Xt = (float2*)(sm + 4608);       // [bc16][130]
  int mi = blockIdx.x, nt = blockIdx.y, bcBase = blockIdx.z*16;
  int tid = threadIdx.x;
  int bg = tid & 3, lg = (tid>>2)&7, ng = tid>>5;
  float2 acc[4][4];
  #pragma unroll
  for (int a = 0; a < 4; ++a)
    #pragma unroll
    for (int j = 0; j < 4; ++j) acc[a][j] = make_float2(0,0);
  for (int zq = 0; zq < 32; zq += 16){
    __syncthreads();
    for (int idx = tid; idx < 4096; idx += TPB){
      int z = idx >> 8, l = (idx>>3)&31, nn = idx&7;
      int n = nt*8 + nn;
      float v = 0.f;
      if (n < 63) v = Dz[(((size_t)(z0+zq+z)*32 + l)*32 + mi)*63 + n] * (float)qw[z0+zq+z];
      Dt[(z*8+nn)*36 + l] = v;
    }
    for (int idx = tid; idx < 2048; idx += TPB){
      int bc = idx >> 7, z = (idx>>3)&15, nn = idx&7;
      int gbc = bcBase + bc, n = nt*8 + nn;
      float2 v = make_float2(0,0);
      if (gbc < BC && n < 63) v = XH[((size_t)gbc*32 + zq + z)*2016 + mi*63 + n];
      Xt[bc*130 + z*8 + nn] = v;
    }
    __syncthreads();
    #pragma unroll 4
    for (int z = 0; z < 16; ++z){
      const float4 d = *(const float4*)&Dt[(z*8+ng)*36 + lg*4];
      float dd[4] = {d.x, d.y, d.z, d.w};
      float2 xv[4];
      #pragma unroll
      for (int j = 0; j < 4; ++j) xv[j] = Xt[(bg + 4*j)*130 + z*8 + ng];
      #pragma unroll
      for (int j = 0; j < 4; ++j)
        #pragma unroll
        for (int dl = 0; dl < 4; ++dl){
          acc[j][dl].x += dd[dl]*xv[j].x;
          acc[j][dl].y += dd[dl]*xv[j].y;
        }
    }
  }
  __syncthreads();
  float2* St = (float2*)sm;                // [bc16][l32][nn8]
  #pragma unroll
  for (int j = 0; j < 4; ++j)
    #pragma unroll
    for (int dl = 0; dl < 4; ++dl)
      St[(((bg + 4*j)*32) + lg*4 + dl)*8 + ng] = acc[j][dl];
  __syncthreads();
  for (int idx = tid; idx < 4096; idx += TPB){
    int bc = idx >> 8, l = (idx>>3)&31, nn = idx&7;
    int gbc = bcBase + bc, n = nt*8 + nn;
    if (gbc < BC && n < 63){
      size_t a = ((size_t)(gbc*32 + l))*2016 + mi*63 + n;
      float2 v = St[idx];
      if (accum){ float2 o = F[a]; v.x += o.x; v.y += o.y; }
      F[a] = v;
    }
  }
}

// ---------------- C[bi,l,mi,n] = sum_k F[bi,l,mi,k]*Deq[l,n,k] — register-tiled ----------------
__global__ __launch_bounds__(TPB) void k_deq_C(const float* __restrict__ Deq, const float2* __restrict__ F,
                                               float2* __restrict__ C, int BC){
  __shared__ __attribute__((aligned(16))) float sm[12604];
  float2* Fb = (float2*)sm;                // [bi64][65pad]
  float* DeqT = sm + 8320;                 // [k63][68pad n]
  int l = blockIdx.x, mi = blockIdx.y, biBase = blockIdx.z*64;
  int tid = threadIdx.x;
  int ngr = tid & 15, big = tid >> 4;
  for (int idx = tid; idx < 3969; idx += TPB){
    int n = idx/63, k = idx - n*63;
    DeqT[k*68 + n] = Deq[((size_t)l*63 + n)*63 + k];
  }
  for (int idx = tid; idx < 4032; idx += TPB){
    int bi = idx/63, k = idx - bi*63;
    int gbi = biBase + bi;
    Fb[bi*65 + k] = (gbi < BC) ? F[((size_t)(gbi*32 + l))*2016 + mi*63 + k] : make_float2(0,0);
  }
  __syncthreads();
  float2 acc[4][4];
  #pragma unroll
  for (int a = 0; a < 4; ++a)
    #pragma unroll
    for (int j = 0; j < 4; ++j) acc[a][j] = make_float2(0,0);
  #pragma unroll 3
  for (int k = 0; k < 63; ++k){
    const float4 d = *(const float4*)&DeqT[k*68 + ngr*4];
    float dd[4] = {d.x, d.y, d.z, d.w};
    float2 fv[4];
    #pragma unroll
    for (int j = 0; j < 4; ++j) fv[j] = Fb[(big + 16*j)*65 + k];
    #pragma unroll
    for (int j = 0; j < 4; ++j)
      #pragma unroll
      for (int dn = 0; dn < 4; ++dn){
        acc[j][dn].x += dd[dn]*fv[j].x;
        acc[j][dn].y += dd[dn]*fv[j].y;
      }
  }
  __syncthreads();
  float2* St = (float2*)sm;                // [bi64][n63]
  #pragma unroll
  for (int j = 0; j < 4; ++j)
    #pragma unroll
    for (int dn = 0; dn < 4; ++dn){
      int n = ngr*4 + dn;
      if (n < 63) St[(big + 16*j)*63 + n] = acc[j][dn];
    }
  __syncthreads();
  for (int idx = tid; idx < 4032; idx += TPB){
    int bi = idx/63, n = idx - bi*63;
    int gbi = biBase + bi;
    if (gbi < BC) C[((size_t)(gbi*32 + l))*2016 + mi*63 + n] = St[idx];
  }
}

// ---------------- Z[b,o,l,mi,n] = sum_i Kh[o,i,n]*C[b,i,l,mi,n] — hybrid, 2 mi per wave ----------------
#define KOC 9
__global__ __launch_bounds__(TPB) void k_kh_z(const float2* __restrict__ C, const float2* __restrict__ Kh,
                                              float2* __restrict__ Z, int I, int O){
  __shared__ float2 Kt[KOC*5*64];          // [oo][ic5][n 64pad]
  int l = blockIdx.x, mic = blockIdx.y, oc = blockIdx.z;
  int lane = threadIdx.x & 63, wid = threadIdx.x >> 6;
  int mi0 = mic*8 + wid*2;
  int n = lane;
  int o0 = oc*KOC;
  float2 acc[2][2][KOC];                   // [mi_local][b][oo]
  #pragma unroll
  for (int ml = 0; ml < 2; ++ml)
    #pragma unroll
    for (int b = 0; b < 2; ++b)
      #pragma unroll
      for (int oo = 0; oo < KOC; ++oo) acc[ml][b][oo] = make_float2(0,0);
  size_t cBase0 = ((size_t)l)*2016 + mi0*63 + n;
  size_t cBase1 = cBase0 + 63;
  for (int i0 = 0; i0 < I; i0 += 5){
    __syncthreads();
    for (int idx = threadIdx.x; idx < KOC*5*64; idx += TPB){
      int nn = idx & 63, rem = idx >> 6;
      int ic = rem % 5, oo = rem / 5;
      float2 v = make_float2(0,0);
      int o = o0 + oo;
      if (o < O && nn < 63) v = Kh[((size_t)o*I + (i0+ic))*63 + nn];
      Kt[(oo*5 + ic)*64 + nn] = v;
    }
    __syncthreads();
    if (n < 63){
      #pragma unroll
      for (int ic = 0; ic < 5; ++ic){
        int i = i0 + ic;
        float2 c00 = C[cBase0 + (size_t)i*64512];
        float2 c01 = C[cBase0 + (size_t)(I + i)*64512];
        float2 c10 = C[cBase1 + (size_t)i*64512];
        float2 c11 = C[cBase1 + (size_t)(I + i)*64512];
        #pragma unroll
        for (int oo = 0; oo < KOC; ++oo){
          float2 kh = Kt[(oo*5 + ic)*64 + n];
          acc[0][0][oo].x += kh.x*c00.x - kh.y*c00.y;
          acc[0][0][oo].y += kh.x*c00.y + kh.y*c00.x;
          acc[0][1][oo].x += kh.x*c01.x - kh.y*c01.y;
          acc[0][1][oo].y += kh.x*c01.y + kh.y*c01.x;
          acc[1][0][oo].x += kh.x*c10.x - kh.y*c10.y;
          acc[1][0][oo].y += kh.x*c10.y + kh.y*c10.x;
          acc[1][1][oo].x += kh.x*c11.x - kh.y*c11.y;
          acc[1][1][oo].y += kh.x*c11.y + kh.y*c11.x;
        }
      }
    }
  }
  if (n < 63){
    #pragma unroll
    for (int ml = 0; ml < 2; ++ml){
      size_t zBase = ((size_t)l)*2016 + (mi0 + ml)*63 + n;
      #pragma unroll
      for (int oo = 0; oo < KOC; ++oo){
        int o = o0 + oo;
        if (o < O){
          Z[zBase + (size_t)(0*O + o)*64512] = acc[ml][0][oo];
          Z[zBase + (size_t)(1*O + o)*64512] = acc[ml][1][oo];
        }
      }
    }
  }
}

// ---------------- Xt[bo,z,mi,n] = sum_l wl*Dz*Z — register-tiled ----------------
__global__ __launch_bounds__(TPB) void k_wig_synth(const float* __restrict__ Dz, const float2* __restrict__ Z,
                                                   float2* __restrict__ Xt_g, int BO){
  __shared__ __attribute__((aligned(16))) float sm[9088];
  float* Dt = sm;                          // [l16][nn8][z 36pad]
  float2* Zt = (float2*)(sm + 4608);       // [bo16][130]
  int mi = blockIdx.x, nt = blockIdx.y;
  int z0 = (blockIdx.z & 1)*32;
  int boBase = (blockIdx.z >> 1)*16;
  int tid = threadIdx.x;
  int bg = tid & 3, zg = (tid>>2)&7, ng = tid>>5;
  float2 acc[4][4];
  #pragma unroll
  for (int a = 0; a < 4; ++a)
    #pragma unroll
    for (int j = 0; j < 4; ++j) acc[a][j] = make_float2(0,0);
  for (int lq = 0; lq < 32; lq += 16){
    __syncthreads();
    for (int idx = tid; idx < 4096; idx += TPB){
      int ll = idx >> 8, z = (idx>>3)&31, nn = idx&7;
      int n = nt*8 + nn, lG = lq + ll;
      float v = 0.f;
      if (n < 63) v = Dz[(((size_t)(z0+z)*32 + lG)*32 + mi)*63 + n] * (0.5f*(float)(2*lG+1));
      Dt[(ll*8+nn)*36 + z] = v;
    }
    for (int idx = tid; idx < 2048; idx += TPB){
      int bo = idx >> 7, ll = (idx>>3)&15, nn = idx&7;
      int gbo = boBase + bo, n = nt*8 + nn;
      float2 v = make_float2(0,0);
      if (gbo < BO && n < 63) v = Z[((size_t)(gbo*32 + lq + ll))*2016 + mi*63 + n];
      Zt[bo*130 + ll*8 + nn] = v;
    }
    __syncthreads();
    #pragma unroll 4
    for (int ll = 0; ll < 16; ++ll){
      const float4 d = *(const float4*)&Dt[(ll*8+ng)*36 + zg*4];
      float dd[4] = {d.x, d.y, d.z, d.w};
      float2 zv[4];
      #pragma unroll
      for (int j = 0; j < 4; ++j) zv[j] = Zt[(bg + 4*j)*130 + ll*8 + ng];
      #pragma unroll
      for (int j = 0; j < 4; ++j)
        #pragma unroll
        for (int dz = 0; dz < 4; ++dz){
          acc[j][dz].x += dd[dz]*zv[j].x;
          acc[j][dz].y += dd[dz]*zv[j].y;
        }
    }
  }
  __syncthreads();
  float2* St = (float2*)sm;                // [bo16][z32][nn8]
  #pragma unroll
  for (int j = 0; j < 4; ++j)
    #pragma unroll
    for (int dz = 0; dz < 4; ++dz)
      St[(((bg + 4*j)*32) + zg*4 + dz)*8 + ng] = acc[j][dz];
  __syncthreads();
  for (int idx = tid; idx < 4096; idx += TPB){
    int bo = idx >> 8, z = (idx>>3)&31, nn = idx&7;
    int gbo = boBase + bo, n = nt*8 + nn;
    if (gbo < BO && n < 63)
      Xt_g[((size_t)gbo*64 + z0 + z)*2016 + mi*63 + n] = St[idx];
  }
}

// ---------------- inverse helpers: stage reduced spectrum rows 0..32, row IFFTs ----------------
__device__ __forceinline__ void inv_stage_rows(const float2* __restrict__ src, float2* bufR,
                                               const float2* W, int lane, int wid, int rl){
  int tid = threadIdx.x;
  if (tid < 64) bufR[32*65 + tid] = make_float2(0,0);
  else if (tid < 96) bufR[(tid-64)*65 + 32] = make_float2(0,0);
  for (int idx = tid; idx < 2016; idx += TPB){
    int mi = idx / 63, ni = idx - mi*63;
    bufR[mi*65 + ((ni+33)&63)] = src[idx];
  }
  __syncthreads();
  // 32 row IFFTs (rows 0..31); row 32 stays zero
  #pragma unroll 2
  for (int j = 0; j < 8; ++j){
    int r = wid*8 + j;
    float2 x = bufR[r*65 + lane];
    x = fft64_lane(x, W, lane);
    bufR[r*65 + rl] = x;
  }
  __syncthreads();
}
__device__ __forceinline__ float2 inv_col_pack(const float2* bufR, int f, int pc){
  float2 r0, r1;
  if (f <= 32){
    r0 = bufR[f*65 + 2*pc];
    r1 = bufR[f*65 + 2*pc + 1];
  } else {
    int g = 64 - f;
    float2 a = bufR[g*65 + 2*pc];
    float2 b = bufR[g*65 + 2*pc + 1];
    r0 = make_float2(a.x, -a.y);
    r1 = make_float2(b.x, -b.y);
  }
  return make_float2(r0.x - r1.y, r0.y + r1.x);   // r0 + i*r1
}

// ---------------- ifft2 (Hermitian-packed) + real + bias -> bf16 X ----------------
__global__ __launch_bounds__(TPB) void k_ifft2_sym(const float2* __restrict__ Xt, ushortT* __restrict__ Xo,
                                                   const float* __restrict__ bias, int O){
  __shared__ float2 W[64];
  __shared__ __attribute__((aligned(16))) float2 bufR[33*65];
  __shared__ uintT ldsOut[64*33];
  int bo = blockIdx.x >> 6;
  int o = bo % O;
  init_W(W, 1.f);
  int tid = threadIdx.x, lane = tid & 63, wid = tid >> 6;
  int rl = (int)(__brev((uintT)lane) >> 26);
  const float2* src = Xt + (size_t)blockIdx.x*2016;
  inv_stage_rows(src, bufR, W, lane, wid, rl);
  float bb = bias[o];
  // 32 packed column IFFTs: lane = f1
  #pragma unroll 2
  for (int j = 0; j < 8; ++j){
    int pc = wid*8 + j;
    float2 w = inv_col_pack(bufR, lane, pc);
    float2 x = fft64_lane(w, W, lane);
    ushortT u0 = f2bf(x.x*(1.f/4096.f) + bb);
    ushortT u1 = f2bf(x.y*(1.f/4096.f) + bb);
    ldsOut[rl*33 + pc] = (uintT)u0 | ((uintT)u1 << 16);
  }
  __syncthreads();
  uintT* dst = (uintT*)(Xo + (size_t)blockIdx.x*4096);
  for (int i = tid; i < 2048; i += TPB){
    int a1 = i >> 5, pc = i & 31;
    dst[i] = ldsOut[a1*33 + pc];
  }
}

// ---------------- conv3 final stats from spectrum (Parseval) ----------------
__global__ __launch_bounds__(TPB) void k_stats3(const float2* __restrict__ Xt, double* __restrict__ part){
  int bo = blockIdx.x, zb = blockIdx.y;
  double s = 0.0, p = 0.0;
  for (int zz = 0; zz < 4; ++zz){
    const float2* pl = Xt + ((size_t)bo*64 + zb*4 + zz)*2016;
    for (int idx = threadIdx.x; idx < 2016; idx += TPB){
      float2 v = pl[idx];
      double q = (double)v.x*v.x + (double)v.y*v.y;
      p += (idx < 63) ? q : 2.0*q;
      if (idx == 31) s += v.x;
    }
  }
  __shared__ double sh[TPB], sh2[TPB];
  sh[threadIdx.x] = s; sh2[threadIdx.x] = p;
  __syncthreads();
  for (int o = 128; o > 0; o >>= 1){
    if (threadIdx.x < o){ sh[threadIdx.x] += sh[threadIdx.x+o]; sh2[threadIdx.x] += sh2[threadIdx.x+o]; }
    __syncthreads();
  }
  if (threadIdx.x == 0){
    part[((size_t)bo*16 + zb)*2 + 0] = sh[0];
    part[((size_t)bo*16 + zb)*2 + 1] = sh2[0];
  }
}

__global__ void k_fstat(const double* __restrict__ part, const float* __restrict__ bias,
                        const float* __restrict__ g, const float* __restrict__ bsh,
                        float2* __restrict__ ss, int O){
  int o = threadIdx.x;
  if (o >= O) return;
  double S = 0.0, P = 0.0;
  for (int b = 0; b < 2; ++b)
    for (int zb = 0; zb < 16; ++zb){
      size_t base = ((size_t)(b*O + o)*16 + zb)*2;
      S += part[base]; P += part[base+1];
    }
  P *= (1.0/4096.0);
  double N = 524288.0;
  double bi = bias[o];
  double mean = S/N + bi;
  double var = P/N + 2.0*bi*S/N + bi*bi - mean*mean;
  double sc = (double)g[o] / sqrt(var + 1e-5);
  ss[o] = make_float2((float)sc, (float)((bi - mean)*sc + (double)bsh[o]));
}

// ---------------- fused ifft2 (Hermitian-packed) + BN + ReLU + mean over gamma ----------------
__global__ __launch_bounds__(TPB) void k_final(const float2* __restrict__ Xt, const float2* __restrict__ ss,
                                               float* __restrict__ out, int O){
  __shared__ float2 W[64];
  __shared__ __attribute__((aligned(16))) float2 bufR[33*65];
  __shared__ float s4[4*64];
  int bo = blockIdx.x >> 6;
  int o = bo % O;
  init_W(W, 1.f);
  int tid = threadIdx.x, lane = tid & 63, wid = tid >> 6;
  int rl = (int)(__brev((uintT)lane) >> 26);
  const float2* src = Xt + (size_t)blockIdx.x*2016;
  inv_stage_rows(src, bufR, W, lane, wid, rl);
  float2 sv = ss[o];
  float acc = 0.f;
  #pragma unroll 2
  for (int j = 0; j < 8; ++j){
    int pc = wid*8 + j;
    float2 w = inv_col_pack(bufR, lane, pc);
    float2 x = fft64_lane(w, W, lane);
    acc += fmaxf(fmaf(x.x*(1.f/4096.f), sv.x, sv.y), 0.f);
    acc += fmaxf(fmaf(x.y*(1.f/4096.f), sv.x, sv.y), 0.f);
  }
  s4[wid*64 + rl] = acc;
  __syncthreads();
  if (tid < 64)
    out[(size_t)blockIdx.x*64 + tid] = (s4[tid] + s4[64+tid] + s4[128+tid] + s4[192+tid]) * (1.f/64.f);
}

extern "C" void kernel_launch(void* const* d_in, const int* in_sizes, int n_in,
                              void* d_out, int out_size, void* d_ws, size_t ws_size,
                              hipStream_t stream){
  const float* x   = (const float*)d_in[0];
  const float* ks2 = (const float*)d_in[1];
  const float* bs2 = (const float*)d_in[2];
  const float* k1  = (const float*)d_in[3];
  const float* b1c = (const float*)d_in[4];
  const float* k2  = (const float*)d_in[5];
  const float* b2c = (const float*)d_in[6];
  const float* k3  = (const float*)d_in[7];
  const float* b3c = (const float*)d_in[8];
  const float* g1 = (const float*)d_in[9],  *bb1 = (const float*)d_in[10];
  const float* g2 = (const float*)d_in[11], *bb2 = (const float*)d_in[12];
  const float* g3 = (const float*)d_in[13], *bb3 = (const float*)d_in[14];
  const float* g4 = (const float*)d_in[15], *bb4 = (const float*)d_in[16];
  float* out = (float*)d_out;

  char* w = (char*)d_ws;
  size_t off = 0;
  auto take = [&](size_t bytes)->char*{
    char* p = w + off;
    off += (bytes + 255) & ~(size_t)255;
    return p;
  };
  float*  Dz   = (float*) take(64ull*32*32*63*4);
  float*  Deq  = (float*) take(32ull*63*63*4);
  double* lf   = (double*)take(65*8);
  double* qw   = (double*)take(64*8);
  double* part = (double*)take(75ull*64*2*8);
  float2* ss   = (float2*)take(75*8);
  float2* KhS2 = (float2*)take(63ull*25*3*8);
  float2* Kh1  = (float2*)take(63ull*25*25*8);
  float2* Kh2  = (float2*)take(63ull*25*50*8);
  float2* Kh3  = (float2*)take(63ull*36*75*8);
  float2* XH2  = (float2*)take(2ull*3*64*63*8);
  float2* F2   = (float2*)take(2ull*3*32*63*8);
  ushortT* X1  = (ushortT*)take(2ull*25*262144*2);
  ushortT* X2  = (ushortT*)take(2ull*25*262144*2);
  ushortT* X3  = (ushortT*)take(2ull*25*262144*2);
  float2* A    = (float2*)take(150ull*32*2016*8);
  float2* B    = (float2*)take(150ull*32*2016*8);
  if (off > ws_size) return;

  dim3 tpb(TPB);
  auto cdiv = [](long long a, long long b){ return (int)((a + b - 1) / b); };

  k_tables<<<1, 64, 0, stream>>>(lf, qw);
  k_wigner<<<dim3(65,32), tpb, 0, stream>>>(lf, Dz, Deq);
  k_kh<<<cdiv(3ll*25*63,TPB),  tpb, 0, stream>>>(ks2, KhS2, 3, 25,  (float)(1.0/sqrt(196608.0)));
  k_kh<<<cdiv(25ll*25*63,TPB), tpb, 0, stream>>>(k1,  Kh1, 25, 25, (float)(1.0/sqrt(1600.0)));
  k_kh<<<cdiv(50ll*25*63,TPB), tpb, 0, stream>>>(k2,  Kh2, 50, 25, (float)(1.0/sqrt(3200.0)));
  k_kh<<<cdiv(75ll*36*63,TPB), tpb, 0, stream>>>(k3,  Kh3, 75, 36, (float)(1.0/sqrt(4800.0)));

  // ---- S2 conv ----
  k_s2_fft<<<cdiv(2ll*3*64*63,TPB), tpb, 0, stream>>>(x, XH2);
  k_s2_F<<<cdiv(2ll*3*32*63,TPB), tpb, 0, stream>>>(Dz, qw, XH2, F2);
  k_s2_zhat<<<cdiv(2ll*25*32*2016,TPB), tpb, 0, stream>>>(Deq, F2, KhS2, B);
  k_wig_synth<<<dim3(32,8,2*cdiv(50,16)), tpb, 0, stream>>>(Dz, B, A, 50);
  k_ifft2_sym<<<50*64, tpb, 0, stream>>>(A, X1, bs2, 25);
  k_bnstats<<<dim3(25,64), tpb, 0, stream>>>(X1, 0, part);

  // ---- generic SO3 conv (stats slots already filled) ----
  auto so3 = [&](const ushortT* Xa, const ushortT* Xb, const ushortT* Xc, int Cin,
                 const float* g, const float* bb, const float2* Kh, int O,
                 const float* bias, ushortT* Xout, int isFinal){
    int BC = 2*Cin, BO = 2*O;
    k_bnfinal<<<1, 128, 0, stream>>>(part, g, bb, ss, Cin);
    for (int z0 = 0; z0 < 64; z0 += 32){
      k_fft2_fwd<<<dim3(BC,32), tpb, 0, stream>>>(Xa, Xb, Xc, ss, A, Cin, z0);
      k_wig_F<<<dim3(32,8,cdiv(BC,16)), tpb, 0, stream>>>(Dz, qw, A, B, BC, z0, z0 > 0 ? 1 : 0);
    }
    k_deq_C<<<dim3(32,32,cdiv(BC,64)), tpb, 0, stream>>>(Deq, B, A, BC);
    k_kh_z<<<dim3(32,4,cdiv(O,KOC)), tpb, 0, stream>>>(A, Kh, B, Cin, O);
    k_wig_synth<<<dim3(32,8,2*cdiv(BO,16)), tpb, 0, stream>>>(Dz, B, A, BO);
    if (!isFinal){
      k_ifft2_sym<<<BO*64, tpb, 0, stream>>>(A, Xout, bias, O);
    } else {
      k_stats3<<<dim3(BO,16), tpb, 0, stream>>>(A, part);
      k_fstat<<<1, 64, 0, stream>>>(part, bias, g4, bb4, ss, O);
      k_final<<<BO*64, tpb, 0, stream>>>(A, ss, out, O);
    }
  };

  so3(X1, X1, X1, 25, g1, bb1, Kh1, 25, b1c, X2, 0);
  k_bnstats<<<dim3(25,64), tpb, 0, stream>>>(X2, 25, part);
  so3(X1, X2, X2, 50, g2, bb2, Kh2, 25, b2c, X3, 0);
  k_bnstats<<<dim3(25,64), tpb, 0, stream>>>(X3, 50, part);
  so3(X1, X2, X3, 75, g3, bb3, Kh3, 36, b3c, nullptr, 1);
}

// Round 10
// 1671.256 us; speedup vs baseline: 1.4418x; 1.0696x over previous
//
#include <hip/hip_runtime.h>
#include <math.h>

#define PI_D 3.14159265358979323846
#define TPB 256
typedef unsigned short ushortT;
typedef unsigned int uintT;

__device__ __forceinline__ float2 cxmul(float2 a, float2 b){
  return make_float2(a.x*b.x - a.y*b.y, a.x*b.y + a.y*b.x);
}
__device__ __forceinline__ float bf2f(ushortT u){
  uintT x = ((uintT)u) << 16;
  return __uint_as_float(x);
}
__device__ __forceinline__ ushortT f2bf(float f){
  uintT x = __float_as_uint(f);
  x = x + 0x7FFFu + ((x >> 16) & 1u);
  return (ushortT)(x >> 16);
}

// ---------------- tables ----------------
__global__ void k_tables(double* lf, double* qw){
  if (threadIdx.x == 0){
    lf[0] = 0.0;
    for (int i = 1; i <= 64; ++i) lf[i] = lf[i-1] + log((double)i);
  }
  int j = threadIdx.x;
  if (j < 64){
    double s1 = sin(PI_D*(2*j+1)/128.0);
    double inner = 0.0;
    for (int k = 0; k < 32; ++k)
      inner += (1.0/(double)(2*k+1)) * sin((double)(2*j+1)*(double)(2*k+1)*PI_D/128.0);
    qw[j] = (2.0/32.0) * s1 * inner;
  }
}

__device__ double wigd(const double* lfs, int l, int mp, int m, double lc, double ls){
  if (mp < -l || mp > l || m < -l || m > l) return 0.0;
  int k0 = (m - mp > 0) ? (m - mp) : 0;
  int k1 = (l + m < l - mp) ? (l + m) : (l - mp);
  double base = 0.5*(lfs[l+mp] + lfs[l-mp] + lfs[l+m] + lfs[l-m]);
  double val = 0.0;
  for (int k = k0; k <= k1; ++k){
    double t = base - lfs[l+m-k] - lfs[k] - lfs[mp-m+k] - lfs[l-mp-k]
             + (double)(2*l + m - mp - 2*k)*lc + (double)(mp - m + 2*k)*ls;
    double e = exp(t);
    val += ((mp - m + k) & 1) ? -e : e;
  }
  return val;
}

// Dz[z][l][mi'][n], Deq[l][r][c]
__global__ __launch_bounds__(TPB) void k_wigner(const double* __restrict__ lf,
                                                float* __restrict__ Dz, float* __restrict__ Deq){
  __shared__ double lfs[65];
  if (threadIdx.x < 65) lfs[threadIdx.x] = lf[threadIdx.x];
  __syncthreads();
  int zs = blockIdx.x, l = blockIdx.y;
  double beta = (zs < 64) ? ((double)zs + 0.5)*PI_D/64.0 : PI_D*0.5;
  double ch = cos(beta*0.5), sh = sin(beta*0.5);
  double lc = log(ch), ls = log(sh);
  if (zs < 64){
    for (int idx = threadIdx.x; idx < 2016; idx += TPB){
      int mi = idx/63, c = idx%63;
      Dz[((size_t)(zs*32 + l)*32 + mi)*63 + c] = (float)wigd(lfs, l, mi, c-31, lc, ls);
    }
  } else {
    for (int idx = threadIdx.x; idx < 3969; idx += TPB){
      int r = idx/63, c = idx%63;
      Deq[((size_t)l*63 + r)*63 + c] = (float)wigd(lfs, l, r-31, c-31, lc, ls);
    }
  }
}

// Kh[o][i][n] = scale * sum_p K[i,o,p] * exp(-i*2pi*p*(n-31)/64)
__global__ void k_kh(const float* __restrict__ K, float2* __restrict__ Kh, int I, int O, float scale){
  int idx = blockIdx.x*blockDim.x + threadIdx.x;
  if (idx >= I*O*63) return;
  int n = idx % 63, i = (idx/63) % I, o = idx/(63*I);
  float sr = 0.f, si = 0.f;
  for (int p = 0; p < 64; ++p){
    int t = (p * (n - 31)) & 63;
    float s, c;
    sincosf(-(float)PI_D/32.f * (float)t, &s, &c);
    float kv = K[(i*O + o)*64 + p];
    sr += kv * c; si += kv * s;
  }
  Kh[((size_t)o*I + i)*63 + n] = make_float2(sr*scale, si*scale);
}

// ---------------- S2 front ----------------
__global__ void k_s2_fft(const float* __restrict__ x, float2* __restrict__ XH2){
  int idx = blockIdx.x*blockDim.x + threadIdx.x;
  if (idx >= 2*3*64*63) return;
  int mi = idx % 63; int z = (idx/63) & 63; int bc = idx / (63*64);
  int f = (mi + 33) & 63;
  const float* row = x + ((size_t)bc*64 + z)*64;
  float sr = 0.f, si = 0.f;
  for (int a = 0; a < 64; ++a){
    int t = (f*a) & 63;
    float s, c;
    sincosf(-(float)PI_D/32.f * (float)t, &s, &c);
    sr += row[a]*c; si += row[a]*s;
  }
  XH2[idx] = make_float2(sr, si);
}

__global__ void k_s2_F(const float* __restrict__ Dz, const double* __restrict__ qw,
                       const float2* __restrict__ XH2, float2* __restrict__ F2){
  int idx = blockIdx.x*blockDim.x + threadIdx.x;
  if (idx >= 2*3*32*63) return;
  int r = idx % 63; int l = (idx/63) & 31; int bc = idx / (63*32);
  float2 acc = make_float2(0,0);
  for (int z = 0; z < 64; ++z){
    float d;
    if (r >= 31) d = Dz[((size_t)(z*32 + l)*32 + (r-31))*63 + 31];
    else {
      d = Dz[((size_t)(z*32 + l)*32 + (31-r))*63 + 31];
      if ((31-r) & 1) d = -d;
    }
    float wv = (float)qw[z] * d;
    float2 v = XH2[((size_t)bc*64 + z)*63 + r];
    acc.x += wv*v.x; acc.y += wv*v.y;
  }
  F2[idx] = acc;
}

__global__ void k_s2_zhat(const float* __restrict__ Deq, const float2* __restrict__ F2,
                          const float2* __restrict__ Kh, float2* __restrict__ Z){
  int idx = blockIdx.x*blockDim.x + threadIdx.x;
  if (idx >= 2*25*32*2016) return;
  int n = idx % 63; int mi = (idx/63) & 31; int l = (idx/2016) & 31;
  int o = (idx/(2016*32)) % 25; int b = idx/(2016*32*25);
  float deq0 = Deq[((size_t)l*63 + n)*63 + 31];
  float2 acc = make_float2(0,0);
  for (int i = 0; i < 3; ++i){
    float2 f = F2[((size_t)(b*3 + i)*32 + l)*63 + (mi+31)];
    float2 kh = Kh[((size_t)(o*3 + i))*63 + n];
    acc.x = fmaf(kh.x, f.x, acc.x); acc.x = fmaf(-kh.y, f.y, acc.x);
    acc.y = fmaf(kh.x, f.y, acc.y); acc.y = fmaf(kh.y, f.x, acc.y);
  }
  Z[((size_t)((b*25+o)*32) + l)*2016 + mi*63 + n] = make_float2(acc.x*deq0, acc.y*deq0);
}

// ---------------- BN stats over bf16 X buffers ----------------
__global__ __launch_bounds__(TPB) void k_bnstats(const ushortT* __restrict__ src, int slotBase,
                                                 double* __restrict__ part){
  int c = blockIdx.x, blk = blockIdx.y;
  const uint2* s4 = (const uint2*)src;
  double s = 0.0, q = 0.0;
  for (int k = 0; k < 8; ++k){
    int g4 = blk*2048 + k*256 + threadIdx.x;
    int b = g4 >> 16, pos4 = g4 & 65535;
    uint2 u = s4[((size_t)(b*25 + c))*65536 + pos4];
    float v0 = bf2f((ushortT)(u.x & 0xffff)), v1 = bf2f((ushortT)(u.x >> 16));
    float v2 = bf2f((ushortT)(u.y & 0xffff)), v3 = bf2f((ushortT)(u.y >> 16));
    s += (double)v0 + v1 + v2 + v3;
    q += (double)v0*v0 + (double)v1*v1 + (double)v2*v2 + (double)v3*v3;
  }
  __shared__ double sh[TPB], sh2[TPB];
  sh[threadIdx.x] = s; sh2[threadIdx.x] = q;
  __syncthreads();
  for (int o = 128; o > 0; o >>= 1){
    if (threadIdx.x < o){ sh[threadIdx.x] += sh[threadIdx.x+o]; sh2[threadIdx.x] += sh2[threadIdx.x+o]; }
    __syncthreads();
  }
  if (threadIdx.x == 0){
    part[((size_t)(slotBase + c)*64 + blk)*2 + 0] = sh[0];
    part[((size_t)(slotBase + c)*64 + blk)*2 + 1] = sh2[0];
  }
}

__global__ void k_bnfinal(const double* __restrict__ part, const float* __restrict__ g,
                          const float* __restrict__ b, float2* __restrict__ ss, int C){
  int c = blockIdx.x*blockDim.x + threadIdx.x;
  if (c >= C) return;
  double s = 0.0, q = 0.0;
  for (int k = 0; k < 64; ++k){
    s += part[((size_t)c*64 + k)*2 + 0];
    q += part[((size_t)c*64 + k)*2 + 1];
  }
  double N = 524288.0;
  double mu = s / N;
  double var = q / N - mu*mu;
  double sc = (double)g[c] / sqrt(var + 1e-5);
  ss[c] = make_float2((float)sc, (float)((double)b[c] - mu*sc));
}

// ---------------- 64-pt FFT across lanes (radix-2 DIF, shfl) ----------------
__device__ __forceinline__ float2 fft64_lane(float2 x, const float2* __restrict__ Wt, int lane){
  #pragma unroll
  for (int st = 0; st < 6; ++st){
    int h = 32 >> st;
    float2 p;
    p.x = __shfl_xor(x.x, h, 64);
    p.y = __shfl_xor(x.y, h, 64);
    if (lane & h){
      float2 s = make_float2(p.x - x.x, p.y - x.y);
      x = cxmul(s, Wt[(lane & (h-1)) << st]);
    } else {
      x = make_float2(x.x + p.x, x.y + p.y);
    }
  }
  return x;
}
__device__ __forceinline__ void init_W(float2* W, float sign){
  if (threadIdx.x < 64){
    float s, c;
    sincosf(sign*(float)(2.0*PI_D/64.0)*(float)threadIdx.x, &s, &c);
    W[threadIdx.x] = make_float2(c, s);
  }
}

// ---------------- fused BN+ReLU + packed real fft2 + reduced extraction ----------------
__global__ __launch_bounds__(TPB) void k_fft2_fwd(const ushortT* __restrict__ X1, const ushortT* __restrict__ X2,
                                                  const ushortT* __restrict__ X3, const float2* __restrict__ ss,
                                                  float2* __restrict__ XH, int Cin, int z0){
  __shared__ float2 W[64];
  __shared__ __attribute__((aligned(16))) float2 smem[4224];   // bufP[64*33] | bufW[64*33]
  float2* bufP = smem;
  float2* bufW = smem + 2112;
  int bc = blockIdx.x, zz = blockIdx.y, z = z0 + zz;
  int b = bc / Cin, ci = bc % Cin;
  const ushortT* src; int cl;
  if (ci < 25){ src = X1; cl = ci; }
  else if (ci < 50){ src = X2; cl = ci - 25; }
  else { src = X3; cl = ci - 50; }
  src += ((size_t)(b*25 + cl)*64 + z)*4096;
  float2 sc = ss[ci];
  init_W(W, -1.f);
  int tid = threadIdx.x, lane = tid & 63, wid = tid >> 6;
  int rl = (int)(__brev((uintT)lane) >> 26);
  const uintT* s32 = (const uintT*)src;
  for (int i = tid; i < 2048; i += TPB){
    uintT u = s32[i];
    float v0 = fmaxf(bf2f((ushortT)(u & 0xffff))*sc.x + sc.y, 0.f);
    float v1 = fmaxf(bf2f((ushortT)(u >> 16))*sc.x + sc.y, 0.f);
    int a1 = i >> 5, c = i & 31;
    bufP[a1*33 + c] = make_float2(v0, v1);
  }
  __syncthreads();
  #pragma unroll 2
  for (int j = 0; j < 8; ++j){
    int c = wid*8 + j;
    float2 x = bufP[lane*33 + c];
    x = fft64_lane(x, W, lane);
    bufW[rl*33 + c] = x;
  }
  __syncthreads();
  for (int i = tid; i < 1024; i += TPB){
    int f1 = i >> 5, c = i & 31;
    float2 Wv = bufW[f1*33 + c];
    float2 Wm = bufW[((64-f1)&63)*33 + c];
    bufP[f1*65 + 2*c]     = make_float2(0.5f*(Wv.x + Wm.x), 0.5f*(Wv.y - Wm.y));
    bufP[f1*65 + 2*c + 1] = make_float2(0.5f*(Wv.y + Wm.y), 0.5f*(Wm.x - Wv.x));
  }
  __syncthreads();
  #pragma unroll 2
  for (int j = 0; j < 8; ++j){
    int r = wid*8 + j;
    float2 x = bufP[r*65 + lane];
    x = fft64_lane(x, W, lane);
    bufP[r*65 + rl] = x;
  }
  __syncthreads();
  float2* dst = XH + ((size_t)bc*32 + zz)*2016;
  for (int idx = tid; idx < 2016; idx += TPB){
    int mi = idx / 63, n = idx % 63;
    dst[idx] = bufP[mi*65 + ((n+33)&63)];
  }
}

// ---------------- F[bc,l,mi,n] (+)= sum_z qw*Dz*XH — register-tiled ----------------
__global__ __launch_bounds__(TPB) void k_wig_F(const float* __restrict__ Dz, const double* __restrict__ qw,
                                               const float2* __restrict__ XH, float2* __restrict__ F,
                                               int BC, int z0, int accum){
  __shared__ __attribute__((aligned(16))) float sm[9088];
  float* Dt = sm;                          // [z16][nn8][l 36pad]
  float2* Xt = (float2*)(sm + 4608);       // [bc16][130]
  int mi = blockIdx.x, nt = blockIdx.y, bcBase = blockIdx.z*16;
  int tid = threadIdx.x;
  int bg = tid & 3, lg = (tid>>2)&7, ng = tid>>5;
  float2 acc[4][4];
  #pragma unroll
  for (int a = 0; a < 4; ++a)
    #pragma unroll
    for (int j = 0; j < 4; ++j) acc[a][j] = make_float2(0,0);
  for (int zq = 0; zq < 32; zq += 16){
    __syncthreads();
    for (int idx = tid; idx < 4096; idx += TPB){
      int z = idx >> 8, l = (idx>>3)&31, nn = idx&7;
      int n = nt*8 + nn;
      float v = 0.f;
      if (n < 63) v = Dz[(((size_t)(z0+zq+z)*32 + l)*32 + mi)*63 + n] * (float)qw[z0+zq+z];
      Dt[(z*8+nn)*36 + l] = v;
    }
    for (int idx = tid; idx < 2048; idx += TPB){
      int bc = idx >> 7, z = (idx>>3)&15, nn = idx&7;
      int gbc = bcBase + bc, n = nt*8 + nn;
      float2 v = make_float2(0,0);
      if (gbc < BC && n < 63) v = XH[((size_t)gbc*32 + zq + z)*2016 + mi*63 + n];
      Xt[bc*130 + z*8 + nn] = v;
    }
    __syncthreads();
    #pragma unroll 4
    for (int z = 0; z < 16; ++z){
      const float4 d = *(const float4*)&Dt[(z*8+ng)*36 + lg*4];
      float dd[4] = {d.x, d.y, d.z, d.w};
      float2 xv[4];
      #pragma unroll
      for (int j = 0; j < 4; ++j) xv[j] = Xt[(bg + 4*j)*130 + z*8 + ng];
      #pragma unroll
      for (int j = 0; j < 4; ++j)
        #pragma unroll
        for (int dl = 0; dl < 4; ++dl){
          acc[j][dl].x += dd[dl]*xv[j].x;
          acc[j][dl].y += dd[dl]*xv[j].y;
        }
    }
  }
  __syncthreads();
  float2* St = (float2*)sm;                // [bc16][l32][nn8]
  #pragma unroll
  for (int j = 0; j < 4; ++j)
    #pragma unroll
    for (int dl = 0; dl < 4; ++dl)
      St[(((bg + 4*j)*32) + lg*4 + dl)*8 + ng] = acc[j][dl];
  __syncthreads();
  for (int idx = tid; idx < 4096; idx += TPB){
    int bc = idx >> 8, l = (idx>>3)&31, nn = idx&7;
    int gbc = bcBase + bc, n = nt*8 + nn;
    if (gbc < BC && n < 63){
      size_t a = ((size_t)(gbc*32 + l))*2016 + mi*63 + n;
      float2 v = St[idx];
      if (accum){ float2 o = F[a]; v.x += o.x; v.y += o.y; }
      F[a] = v;
    }
  }
}

// ---------------- C[bi,l,mi,n] = sum_k F[bi,l,mi,k]*Deq[l,n,k] — register-tiled ----------------
__global__ __launch_bounds__(TPB) void k_deq_C(const float* __restrict__ Deq, const float2* __restrict__ F,
                                               float2* __restrict__ C, int BC){
  __shared__ __attribute__((aligned(16))) float sm[12604];
  float2* Fb = (float2*)sm;                // [bi64][65pad]
  float* DeqT = sm + 8320;                 // [k63][68pad n]
  int l = blockIdx.x, mi = blockIdx.y, biBase = blockIdx.z*64;
  int tid = threadIdx.x;
  int ngr = tid & 15, big = tid >> 4;
  for (int idx = tid; idx < 3969; idx += TPB){
    int n = idx/63, k = idx - n*63;
    DeqT[k*68 + n] = Deq[((size_t)l*63 + n)*63 + k];
  }
  for (int idx = tid; idx < 4032; idx += TPB){
    int bi = idx/63, k = idx - bi*63;
    int gbi = biBase + bi;
    Fb[bi*65 + k] = (gbi < BC) ? F[((size_t)(gbi*32 + l))*2016 + mi*63 + k] : make_float2(0,0);
  }
  __syncthreads();
  float2 acc[4][4];
  #pragma unroll
  for (int a = 0; a < 4; ++a)
    #pragma unroll
    for (int j = 0; j < 4; ++j) acc[a][j] = make_float2(0,0);
  #pragma unroll 3
  for (int k = 0; k < 63; ++k){
    const float4 d = *(const float4*)&DeqT[k*68 + ngr*4];
    float dd[4] = {d.x, d.y, d.z, d.w};
    float2 fv[4];
    #pragma unroll
    for (int j = 0; j < 4; ++j) fv[j] = Fb[(big + 16*j)*65 + k];
    #pragma unroll
    for (int j = 0; j < 4; ++j)
      #pragma unroll
      for (int dn = 0; dn < 4; ++dn){
        acc[j][dn].x += dd[dn]*fv[j].x;
        acc[j][dn].y += dd[dn]*fv[j].y;
      }
  }
  __syncthreads();
  float2* St = (float2*)sm;                // [bi64][n63]
  #pragma unroll
  for (int j = 0; j < 4; ++j)
    #pragma unroll
    for (int dn = 0; dn < 4; ++dn){
      int n = ngr*4 + dn;
      if (n < 63) St[(big + 16*j)*63 + n] = acc[j][dn];
    }
  __syncthreads();
  for (int idx = tid; idx < 4032; idx += TPB){
    int bi = idx/63, n = idx - bi*63;
    int gbi = biBase + bi;
    if (gbi < BC) C[((size_t)(gbi*32 + l))*2016 + mi*63 + n] = St[idx];
  }
}

// ---------------- Z[b,o,l,mi,n] = sum_i Kh[o,i,n]*C[b,i,l,mi,n] ----------------
// hybrid, 2 mi per wave; fmaf cmacs + cv preload + Kt reg-prefetch pipeline
#define KOC 9
__global__ __launch_bounds__(TPB) void k_kh_z(const float2* __restrict__ C, const float2* __restrict__ Kh,
                                              float2* __restrict__ Z, int I, int O){
  __shared__ float2 Kt[KOC*5*64];          // [oo][ic5][n 64pad]
  const int nK = KOC*5*64;                 // 2880
  int l = blockIdx.x, mic = blockIdx.y, oc = blockIdx.z;
  int lane = threadIdx.x & 63, wid = threadIdx.x >> 6;
  int mi0 = mic*8 + wid*2;
  int n = lane;
  int o0 = oc*KOC;
  float2 acc[2][2][KOC];                   // [mi_local][b][oo]
  #pragma unroll
  for (int ml = 0; ml < 2; ++ml)
    #pragma unroll
    for (int b = 0; b < 2; ++b)
      #pragma unroll
      for (int oo = 0; oo < KOC; ++oo) acc[ml][b][oo] = make_float2(0,0);

  float2 pre[12];
  auto loadK = [&](int i0){
    #pragma unroll
    for (int t = 0; t < 12; ++t){
      int idx = threadIdx.x + t*256;
      float2 v = make_float2(0,0);
      if (idx < nK){
        int nn = idx & 63, rem = idx >> 6;
        int ic = rem % 5, oo = rem / 5;
        int o = o0 + oo;
        if (o < O && nn < 63) v = Kh[((size_t)o*I + (i0+ic))*63 + nn];
      }
      pre[t] = v;
    }
  };
  loadK(0);

  size_t cBase0 = ((size_t)l)*2016 + mi0*63 + n;
  size_t cBase1 = cBase0 + 63;
  int nch = I/5;
  for (int c = 0; c < nch; ++c){
    __syncthreads();
    #pragma unroll
    for (int t = 0; t < 12; ++t){
      int idx = threadIdx.x + t*256;
      if (idx < nK) Kt[idx] = pre[t];
    }
    __syncthreads();
    if (c+1 < nch) loadK((c+1)*5);
    if (n < 63){
      int i0 = c*5;
      float2 cv[5][4];
      #pragma unroll
      for (int ic = 0; ic < 5; ++ic){
        int i = i0 + ic;
        cv[ic][0] = C[cBase0 + (size_t)i*64512];
        cv[ic][1] = C[cBase0 + (size_t)(I + i)*64512];
        cv[ic][2] = C[cBase1 + (size_t)i*64512];
        cv[ic][3] = C[cBase1 + (size_t)(I + i)*64512];
      }
      #pragma unroll
      for (int ic = 0; ic < 5; ++ic){
        #pragma unroll
        for (int oo = 0; oo < KOC; ++oo){
          float2 kh = Kt[(oo*5 + ic)*64 + n];
          #pragma unroll
          for (int q = 0; q < 4; ++q){
            float2 cc = cv[ic][q];
            int ml = q >> 1, b = q & 1;
            acc[ml][b][oo].x = fmaf(kh.x, cc.x, acc[ml][b][oo].x);
            acc[ml][b][oo].x = fmaf(-kh.y, cc.y, acc[ml][b][oo].x);
            acc[ml][b][oo].y = fmaf(kh.x, cc.y, acc[ml][b][oo].y);
            acc[ml][b][oo].y = fmaf(kh.y, cc.x, acc[ml][b][oo].y);
          }
        }
      }
    }
  }
  if (n < 63){
    #pragma unroll
    for (int ml = 0; ml < 2; ++ml){
      size_t zBase = ((size_t)l)*2016 + (mi0 + ml)*63 + n;
      #pragma unroll
      for (int oo = 0; oo < KOC; ++oo){
        int o = o0 + oo;
        if (o < O){
          Z[zBase + (size_t)(0*O + o)*64512] = acc[ml][0][oo];
          Z[zBase + (size_t)(1*O + o)*64512] = acc[ml][1][oo];
        }
      }
    }
  }
}

// ---------------- Xt[bo,z,mi,n] = sum_l wl*Dz*Z — register-tiled ----------------
__global__ __launch_bounds__(TPB) void k_wig_synth(const float* __restrict__ Dz, const float2* __restrict__ Z,
                                                   float2* __restrict__ Xt_g, int BO){
  __shared__ __attribute__((aligned(16))) float sm[9088];
  float* Dt = sm;                          // [l16][nn8][z 36pad]
  float2* Zt = (float2*)(sm + 4608);       // [bo16][130]
  int mi = blockIdx.x, nt = blockIdx.y;
  int z0 = (blockIdx.z & 1)*32;
  int boBase = (blockIdx.z >> 1)*16;
  int tid = threadIdx.x;
  int bg = tid & 3, zg = (tid>>2)&7, ng = tid>>5;
  float2 acc[4][4];
  #pragma unroll
  for (int a = 0; a < 4; ++a)
    #pragma unroll
    for (int j = 0; j < 4; ++j) acc[a][j] = make_float2(0,0);
  for (int lq = 0; lq < 32; lq += 16){
    __syncthreads();
    for (int idx = tid; idx < 4096; idx += TPB){
      int ll = idx >> 8, z = (idx>>3)&31, nn = idx&7;
      int n = nt*8 + nn, lG = lq + ll;
      float v = 0.f;
      if (n < 63) v = Dz[(((size_t)(z0+z)*32 + lG)*32 + mi)*63 + n] * (0.5f*(float)(2*lG+1));
      Dt[(ll*8+nn)*36 + z] = v;
    }
    for (int idx = tid; idx < 2048; idx += TPB){
      int bo = idx >> 7, ll = (idx>>3)&15, nn = idx&7;
      int gbo = boBase + bo, n = nt*8 + nn;
      float2 v = make_float2(0,0);
      if (gbo < BO && n < 63) v = Z[((size_t)(gbo*32 + lq + ll))*2016 + mi*63 + n];
      Zt[bo*130 + ll*8 + nn] = v;
    }
    __syncthreads();
    #pragma unroll 4
    for (int ll = 0; ll < 16; ++ll){
      const float4 d = *(const float4*)&Dt[(ll*8+ng)*36 + zg*4];
      float dd[4] = {d.x, d.y, d.z, d.w};
      float2 zv[4];
      #pragma unroll
      for (int j = 0; j < 4; ++j) zv[j] = Zt[(bg + 4*j)*130 + ll*8 + ng];
      #pragma unroll
      for (int j = 0; j < 4; ++j)
        #pragma unroll
        for (int dz = 0; dz < 4; ++dz){
          acc[j][dz].x += dd[dz]*zv[j].x;
          acc[j][dz].y += dd[dz]*zv[j].y;
        }
    }
  }
  __syncthreads();
  float2* St = (float2*)sm;                // [bo16][z32][nn8]
  #pragma unroll
  for (int j = 0; j < 4; ++j)
    #pragma unroll
    for (int dz = 0; dz < 4; ++dz)
      St[(((bg + 4*j)*32) + zg*4 + dz)*8 + ng] = acc[j][dz];
  __syncthreads();
  for (int idx = tid; idx < 4096; idx += TPB){
    int bo = idx >> 8, z = (idx>>3)&31, nn = idx&7;
    int gbo = boBase + bo, n = nt*8 + nn;
    if (gbo < BO && n < 63)
      Xt_g[((size_t)gbo*64 + z0 + z)*2016 + mi*63 + n] = St[idx];
  }
}

// ---------------- inverse helpers ----------------
__device__ __forceinline__ void inv_stage_rows(const float2* __restrict__ src, float2* bufR,
                                               const float2* W, int lane, int wid, int rl){
  int tid = threadIdx.x;
  if (tid < 64) bufR[32*65 + tid] = make_float2(0,0);
  else if (tid < 96) bufR[(tid-64)*65 + 32] = make_float2(0,0);
  for (int idx = tid; idx < 2016; idx += TPB){
    int mi = idx / 63, ni = idx - mi*63;
    bufR[mi*65 + ((ni+33)&63)] = src[idx];
  }
  __syncthreads();
  #pragma unroll 2
  for (int j = 0; j < 8; ++j){
    int r = wid*8 + j;
    float2 x = bufR[r*65 + lane];
    x = fft64_lane(x, W, lane);
    bufR[r*65 + rl] = x;
  }
  __syncthreads();
}
__device__ __forceinline__ float2 inv_col_pack(const float2* bufR, int f, int pc){
  float2 r0, r1;
  if (f <= 32){
    r0 = bufR[f*65 + 2*pc];
    r1 = bufR[f*65 + 2*pc + 1];
  } else {
    int g = 64 - f;
    float2 a = bufR[g*65 + 2*pc];
    float2 b = bufR[g*65 + 2*pc + 1];
    r0 = make_float2(a.x, -a.y);
    r1 = make_float2(b.x, -b.y);
  }
  return make_float2(r0.x - r1.y, r0.y + r1.x);
}

// ---------------- ifft2 (Hermitian-packed) + real + bias -> bf16 X ----------------
__global__ __launch_bounds__(TPB) void k_ifft2_sym(const float2* __restrict__ Xt, ushortT* __restrict__ Xo,
                                                   const float* __restrict__ bias, int O){
  __shared__ float2 W[64];
  __shared__ __attribute__((aligned(16))) float2 bufR[33*65];
  __shared__ uintT ldsOut[64*33];
  int bo = blockIdx.x >> 6;
  int o = bo % O;
  init_W(W, 1.f);
  int tid = threadIdx.x, lane = tid & 63, wid = tid >> 6;
  int rl = (int)(__brev((uintT)lane) >> 26);
  const float2* src = Xt + (size_t)blockIdx.x*2016;
  inv_stage_rows(src, bufR, W, lane, wid, rl);
  float bb = bias[o];
  #pragma unroll 2
  for (int j = 0; j < 8; ++j){
    int pc = wid*8 + j;
    float2 w = inv_col_pack(bufR, lane, pc);
    float2 x = fft64_lane(w, W, lane);
    ushortT u0 = f2bf(x.x*(1.f/4096.f) + bb);
    ushortT u1 = f2bf(x.y*(1.f/4096.f) + bb);
    ldsOut[rl*33 + pc] = (uintT)u0 | ((uintT)u1 << 16);
  }
  __syncthreads();
  uintT* dst = (uintT*)(Xo + (size_t)blockIdx.x*4096);
  for (int i = tid; i < 2048; i += TPB){
    int a1 = i >> 5, pc = i & 31;
    dst[i] = ldsOut[a1*33 + pc];
  }
}

// ---------------- conv3 final stats from spectrum (Parseval) ----------------
__global__ __launch_bounds__(TPB) void k_stats3(const float2* __restrict__ Xt, double* __restrict__ part){
  int bo = blockIdx.x, zb = blockIdx.y;
  double s = 0.0, p = 0.0;
  for (int zz = 0; zz < 4; ++zz){
    const float2* pl = Xt + ((size_t)bo*64 + zb*4 + zz)*2016;
    for (int idx = threadIdx.x; idx < 2016; idx += TPB){
      float2 v = pl[idx];
      double q = (double)v.x*v.x + (double)v.y*v.y;
      p += (idx < 63) ? q : 2.0*q;
      if (idx == 31) s += v.x;
    }
  }
  __shared__ double sh[TPB], sh2[TPB];
  sh[threadIdx.x] = s; sh2[threadIdx.x] = p;
  __syncthreads();
  for (int o = 128; o > 0; o >>= 1){
    if (threadIdx.x < o){ sh[threadIdx.x] += sh[threadIdx.x+o]; sh2[threadIdx.x] += sh2[threadIdx.x+o]; }
    __syncthreads();
  }
  if (threadIdx.x == 0){
    part[((size_t)bo*16 + zb)*2 + 0] = sh[0];
    part[((size_t)bo*16 + zb)*2 + 1] = sh2[0];
  }
}

__global__ void k_fstat(const double* __restrict__ part, const float* __restrict__ bias,
                        const float* __restrict__ g, const float* __restrict__ bsh,
                        float2* __restrict__ ss, int O){
  int o = threadIdx.x;
  if (o >= O) return;
  double S = 0.0, P = 0.0;
  for (int b = 0; b < 2; ++b)
    for (int zb = 0; zb < 16; ++zb){
      size_t base = ((size_t)(b*O + o)*16 + zb)*2;
      S += part[base]; P += part[base+1];
    }
  P *= (1.0/4096.0);
  double N = 524288.0;
  double bi = bias[o];
  double mean = S/N + bi;
  double var = P/N + 2.0*bi*S/N + bi*bi - mean*mean;
  double sc = (double)g[o] / sqrt(var + 1e-5);
  ss[o] = make_float2((float)sc, (float)((bi - mean)*sc + (double)bsh[o]));
}

// ---------------- fused ifft2 (Hermitian-packed) + BN + ReLU + mean over gamma ----------------
__global__ __launch_bounds__(TPB) void k_final(const float2* __restrict__ Xt, const float2* __restrict__ ss,
                                               float* __restrict__ out, int O){
  __shared__ float2 W[64];
  __shared__ __attribute__((aligned(16))) float2 bufR[33*65];
  __shared__ float s4[4*64];
  int bo = blockIdx.x >> 6;
  int o = bo % O;
  init_W(W, 1.f);
  int tid = threadIdx.x, lane = tid & 63, wid = tid >> 6;
  int rl = (int)(__brev((uintT)lane) >> 26);
  const float2* src = Xt + (size_t)blockIdx.x*2016;
  inv_stage_rows(src, bufR, W, lane, wid, rl);
  float2 sv = ss[o];
  float acc = 0.f;
  #pragma unroll 2
  for (int j = 0; j < 8; ++j){
    int pc = wid*8 + j;
    float2 w = inv_col_pack(bufR, lane, pc);
    float2 x = fft64_lane(w, W, lane);
    acc += fmaxf(fmaf(x.x*(1.f/4096.f), sv.x, sv.y), 0.f);
    acc += fmaxf(fmaf(x.y*(1.f/4096.f), sv.x, sv.y), 0.f);
  }
  s4[wid*64 + rl] = acc;
  __syncthreads();
  if (tid < 64)
    out[(size_t)blockIdx.x*64 + tid] = (s4[tid] + s4[64+tid] + s4[128+tid] + s4[192+tid]) * (1.f/64.f);
}

extern "C" void kernel_launch(void* const* d_in, const int* in_sizes, int n_in,
                              void* d_out, int out_size, void* d_ws, size_t ws_size,
                              hipStream_t stream){
  const float* x   = (const float*)d_in[0];
  const float* ks2 = (const float*)d_in[1];
  const float* bs2 = (const float*)d_in[2];
  const float* k1  = (const float*)d_in[3];
  const float* b1c = (const float*)d_in[4];
  const float* k2  = (const float*)d_in[5];
  const float* b2c = (const float*)d_in[6];
  const float* k3  = (const float*)d_in[7];
  const float* b3c = (const float*)d_in[8];
  const float* g1 = (const float*)d_in[9],  *bb1 = (const float*)d_in[10];
  const float* g2 = (const float*)d_in[11], *bb2 = (const float*)d_in[12];
  const float* g3 = (const float*)d_in[13], *bb3 = (const float*)d_in[14];
  const float* g4 = (const float*)d_in[15], *bb4 = (const float*)d_in[16];
  float* out = (float*)d_out;

  char* w = (char*)d_ws;
  size_t off = 0;
  auto take = [&](size_t bytes)->char*{
    char* p = w + off;
    off += (bytes + 255) & ~(size_t)255;
    return p;
  };
  float*  Dz   = (float*) take(64ull*32*32*63*4);
  float*  Deq  = (float*) take(32ull*63*63*4);
  double* lf   = (double*)take(65*8);
  double* qw   = (double*)take(64*8);
  double* part = (double*)take(75ull*64*2*8);
  float2* ss   = (float2*)take(75*8);
  float2* KhS2 = (float2*)take(63ull*25*3*8);
  float2* Kh1  = (float2*)take(63ull*25*25*8);
  float2* Kh2  = (float2*)take(63ull*25*50*8);
  float2* Kh3  = (float2*)take(63ull*36*75*8);
  float2* XH2  = (float2*)take(2ull*3*64*63*8);
  float2* F2   = (float2*)take(2ull*3*32*63*8);
  ushortT* X1  = (ushortT*)take(2ull*25*262144*2);
  ushortT* X2  = (ushortT*)take(2ull*25*262144*2);
  ushortT* X3  = (ushortT*)take(2ull*25*262144*2);
  float2* A    = (float2*)take(150ull*32*2016*8);
  float2* B    = (float2*)take(150ull*32*2016*8);
  if (off > ws_size) return;

  dim3 tpb(TPB);
  auto cdiv = [](long long a, long long b){ return (int)((a + b - 1) / b); };

  k_tables<<<1, 64, 0, stream>>>(lf, qw);
  k_wigner<<<dim3(65,32), tpb, 0, stream>>>(lf, Dz, Deq);
  k_kh<<<cdiv(3ll*25*63,TPB),  tpb, 0, stream>>>(ks2, KhS2, 3, 25,  (float)(1.0/sqrt(196608.0)));
  k_kh<<<cdiv(25ll*25*63,TPB), tpb, 0, stream>>>(k1,  Kh1, 25, 25, (float)(1.0/sqrt(1600.0)));
  k_kh<<<cdiv(50ll*25*63,TPB), tpb, 0, stream>>>(k2,  Kh2, 50, 25, (float)(1.0/sqrt(3200.0)));
  k_kh<<<cdiv(75ll*36*63,TPB), tpb, 0, stream>>>(k3,  Kh3, 75, 36, (float)(1.0/sqrt(4800.0)));

  // ---- S2 conv ----
  k_s2_fft<<<cdiv(2ll*3*64*63,TPB), tpb, 0, stream>>>(x, XH2);
  k_s2_F<<<cdiv(2ll*3*32*63,TPB), tpb, 0, stream>>>(Dz, qw, XH2, F2);
  k_s2_zhat<<<cdiv(2ll*25*32*2016,TPB), tpb, 0, stream>>>(Deq, F2, KhS2, B);
  k_wig_synth<<<dim3(32,8,2*cdiv(50,16)), tpb, 0, stream>>>(Dz, B, A, 50);
  k_ifft2_sym<<<50*64, tpb, 0, stream>>>(A, X1, bs2, 25);
  k_bnstats<<<dim3(25,64), tpb, 0, stream>>>(X1, 0, part);

  // ---- generic SO3 conv (stats slots already filled) ----
  auto so3 = [&](const ushortT* Xa, const ushortT* Xb, const ushortT* Xc, int Cin,
                 const float* g, const float* bb, const float2* Kh, int O,
                 const float* bias, ushortT* Xout, int isFinal){
    int BC = 2*Cin, BO = 2*O;
    k_bnfinal<<<1, 128, 0, stream>>>(part, g, bb, ss, Cin);
    for (int z0 = 0; z0 < 64; z0 += 32){
      k_fft2_fwd<<<dim3(BC,32), tpb, 0, stream>>>(Xa, Xb, Xc, ss, A, Cin, z0);
      k_wig_F<<<dim3(32,8,cdiv(BC,16)), tpb, 0, stream>>>(Dz, qw, A, B, BC, z0, z0 > 0 ? 1 : 0);
    }
    k_deq_C<<<dim3(32,32,cdiv(BC,64)), tpb, 0, stream>>>(Deq, B, A, BC);
    k_kh_z<<<dim3(32,4,cdiv(O,KOC)), tpb, 0, stream>>>(A, Kh, B, Cin, O);
    k_wig_synth<<<dim3(32,8,2*cdiv(BO,16)), tpb, 0, stream>>>(Dz, B, A, BO);
    if (!isFinal){
      k_ifft2_sym<<<BO*64, tpb, 0, stream>>>(A, Xout, bias, O);
    } else {
      k_stats3<<<dim3(BO,16), tpb, 0, stream>>>(A, part);
      k_fstat<<<1, 64, 0, stream>>>(part, bias, g4, bb4, ss, O);
      k_final<<<BO*64, tpb, 0, stream>>>(A, ss, out, O);
    }
  };

  so3(X1, X1, X1, 25, g1, bb1, Kh1, 25, b1c, X2, 0);
  k_bnstats<<<dim3(25,64), tpb, 0, stream>>>(X2, 25, part);
  so3(X1, X2, X2, 50, g2, bb2, Kh2, 25, b2c, X3, 0);
  k_bnstats<<<dim3(25,64), tpb, 0, stream>>>(X3, 50, part);
  so3(X1, X2, X3, 75, g3, bb3, Kh3, 36, b3c, nullptr, 1);
}

// Round 11
// 1515.565 us; speedup vs baseline: 1.5899x; 1.1027x over previous
//
#include <hip/hip_runtime.h>
#include <math.h>

#define PI_D 3.14159265358979323846
#define TPB 256
typedef unsigned short ushortT;
typedef unsigned int uintT;

__device__ __forceinline__ float2 cxmul(float2 a, float2 b){
  return make_float2(a.x*b.x - a.y*b.y, a.x*b.y + a.y*b.x);
}
__device__ __forceinline__ float bf2f(ushortT u){
  uintT x = ((uintT)u) << 16;
  return __uint_as_float(x);
}
__device__ __forceinline__ ushortT f2bf(float f){
  uintT x = __float_as_uint(f);
  x = x + 0x7FFFu + ((x >> 16) & 1u);
  return (ushortT)(x >> 16);
}

// ---------------- tables ----------------
__global__ void k_tables(double* lf, double* qw){
  if (threadIdx.x == 0){
    lf[0] = 0.0;
    for (int i = 1; i <= 64; ++i) lf[i] = lf[i-1] + log((double)i);
  }
  int j = threadIdx.x;
  if (j < 64){
    double s1 = sin(PI_D*(2*j+1)/128.0);
    double inner = 0.0;
    for (int k = 0; k < 32; ++k)
      inner += (1.0/(double)(2*k+1)) * sin((double)(2*j+1)*(double)(2*k+1)*PI_D/128.0);
    qw[j] = (2.0/32.0) * s1 * inner;
  }
}

__device__ double wigd(const double* lfs, int l, int mp, int m, double lc, double ls){
  if (mp < -l || mp > l || m < -l || m > l) return 0.0;
  int k0 = (m - mp > 0) ? (m - mp) : 0;
  int k1 = (l + m < l - mp) ? (l + m) : (l - mp);
  double base = 0.5*(lfs[l+mp] + lfs[l-mp] + lfs[l+m] + lfs[l-m]);
  double val = 0.0;
  for (int k = k0; k <= k1; ++k){
    double t = base - lfs[l+m-k] - lfs[k] - lfs[mp-m+k] - lfs[l-mp-k]
             + (double)(2*l + m - mp - 2*k)*lc + (double)(mp - m + 2*k)*ls;
    double e = exp(t);
    val += ((mp - m + k) & 1) ? -e : e;
  }
  return val;
}

// Dz[z][l][mi'][n], Deq[l][r][c]
__global__ __launch_bounds__(TPB) void k_wigner(const double* __restrict__ lf,
                                                float* __restrict__ Dz, float* __restrict__ Deq){
  __shared__ double lfs[65];
  if (threadIdx.x < 65) lfs[threadIdx.x] = lf[threadIdx.x];
  __syncthreads();
  int zs = blockIdx.x, l = blockIdx.y;
  double beta = (zs < 64) ? ((double)zs + 0.5)*PI_D/64.0 : PI_D*0.5;
  double ch = cos(beta*0.5), sh = sin(beta*0.5);
  double lc = log(ch), ls = log(sh);
  if (zs < 64){
    for (int idx = threadIdx.x; idx < 2016; idx += TPB){
      int mi = idx/63, c = idx%63;
      Dz[((size_t)(zs*32 + l)*32 + mi)*63 + c] = (float)wigd(lfs, l, mi, c-31, lc, ls);
    }
  } else {
    for (int idx = threadIdx.x; idx < 3969; idx += TPB){
      int r = idx/63, c = idx%63;
      Deq[((size_t)l*63 + r)*63 + c] = (float)wigd(lfs, l, r-31, c-31, lc, ls);
    }
  }
}

// Kh[o][i][n] = scale * sum_p K[i,o,p] * exp(-i*2pi*p*(n-31)/64)
__global__ void k_kh(const float* __restrict__ K, float2* __restrict__ Kh, int I, int O, float scale){
  int idx = blockIdx.x*blockDim.x + threadIdx.x;
  if (idx >= I*O*63) return;
  int n = idx % 63, i = (idx/63) % I, o = idx/(63*I);
  float sr = 0.f, si = 0.f;
  for (int p = 0; p < 64; ++p){
    int t = (p * (n - 31)) & 63;
    float s, c;
    sincosf(-(float)PI_D/32.f * (float)t, &s, &c);
    float kv = K[(i*O + o)*64 + p];
    sr += kv * c; si += kv * s;
  }
  Kh[((size_t)o*I + i)*63 + n] = make_float2(sr*scale, si*scale);
}

// ---------------- S2 front ----------------
__global__ void k_s2_fft(const float* __restrict__ x, float2* __restrict__ XH2){
  int idx = blockIdx.x*blockDim.x + threadIdx.x;
  if (idx >= 2*3*64*63) return;
  int mi = idx % 63; int z = (idx/63) & 63; int bc = idx / (63*64);
  int f = (mi + 33) & 63;
  const float* row = x + ((size_t)bc*64 + z)*64;
  float sr = 0.f, si = 0.f;
  for (int a = 0; a < 64; ++a){
    int t = (f*a) & 63;
    float s, c;
    sincosf(-(float)PI_D/32.f * (float)t, &s, &c);
    sr += row[a]*c; si += row[a]*s;
  }
  XH2[idx] = make_float2(sr, si);
}

__global__ void k_s2_F(const float* __restrict__ Dz, const double* __restrict__ qw,
                       const float2* __restrict__ XH2, float2* __restrict__ F2){
  int idx = blockIdx.x*blockDim.x + threadIdx.x;
  if (idx >= 2*3*32*63) return;
  int r = idx % 63; int l = (idx/63) & 31; int bc = idx / (63*32);
  float2 acc = make_float2(0,0);
  for (int z = 0; z < 64; ++z){
    float d;
    if (r >= 31) d = Dz[((size_t)(z*32 + l)*32 + (r-31))*63 + 31];
    else {
      d = Dz[((size_t)(z*32 + l)*32 + (31-r))*63 + 31];
      if ((31-r) & 1) d = -d;
    }
    float wv = (float)qw[z] * d;
    float2 v = XH2[((size_t)bc*64 + z)*63 + r];
    acc.x += wv*v.x; acc.y += wv*v.y;
  }
  F2[idx] = acc;
}

__global__ void k_s2_zhat(const float* __restrict__ Deq, const float2* __restrict__ F2,
                          const float2* __restrict__ Kh, float2* __restrict__ Z){
  int idx = blockIdx.x*blockDim.x + threadIdx.x;
  if (idx >= 2*25*32*2016) return;
  int n = idx % 63; int mi = (idx/63) & 31; int l = (idx/2016) & 31;
  int o = (idx/(2016*32)) % 25; int b = idx/(2016*32*25);
  float deq0 = Deq[((size_t)l*63 + n)*63 + 31];
  float2 acc = make_float2(0,0);
  for (int i = 0; i < 3; ++i){
    float2 f = F2[((size_t)(b*3 + i)*32 + l)*63 + (mi+31)];
    float2 kh = Kh[((size_t)(o*3 + i))*63 + n];
    acc.x = fmaf(kh.x, f.x, acc.x); acc.x = fmaf(-kh.y, f.y, acc.x);
    acc.y = fmaf(kh.x, f.y, acc.y); acc.y = fmaf(kh.y, f.x, acc.y);
  }
  Z[((size_t)((b*25+o)*32) + l)*2016 + mi*63 + n] = make_float2(acc.x*deq0, acc.y*deq0);
}

// ---------------- BN stats over bf16 X buffers ----------------
__global__ __launch_bounds__(TPB) void k_bnstats(const ushortT* __restrict__ src, int slotBase,
                                                 double* __restrict__ part){
  int c = blockIdx.x, blk = blockIdx.y;
  const uint2* s4 = (const uint2*)src;
  double s = 0.0, q = 0.0;
  for (int k = 0; k < 8; ++k){
    int g4 = blk*2048 + k*256 + threadIdx.x;
    int b = g4 >> 16, pos4 = g4 & 65535;
    uint2 u = s4[((size_t)(b*25 + c))*65536 + pos4];
    float v0 = bf2f((ushortT)(u.x & 0xffff)), v1 = bf2f((ushortT)(u.x >> 16));
    float v2 = bf2f((ushortT)(u.y & 0xffff)), v3 = bf2f((ushortT)(u.y >> 16));
    s += (double)v0 + v1 + v2 + v3;
    q += (double)v0*v0 + (double)v1*v1 + (double)v2*v2 + (double)v3*v3;
  }
  __shared__ double sh[TPB], sh2[TPB];
  sh[threadIdx.x] = s; sh2[threadIdx.x] = q;
  __syncthreads();
  for (int o = 128; o > 0; o >>= 1){
    if (threadIdx.x < o){ sh[threadIdx.x] += sh[threadIdx.x+o]; sh2[threadIdx.x] += sh2[threadIdx.x+o]; }
    __syncthreads();
  }
  if (threadIdx.x == 0){
    part[((size_t)(slotBase + c)*64 + blk)*2 + 0] = sh[0];
    part[((size_t)(slotBase + c)*64 + blk)*2 + 1] = sh2[0];
  }
}

__global__ void k_bnfinal(const double* __restrict__ part, const float* __restrict__ g,
                          const float* __restrict__ b, float2* __restrict__ ss, int C){
  int c = blockIdx.x*blockDim.x + threadIdx.x;
  if (c >= C) return;
  double s = 0.0, q = 0.0;
  for (int k = 0; k < 64; ++k){
    s += part[((size_t)c*64 + k)*2 + 0];
    q += part[((size_t)c*64 + k)*2 + 1];
  }
  double N = 524288.0;
  double mu = s / N;
  double var = q / N - mu*mu;
  double sc = (double)g[c] / sqrt(var + 1e-5);
  ss[c] = make_float2((float)sc, (float)((double)b[c] - mu*sc));
}

// ---------------- 64-pt FFT across lanes (radix-2 DIF, shfl) ----------------
__device__ __forceinline__ float2 fft64_lane(float2 x, const float2* __restrict__ Wt, int lane){
  #pragma unroll
  for (int st = 0; st < 6; ++st){
    int h = 32 >> st;
    float2 p;
    p.x = __shfl_xor(x.x, h, 64);
    p.y = __shfl_xor(x.y, h, 64);
    if (lane & h){
      float2 s = make_float2(p.x - x.x, p.y - x.y);
      x = cxmul(s, Wt[(lane & (h-1)) << st]);
    } else {
      x = make_float2(x.x + p.x, x.y + p.y);
    }
  }
  return x;
}
__device__ __forceinline__ void init_W(float2* W, float sign){
  if (threadIdx.x < 64){
    float s, c;
    sincosf(sign*(float)(2.0*PI_D/64.0)*(float)threadIdx.x, &s, &c);
    W[threadIdx.x] = make_float2(c, s);
  }
}

// ---------------- fused BN+ReLU + packed real fft2 + reduced extraction ----------------
__global__ __launch_bounds__(TPB) void k_fft2_fwd(const ushortT* __restrict__ X1, const ushortT* __restrict__ X2,
                                                  const ushortT* __restrict__ X3, const float2* __restrict__ ss,
                                                  float2* __restrict__ XH, int Cin, int z0){
  __shared__ float2 W[64];
  __shared__ __attribute__((aligned(16))) float2 smem[4224];   // bufP[64*33] | bufW[64*33]
  float2* bufP = smem;
  float2* bufW = smem + 2112;
  int bc = blockIdx.x, zz = blockIdx.y, z = z0 + zz;
  int b = bc / Cin, ci = bc % Cin;
  const ushortT* src; int cl;
  if (ci < 25){ src = X1; cl = ci; }
  else if (ci < 50){ src = X2; cl = ci - 25; }
  else { src = X3; cl = ci - 50; }
  src += ((size_t)(b*25 + cl)*64 + z)*4096;
  float2 sc = ss[ci];
  init_W(W, -1.f);
  int tid = threadIdx.x, lane = tid & 63, wid = tid >> 6;
  int rl = (int)(__brev((uintT)lane) >> 26);
  const uintT* s32 = (const uintT*)src;
  for (int i = tid; i < 2048; i += TPB){
    uintT u = s32[i];
    float v0 = fmaxf(bf2f((ushortT)(u & 0xffff))*sc.x + sc.y, 0.f);
    float v1 = fmaxf(bf2f((ushortT)(u >> 16))*sc.x + sc.y, 0.f);
    int a1 = i >> 5, c = i & 31;
    bufP[a1*33 + c] = make_float2(v0, v1);
  }
  __syncthreads();
  #pragma unroll 2
  for (int j = 0; j < 8; ++j){
    int c = wid*8 + j;
    float2 x = bufP[lane*33 + c];
    x = fft64_lane(x, W, lane);
    bufW[rl*33 + c] = x;
  }
  __syncthreads();
  for (int i = tid; i < 1024; i += TPB){
    int f1 = i >> 5, c = i & 31;
    float2 Wv = bufW[f1*33 + c];
    float2 Wm = bufW[((64-f1)&63)*33 + c];
    bufP[f1*65 + 2*c]     = make_float2(0.5f*(Wv.x + Wm.x), 0.5f*(Wv.y - Wm.y));
    bufP[f1*65 + 2*c + 1] = make_float2(0.5f*(Wv.y + Wm.y), 0.5f*(Wm.x - Wv.x));
  }
  __syncthreads();
  #pragma unroll 2
  for (int j = 0; j < 8; ++j){
    int r = wid*8 + j;
    float2 x = bufP[r*65 + lane];
    x = fft64_lane(x, W, lane);
    bufP[r*65 + rl] = x;
  }
  __syncthreads();
  float2* dst = XH + ((size_t)bc*32 + zz)*2016;
  for (int idx = tid; idx < 2016; idx += TPB){
    int mi = idx / 63, n = idx % 63;
    dst[idx] = bufP[mi*65 + ((n+33)&63)];
  }
}

// ---------------- F[bc,l,mi,n] = sum_z(all 64) qw*Dz*XH — single pass, F in-place over XHa ----------------
// grid (32 mi, 8 nt, ceil(BC/16)); block 256
#define SKEW(e) ((e) + ((e)>>4))
__global__ __launch_bounds__(TPB) void k_wig_F(const float* __restrict__ Dz, const double* __restrict__ qw,
                                               const float2* __restrict__ XHa, const float2* __restrict__ XHb,
                                               float2* __restrict__ F, int BC){
  __shared__ __attribute__((aligned(16))) float sm[9088];
  float* Dt = sm;                          // [z16][nn8][l 36pad]
  float2* Xt = (float2*)(sm + 4608);       // [bc16][130]
  int mi = blockIdx.x, nt = blockIdx.y, bcBase = blockIdx.z*16;
  int tid = threadIdx.x;
  int bg = tid & 3, lg = (tid>>2)&7, ng = tid>>5;
  float2 acc[4][4];
  #pragma unroll
  for (int a = 0; a < 4; ++a)
    #pragma unroll
    for (int j = 0; j < 4; ++j) acc[a][j] = make_float2(0,0);
  for (int chunk = 0; chunk < 4; ++chunk){
    const float2* XH = (chunk < 2) ? XHa : XHb;
    int zq = (chunk & 1)*16;      // z offset within buffer
    int gz0 = chunk*16;           // global z
    __syncthreads();
    for (int idx = tid; idx < 4096; idx += TPB){
      int z = idx >> 8, l = (idx>>3)&31, nn = idx&7;
      int n = nt*8 + nn;
      float v = 0.f;
      if (n < 63) v = Dz[(((size_t)(gz0+z)*32 + l)*32 + mi)*63 + n] * (float)qw[gz0+z];
      Dt[(z*8+nn)*36 + l] = v;
    }
    for (int idx = tid; idx < 2048; idx += TPB){
      int bc = idx >> 7, z = (idx>>3)&15, nn = idx&7;
      int gbc = bcBase + bc, n = nt*8 + nn;
      float2 v = make_float2(0,0);
      if (gbc < BC && n < 63) v = XH[((size_t)gbc*32 + zq + z)*2016 + mi*63 + n];
      Xt[bc*130 + z*8 + nn] = v;
    }
    __syncthreads();
    #pragma unroll 4
    for (int z = 0; z < 16; ++z){
      const float4 d = *(const float4*)&Dt[(z*8+ng)*36 + lg*4];
      float dd[4] = {d.x, d.y, d.z, d.w};
      float2 xv[4];
      #pragma unroll
      for (int j = 0; j < 4; ++j) xv[j] = Xt[(bg + 4*j)*130 + z*8 + ng];
      #pragma unroll
      for (int j = 0; j < 4; ++j)
        #pragma unroll
        for (int dl = 0; dl < 4; ++dl){
          acc[j][dl].x = fmaf(dd[dl], xv[j].x, acc[j][dl].x);
          acc[j][dl].y = fmaf(dd[dl], xv[j].y, acc[j][dl].y);
        }
    }
  }
  __syncthreads();
  float2* St = (float2*)sm;                // skewed [bc16][l32][nn8]
  #pragma unroll
  for (int j = 0; j < 4; ++j)
    #pragma unroll
    for (int dl = 0; dl < 4; ++dl){
      int e = (bg + 4*j)*256 + (lg*4 + dl)*8 + ng;
      St[SKEW(e)] = acc[j][dl];
    }
  __syncthreads();
  for (int idx = tid; idx < 4096; idx += TPB){
    int bc = idx >> 8, l = (idx>>3)&31, nn = idx&7;
    int gbc = bcBase + bc, n = nt*8 + nn;
    if (gbc < BC && n < 63)
      F[((size_t)(gbc*32 + l))*2016 + mi*63 + n] = St[SKEW(idx)];
  }
}

// ---------------- C[bi,l,mi,n] = sum_k F[bi,l,mi,k]*Deq[l,n,k] — register-tiled ----------------
__global__ __launch_bounds__(TPB) void k_deq_C(const float* __restrict__ Deq, const float2* __restrict__ F,
                                               float2* __restrict__ C, int BC){
  __shared__ __attribute__((aligned(16))) float sm[12604];
  float2* Fb = (float2*)sm;                // [bi64][65pad]
  float* DeqT = sm + 8320;                 // [k63][68pad n]
  int l = blockIdx.x, mi = blockIdx.y, biBase = blockIdx.z*64;
  int tid = threadIdx.x;
  int ngr = tid & 15, big = tid >> 4;
  for (int idx = tid; idx < 3969; idx += TPB){
    int n = idx/63, k = idx - n*63;
    DeqT[k*68 + n] = Deq[((size_t)l*63 + n)*63 + k];
  }
  for (int idx = tid; idx < 4032; idx += TPB){
    int bi = idx/63, k = idx - bi*63;
    int gbi = biBase + bi;
    Fb[bi*65 + k] = (gbi < BC) ? F[((size_t)(gbi*32 + l))*2016 + mi*63 + k] : make_float2(0,0);
  }
  __syncthreads();
  float2 acc[4][4];
  #pragma unroll
  for (int a = 0; a < 4; ++a)
    #pragma unroll
    for (int j = 0; j < 4; ++j) acc[a][j] = make_float2(0,0);
  #pragma unroll 3
  for (int k = 0; k < 63; ++k){
    const float4 d = *(const float4*)&DeqT[k*68 + ngr*4];
    float dd[4] = {d.x, d.y, d.z, d.w};
    float2 fv[4];
    #pragma unroll
    for (int j = 0; j < 4; ++j) fv[j] = Fb[(big + 16*j)*65 + k];
    #pragma unroll
    for (int j = 0; j < 4; ++j)
      #pragma unroll
      for (int dn = 0; dn < 4; ++dn){
        acc[j][dn].x = fmaf(dd[dn], fv[j].x, acc[j][dn].x);
        acc[j][dn].y = fmaf(dd[dn], fv[j].y, acc[j][dn].y);
      }
  }
  __syncthreads();
  float2* St = (float2*)sm;                // [bi64][n63]
  #pragma unroll
  for (int j = 0; j < 4; ++j)
    #pragma unroll
    for (int dn = 0; dn < 4; ++dn){
      int n = ngr*4 + dn;
      if (n < 63) St[(big + 16*j)*63 + n] = acc[j][dn];
    }
  __syncthreads();
  for (int idx = tid; idx < 4032; idx += TPB){
    int bi = idx/63, n = idx - bi*63;
    int gbi = biBase + bi;
    if (gbi < BC) C[((size_t)(gbi*32 + l))*2016 + mi*63 + n] = St[idx];
  }
}

// ---------------- Z[b,o,l,mi,n] = sum_i Kh[o,i,n]*C[b,i,l,mi,n] ----------------
#define KOC 9
__global__ __launch_bounds__(TPB) void k_kh_z(const float2* __restrict__ C, const float2* __restrict__ Kh,
                                              float2* __restrict__ Z, int I, int O){
  __shared__ float2 Kt[KOC*5*64];          // [oo][ic5][n 64pad]
  const int nK = KOC*5*64;                 // 2880
  int l = blockIdx.x, mic = blockIdx.y, oc = blockIdx.z;
  int lane = threadIdx.x & 63, wid = threadIdx.x >> 6;
  int mi0 = mic*8 + wid*2;
  int n = lane;
  int o0 = oc*KOC;
  float2 acc[2][2][KOC];                   // [mi_local][b][oo]
  #pragma unroll
  for (int ml = 0; ml < 2; ++ml)
    #pragma unroll
    for (int b = 0; b < 2; ++b)
      #pragma unroll
      for (int oo = 0; oo < KOC; ++oo) acc[ml][b][oo] = make_float2(0,0);

  float2 pre[12];
  auto loadK = [&](int i0){
    #pragma unroll
    for (int t = 0; t < 12; ++t){
      int idx = threadIdx.x + t*256;
      float2 v = make_float2(0,0);
      if (idx < nK){
        int nn = idx & 63, rem = idx >> 6;
        int ic = rem % 5, oo = rem / 5;
        int o = o0 + oo;
        if (o < O && nn < 63) v = Kh[((size_t)o*I + (i0+ic))*63 + nn];
      }
      pre[t] = v;
    }
  };
  loadK(0);

  size_t cBase0 = ((size_t)l)*2016 + mi0*63 + n;
  size_t cBase1 = cBase0 + 63;
  int nch = I/5;
  for (int c = 0; c < nch; ++c){
    __syncthreads();
    #pragma unroll
    for (int t = 0; t < 12; ++t){
      int idx = threadIdx.x + t*256;
      if (idx < nK) Kt[idx] = pre[t];
    }
    __syncthreads();
    if (c+1 < nch) loadK((c+1)*5);
    if (n < 63){
      int i0 = c*5;
      float2 cv[5][4];
      #pragma unroll
      for (int ic = 0; ic < 5; ++ic){
        int i = i0 + ic;
        cv[ic][0] = C[cBase0 + (size_t)i*64512];
        cv[ic][1] = C[cBase0 + (size_t)(I + i)*64512];
        cv[ic][2] = C[cBase1 + (size_t)i*64512];
        cv[ic][3] = C[cBase1 + (size_t)(I + i)*64512];
      }
      #pragma unroll
      for (int ic = 0; ic < 5; ++ic){
        #pragma unroll
        for (int oo = 0; oo < KOC; ++oo){
          float2 kh = Kt[(oo*5 + ic)*64 + n];
          #pragma unroll
          for (int q = 0; q < 4; ++q){
            float2 cc = cv[ic][q];
            int ml = q >> 1, b = q & 1;
            acc[ml][b][oo].x = fmaf(kh.x, cc.x, acc[ml][b][oo].x);
            acc[ml][b][oo].x = fmaf(-kh.y, cc.y, acc[ml][b][oo].x);
            acc[ml][b][oo].y = fmaf(kh.x, cc.y, acc[ml][b][oo].y);
            acc[ml][b][oo].y = fmaf(kh.y, cc.x, acc[ml][b][oo].y);
          }
        }
      }
    }
  }
  if (n < 63){
    #pragma unroll
    for (int ml = 0; ml < 2; ++ml){
      size_t zBase = ((size_t)l)*2016 + (mi0 + ml)*63 + n;
      #pragma unroll
      for (int oo = 0; oo < KOC; ++oo){
        int o = o0 + oo;
        if (o < O){
          Z[zBase + (size_t)(0*O + o)*64512] = acc[ml][0][oo];
          Z[zBase + (size_t)(1*O + o)*64512] = acc[ml][1][oo];
        }
      }
    }
  }
}

// ---------------- Xt[bo,z,mi,n] = sum_l wl*Dz*Z — register-tiled, skewed epilogue ----------------
__global__ __launch_bounds__(TPB) void k_wig_synth(const float* __restrict__ Dz, const float2* __restrict__ Z,
                                                   float2* __restrict__ Xt_g, int BO){
  __shared__ __attribute__((aligned(16))) float sm[9088];
  float* Dt = sm;                          // [l16][nn8][z 36pad]
  float2* Zt = (float2*)(sm + 4608);       // [bo16][130]
  int mi = blockIdx.x, nt = blockIdx.y;
  int z0 = (blockIdx.z & 1)*32;
  int boBase = (blockIdx.z >> 1)*16;
  int tid = threadIdx.x;
  int bg = tid & 3, zg = (tid>>2)&7, ng = tid>>5;
  float2 acc[4][4];
  #pragma unroll
  for (int a = 0; a < 4; ++a)
    #pragma unroll
    for (int j = 0; j < 4; ++j) acc[a][j] = make_float2(0,0);
  for (int lq = 0; lq < 32; lq += 16){
    __syncthreads();
    for (int idx = tid; idx < 4096; idx += TPB){
      int ll = idx >> 8, z = (idx>>3)&31, nn = idx&7;
      int n = nt*8 + nn, lG = lq + ll;
      float v = 0.f;
      if (n < 63) v = Dz[(((size_t)(z0+z)*32 + lG)*32 + mi)*63 + n] * (0.5f*(float)(2*lG+1));
      Dt[(ll*8+nn)*36 + z] = v;
    }
    for (int idx = tid; idx < 2048; idx += TPB){
      int bo = idx >> 7, ll = (idx>>3)&15, nn = idx&7;
      int gbo = boBase + bo, n = nt*8 + nn;
      float2 v = make_float2(0,0);
      if (gbo < BO && n < 63) v = Z[((size_t)(gbo*32 + lq + ll))*2016 + mi*63 + n];
      Zt[bo*130 + ll*8 + nn] = v;
    }
    __syncthreads();
    #pragma unroll 4
    for (int ll = 0; ll < 16; ++ll){
      const float4 d = *(const float4*)&Dt[(ll*8+ng)*36 + zg*4];
      float dd[4] = {d.x, d.y, d.z, d.w};
      float2 zv[4];
      #pragma unroll
      for (int j = 0; j < 4; ++j) zv[j] = Zt[(bg + 4*j)*130 + ll*8 + ng];
      #pragma unroll
      for (int j = 0; j < 4; ++j)
        #pragma unroll
        for (int dz = 0; dz < 4; ++dz){
          acc[j][dz].x = fmaf(dd[dz], zv[j].x, acc[j][dz].x);
          acc[j][dz].y = fmaf(dd[dz], zv[j].y, acc[j][dz].y);
        }
    }
  }
  __syncthreads();
  float2* St = (float2*)sm;                // skewed [bo16][z32][nn8]
  #pragma unroll
  for (int j = 0; j < 4; ++j)
    #pragma unroll
    for (int dz = 0; dz < 4; ++dz){
      int e = (bg + 4*j)*256 + (zg*4 + dz)*8 + ng;
      St[SKEW(e)] = acc[j][dz];
    }
  __syncthreads();
  for (int idx = tid; idx < 4096; idx += TPB){
    int bo = idx >> 8, z = (idx>>3)&31, nn = idx&7;
    int gbo = boBase + bo, n = nt*8 + nn;
    if (gbo < BO && n < 63)
      Xt_g[((size_t)gbo*64 + z0 + z)*2016 + mi*63 + n] = St[SKEW(idx)];
  }
}

// ---------------- inverse helpers ----------------
__device__ __forceinline__ void inv_stage_rows(const float2* __restrict__ src, float2* bufR,
                                               const float2* W, int lane, int wid, int rl){
  int tid = threadIdx.x;
  if (tid < 64) bufR[32*65 + tid] = make_float2(0,0);
  else if (tid < 96) bufR[(tid-64)*65 + 32] = make_float2(0,0);
  for (int idx = tid; idx < 2016; idx += TPB){
    int mi = idx / 63, ni = idx - mi*63;
    bufR[mi*65 + ((ni+33)&63)] = src[idx];
  }
  __syncthreads();
  #pragma unroll 2
  for (int j = 0; j < 8; ++j){
    int r = wid*8 + j;
    float2 x = bufR[r*65 + lane];
    x = fft64_lane(x, W, lane);
    bufR[r*65 + rl] = x;
  }
  __syncthreads();
}
__device__ __forceinline__ float2 inv_col_pack(const float2* bufR, int f, int pc){
  float2 r0, r1;
  if (f <= 32){
    r0 = bufR[f*65 + 2*pc];
    r1 = bufR[f*65 + 2*pc + 1];
  } else {
    int g = 64 - f;
    float2 a = bufR[g*65 + 2*pc];
    float2 b = bufR[g*65 + 2*pc + 1];
    r0 = make_float2(a.x, -a.y);
    r1 = make_float2(b.x, -b.y);
  }
  return make_float2(r0.x - r1.y, r0.y + r1.x);
}

// ---------------- ifft2 (Hermitian-packed) + real + bias -> bf16 X ----------------
__global__ __launch_bounds__(TPB) void k_ifft2_sym(const float2* __restrict__ Xt, ushortT* __restrict__ Xo,
                                                   const float* __restrict__ bias, int O){
  __shared__ float2 W[64];
  __shared__ __attribute__((aligned(16))) float2 bufR[33*65];
  __shared__ uintT ldsOut[64*33];
  int bo = blockIdx.x >> 6;
  int o = bo % O;
  init_W(W, 1.f);
  int tid = threadIdx.x, lane = tid & 63, wid = tid >> 6;
  int rl = (int)(__brev((uintT)lane) >> 26);
  const float2* src = Xt + (size_t)blockIdx.x*2016;
  inv_stage_rows(src, bufR, W, lane, wid, rl);
  float bb = bias[o];
  #pragma unroll 2
  for (int j = 0; j < 8; ++j){
    int pc = wid*8 + j;
    float2 w = inv_col_pack(bufR, lane, pc);
    float2 x = fft64_lane(w, W, lane);
    ushortT u0 = f2bf(x.x*(1.f/4096.f) + bb);
    ushortT u1 = f2bf(x.y*(1.f/4096.f) + bb);
    ldsOut[rl*33 + pc] = (uintT)u0 | ((uintT)u1 << 16);
  }
  __syncthreads();
  uintT* dst = (uintT*)(Xo + (size_t)blockIdx.x*4096);
  for (int i = tid; i < 2048; i += TPB){
    int a1 = i >> 5, pc = i & 31;
    dst[i] = ldsOut[a1*33 + pc];
  }
}

// ---------------- conv3 final stats from spectrum (Parseval) ----------------
__global__ __launch_bounds__(TPB) void k_stats3(const float2* __restrict__ Xt, double* __restrict__ part){
  int bo = blockIdx.x, zb = blockIdx.y;
  double s = 0.0, p = 0.0;
  for (int zz = 0; zz < 4; ++zz){
    const float2* pl = Xt + ((size_t)bo*64 + zb*4 + zz)*2016;
    for (int idx = threadIdx.x; idx < 2016; idx += TPB){
      float2 v = pl[idx];
      double q = (double)v.x*v.x + (double)v.y*v.y;
      p += (idx < 63) ? q : 2.0*q;
      if (idx == 31) s += v.x;
    }
  }
  __shared__ double sh[TPB], sh2[TPB];
  sh[threadIdx.x] = s; sh2[threadIdx.x] = p;
  __syncthreads();
  for (int o = 128; o > 0; o >>= 1){
    if (threadIdx.x < o){ sh[threadIdx.x] += sh[threadIdx.x+o]; sh2[threadIdx.x] += sh2[threadIdx.x+o]; }
    __syncthreads();
  }
  if (threadIdx.x == 0){
    part[((size_t)bo*16 + zb)*2 + 0] = sh[0];
    part[((size_t)bo*16 + zb)*2 + 1] = sh2[0];
  }
}

__global__ void k_fstat(const double* __restrict__ part, const float* __restrict__ bias,
                        const float* __restrict__ g, const float* __restrict__ bsh,
                        float2* __restrict__ ss, int O){
  int o = threadIdx.x;
  if (o >= O) return;
  double S = 0.0, P = 0.0;
  for (int b = 0; b < 2; ++b)
    for (int zb = 0; zb < 16; ++zb){
      size_t base = ((size_t)(b*O + o)*16 + zb)*2;
      S += part[base]; P += part[base+1];
    }
  P *= (1.0/4096.0);
  double N = 524288.0;
  double bi = bias[o];
  double mean = S/N + bi;
  double var = P/N + 2.0*bi*S/N + bi*bi - mean*mean;
  double sc = (double)g[o] / sqrt(var + 1e-5);
  ss[o] = make_float2((float)sc, (float)((bi - mean)*sc + (double)bsh[o]));
}

// ---------------- fused ifft2 (Hermitian-packed) + BN + ReLU + mean over gamma ----------------
__global__ __launch_bounds__(TPB) void k_final(const float2* __restrict__ Xt, const float2* __restrict__ ss,
                                               float* __restrict__ out, int O){
  __shared__ float2 W[64];
  __shared__ __attribute__((aligned(16))) float2 bufR[33*65];
  __shared__ float s4[4*64];
  int bo = blockIdx.x >> 6;
  int o = bo % O;
  init_W(W, 1.f);
  int tid = threadIdx.x, lane = tid & 63, wid = tid >> 6;
  int rl = (int)(__brev((uintT)lane) >> 26);
  const float2* src = Xt + (size_t)blockIdx.x*2016;
  inv_stage_rows(src, bufR, W, lane, wid, rl);
  float2 sv = ss[o];
  float acc = 0.f;
  #pragma unroll 2
  for (int j = 0; j < 8; ++j){
    int pc = wid*8 + j;
    float2 w = inv_col_pack(bufR, lane, pc);
    float2 x = fft64_lane(w, W, lane);
    acc += fmaxf(fmaf(x.x*(1.f/4096.f), sv.x, sv.y), 0.f);
    acc += fmaxf(fmaf(x.y*(1.f/4096.f), sv.x, sv.y), 0.f);
  }
  s4[wid*64 + rl] = acc;
  __syncthreads();
  if (tid < 64)
    out[(size_t)blockIdx.x*64 + tid] = (s4[tid] + s4[64+tid] + s4[128+tid] + s4[192+tid]) * (1.f/64.f);
}

extern "C" void kernel_launch(void* const* d_in, const int* in_sizes, int n_in,
                              void* d_out, int out_size, void* d_ws, size_t ws_size,
                              hipStream_t stream){
  const float* x   = (const float*)d_in[0];
  const float* ks2 = (const float*)d_in[1];
  const float* bs2 = (const float*)d_in[2];
  const float* k1  = (const float*)d_in[3];
  const float* b1c = (const float*)d_in[4];
  const float* k2  = (const float*)d_in[5];
  const float* b2c = (const float*)d_in[6];
  const float* k3  = (const float*)d_in[7];
  const float* b3c = (const float*)d_in[8];
  const float* g1 = (const float*)d_in[9],  *bb1 = (const float*)d_in[10];
  const float* g2 = (const float*)d_in[11], *bb2 = (const float*)d_in[12];
  const float* g3 = (const float*)d_in[13], *bb3 = (const float*)d_in[14];
  const float* g4 = (const float*)d_in[15], *bb4 = (const float*)d_in[16];
  float* out = (float*)d_out;

  char* w = (char*)d_ws;
  size_t off = 0;
  auto take = [&](size_t bytes)->char*{
    char* p = w + off;
    off += (bytes + 255) & ~(size_t)255;
    return p;
  };
  float*  Dz   = (float*) take(64ull*32*32*63*4);
  float*  Deq  = (float*) take(32ull*63*63*4);
  double* lf   = (double*)take(65*8);
  double* qw   = (double*)take(64*8);
  double* part = (double*)take(75ull*64*2*8);
  float2* ss   = (float2*)take(75*8);
  float2* KhS2 = (float2*)take(63ull*25*3*8);
  float2* Kh1  = (float2*)take(63ull*25*25*8);
  float2* Kh2  = (float2*)take(63ull*25*50*8);
  float2* Kh3  = (float2*)take(63ull*36*75*8);
  float2* XH2  = (float2*)take(2ull*3*64*63*8);
  float2* F2   = (float2*)take(2ull*3*32*63*8);
  ushortT* X1  = (ushortT*)take(2ull*25*262144*2);
  ushortT* X2  = (ushortT*)take(2ull*25*262144*2);
  ushortT* X3  = (ushortT*)take(2ull*25*262144*2);
  float2* A    = (float2*)take(150ull*32*2016*8);
  float2* B    = (float2*)take(150ull*32*2016*8);
  if (off > ws_size) return;

  dim3 tpb(TPB);
  auto cdiv = [](long long a, long long b){ return (int)((a + b - 1) / b); };

  k_tables<<<1, 64, 0, stream>>>(lf, qw);
  k_wigner<<<dim3(65,32), tpb, 0, stream>>>(lf, Dz, Deq);
  k_kh<<<cdiv(3ll*25*63,TPB),  tpb, 0, stream>>>(ks2, KhS2, 3, 25,  (float)(1.0/sqrt(196608.0)));
  k_kh<<<cdiv(25ll*25*63,TPB), tpb, 0, stream>>>(k1,  Kh1, 25, 25, (float)(1.0/sqrt(1600.0)));
  k_kh<<<cdiv(50ll*25*63,TPB), tpb, 0, stream>>>(k2,  Kh2, 50, 25, (float)(1.0/sqrt(3200.0)));
  k_kh<<<cdiv(75ll*36*63,TPB), tpb, 0, stream>>>(k3,  Kh3, 75, 36, (float)(1.0/sqrt(4800.0)));

  // ---- S2 conv ----
  k_s2_fft<<<cdiv(2ll*3*64*63,TPB), tpb, 0, stream>>>(x, XH2);
  k_s2_F<<<cdiv(2ll*3*32*63,TPB), tpb, 0, stream>>>(Dz, qw, XH2, F2);
  k_s2_zhat<<<cdiv(2ll*25*32*2016,TPB), tpb, 0, stream>>>(Deq, F2, KhS2, B);
  k_wig_synth<<<dim3(32,8,2*cdiv(50,16)), tpb, 0, stream>>>(Dz, B, A, 50);
  k_ifft2_sym<<<50*64, tpb, 0, stream>>>(A, X1, bs2, 25);
  k_bnstats<<<dim3(25,64), tpb, 0, stream>>>(X1, 0, part);

  // ---- generic SO3 conv (stats slots already filled) ----
  auto so3 = [&](const ushortT* Xa, const ushortT* Xb, const ushortT* Xc, int Cin,
                 const float* g, const float* bb, const float2* Kh, int O,
                 const float* bias, ushortT* Xout, int isFinal){
    int BC = 2*Cin, BO = 2*O;
    k_bnfinal<<<1, 128, 0, stream>>>(part, g, bb, ss, Cin);
    k_fft2_fwd<<<dim3(BC,32), tpb, 0, stream>>>(Xa, Xb, Xc, ss, A, Cin, 0);
    k_fft2_fwd<<<dim3(BC,32), tpb, 0, stream>>>(Xa, Xb, Xc, ss, B, Cin, 32);
    k_wig_F<<<dim3(32,8,cdiv(BC,16)), tpb, 0, stream>>>(Dz, qw, A, B, A, BC);   // F in-place over A
    k_deq_C<<<dim3(32,32,cdiv(BC,64)), tpb, 0, stream>>>(Deq, A, B, BC);        // C -> B
    k_kh_z<<<dim3(32,4,cdiv(O,KOC)), tpb, 0, stream>>>(B, Kh, A, Cin, O);       // Z -> A
    k_wig_synth<<<dim3(32,8,2*cdiv(BO,16)), tpb, 0, stream>>>(Dz, A, B, BO);    // Xt -> B
    if (!isFinal){
      k_ifft2_sym<<<BO*64, tpb, 0, stream>>>(B, Xout, bias, O);
    } else {
      k_stats3<<<dim3(BO,16), tpb, 0, stream>>>(B, part);
      k_fstat<<<1, 64, 0, stream>>>(part, bias, g4, bb4, ss, O);
      k_final<<<BO*64, tpb, 0, stream>>>(B, ss, out, O);
    }
  };

  so3(X1, X1, X1, 25, g1, bb1, Kh1, 25, b1c, X2, 0);
  k_bnstats<<<dim3(25,64), tpb, 0, stream>>>(X2, 25, part);
  so3(X1, X2, X2, 50, g2, bb2, Kh2, 25, b2c, X3, 0);
  k_bnstats<<<dim3(25,64), tpb, 0, stream>>>(X3, 50, part);
  so3(X1, X2, X3, 75, g3, bb3, Kh3, 36, b3c, nullptr, 1);
}

// Round 12
// 1413.190 us; speedup vs baseline: 1.7050x; 1.0724x over previous
//
#include <hip/hip_runtime.h>
#include <math.h>

#define PI_D 3.14159265358979323846
#define TPB 256
typedef unsigned short ushortT;
typedef unsigned int uintT;

__device__ __forceinline__ float2 cxmul(float2 a, float2 b){
  return make_float2(a.x*b.x - a.y*b.y, a.x*b.y + a.y*b.x);
}
__device__ __forceinline__ float bf2f(ushortT u){
  uintT x = ((uintT)u) << 16;
  return __uint_as_float(x);
}
__device__ __forceinline__ ushortT f2bf(float f){
  uintT x = __float_as_uint(f);
  x = x + 0x7FFFu + ((x >> 16) & 1u);
  return (ushortT)(x >> 16);
}

// ---------------- tables ----------------
__global__ void k_tables(double* lf, double* qw){
  if (threadIdx.x == 0){
    lf[0] = 0.0;
    for (int i = 1; i <= 64; ++i) lf[i] = lf[i-1] + log((double)i);
  }
  int j = threadIdx.x;
  if (j < 64){
    double s1 = sin(PI_D*(2*j+1)/128.0);
    double inner = 0.0;
    for (int k = 0; k < 32; ++k)
      inner += (1.0/(double)(2*k+1)) * sin((double)(2*j+1)*(double)(2*k+1)*PI_D/128.0);
    qw[j] = (2.0/32.0) * s1 * inner;
  }
}

__device__ double wigd(const double* lfs, int l, int mp, int m, double lc, double ls){
  if (mp < -l || mp > l || m < -l || m > l) return 0.0;
  int k0 = (m - mp > 0) ? (m - mp) : 0;
  int k1 = (l + m < l - mp) ? (l + m) : (l - mp);
  double base = 0.5*(lfs[l+mp] + lfs[l-mp] + lfs[l+m] + lfs[l-m]);
  double val = 0.0;
  for (int k = k0; k <= k1; ++k){
    double t = base - lfs[l+m-k] - lfs[k] - lfs[mp-m+k] - lfs[l-mp-k]
             + (double)(2*l + m - mp - 2*k)*lc + (double)(mp - m + 2*k)*ls;
    double e = exp(t);
    val += ((mp - m + k) & 1) ? -e : e;
  }
  return val;
}

// Dz2[mi][nt][z][l][nn] (n = nt*8+nn, zero pad n=63), D0[z][l][mi] (m=0 col), Deq[l][r][c]
__global__ __launch_bounds__(TPB) void k_wigner(const double* __restrict__ lf,
                                                float* __restrict__ Dz2, float* __restrict__ D0,
                                                float* __restrict__ Deq){
  __shared__ double lfs[65];
  if (threadIdx.x < 65) lfs[threadIdx.x] = lf[threadIdx.x];
  __syncthreads();
  int zs = blockIdx.x, l = blockIdx.y;
  double beta = (zs < 64) ? ((double)zs + 0.5)*PI_D/64.0 : PI_D*0.5;
  double ch = cos(beta*0.5), sh = sin(beta*0.5);
  double lc = log(ch), ls = log(sh);
  if (zs < 64){
    for (int idx = threadIdx.x; idx < 2048; idx += TPB){
      int mi = idx >> 6, nf = idx & 63;
      float v = (nf < 63) ? (float)wigd(lfs, l, mi, nf-31, lc, ls) : 0.f;
      int nt = nf >> 3, nn = nf & 7;
      Dz2[(((size_t)(mi*8 + nt)*64 + zs)*32 + l)*8 + nn] = v;
      if (nf == 31) D0[((size_t)zs*32 + l)*32 + mi] = v;
    }
  } else {
    for (int idx = threadIdx.x; idx < 3969; idx += TPB){
      int r = idx/63, c = idx%63;
      Deq[((size_t)l*63 + r)*63 + c] = (float)wigd(lfs, l, r-31, c-31, lc, ls);
    }
  }
}

// Kh[o][i][n] = scale * sum_p K[i,o,p] * exp(-i*2pi*p*(n-31)/64)
__global__ void k_kh(const float* __restrict__ K, float2* __restrict__ Kh, int I, int O, float scale){
  int idx = blockIdx.x*blockDim.x + threadIdx.x;
  if (idx >= I*O*63) return;
  int n = idx % 63, i = (idx/63) % I, o = idx/(63*I);
  float sr = 0.f, si = 0.f;
  for (int p = 0; p < 64; ++p){
    int t = (p * (n - 31)) & 63;
    float s, c;
    sincosf(-(float)PI_D/32.f * (float)t, &s, &c);
    float kv = K[(i*O + o)*64 + p];
    sr += kv * c; si += kv * s;
  }
  Kh[((size_t)o*I + i)*63 + n] = make_float2(sr*scale, si*scale);
}

// ---------------- S2 front ----------------
__global__ void k_s2_fft(const float* __restrict__ x, float2* __restrict__ XH2){
  int idx = blockIdx.x*blockDim.x + threadIdx.x;
  if (idx >= 2*3*64*63) return;
  int mi = idx % 63; int z = (idx/63) & 63; int bc = idx / (63*64);
  int f = (mi + 33) & 63;
  const float* row = x + ((size_t)bc*64 + z)*64;
  float sr = 0.f, si = 0.f;
  for (int a = 0; a < 64; ++a){
    int t = (f*a) & 63;
    float s, c;
    sincosf(-(float)PI_D/32.f * (float)t, &s, &c);
    sr += row[a]*c; si += row[a]*s;
  }
  XH2[idx] = make_float2(sr, si);
}

__global__ void k_s2_F(const float* __restrict__ D0, const double* __restrict__ qw,
                       const float2* __restrict__ XH2, float2* __restrict__ F2){
  int idx = blockIdx.x*blockDim.x + threadIdx.x;
  if (idx >= 2*3*32*63) return;
  int r = idx % 63; int l = (idx/63) & 31; int bc = idx / (63*32);
  float2 acc = make_float2(0,0);
  for (int z = 0; z < 64; ++z){
    float d;
    if (r >= 31) d = D0[((size_t)z*32 + l)*32 + (r-31)];
    else {
      d = D0[((size_t)z*32 + l)*32 + (31-r)];
      if ((31-r) & 1) d = -d;
    }
    float wv = (float)qw[z] * d;
    float2 v = XH2[((size_t)bc*64 + z)*63 + r];
    acc.x += wv*v.x; acc.y += wv*v.y;
  }
  F2[idx] = acc;
}

__global__ void k_s2_zhat(const float* __restrict__ Deq, const float2* __restrict__ F2,
                          const float2* __restrict__ Kh, float2* __restrict__ Z){
  int idx = blockIdx.x*blockDim.x + threadIdx.x;
  if (idx >= 2*25*32*2016) return;
  int n = idx % 63; int mi = (idx/63) & 31; int l = (idx/2016) & 31;
  int o = (idx/(2016*32)) % 25; int b = idx/(2016*32*25);
  float deq0 = Deq[((size_t)l*63 + n)*63 + 31];
  float2 acc = make_float2(0,0);
  for (int i = 0; i < 3; ++i){
    float2 f = F2[((size_t)(b*3 + i)*32 + l)*63 + (mi+31)];
    float2 kh = Kh[((size_t)(o*3 + i))*63 + n];
    acc.x = fmaf(kh.x, f.x, acc.x); acc.x = fmaf(-kh.y, f.y, acc.x);
    acc.y = fmaf(kh.x, f.y, acc.y); acc.y = fmaf(kh.y, f.x, acc.y);
  }
  Z[((size_t)((b*25+o)*32) + l)*2016 + mi*63 + n] = make_float2(acc.x*deq0, acc.y*deq0);
}

// ---------------- BN stats over bf16 X buffers ----------------
__global__ __launch_bounds__(TPB) void k_bnstats(const ushortT* __restrict__ src, int slotBase,
                                                 double* __restrict__ part){
  int c = blockIdx.x, blk = blockIdx.y;
  const uint2* s4 = (const uint2*)src;
  double s = 0.0, q = 0.0;
  for (int k = 0; k < 8; ++k){
    int g4 = blk*2048 + k*256 + threadIdx.x;
    int b = g4 >> 16, pos4 = g4 & 65535;
    uint2 u = s4[((size_t)(b*25 + c))*65536 + pos4];
    float v0 = bf2f((ushortT)(u.x & 0xffff)), v1 = bf2f((ushortT)(u.x >> 16));
    float v2 = bf2f((ushortT)(u.y & 0xffff)), v3 = bf2f((ushortT)(u.y >> 16));
    s += (double)v0 + v1 + v2 + v3;
    q += (double)v0*v0 + (double)v1*v1 + (double)v2*v2 + (double)v3*v3;
  }
  __shared__ double sh[TPB], sh2[TPB];
  sh[threadIdx.x] = s; sh2[threadIdx.x] = q;
  __syncthreads();
  for (int o = 128; o > 0; o >>= 1){
    if (threadIdx.x < o){ sh[threadIdx.x] += sh[threadIdx.x+o]; sh2[threadIdx.x] += sh2[threadIdx.x+o]; }
    __syncthreads();
  }
  if (threadIdx.x == 0){
    part[((size_t)(slotBase + c)*64 + blk)*2 + 0] = sh[0];
    part[((size_t)(slotBase + c)*64 + blk)*2 + 1] = sh2[0];
  }
}

__global__ void k_bnfinal(const double* __restrict__ part, const float* __restrict__ g,
                          const float* __restrict__ b, float2* __restrict__ ss, int C){
  int c = blockIdx.x*blockDim.x + threadIdx.x;
  if (c >= C) return;
  double s = 0.0, q = 0.0;
  for (int k = 0; k < 64; ++k){
    s += part[((size_t)c*64 + k)*2 + 0];
    q += part[((size_t)c*64 + k)*2 + 1];
  }
  double N = 524288.0;
  double mu = s / N;
  double var = q / N - mu*mu;
  double sc = (double)g[c] / sqrt(var + 1e-5);
  ss[c] = make_float2((float)sc, (float)((double)b[c] - mu*sc));
}

// ---------------- 64-pt FFT across lanes (radix-2 DIF, shfl) ----------------
__device__ __forceinline__ float2 fft64_lane(float2 x, const float2* __restrict__ Wt, int lane){
  #pragma unroll
  for (int st = 0; st < 6; ++st){
    int h = 32 >> st;
    float2 p;
    p.x = __shfl_xor(x.x, h, 64);
    p.y = __shfl_xor(x.y, h, 64);
    if (lane & h){
      float2 s = make_float2(p.x - x.x, p.y - x.y);
      x = cxmul(s, Wt[(lane & (h-1)) << st]);
    } else {
      x = make_float2(x.x + p.x, x.y + p.y);
    }
  }
  return x;
}
__device__ __forceinline__ void init_W(float2* W, float sign){
  if (threadIdx.x < 64){
    float s, c;
    sincosf(sign*(float)(2.0*PI_D/64.0)*(float)threadIdx.x, &s, &c);
    W[threadIdx.x] = make_float2(c, s);
  }
}

// ---------------- fused BN+ReLU + packed real fft2 + reduced extraction ----------------
__global__ __launch_bounds__(TPB) void k_fft2_fwd(const ushortT* __restrict__ X1, const ushortT* __restrict__ X2,
                                                  const ushortT* __restrict__ X3, const float2* __restrict__ ss,
                                                  float2* __restrict__ XH, int Cin, int z0){
  __shared__ float2 W[64];
  __shared__ __attribute__((aligned(16))) float2 smem[4224];   // bufP[64*33] | bufW[64*33]
  float2* bufP = smem;
  float2* bufW = smem + 2112;
  int bc = blockIdx.x, zz = blockIdx.y, z = z0 + zz;
  int b = bc / Cin, ci = bc % Cin;
  const ushortT* src; int cl;
  if (ci < 25){ src = X1; cl = ci; }
  else if (ci < 50){ src = X2; cl = ci - 25; }
  else { src = X3; cl = ci - 50; }
  src += ((size_t)(b*25 + cl)*64 + z)*4096;
  float2 sc = ss[ci];
  init_W(W, -1.f);
  int tid = threadIdx.x, lane = tid & 63, wid = tid >> 6;
  int rl = (int)(__brev((uintT)lane) >> 26);
  const uintT* s32 = (const uintT*)src;
  for (int i = tid; i < 2048; i += TPB){
    uintT u = s32[i];
    float v0 = fmaxf(bf2f((ushortT)(u & 0xffff))*sc.x + sc.y, 0.f);
    float v1 = fmaxf(bf2f((ushortT)(u >> 16))*sc.x + sc.y, 0.f);
    int a1 = i >> 5, c = i & 31;
    bufP[a1*33 + c] = make_float2(v0, v1);
  }
  __syncthreads();
  #pragma unroll 2
  for (int j = 0; j < 8; ++j){
    int c = wid*8 + j;
    float2 x = bufP[lane*33 + c];
    x = fft64_lane(x, W, lane);
    bufW[rl*33 + c] = x;
  }
  __syncthreads();
  for (int i = tid; i < 1024; i += TPB){
    int f1 = i >> 5, c = i & 31;
    float2 Wv = bufW[f1*33 + c];
    float2 Wm = bufW[((64-f1)&63)*33 + c];
    bufP[f1*65 + 2*c]     = make_float2(0.5f*(Wv.x + Wm.x), 0.5f*(Wv.y - Wm.y));
    bufP[f1*65 + 2*c + 1] = make_float2(0.5f*(Wv.y + Wm.y), 0.5f*(Wm.x - Wv.x));
  }
  __syncthreads();
  #pragma unroll 2
  for (int j = 0; j < 8; ++j){
    int r = wid*8 + j;
    float2 x = bufP[r*65 + lane];
    x = fft64_lane(x, W, lane);
    bufP[r*65 + rl] = x;
  }
  __syncthreads();
  float2* dst = XH + ((size_t)bc*32 + zz)*2016;
  for (int idx = tid; idx < 2016; idx += TPB){
    int mi = idx / 63, n = idx % 63;
    dst[idx] = bufP[mi*65 + ((n+33)&63)];
  }
}

// ---------------- F[bc,l,mi,n] = sum_z(all 64) qw*Dz*XH — single pass, F in-place over XHa ----------------
// grid (32 mi, 8 nt, ceil(BC/16)); block 256
#define SKEW(e) ((e) + ((e)>>4))
__global__ __launch_bounds__(TPB) void k_wig_F(const float* __restrict__ Dz2, const double* __restrict__ qw,
                                               const float2* __restrict__ XHa, const float2* __restrict__ XHb,
                                               float2* __restrict__ F, int BC){
  __shared__ __attribute__((aligned(16))) float sm[9088];
  float* Dt = sm;                          // [z16][nn8][l 36pad]
  float2* Xt = (float2*)(sm + 4608);       // [bc16][130]
  int mi = blockIdx.x, nt = blockIdx.y, bcBase = blockIdx.z*16;
  int tid = threadIdx.x;
  int bg = tid & 3, lg = (tid>>2)&7, ng = tid>>5;
  const float* DzB = Dz2 + ((size_t)(mi*8 + nt)*64)*256;
  float2 acc[4][4];
  #pragma unroll
  for (int a = 0; a < 4; ++a)
    #pragma unroll
    for (int j = 0; j < 4; ++j) acc[a][j] = make_float2(0,0);
  for (int chunk = 0; chunk < 4; ++chunk){
    const float2* XH = (chunk < 2) ? XHa : XHb;
    int zq = (chunk & 1)*16;      // z offset within buffer
    int gz0 = chunk*16;           // global z
    __syncthreads();
    for (int idx = tid; idx < 4096; idx += TPB){
      int z = idx >> 8, l = (idx>>3)&31, nn = idx&7;
      float v = DzB[(size_t)gz0*256 + idx] * (float)qw[gz0+z];
      Dt[(z*8+nn)*36 + l] = v;
    }
    for (int idx = tid; idx < 2048; idx += TPB){
      int bc = idx >> 7, z = (idx>>3)&15, nn = idx&7;
      int gbc = bcBase + bc, n = nt*8 + nn;
      float2 v = make_float2(0,0);
      if (gbc < BC && n < 63) v = XH[((size_t)gbc*32 + zq + z)*2016 + mi*63 + n];
      Xt[bc*130 + z*8 + nn] = v;
    }
    __syncthreads();
    #pragma unroll 4
    for (int z = 0; z < 16; ++z){
      const float4 d = *(const float4*)&Dt[(z*8+ng)*36 + lg*4];
      float dd[4] = {d.x, d.y, d.z, d.w};
      float2 xv[4];
      #pragma unroll
      for (int j = 0; j < 4; ++j) xv[j] = Xt[(bg + 4*j)*130 + z*8 + ng];
      #pragma unroll
      for (int j = 0; j < 4; ++j)
        #pragma unroll
        for (int dl = 0; dl < 4; ++dl){
          acc[j][dl].x = fmaf(dd[dl], xv[j].x, acc[j][dl].x);
          acc[j][dl].y = fmaf(dd[dl], xv[j].y, acc[j][dl].y);
        }
    }
  }
  __syncthreads();
  float2* St = (float2*)sm;                // skewed [bc16][l32][nn8]
  #pragma unroll
  for (int j = 0; j < 4; ++j)
    #pragma unroll
    for (int dl = 0; dl < 4; ++dl){
      int e = (bg + 4*j)*256 + (lg*4 + dl)*8 + ng;
      St[SKEW(e)] = acc[j][dl];
    }
  __syncthreads();
  for (int idx = tid; idx < 4096; idx += TPB){
    int bc = idx >> 8, l = (idx>>3)&31, nn = idx&7;
    int gbc = bcBase + bc, n = nt*8 + nn;
    if (gbc < BC && n < 63)
      F[((size_t)(gbc*32 + l))*2016 + mi*63 + n] = St[SKEW(idx)];
  }
}

// ---------------- C[bi,l,mi,n] = sum_k F[bi,l,mi,k]*Deq[l,n,k] — register-tiled ----------------
__global__ __launch_bounds__(TPB) void k_deq_C(const float* __restrict__ Deq, const float2* __restrict__ F,
                                               float2* __restrict__ C, int BC){
  __shared__ __attribute__((aligned(16))) float sm[12604];
  float2* Fb = (float2*)sm;                // [bi64][65pad]
  float* DeqT = sm + 8320;                 // [k63][68pad n]
  int l = blockIdx.x, mi = blockIdx.y, biBase = blockIdx.z*64;
  int tid = threadIdx.x;
  int ngr = tid & 15, big = tid >> 4;
  for (int idx = tid; idx < 3969; idx += TPB){
    int n = idx/63, k = idx - n*63;
    DeqT[k*68 + n] = Deq[((size_t)l*63 + n)*63 + k];
  }
  for (int idx = tid; idx < 4032; idx += TPB){
    int bi = idx/63, k = idx - bi*63;
    int gbi = biBase + bi;
    Fb[bi*65 + k] = (gbi < BC) ? F[((size_t)(gbi*32 + l))*2016 + mi*63 + k] : make_float2(0,0);
  }
  __syncthreads();
  float2 acc[4][4];
  #pragma unroll
  for (int a = 0; a < 4; ++a)
    #pragma unroll
    for (int j = 0; j < 4; ++j) acc[a][j] = make_float2(0,0);
  #pragma unroll 3
  for (int k = 0; k < 63; ++k){
    const float4 d = *(const float4*)&DeqT[k*68 + ngr*4];
    float dd[4] = {d.x, d.y, d.z, d.w};
    float2 fv[4];
    #pragma unroll
    for (int j = 0; j < 4; ++j) fv[j] = Fb[(big + 16*j)*65 + k];
    #pragma unroll
    for (int j = 0; j < 4; ++j)
      #pragma unroll
      for (int dn = 0; dn < 4; ++dn){
        acc[j][dn].x = fmaf(dd[dn], fv[j].x, acc[j][dn].x);
        acc[j][dn].y = fmaf(dd[dn], fv[j].y, acc[j][dn].y);
      }
  }
  __syncthreads();
  float2* St = (float2*)sm;                // [bi64][n63]
  #pragma unroll
  for (int j = 0; j < 4; ++j)
    #pragma unroll
    for (int dn = 0; dn < 4; ++dn){
      int n = ngr*4 + dn;
      if (n < 63) St[(big + 16*j)*63 + n] = acc[j][dn];
    }
  __syncthreads();
  for (int idx = tid; idx < 4032; idx += TPB){
    int bi = idx/63, n = idx - bi*63;
    int gbi = biBase + bi;
    if (gbi < BC) C[((size_t)(gbi*32 + l))*2016 + mi*63 + n] = St[idx];
  }
}

// ---------------- Z[b,o,l,mi,n] = sum_i Kh[o,i,n]*C[b,i,l,mi,n] ----------------
#define KOC 9
__global__ __launch_bounds__(TPB) void k_kh_z(const float2* __restrict__ C, const float2* __restrict__ Kh,
                                              float2* __restrict__ Z, int I, int O){
  __shared__ float2 Kt[KOC*5*64];          // [oo][ic5][n 64pad]
  const int nK = KOC*5*64;                 // 2880
  int l = blockIdx.x, mic = blockIdx.y, oc = blockIdx.z;
  int lane = threadIdx.x & 63, wid = threadIdx.x >> 6;
  int mi0 = mic*8 + wid*2;
  int n = lane;
  int o0 = oc*KOC;
  float2 acc[2][2][KOC];                   // [mi_local][b][oo]
  #pragma unroll
  for (int ml = 0; ml < 2; ++ml)
    #pragma unroll
    for (int b = 0; b < 2; ++b)
      #pragma unroll
      for (int oo = 0; oo < KOC; ++oo) acc[ml][b][oo] = make_float2(0,0);

  float2 pre[12];
  auto loadK = [&](int i0){
    #pragma unroll
    for (int t = 0; t < 12; ++t){
      int idx = threadIdx.x + t*256;
      float2 v = make_float2(0,0);
      if (idx < nK){
        int nn = idx & 63, rem = idx >> 6;
        int ic = rem % 5, oo = rem / 5;
        int o = o0 + oo;
        if (o < O && nn < 63) v = Kh[((size_t)o*I + (i0+ic))*63 + nn];
      }
      pre[t] = v;
    }
  };
  loadK(0);

  size_t cBase0 = ((size_t)l)*2016 + mi0*63 + n;
  size_t cBase1 = cBase0 + 63;
  int nch = I/5;
  for (int c = 0; c < nch; ++c){
    __syncthreads();
    #pragma unroll
    for (int t = 0; t < 12; ++t){
      int idx = threadIdx.x + t*256;
      if (idx < nK) Kt[idx] = pre[t];
    }
    __syncthreads();
    if (c+1 < nch) loadK((c+1)*5);
    if (n < 63){
      int i0 = c*5;
      float2 cv[5][4];
      #pragma unroll
      for (int ic = 0; ic < 5; ++ic){
        int i = i0 + ic;
        cv[ic][0] = C[cBase0 + (size_t)i*64512];
        cv[ic][1] = C[cBase0 + (size_t)(I + i)*64512];
        cv[ic][2] = C[cBase1 + (size_t)i*64512];
        cv[ic][3] = C[cBase1 + (size_t)(I + i)*64512];
      }
      #pragma unroll
      for (int ic = 0; ic < 5; ++ic){
        #pragma unroll
        for (int oo = 0; oo < KOC; ++oo){
          float2 kh = Kt[(oo*5 + ic)*64 + n];
          #pragma unroll
          for (int q = 0; q < 4; ++q){
            float2 cc = cv[ic][q];
            int ml = q >> 1, b = q & 1;
            acc[ml][b][oo].x = fmaf(kh.x, cc.x, acc[ml][b][oo].x);
            acc[ml][b][oo].x = fmaf(-kh.y, cc.y, acc[ml][b][oo].x);
            acc[ml][b][oo].y = fmaf(kh.x, cc.y, acc[ml][b][oo].y);
            acc[ml][b][oo].y = fmaf(kh.y, cc.x, acc[ml][b][oo].y);
          }
        }
      }
    }
  }
  if (n < 63){
    #pragma unroll
    for (int ml = 0; ml < 2; ++ml){
      size_t zBase = ((size_t)l)*2016 + (mi0 + ml)*63 + n;
      #pragma unroll
      for (int oo = 0; oo < KOC; ++oo){
        int o = o0 + oo;
        if (o < O){
          Z[zBase + (size_t)(0*O + o)*64512] = acc[ml][0][oo];
          Z[zBase + (size_t)(1*O + o)*64512] = acc[ml][1][oo];
        }
      }
    }
  }
}

// ---------------- Xt[bo,z,mi,n] = sum_l wl*Dz*Z — register-tiled, skewed epilogue ----------------
__global__ __launch_bounds__(TPB) void k_wig_synth(const float* __restrict__ Dz2, const float2* __restrict__ Z,
                                                   float2* __restrict__ Xt_g, int BO){
  __shared__ __attribute__((aligned(16))) float sm[9088];
  float* Dt = sm;                          // [l16][nn8][z 36pad]
  float2* Zt = (float2*)(sm + 4608);       // [bo16][130]
  int mi = blockIdx.x, nt = blockIdx.y;
  int z0 = (blockIdx.z & 1)*32;
  int boBase = (blockIdx.z >> 1)*16;
  int tid = threadIdx.x;
  int bg = tid & 3, zg = (tid>>2)&7, ng = tid>>5;
  const float* DzB = Dz2 + ((size_t)(mi*8 + nt)*64)*256;
  float2 acc[4][4];
  #pragma unroll
  for (int a = 0; a < 4; ++a)
    #pragma unroll
    for (int j = 0; j < 4; ++j) acc[a][j] = make_float2(0,0);
  for (int lq = 0; lq < 32; lq += 16){
    __syncthreads();
    for (int idx = tid; idx < 4096; idx += TPB){
      int z = idx >> 7, ll = (idx>>3)&15, nn = idx&7;
      int lG = lq + ll;
      float v = DzB[(size_t)(z0+z)*256 + lG*8 + nn] * (0.5f*(float)(2*lG+1));
      Dt[(ll*8+nn)*36 + z] = v;
    }
    for (int idx = tid; idx < 2048; idx += TPB){
      int bo = idx >> 7, ll = (idx>>3)&15, nn = idx&7;
      int gbo = boBase + bo, n = nt*8 + nn;
      float2 v = make_float2(0,0);
      if (gbo < BO && n < 63) v = Z[((size_t)(gbo*32 + lq + ll))*2016 + mi*63 + n];
      Zt[bo*130 + ll*8 + nn] = v;
    }
    __syncthreads();
    #pragma unroll 4
    for (int ll = 0; ll < 16; ++ll){
      const float4 d = *(const float4*)&Dt[(ll*8+ng)*36 + zg*4];
      float dd[4] = {d.x, d.y, d.z, d.w};
      float2 zv[4];
      #pragma unroll
      for (int j = 0; j < 4; ++j) zv[j] = Zt[(bg + 4*j)*130 + ll*8 + ng];
      #pragma unroll
      for (int j = 0; j < 4; ++j)
        #pragma unroll
        for (int dz = 0; dz < 4; ++dz){
          acc[j][dz].x = fmaf(dd[dz], zv[j].x, acc[j][dz].x);
          acc[j][dz].y = fmaf(dd[dz], zv[j].y, acc[j][dz].y);
        }
    }
  }
  __syncthreads();
  float2* St = (float2*)sm;                // skewed [bo16][z32][nn8]
  #pragma unroll
  for (int j = 0; j < 4; ++j)
    #pragma unroll
    for (int dz = 0; dz < 4; ++dz){
      int e = (bg + 4*j)*256 + (zg*4 + dz)*8 + ng;
      St[SKEW(e)] = acc[j][dz];
    }
  __syncthreads();
  for (int idx = tid; idx < 4096; idx += TPB){
    int bo = idx >> 8, z = (idx>>3)&31, nn = idx&7;
    int gbo = boBase + bo, n = nt*8 + nn;
    if (gbo < BO && n < 63)
      Xt_g[((size_t)gbo*64 + z0 + z)*2016 + mi*63 + n] = St[SKEW(idx)];
  }
}

// ---------------- inverse helpers ----------------
__device__ __forceinline__ void inv_stage_rows(const float2* __restrict__ src, float2* bufR,
                                               const float2* W, int lane, int wid, int rl){
  int tid = threadIdx.x;
  if (tid < 64) bufR[32*65 + tid] = make_float2(0,0);
  else if (tid < 96) bufR[(tid-64)*65 + 32] = make_float2(0,0);
  for (int idx = tid; idx < 2016; idx += TPB){
    int mi = idx / 63, ni = idx - mi*63;
    bufR[mi*65 + ((ni+33)&63)] = src[idx];
  }
  __syncthreads();
  #pragma unroll 2
  for (int j = 0; j < 8; ++j){
    int r = wid*8 + j;
    float2 x = bufR[r*65 + lane];
    x = fft64_lane(x, W, lane);
    bufR[r*65 + rl] = x;
  }
  __syncthreads();
}
__device__ __forceinline__ float2 inv_col_pack(const float2* bufR, int f, int pc){
  float2 r0, r1;
  if (f <= 32){
    r0 = bufR[f*65 + 2*pc];
    r1 = bufR[f*65 + 2*pc + 1];
  } else {
    int g = 64 - f;
    float2 a = bufR[g*65 + 2*pc];
    float2 b = bufR[g*65 + 2*pc + 1];
    r0 = make_float2(a.x, -a.y);
    r1 = make_float2(b.x, -b.y);
  }
  return make_float2(r0.x - r1.y, r0.y + r1.x);
}

// ---------------- ifft2 (Hermitian-packed) + real + bias -> bf16 X ----------------
__global__ __launch_bounds__(TPB) void k_ifft2_sym(const float2* __restrict__ Xt, ushortT* __restrict__ Xo,
                                                   const float* __restrict__ bias, int O){
  __shared__ float2 W[64];
  __shared__ __attribute__((aligned(16))) float2 bufR[33*65];
  __shared__ uintT ldsOut[64*33];
  int bo = blockIdx.x >> 6;
  int o = bo % O;
  init_W(W, 1.f);
  int tid = threadIdx.x, lane = tid & 63, wid = tid >> 6;
  int rl = (int)(__brev((uintT)lane) >> 26);
  const float2* src = Xt + (size_t)blockIdx.x*2016;
  inv_stage_rows(src, bufR, W, lane, wid, rl);
  float bb = bias[o];
  #pragma unroll 2
  for (int j = 0; j < 8; ++j){
    int pc = wid*8 + j;
    float2 w = inv_col_pack(bufR, lane, pc);
    float2 x = fft64_lane(w, W, lane);
    ushortT u0 = f2bf(x.x*(1.f/4096.f) + bb);
    ushortT u1 = f2bf(x.y*(1.f/4096.f) + bb);
    ldsOut[rl*33 + pc] = (uintT)u0 | ((uintT)u1 << 16);
  }
  __syncthreads();
  uintT* dst = (uintT*)(Xo + (size_t)blockIdx.x*4096);
  for (int i = tid; i < 2048; i += TPB){
    int a1 = i >> 5, pc = i & 31;
    dst[i] = ldsOut[a1*33 + pc];
  }
}

// ---------------- conv3 final stats from spectrum (Parseval) ----------------
__global__ __launch_bounds__(TPB) void k_stats3(const float2* __restrict__ Xt, double* __restrict__ part){
  int bo = blockIdx.x, zb = blockIdx.y;
  double s = 0.0, p = 0.0;
  for (int zz = 0; zz < 4; ++zz){
    const float2* pl = Xt + ((size_t)bo*64 + zb*4 + zz)*2016;
    for (int idx = threadIdx.x; idx < 2016; idx += TPB){
      float2 v = pl[idx];
      double q = (double)v.x*v.x + (double)v.y*v.y;
      p += (idx < 63) ? q : 2.0*q;
      if (idx == 31) s += v.x;
    }
  }
  __shared__ double sh[TPB], sh2[TPB];
  sh[threadIdx.x] = s; sh2[threadIdx.x] = p;
  __syncthreads();
  for (int o = 128; o > 0; o >>= 1){
    if (threadIdx.x < o){ sh[threadIdx.x] += sh[threadIdx.x+o]; sh2[threadIdx.x] += sh2[threadIdx.x+o]; }
    __syncthreads();
  }
  if (threadIdx.x == 0){
    part[((size_t)bo*16 + zb)*2 + 0] = sh[0];
    part[((size_t)bo*16 + zb)*2 + 1] = sh2[0];
  }
}

__global__ void k_fstat(const double* __restrict__ part, const float* __restrict__ bias,
                        const float* __restrict__ g, const float* __restrict__ bsh,
                        float2* __restrict__ ss, int O){
  int o = threadIdx.x;
  if (o >= O) return;
  double S = 0.0, P = 0.0;
  for (int b = 0; b < 2; ++b)
    for (int zb = 0; zb < 16; ++zb){
      size_t base = ((size_t)(b*O + o)*16 + zb)*2;
      S += part[base]; P += part[base+1];
    }
  P *= (1.0/4096.0);
  double N = 524288.0;
  double bi = bias[o];
  double mean = S/N + bi;
  double var = P/N + 2.0*bi*S/N + bi*bi - mean*mean;
  double sc = (double)g[o] / sqrt(var + 1e-5);
  ss[o] = make_float2((float)sc, (float)((bi - mean)*sc + (double)bsh[o]));
}

// ---------------- fused ifft2 (Hermitian-packed) + BN + ReLU + mean over gamma ----------------
__global__ __launch_bounds__(TPB) void k_final(const float2* __restrict__ Xt, const float2* __restrict__ ss,
                                               float* __restrict__ out, int O){
  __shared__ float2 W[64];
  __shared__ __attribute__((aligned(16))) float2 bufR[33*65];
  __shared__ float s4[4*64];
  int bo = blockIdx.x >> 6;
  int o = bo % O;
  init_W(W, 1.f);
  int tid = threadIdx.x, lane = tid & 63, wid = tid >> 6;
  int rl = (int)(__brev((uintT)lane) >> 26);
  const float2* src = Xt + (size_t)blockIdx.x*2016;
  inv_stage_rows(src, bufR, W, lane, wid, rl);
  float2 sv = ss[o];
  float acc = 0.f;
  #pragma unroll 2
  for (int j = 0; j < 8; ++j){
    int pc = wid*8 + j;
    float2 w = inv_col_pack(bufR, lane, pc);
    float2 x = fft64_lane(w, W, lane);
    acc += fmaxf(fmaf(x.x*(1.f/4096.f), sv.x, sv.y), 0.f);
    acc += fmaxf(fmaf(x.y*(1.f/4096.f), sv.x, sv.y), 0.f);
  }
  s4[wid*64 + rl] = acc;
  __syncthreads();
  if (tid < 64)
    out[(size_t)blockIdx.x*64 + tid] = (s4[tid] + s4[64+tid] + s4[128+tid] + s4[192+tid]) * (1.f/64.f);
}

extern "C" void kernel_launch(void* const* d_in, const int* in_sizes, int n_in,
                              void* d_out, int out_size, void* d_ws, size_t ws_size,
                              hipStream_t stream){
  const float* x   = (const float*)d_in[0];
  const float* ks2 = (const float*)d_in[1];
  const float* bs2 = (const float*)d_in[2];
  const float* k1  = (const float*)d_in[3];
  const float* b1c = (const float*)d_in[4];
  const float* k2  = (const float*)d_in[5];
  const float* b2c = (const float*)d_in[6];
  const float* k3  = (const float*)d_in[7];
  const float* b3c = (const float*)d_in[8];
  const float* g1 = (const float*)d_in[9],  *bb1 = (const float*)d_in[10];
  const float* g2 = (const float*)d_in[11], *bb2 = (const float*)d_in[12];
  const float* g3 = (const float*)d_in[13], *bb3 = (const float*)d_in[14];
  const float* g4 = (const float*)d_in[15], *bb4 = (const float*)d_in[16];
  float* out = (float*)d_out;

  char* w = (char*)d_ws;
  size_t off = 0;
  auto take = [&](size_t bytes)->char*{
    char* p = w + off;
    off += (bytes + 255) & ~(size_t)255;
    return p;
  };
  float*  Dz2  = (float*) take(32ull*8*64*32*8*4);    // 16.8 MB tiled
  float*  D0   = (float*) take(64ull*32*32*4);        // 0.26 MB
  float*  Deq  = (float*) take(32ull*63*63*4);
  double* lf   = (double*)take(65*8);
  double* qw   = (double*)take(64*8);
  double* part = (double*)take(75ull*64*2*8);
  float2* ss   = (float2*)take(75*8);
  float2* KhS2 = (float2*)take(63ull*25*3*8);
  float2* Kh1  = (float2*)take(63ull*25*25*8);
  float2* Kh2  = (float2*)take(63ull*25*50*8);
  float2* Kh3  = (float2*)take(63ull*36*75*8);
  float2* XH2  = (float2*)take(2ull*3*64*63*8);
  float2* F2   = (float2*)take(2ull*3*32*63*8);
  ushortT* X1  = (ushortT*)take(2ull*25*262144*2);
  ushortT* X2  = (ushortT*)take(2ull*25*262144*2);
  ushortT* X3  = (ushortT*)take(2ull*25*262144*2);
  float2* A    = (float2*)take(150ull*32*2016*8);
  float2* B    = (float2*)take(150ull*32*2016*8);
  if (off > ws_size) return;

  dim3 tpb(TPB);
  auto cdiv = [](long long a, long long b){ return (int)((a + b - 1) / b); };

  k_tables<<<1, 64, 0, stream>>>(lf, qw);
  k_wigner<<<dim3(65,32), tpb, 0, stream>>>(lf, Dz2, D0, Deq);
  k_kh<<<cdiv(3ll*25*63,TPB),  tpb, 0, stream>>>(ks2, KhS2, 3, 25,  (float)(1.0/sqrt(196608.0)));
  k_kh<<<cdiv(25ll*25*63,TPB), tpb, 0, stream>>>(k1,  Kh1, 25, 25, (float)(1.0/sqrt(1600.0)));
  k_kh<<<cdiv(50ll*25*63,TPB), tpb, 0, stream>>>(k2,  Kh2, 50, 25, (float)(1.0/sqrt(3200.0)));
  k_kh<<<cdiv(75ll*36*63,TPB), tpb, 0, stream>>>(k3,  Kh3, 75, 36, (float)(1.0/sqrt(4800.0)));

  // ---- S2 conv ----
  k_s2_fft<<<cdiv(2ll*3*64*63,TPB), tpb, 0, stream>>>(x, XH2);
  k_s2_F<<<cdiv(2ll*3*32*63,TPB), tpb, 0, stream>>>(D0, qw, XH2, F2);
  k_s2_zhat<<<cdiv(2ll*25*32*2016,TPB), tpb, 0, stream>>>(Deq, F2, KhS2, B);
  k_wig_synth<<<dim3(32,8,2*cdiv(50,16)), tpb, 0, stream>>>(Dz2, B, A, 50);
  k_ifft2_sym<<<50*64, tpb, 0, stream>>>(A, X1, bs2, 25);
  k_bnstats<<<dim3(25,64), tpb, 0, stream>>>(X1, 0, part);

  // ---- generic SO3 conv (stats slots already filled) ----
  auto so3 = [&](const ushortT* Xa, const ushortT* Xb, const ushortT* Xc, int Cin,
                 const float* g, const float* bb, const float2* Kh, int O,
                 const float* bias, ushortT* Xout, int isFinal){
    int BC = 2*Cin, BO = 2*O;
    k_bnfinal<<<1, 128, 0, stream>>>(part, g, bb, ss, Cin);
    k_fft2_fwd<<<dim3(BC,32), tpb, 0, stream>>>(Xa, Xb, Xc, ss, A, Cin, 0);
    k_fft2_fwd<<<dim3(BC,32), tpb, 0, stream>>>(Xa, Xb, Xc, ss, B, Cin, 32);
    k_wig_F<<<dim3(32,8,cdiv(BC,16)), tpb, 0, stream>>>(Dz2, qw, A, B, A, BC);  // F in-place over A
    k_deq_C<<<dim3(32,32,cdiv(BC,64)), tpb, 0, stream>>>(Deq, A, B, BC);        // C -> B
    k_kh_z<<<dim3(32,4,cdiv(O,KOC)), tpb, 0, stream>>>(B, Kh, A, Cin, O);       // Z -> A
    k_wig_synth<<<dim3(32,8,2*cdiv(BO,16)), tpb, 0, stream>>>(Dz2, A, B, BO);   // Xt -> B
    if (!isFinal){
      k_ifft2_sym<<<BO*64, tpb, 0, stream>>>(B, Xout, bias, O);
    } else {
      k_stats3<<<dim3(BO,16), tpb, 0, stream>>>(B, part);
      k_fstat<<<1, 64, 0, stream>>>(part, bias, g4, bb4, ss, O);
      k_final<<<BO*64, tpb, 0, stream>>>(B, ss, out, O);
    }
  };

  so3(X1, X1, X1, 25, g1, bb1, Kh1, 25, b1c, X2, 0);
  k_bnstats<<<dim3(25,64), tpb, 0, stream>>>(X2, 25, part);
  so3(X1, X2, X2, 50, g2, bb2, Kh2, 25, b2c, X3, 0);
  k_bnstats<<<dim3(25,64), tpb, 0, stream>>>(X3, 50, part);
  so3(X1, X2, X3, 75, g3, bb3, Kh3, 36, b3c, nullptr, 1);
}

// Round 14
// 1399.039 us; speedup vs baseline: 1.7223x; 1.0101x over previous
//
#include <hip/hip_runtime.h>
#include <math.h>

#define PI_D 3.14159265358979323846
#define TPB 256
typedef unsigned short ushortT;
typedef unsigned int uintT;

__device__ __forceinline__ float2 cxmul(float2 a, float2 b){
  return make_float2(a.x*b.x - a.y*b.y, a.x*b.y + a.y*b.x);
}
__device__ __forceinline__ float bf2f(ushortT u){
  uintT x = ((uintT)u) << 16;
  return __uint_as_float(x);
}
__device__ __forceinline__ ushortT f2bf(float f){
  uintT x = __float_as_uint(f);
  x = x + 0x7FFFu + ((x >> 16) & 1u);
  return (ushortT)(x >> 16);
}
__device__ __forceinline__ uintT pk2(float2 v){
  return (uintT)f2bf(v.x) | ((uintT)f2bf(v.y) << 16);
}
__device__ __forceinline__ float2 up2(uintT u){
  return make_float2(bf2f((ushortT)(u & 0xffff)), bf2f((ushortT)(u >> 16)));
}

// ---------------- tables ----------------
__global__ void k_tables(double* lf, double* qw){
  if (threadIdx.x == 0){
    lf[0] = 0.0;
    for (int i = 1; i <= 64; ++i) lf[i] = lf[i-1] + log((double)i);
  }
  int j = threadIdx.x;
  if (j < 64){
    double s1 = sin(PI_D*(2*j+1)/128.0);
    double inner = 0.0;
    for (int k = 0; k < 32; ++k)
      inner += (1.0/(double)(2*k+1)) * sin((double)(2*j+1)*(double)(2*k+1)*PI_D/128.0);
    qw[j] = (2.0/32.0) * s1 * inner;
  }
}

__device__ double wigd(const double* lfs, int l, int mp, int m, double lc, double ls){
  if (mp < -l || mp > l || m < -l || m > l) return 0.0;
  int k0 = (m - mp > 0) ? (m - mp) : 0;
  int k1 = (l + m < l - mp) ? (l + m) : (l - mp);
  double base = 0.5*(lfs[l+mp] + lfs[l-mp] + lfs[l+m] + lfs[l-m]);
  double val = 0.0;
  for (int k = k0; k <= k1; ++k){
    double t = base - lfs[l+m-k] - lfs[k] - lfs[mp-m+k] - lfs[l-mp-k]
             + (double)(2*l + m - mp - 2*k)*lc + (double)(mp - m + 2*k)*ls;
    double e = exp(t);
    val += ((mp - m + k) & 1) ? -e : e;
  }
  return val;
}

// Dz2[mi][nt][z][l][nn] (n = nt*8+nn, zero pad n=63), D0[z][l][mi], Deq[l][r][c]
__global__ __launch_bounds__(TPB) void k_wigner(const double* __restrict__ lf,
                                                float* __restrict__ Dz2, float* __restrict__ D0,
                                                float* __restrict__ Deq){
  __shared__ double lfs[65];
  if (threadIdx.x < 65) lfs[threadIdx.x] = lf[threadIdx.x];
  __syncthreads();
  int zs = blockIdx.x, l = blockIdx.y;
  double beta = (zs < 64) ? ((double)zs + 0.5)*PI_D/64.0 : PI_D*0.5;
  double ch = cos(beta*0.5), sh = sin(beta*0.5);
  double lc = log(ch), ls = log(sh);
  if (zs < 64){
    for (int idx = threadIdx.x; idx < 2048; idx += TPB){
      int mi = idx >> 6, nf = idx & 63;
      float v = (nf < 63) ? (float)wigd(lfs, l, mi, nf-31, lc, ls) : 0.f;
      int nt = nf >> 3, nn = nf & 7;
      Dz2[(((size_t)(mi*8 + nt)*64 + zs)*32 + l)*8 + nn] = v;
      if (nf == 31) D0[((size_t)zs*32 + l)*32 + mi] = v;
    }
  } else {
    for (int idx = threadIdx.x; idx < 3969; idx += TPB){
      int r = idx/63, c = idx%63;
      Deq[((size_t)l*63 + r)*63 + c] = (float)wigd(lfs, l, r-31, c-31, lc, ls);
    }
  }
}

// Kh[o][i][n]
__global__ void k_kh(const float* __restrict__ K, float2* __restrict__ Kh, int I, int O, float scale){
  int idx = blockIdx.x*blockDim.x + threadIdx.x;
  if (idx >= I*O*63) return;
  int n = idx % 63, i = (idx/63) % I, o = idx/(63*I);
  float sr = 0.f, si = 0.f;
  for (int p = 0; p < 64; ++p){
    int t = (p * (n - 31)) & 63;
    float s, c;
    sincosf(-(float)PI_D/32.f * (float)t, &s, &c);
    float kv = K[(i*O + o)*64 + p];
    sr += kv * c; si += kv * s;
  }
  Kh[((size_t)o*I + i)*63 + n] = make_float2(sr*scale, si*scale);
}

// ---------------- S2 front ----------------
__global__ void k_s2_fft(const float* __restrict__ x, float2* __restrict__ XH2){
  int idx = blockIdx.x*blockDim.x + threadIdx.x;
  if (idx >= 2*3*64*63) return;
  int mi = idx % 63; int z = (idx/63) & 63; int bc = idx / (63*64);
  int f = (mi + 33) & 63;
  const float* row = x + ((size_t)bc*64 + z)*64;
  float sr = 0.f, si = 0.f;
  for (int a = 0; a < 64; ++a){
    int t = (f*a) & 63;
    float s, c;
    sincosf(-(float)PI_D/32.f * (float)t, &s, &c);
    sr += row[a]*c; si += row[a]*s;
  }
  XH2[idx] = make_float2(sr, si);
}

__global__ void k_s2_F(const float* __restrict__ D0, const double* __restrict__ qw,
                       const float2* __restrict__ XH2, float2* __restrict__ F2){
  int idx = blockIdx.x*blockDim.x + threadIdx.x;
  if (idx >= 2*3*32*63) return;
  int r = idx % 63; int l = (idx/63) & 31; int bc = idx / (63*32);
  float2 acc = make_float2(0,0);
  for (int z = 0; z < 64; ++z){
    float d;
    if (r >= 31) d = D0[((size_t)z*32 + l)*32 + (r-31)];
    else {
      d = D0[((size_t)z*32 + l)*32 + (31-r)];
      if ((31-r) & 1) d = -d;
    }
    float wv = (float)qw[z] * d;
    float2 v = XH2[((size_t)bc*64 + z)*63 + r];
    acc.x += wv*v.x; acc.y += wv*v.y;
  }
  F2[idx] = acc;
}

__global__ void k_s2_zhat(const float* __restrict__ Deq, const float2* __restrict__ F2,
                          const float2* __restrict__ Kh, uintT* __restrict__ Z){
  int idx = blockIdx.x*blockDim.x + threadIdx.x;
  if (idx >= 2*25*32*2016) return;
  int n = idx % 63; int mi = (idx/63) & 31; int l = (idx/2016) & 31;
  int o = (idx/(2016*32)) % 25; int b = idx/(2016*32*25);
  float deq0 = Deq[((size_t)l*63 + n)*63 + 31];
  float2 acc = make_float2(0,0);
  for (int i = 0; i < 3; ++i){
    float2 f = F2[((size_t)(b*3 + i)*32 + l)*63 + (mi+31)];
    float2 kh = Kh[((size_t)(o*3 + i))*63 + n];
    acc.x = fmaf(kh.x, f.x, acc.x); acc.x = fmaf(-kh.y, f.y, acc.x);
    acc.y = fmaf(kh.x, f.y, acc.y); acc.y = fmaf(kh.y, f.x, acc.y);
  }
  Z[((size_t)((b*25+o)*32) + l)*2016 + mi*63 + n] = pk2(make_float2(acc.x*deq0, acc.y*deq0));
}

// ---------------- BN stats over bf16 X buffers ----------------
__global__ __launch_bounds__(TPB) void k_bnstats(const ushortT* __restrict__ src, int slotBase,
                                                 double* __restrict__ part){
  int c = blockIdx.x, blk = blockIdx.y;
  const uint2* s4 = (const uint2*)src;
  double s = 0.0, q = 0.0;
  for (int k = 0; k < 8; ++k){
    int g4 = blk*2048 + k*256 + threadIdx.x;
    int b = g4 >> 16, pos4 = g4 & 65535;
    uint2 u = s4[((size_t)(b*25 + c))*65536 + pos4];
    float v0 = bf2f((ushortT)(u.x & 0xffff)), v1 = bf2f((ushortT)(u.x >> 16));
    float v2 = bf2f((ushortT)(u.y & 0xffff)), v3 = bf2f((ushortT)(u.y >> 16));
    s += (double)v0 + v1 + v2 + v3;
    q += (double)v0*v0 + (double)v1*v1 + (double)v2*v2 + (double)v3*v3;
  }
  __shared__ double sh[TPB], sh2[TPB];
  sh[threadIdx.x] = s; sh2[threadIdx.x] = q;
  __syncthreads();
  for (int o = 128; o > 0; o >>= 1){
    if (threadIdx.x < o){ sh[threadIdx.x] += sh[threadIdx.x+o]; sh2[threadIdx.x] += sh2[threadIdx.x+o]; }
    __syncthreads();
  }
  if (threadIdx.x == 0){
    part[((size_t)(slotBase + c)*64 + blk)*2 + 0] = sh[0];
    part[((size_t)(slotBase + c)*64 + blk)*2 + 1] = sh2[0];
  }
}

__global__ void k_bnfinal(const double* __restrict__ part, const float* __restrict__ g,
                          const float* __restrict__ b, float2* __restrict__ ss, int C){
  int c = blockIdx.x*blockDim.x + threadIdx.x;
  if (c >= C) return;
  double s = 0.0, q = 0.0;
  for (int k = 0; k < 64; ++k){
    s += part[((size_t)c*64 + k)*2 + 0];
    q += part[((size_t)c*64 + k)*2 + 1];
  }
  double N = 524288.0;
  double mu = s / N;
  double var = q / N - mu*mu;
  double sc = (double)g[c] / sqrt(var + 1e-5);
  ss[c] = make_float2((float)sc, (float)((double)b[c] - mu*sc));
}

// ---------------- 64-pt FFT across lanes ----------------
__device__ __forceinline__ float2 fft64_lane(float2 x, const float2* __restrict__ Wt, int lane){
  #pragma unroll
  for (int st = 0; st < 6; ++st){
    int h = 32 >> st;
    float2 p;
    p.x = __shfl_xor(x.x, h, 64);
    p.y = __shfl_xor(x.y, h, 64);
    if (lane & h){
      float2 s = make_float2(p.x - x.x, p.y - x.y);
      x = cxmul(s, Wt[(lane & (h-1)) << st]);
    } else {
      x = make_float2(x.x + p.x, x.y + p.y);
    }
  }
  return x;
}
__device__ __forceinline__ void init_W(float2* W, float sign){
  if (threadIdx.x < 64){
    float s, c;
    sincosf(sign*(float)(2.0*PI_D/64.0)*(float)threadIdx.x, &s, &c);
    W[threadIdx.x] = make_float2(c, s);
  }
}

// ---------------- fused BN+ReLU + packed real fft2 -> bf16-packed XH ----------------
__global__ __launch_bounds__(TPB) void k_fft2_fwd(const ushortT* __restrict__ X1, const ushortT* __restrict__ X2,
                                                  const ushortT* __restrict__ X3, const float2* __restrict__ ss,
                                                  uintT* __restrict__ XH, int Cin, int z0){
  __shared__ float2 W[64];
  __shared__ __attribute__((aligned(16))) float2 smem[4224];
  float2* bufP = smem;
  float2* bufW = smem + 2112;
  int bc = blockIdx.x, zz = blockIdx.y, z = z0 + zz;
  int b = bc / Cin, ci = bc % Cin;
  const ushortT* src; int cl;
  if (ci < 25){ src = X1; cl = ci; }
  else if (ci < 50){ src = X2; cl = ci - 25; }
  else { src = X3; cl = ci - 50; }
  src += ((size_t)(b*25 + cl)*64 + z)*4096;
  float2 sc = ss[ci];
  init_W(W, -1.f);
  int tid = threadIdx.x, lane = tid & 63, wid = tid >> 6;
  int rl = (int)(__brev((uintT)lane) >> 26);
  const uintT* s32 = (const uintT*)src;
  for (int i = tid; i < 2048; i += TPB){
    uintT u = s32[i];
    float v0 = fmaxf(bf2f((ushortT)(u & 0xffff))*sc.x + sc.y, 0.f);
    float v1 = fmaxf(bf2f((ushortT)(u >> 16))*sc.x + sc.y, 0.f);
    int a1 = i >> 5, c = i & 31;
    bufP[a1*33 + c] = make_float2(v0, v1);
  }
  __syncthreads();
  #pragma unroll 2
  for (int j = 0; j < 8; ++j){
    int c = wid*8 + j;
    float2 x = bufP[lane*33 + c];
    x = fft64_lane(x, W, lane);
    bufW[rl*33 + c] = x;
  }
  __syncthreads();
  for (int i = tid; i < 1024; i += TPB){
    int f1 = i >> 5, c = i & 31;
    float2 Wv = bufW[f1*33 + c];
    float2 Wm = bufW[((64-f1)&63)*33 + c];
    bufP[f1*65 + 2*c]     = make_float2(0.5f*(Wv.x + Wm.x), 0.5f*(Wv.y - Wm.y));
    bufP[f1*65 + 2*c + 1] = make_float2(0.5f*(Wv.y + Wm.y), 0.5f*(Wm.x - Wv.x));
  }
  __syncthreads();
  #pragma unroll 2
  for (int j = 0; j < 8; ++j){
    int r = wid*8 + j;
    float2 x = bufP[r*65 + lane];
    x = fft64_lane(x, W, lane);
    bufP[r*65 + rl] = x;
  }
  __syncthreads();
  uintT* dst = XH + ((size_t)bc*32 + zz)*2016;
  for (int idx = tid; idx < 2016; idx += TPB){
    int mi = idx / 63, n = idx % 63;
    dst[idx] = pk2(bufP[mi*65 + ((n+33)&63)]);
  }
}

// ---------------- F[bc,l,mi,n] = sum_z qw*Dz*XH — bf16-packed XH in, fp32 F out ----------------
#define SKEW(e) ((e) + ((e)>>4))
__global__ __launch_bounds__(TPB) void k_wig_F(const float* __restrict__ Dz2, const double* __restrict__ qw,
                                               const uintT* __restrict__ XHa, const uintT* __restrict__ XHb,
                                               float2* __restrict__ F, int BC){
  __shared__ __attribute__((aligned(16))) float sm[9088];
  float* Dt = sm;                          // [z16][nn8][l 36pad]
  float2* Xt = (float2*)(sm + 4608);       // [bc16][130]
  int mi = blockIdx.x, nt = blockIdx.y, bcBase = blockIdx.z*16;
  int tid = threadIdx.x;
  int bg = tid & 3, lg = (tid>>2)&7, ng = tid>>5;
  const float* DzB = Dz2 + ((size_t)(mi*8 + nt)*64)*256;
  float2 acc[4][4];
  #pragma unroll
  for (int a = 0; a < 4; ++a)
    #pragma unroll
    for (int j = 0; j < 4; ++j) acc[a][j] = make_float2(0,0);
  for (int chunk = 0; chunk < 4; ++chunk){
    const uintT* XH = (chunk < 2) ? XHa : XHb;
    int zq = (chunk & 1)*16;
    int gz0 = chunk*16;
    __syncthreads();
    for (int idx = tid; idx < 4096; idx += TPB){
      int z = idx >> 8;
      float v = DzB[(size_t)gz0*256 + idx] * (float)qw[gz0+z];
      int l = (idx>>3)&31, nn = idx&7;
      Dt[(z*8+nn)*36 + l] = v;
    }
    for (int idx = tid; idx < 2048; idx += TPB){
      int bc = idx >> 7, z = (idx>>3)&15, nn = idx&7;
      int gbc = bcBase + bc, n = nt*8 + nn;
      float2 v = make_float2(0,0);
      if (gbc < BC && n < 63) v = up2(XH[((size_t)gbc*32 + zq + z)*2016 + mi*63 + n]);
      Xt[bc*130 + z*8 + nn] = v;
    }
    __syncthreads();
    #pragma unroll 4
    for (int z = 0; z < 16; ++z){
      const float4 d = *(const float4*)&Dt[(z*8+ng)*36 + lg*4];
      float dd[4] = {d.x, d.y, d.z, d.w};
      float2 xv[4];
      #pragma unroll
      for (int j = 0; j < 4; ++j) xv[j] = Xt[(bg + 4*j)*130 + z*8 + ng];
      #pragma unroll
      for (int j = 0; j < 4; ++j)
        #pragma unroll
        for (int dl = 0; dl < 4; ++dl){
          acc[j][dl].x = fmaf(dd[dl], xv[j].x, acc[j][dl].x);
          acc[j][dl].y = fmaf(dd[dl], xv[j].y, acc[j][dl].y);
        }
    }
  }
  __syncthreads();
  float2* St = (float2*)sm;
  #pragma unroll
  for (int j = 0; j < 4; ++j)
    #pragma unroll
    for (int dl = 0; dl < 4; ++dl){
      int e = (bg + 4*j)*256 + (lg*4 + dl)*8 + ng;
      St[SKEW(e)] = acc[j][dl];
    }
  __syncthreads();
  for (int idx = tid; idx < 4096; idx += TPB){
    int bc = idx >> 8, l = (idx>>3)&31, nn = idx&7;
    int gbc = bcBase + bc, n = nt*8 + nn;
    if (gbc < BC && n < 63)
      F[((size_t)(gbc*32 + l))*2016 + mi*63 + n] = St[SKEW(idx)];
  }
}

// ---------------- C[bi,l,mi,n] = sum_k F[bi,l,mi,k]*Deq[l,n,k] — in-place safe ----------------
__global__ __launch_bounds__(TPB) void k_deq_C(const float* __restrict__ Deq, const float2* __restrict__ F,
                                               float2* __restrict__ C, int BC){
  __shared__ __attribute__((aligned(16))) float sm[12604];
  float2* Fb = (float2*)sm;
  float* DeqT = sm + 8320;
  int l = blockIdx.x, mi = blockIdx.y, biBase = blockIdx.z*64;
  int tid = threadIdx.x;
  int ngr = tid & 15, big = tid >> 4;
  for (int idx = tid; idx < 3969; idx += TPB){
    int n = idx/63, k = idx - n*63;
    DeqT[k*68 + n] = Deq[((size_t)l*63 + n)*63 + k];
  }
  for (int idx = tid; idx < 4032; idx += TPB){
    int bi = idx/63, k = idx - bi*63;
    int gbi = biBase + bi;
    Fb[bi*65 + k] = (gbi < BC) ? F[((size_t)(gbi*32 + l))*2016 + mi*63 + k] : make_float2(0,0);
  }
  __syncthreads();
  float2 acc[4][4];
  #pragma unroll
  for (int a = 0; a < 4; ++a)
    #pragma unroll
    for (int j = 0; j < 4; ++j) acc[a][j] = make_float2(0,0);
  #pragma unroll 3
  for (int k = 0; k < 63; ++k){
    const float4 d = *(const float4*)&DeqT[k*68 + ngr*4];
    float dd[4] = {d.x, d.y, d.z, d.w};
    float2 fv[4];
    #pragma unroll
    for (int j = 0; j < 4; ++j) fv[j] = Fb[(big + 16*j)*65 + k];
    #pragma unroll
    for (int j = 0; j < 4; ++j)
      #pragma unroll
      for (int dn = 0; dn < 4; ++dn){
        acc[j][dn].x = fmaf(dd[dn], fv[j].x, acc[j][dn].x);
        acc[j][dn].y = fmaf(dd[dn], fv[j].y, acc[j][dn].y);
      }
  }
  __syncthreads();
  float2* St = (float2*)sm;
  #pragma unroll
  for (int j = 0; j < 4; ++j)
    #pragma unroll
    for (int dn = 0; dn < 4; ++dn){
      int n = ngr*4 + dn;
      if (n < 63) St[(big + 16*j)*63 + n] = acc[j][dn];
    }
  __syncthreads();
  for (int idx = tid; idx < 4032; idx += TPB){
    int bi = idx/63, n = idx - bi*63;
    int gbi = biBase + bi;
    if (gbi < BC) C[((size_t)(gbi*32 + l))*2016 + mi*63 + n] = St[idx];
  }
}

// ---------------- Z[b,o,l,mi,n] = sum_i Kh[o,i,n]*C[b,i,l,mi,n] — fp32 C in, packed Z out ----------------
#define KOC 9
__global__ __launch_bounds__(TPB) void k_kh_z(const float2* __restrict__ C, const float2* __restrict__ Kh,
                                              uintT* __restrict__ Z, int I, int O){
  __shared__ float2 Kt[KOC*5*64];
  const int nK = KOC*5*64;
  int l = blockIdx.x, mic = blockIdx.y, oc = blockIdx.z;
  int lane = threadIdx.x & 63, wid = threadIdx.x >> 6;
  int mi0 = mic*8 + wid*2;
  int n = lane;
  int o0 = oc*KOC;
  float2 acc[2][2][KOC];
  #pragma unroll
  for (int ml = 0; ml < 2; ++ml)
    #pragma unroll
    for (int b = 0; b < 2; ++b)
      #pragma unroll
      for (int oo = 0; oo < KOC; ++oo) acc[ml][b][oo] = make_float2(0,0);

  float2 pre[12];
  auto loadK = [&](int i0){
    #pragma unroll
    for (int t = 0; t < 12; ++t){
      int idx = threadIdx.x + t*256;
      float2 v = make_float2(0,0);
      if (idx < nK){
        int nn = idx & 63, rem = idx >> 6;
        int ic = rem % 5, oo = rem / 5;
        int o = o0 + oo;
        if (o < O && nn < 63) v = Kh[((size_t)o*I + (i0+ic))*63 + nn];
      }
      pre[t] = v;
    }
  };
  loadK(0);

  size_t cBase0 = ((size_t)l)*2016 + mi0*63 + n;
  size_t cBase1 = cBase0 + 63;
  int nch = I/5;
  for (int c = 0; c < nch; ++c){
    __syncthreads();
    #pragma unroll
    for (int t = 0; t < 12; ++t){
      int idx = threadIdx.x + t*256;
      if (idx < nK) Kt[idx] = pre[t];
    }
    __syncthreads();
    if (c+1 < nch) loadK((c+1)*5);
    if (n < 63){
      int i0 = c*5;
      float2 cv[5][4];
      #pragma unroll
      for (int ic = 0; ic < 5; ++ic){
        int i = i0 + ic;
        cv[ic][0] = C[cBase0 + (size_t)i*64512];
        cv[ic][1] = C[cBase0 + (size_t)(I + i)*64512];
        cv[ic][2] = C[cBase1 + (size_t)i*64512];
        cv[ic][3] = C[cBase1 + (size_t)(I + i)*64512];
      }
      #pragma unroll
      for (int ic = 0; ic < 5; ++ic){
        #pragma unroll
        for (int oo = 0; oo < KOC; ++oo){
          float2 kh = Kt[(oo*5 + ic)*64 + n];
          #pragma unroll
          for (int q = 0; q < 4; ++q){
            float2 cc = cv[ic][q];
            int ml = q >> 1, b = q & 1;
            acc[ml][b][oo].x = fmaf(kh.x, cc.x, acc[ml][b][oo].x);
            acc[ml][b][oo].x = fmaf(-kh.y, cc.y, acc[ml][b][oo].x);
            acc[ml][b][oo].y = fmaf(kh.x, cc.y, acc[ml][b][oo].y);
            acc[ml][b][oo].y = fmaf(kh.y, cc.x, acc[ml][b][oo].y);
          }
        }
      }
    }
  }
  if (n < 63){
    #pragma unroll
    for (int ml = 0; ml < 2; ++ml){
      size_t zBase = ((size_t)l)*2016 + (mi0 + ml)*63 + n;
      #pragma unroll
      for (int oo = 0; oo < KOC; ++oo){
        int o = o0 + oo;
        if (o < O){
          Z[zBase + (size_t)(0*O + o)*64512] = pk2(acc[ml][0][oo]);
          Z[zBase + (size_t)(1*O + o)*64512] = pk2(acc[ml][1][oo]);
        }
      }
    }
  }
}

// ---------------- Xt[bo,z,mi,n] = sum_l wl*Dz*Z — packed Z in, packed Xt out ----------------
__global__ __launch_bounds__(TPB) void k_wig_synth(const float* __restrict__ Dz2, const uintT* __restrict__ Z,
                                                   uintT* __restrict__ Xt_g, int BO){
  __shared__ __attribute__((aligned(16))) float sm[9088];
  float* Dt = sm;                          // [l16][nn8][z 36pad]
  float2* Zt = (float2*)(sm + 4608);       // [bo16][130]
  int mi = blockIdx.x, nt = blockIdx.y;
  int z0 = (blockIdx.z & 1)*32;
  int boBase = (blockIdx.z >> 1)*16;
  int tid = threadIdx.x;
  int bg = tid & 3, zg = (tid>>2)&7, ng = tid>>5;
  const float* DzB = Dz2 + ((size_t)(mi*8 + nt)*64)*256;
  float2 acc[4][4];
  #pragma unroll
  for (int a = 0; a < 4; ++a)
    #pragma unroll
    for (int j = 0; j < 4; ++j) acc[a][j] = make_float2(0,0);
  for (int lq = 0; lq < 32; lq += 16){
    __syncthreads();
    for (int idx = tid; idx < 4096; idx += TPB){
      int z = idx >> 7, ll = (idx>>3)&15, nn = idx&7;
      int lG = lq + ll;
      float v = DzB[(size_t)(z0+z)*256 + lG*8 + nn] * (0.5f*(float)(2*lG+1));
      Dt[(ll*8+nn)*36 + z] = v;
    }
    for (int idx = tid; idx < 2048; idx += TPB){
      int bo = idx >> 7, ll = (idx>>3)&15, nn = idx&7;
      int gbo = boBase + bo, n = nt*8 + nn;
      float2 v = make_float2(0,0);
      if (gbo < BO && n < 63) v = up2(Z[((size_t)(gbo*32 + lq + ll))*2016 + mi*63 + n]);
      Zt[bo*130 + ll*8 + nn] = v;
    }
    __syncthreads();
    #pragma unroll 4
    for (int ll = 0; ll < 16; ++ll){
      const float4 d = *(const float4*)&Dt[(ll*8+ng)*36 + zg*4];
      float dd[4] = {d.x, d.y, d.z, d.w};
      float2 zv[4];
      #pragma unroll
      for (int j = 0; j < 4; ++j) zv[j] = Zt[(bg + 4*j)*130 + ll*8 + ng];
      #pragma unroll
      for (int j = 0; j < 4; ++j)
        #pragma unroll
        for (int dz = 0; dz < 4; ++dz){
          acc[j][dz].x = fmaf(dd[dz], zv[j].x, acc[j][dz].x);
          acc[j][dz].y = fmaf(dd[dz], zv[j].y, acc[j][dz].y);
        }
    }
  }
  __syncthreads();
  float2* St = (float2*)sm;
  #pragma unroll
  for (int j = 0; j < 4; ++j)
    #pragma unroll
    for (int dz = 0; dz < 4; ++dz){
      int e = (bg + 4*j)*256 + (zg*4 + dz)*8 + ng;
      St[SKEW(e)] = acc[j][dz];
    }
  __syncthreads();
  for (int idx = tid; idx < 4096; idx += TPB){
    int bo = idx >> 8, z = (idx>>3)&31, nn = idx&7;
    int gbo = boBase + bo, n = nt*8 + nn;
    if (gbo < BO && n < 63)
      Xt_g[((size_t)gbo*64 + z0 + z)*2016 + mi*63 + n] = pk2(St[SKEW(idx)]);
  }
}

// ---------------- inverse helpers (bf16-packed src) ----------------
__device__ __forceinline__ void inv_stage_rows(const uintT* __restrict__ src, float2* bufR,
                                               const float2* W, int lane, int wid, int rl){
  int tid = threadIdx.x;
  if (tid < 64) bufR[32*65 + tid] = make_float2(0,0);
  else if (tid < 96) bufR[(tid-64)*65 + 32] = make_float2(0,0);
  for (int idx = tid; idx < 2016; idx += TPB){
    int mi = idx / 63, ni = idx - mi*63;
    bufR[mi*65 + ((ni+33)&63)] = up2(src[idx]);
  }
  __syncthreads();
  #pragma unroll 2
  for (int j = 0; j < 8; ++j){
    int r = wid*8 + j;
    float2 x = bufR[r*65 + lane];
    x = fft64_lane(x, W, lane);
    bufR[r*65 + rl] = x;
  }
  __syncthreads();
}
__device__ __forceinline__ float2 inv_col_pack(const float2* bufR, int f, int pc){
  float2 r0, r1;
  if (f <= 32){
    r0 = bufR[f*65 + 2*pc];
    r1 = bufR[f*65 + 2*pc + 1];
  } else {
    int g = 64 - f;
    float2 a = bufR[g*65 + 2*pc];
    float2 b = bufR[g*65 + 2*pc + 1];
    r0 = make_float2(a.x, -a.y);
    r1 = make_float2(b.x, -b.y);
  }
  return make_float2(r0.x - r1.y, r0.y + r1.x);
}

// ---------------- ifft2 + real + bias -> bf16 X ----------------
__global__ __launch_bounds__(TPB) void k_ifft2_sym(const uintT* __restrict__ Xt, ushortT* __restrict__ Xo,
                                                   const float* __restrict__ bias, int O){
  __shared__ float2 W[64];
  __shared__ __attribute__((aligned(16))) float2 bufR[33*65];
  __shared__ uintT ldsOut[64*33];
  int bo = blockIdx.x >> 6;
  int o = bo % O;
  init_W(W, 1.f);
  int tid = threadIdx.x, lane = tid & 63, wid = tid >> 6;
  int rl = (int)(__brev((uintT)lane) >> 26);
  const uintT* src = Xt + (size_t)blockIdx.x*2016;
  inv_stage_rows(src, bufR, W, lane, wid, rl);
  float bb = bias[o];
  #pragma unroll 2
  for (int j = 0; j < 8; ++j){
    int pc = wid*8 + j;
    float2 w = inv_col_pack(bufR, lane, pc);
    float2 x = fft64_lane(w, W, lane);
    ushortT u0 = f2bf(x.x*(1.f/4096.f) + bb);
    ushortT u1 = f2bf(x.y*(1.f/4096.f) + bb);
    ldsOut[rl*33 + pc] = (uintT)u0 | ((uintT)u1 << 16);
  }
  __syncthreads();
  uintT* dst = (uintT*)(Xo + (size_t)blockIdx.x*4096);
  for (int i = tid; i < 2048; i += TPB){
    int a1 = i >> 5, pc = i & 31;
    dst[i] = ldsOut[a1*33 + pc];
  }
}

// ---------------- conv3 final stats from spectrum (Parseval, bf16-packed) ----------------
__global__ __launch_bounds__(TPB) void k_stats3(const uintT* __restrict__ Xt, double* __restrict__ part){
  int bo = blockIdx.x, zb = blockIdx.y;
  double s = 0.0, p = 0.0;
  for (int zz = 0; zz < 4; ++zz){
    const uintT* pl = Xt + ((size_t)bo*64 + zb*4 + zz)*2016;
    for (int idx = threadIdx.x; idx < 2016; idx += TPB){
      float2 v = up2(pl[idx]);
      double q = (double)v.x*v.x + (double)v.y*v.y;
      p += (idx < 63) ? q : 2.0*q;
      if (idx == 31) s += v.x;
    }
  }
  __shared__ double sh[TPB], sh2[TPB];
  sh[threadIdx.x] = s; sh2[threadIdx.x] = p;
  __syncthreads();
  for (int o = 128; o > 0; o >>= 1){
    if (threadIdx.x < o){ sh[threadIdx.x] += sh[threadIdx.x+o]; sh2[threadIdx.x] += sh2[threadIdx.x+o]; }
    __syncthreads();
  }
  if (threadIdx.x == 0){
    part[((size_t)bo*16 + zb)*2 + 0] = sh[0];
    part[((size_t)bo*16 + zb)*2 + 1] = sh2[0];
  }
}

__global__ void k_fstat(const double* __restrict__ part, const float* __restrict__ bias,
                        const float* __restrict__ g, const float* __restrict__ bsh,
                        float2* __restrict__ ss, int O){
  int o = threadIdx.x;
  if (o >= O) return;
  double S = 0.0, P = 0.0;
  for (int b = 0; b < 2; ++b)
    for (int zb = 0; zb < 16; ++zb){
      size_t base = ((size_t)(b*O + o)*16 + zb)*2;
      S += part[base]; P += part[base+1];
    }
  P *= (1.0/4096.0);
  double N = 524288.0;
  double bi = bias[o];
  double mean = S/N + bi;
  double var = P/N + 2.0*bi*S/N + bi*bi - mean*mean;
  double sc = (double)g[o] / sqrt(var + 1e-5);
  ss[o] = make_float2((float)sc, (float)((bi - mean)*sc + (double)bsh[o]));
}

// ---------------- fused ifft2 + BN + ReLU + mean over gamma ----------------
__global__ __launch_bounds__(TPB) void k_final(const uintT* __restrict__ Xt, const float2* __restrict__ ss,
                                               float* __restrict__ out, int O){
  __shared__ float2 W[64];
  __shared__ __attribute__((aligned(16))) float2 bufR[33*65];
  __shared__ float s4[4*64];
  int bo = blockIdx.x >> 6;
  int o = bo % O;
  init_W(W, 1.f);
  int tid = threadIdx.x, lane = tid & 63, wid = tid >> 6;
  int rl = (int)(__brev((uintT)lane) >> 26);
  const uintT* src = Xt + (size_t)blockIdx.x*2016;
  inv_stage_rows(src, bufR, W, lane, wid, rl);
  float2 sv = ss[o];
  float acc = 0.f;
  #pragma unroll 2
  for (int j = 0; j < 8; ++j){
    int pc = wid*8 + j;
    float2 w = inv_col_pack(bufR, lane, pc);
    float2 x = fft64_lane(w, W, lane);
    acc += fmaxf(fmaf(x.x*(1.f/4096.f), sv.x, sv.y), 0.f);
    acc += fmaxf(fmaf(x.y*(1.f/4096.f), sv.x, sv.y), 0.f);
  }
  s4[wid*64 + rl] = acc;
  __syncthreads();
  if (tid < 64)
    out[(size_t)blockIdx.x*64 + tid] = (s4[tid] + s4[64+tid] + s4[128+tid] + s4[192+tid]) * (1.f/64.f);
}

extern "C" void kernel_launch(void* const* d_in, const int* in_sizes, int n_in,
                              void* d_out, int out_size, void* d_ws, size_t ws_size,
                              hipStream_t stream){
  const float* x   = (const float*)d_in[0];
  const float* ks2 = (const float*)d_in[1];
  const float* bs2 = (const float*)d_in[2];
  const float* k1  = (const float*)d_in[3];
  const float* b1c = (const float*)d_in[4];
  const float* k2  = (const float*)d_in[5];
  const float* b2c = (const float*)d_in[6];
  const float* k3  = (const float*)d_in[7];
  const float* b3c = (const float*)d_in[8];
  const float* g1 = (const float*)d_in[9],  *bb1 = (const float*)d_in[10];
  const float* g2 = (const float*)d_in[11], *bb2 = (const float*)d_in[12];
  const float* g3 = (const float*)d_in[13], *bb3 = (const float*)d_in[14];
  const float* g4 = (const float*)d_in[15], *bb4 = (const float*)d_in[16];
  float* out = (float*)d_out;

  char* w = (char*)d_ws;
  size_t off = 0;
  auto take = [&](size_t bytes)->char*{
    char* p = w + off;
    off += (bytes + 255) & ~(size_t)255;
    return p;
  };
  float*  Dz2  = (float*) take(32ull*8*64*32*8*4);    // 16.8 MB tiled
  float*  D0   = (float*) take(64ull*32*32*4);
  float*  Deq  = (float*) take(32ull*63*63*4);
  double* lf   = (double*)take(65*8);
  double* qw   = (double*)take(64*8);
  double* part = (double*)take(75ull*64*2*8);
  float2* ss   = (float2*)take(75*8);
  float2* KhS2 = (float2*)take(63ull*25*3*8);
  float2* Kh1  = (float2*)take(63ull*25*25*8);
  float2* Kh2  = (float2*)take(63ull*25*50*8);
  float2* Kh3  = (float2*)take(63ull*36*75*8);
  float2* XH2  = (float2*)take(2ull*3*64*63*8);
  float2* F2   = (float2*)take(2ull*3*32*63*8);
  ushortT* X1  = (ushortT*)take(2ull*25*262144*2);
  ushortT* X2  = (ushortT*)take(2ull*25*262144*2);
  ushortT* X3  = (ushortT*)take(2ull*25*262144*2);
  uintT*  Ah   = (uintT*) take(150ull*32*2016*4);     // 38.7 MB bf16-packed
  uintT*  Bh   = (uintT*) take(150ull*32*2016*4);
  float2* P    = (float2*)take(150ull*32*2016*8);     // 77.4 MB fp32 (F, C in-place)
  if (off > ws_size) return;

  dim3 tpb(TPB);
  auto cdiv = [](long long a, long long b){ return (int)((a + b - 1) / b); };

  k_tables<<<1, 64, 0, stream>>>(lf, qw);
  k_wigner<<<dim3(65,32), tpb, 0, stream>>>(lf, Dz2, D0, Deq);
  k_kh<<<cdiv(3ll*25*63,TPB),  tpb, 0, stream>>>(ks2, KhS2, 3, 25,  (float)(1.0/sqrt(196608.0)));
  k_kh<<<cdiv(25ll*25*63,TPB), tpb, 0, stream>>>(k1,  Kh1, 25, 25, (float)(1.0/sqrt(1600.0)));
  k_kh<<<cdiv(50ll*25*63,TPB), tpb, 0, stream>>>(k2,  Kh2, 50, 25, (float)(1.0/sqrt(3200.0)));
  k_kh<<<cdiv(75ll*36*63,TPB), tpb, 0, stream>>>(k3,  Kh3, 75, 36, (float)(1.0/sqrt(4800.0)));

  // ---- S2 conv ----
  k_s2_fft<<<cdiv(2ll*3*64*63,TPB), tpb, 0, stream>>>(x, XH2);
  k_s2_F<<<cdiv(2ll*3*32*63,TPB), tpb, 0, stream>>>(D0, qw, XH2, F2);
  k_s2_zhat<<<cdiv(2ll*25*32*2016,TPB), tpb, 0, stream>>>(Deq, F2, KhS2, Ah);
  k_wig_synth<<<dim3(32,8,2*cdiv(50,16)), tpb, 0, stream>>>(Dz2, Ah, Bh, 50);
  k_ifft2_sym<<<50*64, tpb, 0, stream>>>(Bh, X1, bs2, 25);
  k_bnstats<<<dim3(25,64), tpb, 0, stream>>>(X1, 0, part);

  // ---- generic SO3 conv ----
  auto so3 = [&](const ushortT* Xa, const ushortT* Xb, const ushortT* Xc, int Cin,
                 const float* g, const float* bb, const float2* Kh, int O,
                 const float* bias, ushortT* Xout, int isFinal){
    int BC = 2*Cin, BO = 2*O;
    k_bnfinal<<<1, 128, 0, stream>>>(part, g, bb, ss, Cin);
    k_fft2_fwd<<<dim3(BC,32), tpb, 0, stream>>>(Xa, Xb, Xc, ss, Ah, Cin, 0);
    k_fft2_fwd<<<dim3(BC,32), tpb, 0, stream>>>(Xa, Xb, Xc, ss, Bh, Cin, 32);
    k_wig_F<<<dim3(32,8,cdiv(BC,16)), tpb, 0, stream>>>(Dz2, qw, Ah, Bh, P, BC);
    k_deq_C<<<dim3(32,32,cdiv(BC,64)), tpb, 0, stream>>>(Deq, P, P, BC);        // C in-place
    k_kh_z<<<dim3(32,4,cdiv(O,KOC)), tpb, 0, stream>>>(P, Kh, Ah, Cin, O);      // Z packed -> Ah
    k_wig_synth<<<dim3(32,8,2*cdiv(BO,16)), tpb, 0, stream>>>(Dz2, Ah, Bh, BO); // Xt packed -> Bh
    if (!isFinal){
      k_ifft2_sym<<<BO*64, tpb, 0, stream>>>(Bh, Xout, bias, O);
    } else {
      k_stats3<<<dim3(BO,16), tpb, 0, stream>>>(Bh, part);
      k_fstat<<<1, 64, 0, stream>>>(part, bias, g4, bb4, ss, O);
      k_final<<<BO*64, tpb, 0, stream>>>(Bh, ss, out, O);
    }
  };

  so3(X1, X1, X1, 25, g1, bb1, Kh1, 25, b1c, X2, 0);
  k_bnstats<<<dim3(25,64), tpb, 0, stream>>>(X2, 25, part);
  so3(X1, X2, X2, 50, g2, bb2, Kh2, 25, b2c, X3, 0);
  k_bnstats<<<dim3(25,64), tpb, 0, stream>>>(X3, 50, part);
  so3(X1, X2, X3, 75, g3, bb3, Kh3, 36, b3c, nullptr, 1);
}

// Round 15
// 1389.147 us; speedup vs baseline: 1.7346x; 1.0071x over previous
//
#include <hip/hip_runtime.h>
#include <math.h>

#define PI_D 3.14159265358979323846
#define TPB 256
typedef unsigned short ushortT;
typedef unsigned int uintT;

__device__ __forceinline__ float2 cxmul(float2 a, float2 b){
  return make_float2(a.x*b.x - a.y*b.y, a.x*b.y + a.y*b.x);
}
__device__ __forceinline__ float bf2f(ushortT u){
  uintT x = ((uintT)u) << 16;
  return __uint_as_float(x);
}
__device__ __forceinline__ ushortT f2bf(float f){
  uintT x = __float_as_uint(f);
  x = x + 0x7FFFu + ((x >> 16) & 1u);
  return (ushortT)(x >> 16);
}
__device__ __forceinline__ uintT pk2(float2 v){
  return (uintT)f2bf(v.x) | ((uintT)f2bf(v.y) << 16);
}
__device__ __forceinline__ float2 up2(uintT u){
  return make_float2(bf2f((ushortT)(u & 0xffff)), bf2f((ushortT)(u >> 16)));
}

// ---------------- tables ----------------
__global__ void k_tables(double* lf, double* qw){
  if (threadIdx.x == 0){
    lf[0] = 0.0;
    for (int i = 1; i <= 64; ++i) lf[i] = lf[i-1] + log((double)i);
  }
  int j = threadIdx.x;
  if (j < 64){
    double s1 = sin(PI_D*(2*j+1)/128.0);
    double inner = 0.0;
    for (int k = 0; k < 32; ++k)
      inner += (1.0/(double)(2*k+1)) * sin((double)(2*j+1)*(double)(2*k+1)*PI_D/128.0);
    qw[j] = (2.0/32.0) * s1 * inner;
  }
}

__device__ double wigd(const double* lfs, int l, int mp, int m, double lc, double ls){
  if (mp < -l || mp > l || m < -l || m > l) return 0.0;
  int k0 = (m - mp > 0) ? (m - mp) : 0;
  int k1 = (l + m < l - mp) ? (l + m) : (l - mp);
  double base = 0.5*(lfs[l+mp] + lfs[l-mp] + lfs[l+m] + lfs[l-m]);
  double val = 0.0;
  for (int k = k0; k <= k1; ++k){
    double t = base - lfs[l+m-k] - lfs[k] - lfs[mp-m+k] - lfs[l-mp-k]
             + (double)(2*l + m - mp - 2*k)*lc + (double)(mp - m + 2*k)*ls;
    double e = exp(t);
    val += ((mp - m + k) & 1) ? -e : e;
  }
  return val;
}

// Dz2[mi][nt][z][l][nn] (n = nt*8+nn, zero pad n=63), D0[z][l][mi], Deq[l][r][c]
__global__ __launch_bounds__(TPB) void k_wigner(const double* __restrict__ lf,
                                                float* __restrict__ Dz2, float* __restrict__ D0,
                                                float* __restrict__ Deq){
  __shared__ double lfs[65];
  if (threadIdx.x < 65) lfs[threadIdx.x] = lf[threadIdx.x];
  __syncthreads();
  int zs = blockIdx.x, l = blockIdx.y;
  double beta = (zs < 64) ? ((double)zs + 0.5)*PI_D/64.0 : PI_D*0.5;
  double ch = cos(beta*0.5), sh = sin(beta*0.5);
  double lc = log(ch), ls = log(sh);
  if (zs < 64){
    for (int idx = threadIdx.x; idx < 2048; idx += TPB){
      int mi = idx >> 6, nf = idx & 63;
      float v = (nf < 63) ? (float)wigd(lfs, l, mi, nf-31, lc, ls) : 0.f;
      int nt = nf >> 3, nn = nf & 7;
      Dz2[(((size_t)(mi*8 + nt)*64 + zs)*32 + l)*8 + nn] = v;
      if (nf == 31) D0[((size_t)zs*32 + l)*32 + mi] = v;
    }
  } else {
    for (int idx = threadIdx.x; idx < 3969; idx += TPB){
      int r = idx/63, c = idx%63;
      Deq[((size_t)l*63 + r)*63 + c] = (float)wigd(lfs, l, r-31, c-31, lc, ls);
    }
  }
}

// Kh[o][i][n]
__global__ void k_kh(const float* __restrict__ K, float2* __restrict__ Kh, int I, int O, float scale){
  int idx = blockIdx.x*blockDim.x + threadIdx.x;
  if (idx >= I*O*63) return;
  int n = idx % 63, i = (idx/63) % I, o = idx/(63*I);
  float sr = 0.f, si = 0.f;
  for (int p = 0; p < 64; ++p){
    int t = (p * (n - 31)) & 63;
    float s, c;
    sincosf(-(float)PI_D/32.f * (float)t, &s, &c);
    float kv = K[(i*O + o)*64 + p];
    sr += kv * c; si += kv * s;
  }
  Kh[((size_t)o*I + i)*63 + n] = make_float2(sr*scale, si*scale);
}

// ---------------- S2 front ----------------
__global__ void k_s2_fft(const float* __restrict__ x, float2* __restrict__ XH2){
  int idx = blockIdx.x*blockDim.x + threadIdx.x;
  if (idx >= 2*3*64*63) return;
  int mi = idx % 63; int z = (idx/63) & 63; int bc = idx / (63*64);
  int f = (mi + 33) & 63;
  const float* row = x + ((size_t)bc*64 + z)*64;
  float sr = 0.f, si = 0.f;
  for (int a = 0; a < 64; ++a){
    int t = (f*a) & 63;
    float s, c;
    sincosf(-(float)PI_D/32.f * (float)t, &s, &c);
    sr += row[a]*c; si += row[a]*s;
  }
  XH2[idx] = make_float2(sr, si);
}

__global__ void k_s2_F(const float* __restrict__ D0, const double* __restrict__ qw,
                       const float2* __restrict__ XH2, float2* __restrict__ F2){
  int idx = blockIdx.x*blockDim.x + threadIdx.x;
  if (idx >= 2*3*32*63) return;
  int r = idx % 63; int l = (idx/63) & 31; int bc = idx / (63*32);
  float2 acc = make_float2(0,0);
  for (int z = 0; z < 64; ++z){
    float d;
    if (r >= 31) d = D0[((size_t)z*32 + l)*32 + (r-31)];
    else {
      d = D0[((size_t)z*32 + l)*32 + (31-r)];
      if ((31-r) & 1) d = -d;
    }
    float wv = (float)qw[z] * d;
    float2 v = XH2[((size_t)bc*64 + z)*63 + r];
    acc.x += wv*v.x; acc.y += wv*v.y;
  }
  F2[idx] = acc;
}

__global__ void k_s2_zhat(const float* __restrict__ Deq, const float2* __restrict__ F2,
                          const float2* __restrict__ Kh, uintT* __restrict__ Z){
  int idx = blockIdx.x*blockDim.x + threadIdx.x;
  if (idx >= 2*25*32*2016) return;
  int n = idx % 63; int mi = (idx/63) & 31; int l = (idx/2016) & 31;
  int o = (idx/(2016*32)) % 25; int b = idx/(2016*32*25);
  float deq0 = Deq[((size_t)l*63 + n)*63 + 31];
  float2 acc = make_float2(0,0);
  for (int i = 0; i < 3; ++i){
    float2 f = F2[((size_t)(b*3 + i)*32 + l)*63 + (mi+31)];
    float2 kh = Kh[((size_t)(o*3 + i))*63 + n];
    acc.x = fmaf(kh.x, f.x, acc.x); acc.x = fmaf(-kh.y, f.y, acc.x);
    acc.y = fmaf(kh.x, f.y, acc.y); acc.y = fmaf(kh.y, f.x, acc.y);
  }
  Z[((size_t)((b*25+o)*32) + l)*2016 + mi*63 + n] = pk2(make_float2(acc.x*deq0, acc.y*deq0));
}

// ---------------- BN stats over bf16 X buffers ----------------
__global__ __launch_bounds__(TPB) void k_bnstats(const ushortT* __restrict__ src, int slotBase,
                                                 double* __restrict__ part){
  int c = blockIdx.x, blk = blockIdx.y;
  const uint2* s4 = (const uint2*)src;
  double s = 0.0, q = 0.0;
  for (int k = 0; k < 8; ++k){
    int g4 = blk*2048 + k*256 + threadIdx.x;
    int b = g4 >> 16, pos4 = g4 & 65535;
    uint2 u = s4[((size_t)(b*25 + c))*65536 + pos4];
    float v0 = bf2f((ushortT)(u.x & 0xffff)), v1 = bf2f((ushortT)(u.x >> 16));
    float v2 = bf2f((ushortT)(u.y & 0xffff)), v3 = bf2f((ushortT)(u.y >> 16));
    s += (double)v0 + v1 + v2 + v3;
    q += (double)v0*v0 + (double)v1*v1 + (double)v2*v2 + (double)v3*v3;
  }
  __shared__ double sh[TPB], sh2[TPB];
  sh[threadIdx.x] = s; sh2[threadIdx.x] = q;
  __syncthreads();
  for (int o = 128; o > 0; o >>= 1){
    if (threadIdx.x < o){ sh[threadIdx.x] += sh[threadIdx.x+o]; sh2[threadIdx.x] += sh2[threadIdx.x+o]; }
    __syncthreads();
  }
  if (threadIdx.x == 0){
    part[((size_t)(slotBase + c)*64 + blk)*2 + 0] = sh[0];
    part[((size_t)(slotBase + c)*64 + blk)*2 + 1] = sh2[0];
  }
}

__global__ void k_bnfinal(const double* __restrict__ part, const float* __restrict__ g,
                          const float* __restrict__ b, float2* __restrict__ ss, int C){
  int c = blockIdx.x*blockDim.x + threadIdx.x;
  if (c >= C) return;
  double s = 0.0, q = 0.0;
  for (int k = 0; k < 64; ++k){
    s += part[((size_t)c*64 + k)*2 + 0];
    q += part[((size_t)c*64 + k)*2 + 1];
  }
  double N = 524288.0;
  double mu = s / N;
  double var = q / N - mu*mu;
  double sc = (double)g[c] / sqrt(var + 1e-5);
  ss[c] = make_float2((float)sc, (float)((double)b[c] - mu*sc));
}

// ---------------- 64-pt FFT across lanes ----------------
__device__ __forceinline__ float2 fft64_lane(float2 x, const float2* __restrict__ Wt, int lane){
  #pragma unroll
  for (int st = 0; st < 6; ++st){
    int h = 32 >> st;
    float2 p;
    p.x = __shfl_xor(x.x, h, 64);
    p.y = __shfl_xor(x.y, h, 64);
    if (lane & h){
      float2 s = make_float2(p.x - x.x, p.y - x.y);
      x = cxmul(s, Wt[(lane & (h-1)) << st]);
    } else {
      x = make_float2(x.x + p.x, x.y + p.y);
    }
  }
  return x;
}
__device__ __forceinline__ void init_W(float2* W, float sign){
  if (threadIdx.x < 64){
    float s, c;
    sincosf(sign*(float)(2.0*PI_D/64.0)*(float)threadIdx.x, &s, &c);
    W[threadIdx.x] = make_float2(c, s);
  }
}

// ---------------- fused BN+ReLU + packed real fft2 -> bf16-packed XH ----------------
__global__ __launch_bounds__(TPB) void k_fft2_fwd(const ushortT* __restrict__ X1, const ushortT* __restrict__ X2,
                                                  const ushortT* __restrict__ X3, const float2* __restrict__ ss,
                                                  uintT* __restrict__ XH, int Cin, int z0){
  __shared__ float2 W[64];
  __shared__ __attribute__((aligned(16))) float2 smem[4224];
  float2* bufP = smem;
  float2* bufW = smem + 2112;
  int bc = blockIdx.x, zz = blockIdx.y, z = z0 + zz;
  int b = bc / Cin, ci = bc % Cin;
  const ushortT* src; int cl;
  if (ci < 25){ src = X1; cl = ci; }
  else if (ci < 50){ src = X2; cl = ci - 25; }
  else { src = X3; cl = ci - 50; }
  src += ((size_t)(b*25 + cl)*64 + z)*4096;
  float2 sc = ss[ci];
  init_W(W, -1.f);
  int tid = threadIdx.x, lane = tid & 63, wid = tid >> 6;
  int rl = (int)(__brev((uintT)lane) >> 26);
  const uintT* s32 = (const uintT*)src;
  for (int i = tid; i < 2048; i += TPB){
    uintT u = s32[i];
    float v0 = fmaxf(bf2f((ushortT)(u & 0xffff))*sc.x + sc.y, 0.f);
    float v1 = fmaxf(bf2f((ushortT)(u >> 16))*sc.x + sc.y, 0.f);
    int a1 = i >> 5, c = i & 31;
    bufP[a1*33 + c] = make_float2(v0, v1);
  }
  __syncthreads();
  #pragma unroll 2
  for (int j = 0; j < 8; ++j){
    int c = wid*8 + j;
    float2 x = bufP[lane*33 + c];
    x = fft64_lane(x, W, lane);
    bufW[rl*33 + c] = x;
  }
  __syncthreads();
  for (int i = tid; i < 1024; i += TPB){
    int f1 = i >> 5, c = i & 31;
    float2 Wv = bufW[f1*33 + c];
    float2 Wm = bufW[((64-f1)&63)*33 + c];
    bufP[f1*65 + 2*c]     = make_float2(0.5f*(Wv.x + Wm.x), 0.5f*(Wv.y - Wm.y));
    bufP[f1*65 + 2*c + 1] = make_float2(0.5f*(Wv.y + Wm.y), 0.5f*(Wm.x - Wv.x));
  }
  __syncthreads();
  #pragma unroll 2
  for (int j = 0; j < 8; ++j){
    int r = wid*8 + j;
    float2 x = bufP[r*65 + lane];
    x = fft64_lane(x, W, lane);
    bufP[r*65 + rl] = x;
  }
  __syncthreads();
  uintT* dst = XH + ((size_t)bc*32 + zz)*2016;
  for (int idx = tid; idx < 2016; idx += TPB){
    int mi = idx / 63, n = idx % 63;
    dst[idx] = pk2(bufP[mi*65 + ((n+33)&63)]);
  }
}

// ---------------- F[bc,l,mi,n] = sum_z qw*Dz*XH — packed in, packed out ----------------
#define SKEW(e) ((e) + ((e)>>4))
__global__ __launch_bounds__(TPB) void k_wig_F(const float* __restrict__ Dz2, const double* __restrict__ qw,
                                               const uintT* __restrict__ XHa, const uintT* __restrict__ XHb,
                                               uintT* __restrict__ F, int BC){
  __shared__ __attribute__((aligned(16))) float sm[9088];
  float* Dt = sm;                          // [z16][nn8][l 36pad]
  float2* Xt = (float2*)(sm + 4608);       // [bc16][130]
  int mi = blockIdx.x, nt = blockIdx.y, bcBase = blockIdx.z*16;
  int tid = threadIdx.x;
  int bg = tid & 3, lg = (tid>>2)&7, ng = tid>>5;
  const float* DzB = Dz2 + ((size_t)(mi*8 + nt)*64)*256;
  float2 acc[4][4];
  #pragma unroll
  for (int a = 0; a < 4; ++a)
    #pragma unroll
    for (int j = 0; j < 4; ++j) acc[a][j] = make_float2(0,0);
  for (int chunk = 0; chunk < 4; ++chunk){
    const uintT* XH = (chunk < 2) ? XHa : XHb;
    int zq = (chunk & 1)*16;
    int gz0 = chunk*16;
    __syncthreads();
    for (int idx = tid; idx < 4096; idx += TPB){
      int z = idx >> 8;
      float v = DzB[(size_t)gz0*256 + idx] * (float)qw[gz0+z];
      int l = (idx>>3)&31, nn = idx&7;
      Dt[(z*8+nn)*36 + l] = v;
    }
    for (int idx = tid; idx < 2048; idx += TPB){
      int bc = idx >> 7, z = (idx>>3)&15, nn = idx&7;
      int gbc = bcBase + bc, n = nt*8 + nn;
      float2 v = make_float2(0,0);
      if (gbc < BC && n < 63) v = up2(XH[((size_t)gbc*32 + zq + z)*2016 + mi*63 + n]);
      Xt[bc*130 + z*8 + nn] = v;
    }
    __syncthreads();
    #pragma unroll 4
    for (int z = 0; z < 16; ++z){
      const float4 d = *(const float4*)&Dt[(z*8+ng)*36 + lg*4];
      float dd[4] = {d.x, d.y, d.z, d.w};
      float2 xv[4];
      #pragma unroll
      for (int j = 0; j < 4; ++j) xv[j] = Xt[(bg + 4*j)*130 + z*8 + ng];
      #pragma unroll
      for (int j = 0; j < 4; ++j)
        #pragma unroll
        for (int dl = 0; dl < 4; ++dl){
          acc[j][dl].x = fmaf(dd[dl], xv[j].x, acc[j][dl].x);
          acc[j][dl].y = fmaf(dd[dl], xv[j].y, acc[j][dl].y);
        }
    }
  }
  __syncthreads();
  float2* St = (float2*)sm;
  #pragma unroll
  for (int j = 0; j < 4; ++j)
    #pragma unroll
    for (int dl = 0; dl < 4; ++dl){
      int e = (bg + 4*j)*256 + (lg*4 + dl)*8 + ng;
      St[SKEW(e)] = acc[j][dl];
    }
  __syncthreads();
  for (int idx = tid; idx < 4096; idx += TPB){
    int bc = idx >> 8, l = (idx>>3)&31, nn = idx&7;
    int gbc = bcBase + bc, n = nt*8 + nn;
    if (gbc < BC && n < 63)
      F[((size_t)(gbc*32 + l))*2016 + mi*63 + n] = pk2(St[SKEW(idx)]);
  }
}

// ---------------- C[bi,l,mi,n] = sum_k F[bi,l,mi,k]*Deq[l,n,k] — packed in/out, in-place safe ----------------
__global__ __launch_bounds__(TPB) void k_deq_C(const float* __restrict__ Deq, const uintT* __restrict__ F,
                                               uintT* __restrict__ C, int BC){
  __shared__ __attribute__((aligned(16))) float sm[12604];
  float2* Fb = (float2*)sm;
  float* DeqT = sm + 8320;
  int l = blockIdx.x, mi = blockIdx.y, biBase = blockIdx.z*64;
  int tid = threadIdx.x;
  int ngr = tid & 15, big = tid >> 4;
  for (int idx = tid; idx < 3969; idx += TPB){
    int n = idx/63, k = idx - n*63;
    DeqT[k*68 + n] = Deq[((size_t)l*63 + n)*63 + k];
  }
  for (int idx = tid; idx < 4032; idx += TPB){
    int bi = idx/63, k = idx - bi*63;
    int gbi = biBase + bi;
    Fb[bi*65 + k] = (gbi < BC) ? up2(F[((size_t)(gbi*32 + l))*2016 + mi*63 + k]) : make_float2(0,0);
  }
  __syncthreads();
  float2 acc[4][4];
  #pragma unroll
  for (int a = 0; a < 4; ++a)
    #pragma unroll
    for (int j = 0; j < 4; ++j) acc[a][j] = make_float2(0,0);
  #pragma unroll 3
  for (int k = 0; k < 63; ++k){
    const float4 d = *(const float4*)&DeqT[k*68 + ngr*4];
    float dd[4] = {d.x, d.y, d.z, d.w};
    float2 fv[4];
    #pragma unroll
    for (int j = 0; j < 4; ++j) fv[j] = Fb[(big + 16*j)*65 + k];
    #pragma unroll
    for (int j = 0; j < 4; ++j)
      #pragma unroll
      for (int dn = 0; dn < 4; ++dn){
        acc[j][dn].x = fmaf(dd[dn], fv[j].x, acc[j][dn].x);
        acc[j][dn].y = fmaf(dd[dn], fv[j].y, acc[j][dn].y);
      }
  }
  __syncthreads();
  float2* St = (float2*)sm;
  #pragma unroll
  for (int j = 0; j < 4; ++j)
    #pragma unroll
    for (int dn = 0; dn < 4; ++dn){
      int n = ngr*4 + dn;
      if (n < 63) St[(big + 16*j)*63 + n] = acc[j][dn];
    }
  __syncthreads();
  for (int idx = tid; idx < 4032; idx += TPB){
    int bi = idx/63, n = idx - bi*63;
    int gbi = biBase + bi;
    if (gbi < BC) C[((size_t)(gbi*32 + l))*2016 + mi*63 + n] = pk2(St[idx]);
  }
}

// ---------------- Z[b,o,l,mi,n] = sum_i Kh[o,i,n]*C[b,i,l,mi,n] — packed C in, packed Z out ----------------
#define KOC 9
__global__ __launch_bounds__(TPB) void k_kh_z(const uintT* __restrict__ C, const float2* __restrict__ Kh,
                                              uintT* __restrict__ Z, int I, int O){
  __shared__ float2 Kt[KOC*5*64];
  const int nK = KOC*5*64;
  int l = blockIdx.x, mic = blockIdx.y, oc = blockIdx.z;
  int lane = threadIdx.x & 63, wid = threadIdx.x >> 6;
  int mi0 = mic*8 + wid*2;
  int n = lane;
  int o0 = oc*KOC;
  float2 acc[2][2][KOC];
  #pragma unroll
  for (int ml = 0; ml < 2; ++ml)
    #pragma unroll
    for (int b = 0; b < 2; ++b)
      #pragma unroll
      for (int oo = 0; oo < KOC; ++oo) acc[ml][b][oo] = make_float2(0,0);

  float2 pre[12];
  auto loadK = [&](int i0){
    #pragma unroll
    for (int t = 0; t < 12; ++t){
      int idx = threadIdx.x + t*256;
      float2 v = make_float2(0,0);
      if (idx < nK){
        int nn = idx & 63, rem = idx >> 6;
        int ic = rem % 5, oo = rem / 5;
        int o = o0 + oo;
        if (o < O && nn < 63) v = Kh[((size_t)o*I + (i0+ic))*63 + nn];
      }
      pre[t] = v;
    }
  };
  loadK(0);

  size_t cBase0 = ((size_t)l)*2016 + mi0*63 + n;
  size_t cBase1 = cBase0 + 63;
  int nch = I/5;
  for (int c = 0; c < nch; ++c){
    __syncthreads();
    #pragma unroll
    for (int t = 0; t < 12; ++t){
      int idx = threadIdx.x + t*256;
      if (idx < nK) Kt[idx] = pre[t];
    }
    __syncthreads();
    if (c+1 < nch) loadK((c+1)*5);
    if (n < 63){
      int i0 = c*5;
      float2 cv[5][4];
      #pragma unroll
      for (int ic = 0; ic < 5; ++ic){
        int i = i0 + ic;
        cv[ic][0] = up2(C[cBase0 + (size_t)i*64512]);
        cv[ic][1] = up2(C[cBase0 + (size_t)(I + i)*64512]);
        cv[ic][2] = up2(C[cBase1 + (size_t)i*64512]);
        cv[ic][3] = up2(C[cBase1 + (size_t)(I + i)*64512]);
      }
      #pragma unroll
      for (int ic = 0; ic < 5; ++ic){
        #pragma unroll
        for (int oo = 0; oo < KOC; ++oo){
          float2 kh = Kt[(oo*5 + ic)*64 + n];
          #pragma unroll
          for (int q = 0; q < 4; ++q){
            float2 cc = cv[ic][q];
            int ml = q >> 1, b = q & 1;
            acc[ml][b][oo].x = fmaf(kh.x, cc.x, acc[ml][b][oo].x);
            acc[ml][b][oo].x = fmaf(-kh.y, cc.y, acc[ml][b][oo].x);
            acc[ml][b][oo].y = fmaf(kh.x, cc.y, acc[ml][b][oo].y);
            acc[ml][b][oo].y = fmaf(kh.y, cc.x, acc[ml][b][oo].y);
          }
        }
      }
    }
  }
  if (n < 63){
    #pragma unroll
    for (int ml = 0; ml < 2; ++ml){
      size_t zBase = ((size_t)l)*2016 + (mi0 + ml)*63 + n;
      #pragma unroll
      for (int oo = 0; oo < KOC; ++oo){
        int o = o0 + oo;
        if (o < O){
          Z[zBase + (size_t)(0*O + o)*64512] = pk2(acc[ml][0][oo]);
          Z[zBase + (size_t)(1*O + o)*64512] = pk2(acc[ml][1][oo]);
        }
      }
    }
  }
}

// ---------------- Xt[bo,z,mi,n] = sum_l wl*Dz*Z — packed Z in, packed Xt out ----------------
__global__ __launch_bounds__(TPB) void k_wig_synth(const float* __restrict__ Dz2, const uintT* __restrict__ Z,
                                                   uintT* __restrict__ Xt_g, int BO){
  __shared__ __attribute__((aligned(16))) float sm[9088];
  float* Dt = sm;                          // [l16][nn8][z 36pad]
  float2* Zt = (float2*)(sm + 4608);       // [bo16][130]
  int mi = blockIdx.x, nt = blockIdx.y;
  int z0 = (blockIdx.z & 1)*32;
  int boBase = (blockIdx.z >> 1)*16;
  int tid = threadIdx.x;
  int bg = tid & 3, zg = (tid>>2)&7, ng = tid>>5;
  const float* DzB = Dz2 + ((size_t)(mi*8 + nt)*64)*256;
  float2 acc[4][4];
  #pragma unroll
  for (int a = 0; a < 4; ++a)
    #pragma unroll
    for (int j = 0; j < 4; ++j) acc[a][j] = make_float2(0,0);
  for (int lq = 0; lq < 32; lq += 16){
    __syncthreads();
    for (int idx = tid; idx < 4096; idx += TPB){
      int z = idx >> 7, ll = (idx>>3)&15, nn = idx&7;
      int lG = lq + ll;
      float v = DzB[(size_t)(z0+z)*256 + lG*8 + nn] * (0.5f*(float)(2*lG+1));
      Dt[(ll*8+nn)*36 + z] = v;
    }
    for (int idx = tid; idx < 2048; idx += TPB){
      int bo = idx >> 7, ll = (idx>>3)&15, nn = idx&7;
      int gbo = boBase + bo, n = nt*8 + nn;
      float2 v = make_float2(0,0);
      if (gbo < BO && n < 63) v = up2(Z[((size_t)(gbo*32 + lq + ll))*2016 + mi*63 + n]);
      Zt[bo*130 + ll*8 + nn] = v;
    }
    __syncthreads();
    #pragma unroll 4
    for (int ll = 0; ll < 16; ++ll){
      const float4 d = *(const float4*)&Dt[(ll*8+ng)*36 + zg*4];
      float dd[4] = {d.x, d.y, d.z, d.w};
      float2 zv[4];
      #pragma unroll
      for (int j = 0; j < 4; ++j) zv[j] = Zt[(bg + 4*j)*130 + ll*8 + ng];
      #pragma unroll
      for (int j = 0; j < 4; ++j)
        #pragma unroll
        for (int dz = 0; dz < 4; ++dz){
          acc[j][dz].x = fmaf(dd[dz], zv[j].x, acc[j][dz].x);
          acc[j][dz].y = fmaf(dd[dz], zv[j].y, acc[j][dz].y);
        }
    }
  }
  __syncthreads();
  float2* St = (float2*)sm;
  #pragma unroll
  for (int j = 0; j < 4; ++j)
    #pragma unroll
    for (int dz = 0; dz < 4; ++dz){
      int e = (bg + 4*j)*256 + (zg*4 + dz)*8 + ng;
      St[SKEW(e)] = acc[j][dz];
    }
  __syncthreads();
  for (int idx = tid; idx < 4096; idx += TPB){
    int bo = idx >> 8, z = (idx>>3)&31, nn = idx&7;
    int gbo = boBase + bo, n = nt*8 + nn;
    if (gbo < BO && n < 63)
      Xt_g[((size_t)gbo*64 + z0 + z)*2016 + mi*63 + n] = pk2(St[SKEW(idx)]);
  }
}

// ---------------- inverse helpers (bf16-packed src) ----------------
__device__ __forceinline__ void inv_stage_rows(const uintT* __restrict__ src, float2* bufR,
                                               const float2* W, int lane, int wid, int rl){
  int tid = threadIdx.x;
  if (tid < 64) bufR[32*65 + tid] = make_float2(0,0);
  else if (tid < 96) bufR[(tid-64)*65 + 32] = make_float2(0,0);
  for (int idx = tid; idx < 2016; idx += TPB){
    int mi = idx / 63, ni = idx - mi*63;
    bufR[mi*65 + ((ni+33)&63)] = up2(src[idx]);
  }
  __syncthreads();
  #pragma unroll 2
  for (int j = 0; j < 8; ++j){
    int r = wid*8 + j;
    float2 x = bufR[r*65 + lane];
    x = fft64_lane(x, W, lane);
    bufR[r*65 + rl] = x;
  }
  __syncthreads();
}
__device__ __forceinline__ float2 inv_col_pack(const float2* bufR, int f, int pc){
  float2 r0, r1;
  if (f <= 32){
    r0 = bufR[f*65 + 2*pc];
    r1 = bufR[f*65 + 2*pc + 1];
  } else {
    int g = 64 - f;
    float2 a = bufR[g*65 + 2*pc];
    float2 b = bufR[g*65 + 2*pc + 1];
    r0 = make_float2(a.x, -a.y);
    r1 = make_float2(b.x, -b.y);
  }
  return make_float2(r0.x - r1.y, r0.y + r1.x);
}

// ---------------- ifft2 + real + bias -> bf16 X ----------------
__global__ __launch_bounds__(TPB) void k_ifft2_sym(const uintT* __restrict__ Xt, ushortT* __restrict__ Xo,
                                                   const float* __restrict__ bias, int O){
  __shared__ float2 W[64];
  __shared__ __attribute__((aligned(16))) float2 bufR[33*65];
  __shared__ uintT ldsOut[64*33];
  int bo = blockIdx.x >> 6;
  int o = bo % O;
  init_W(W, 1.f);
  int tid = threadIdx.x, lane = tid & 63, wid = tid >> 6;
  int rl = (int)(__brev((uintT)lane) >> 26);
  const uintT* src = Xt + (size_t)blockIdx.x*2016;
  inv_stage_rows(src, bufR, W, lane, wid, rl);
  float bb = bias[o];
  #pragma unroll 2
  for (int j = 0; j < 8; ++j){
    int pc = wid*8 + j;
    float2 w = inv_col_pack(bufR, lane, pc);
    float2 x = fft64_lane(w, W, lane);
    ushortT u0 = f2bf(x.x*(1.f/4096.f) + bb);
    ushortT u1 = f2bf(x.y*(1.f/4096.f) + bb);
    ldsOut[rl*33 + pc] = (uintT)u0 | ((uintT)u1 << 16);
  }
  __syncthreads();
  uintT* dst = (uintT*)(Xo + (size_t)blockIdx.x*4096);
  for (int i = tid; i < 2048; i += TPB){
    int a1 = i >> 5, pc = i & 31;
    dst[i] = ldsOut[a1*33 + pc];
  }
}

// ---------------- conv3 final stats from spectrum (Parseval, bf16-packed) ----------------
__global__ __launch_bounds__(TPB) void k_stats3(const uintT* __restrict__ Xt, double* __restrict__ part){
  int bo = blockIdx.x, zb = blockIdx.y;
  double s = 0.0, p = 0.0;
  for (int zz = 0; zz < 4; ++zz){
    const uintT* pl = Xt + ((size_t)bo*64 + zb*4 + zz)*2016;
    for (int idx = threadIdx.x; idx < 2016; idx += TPB){
      float2 v = up2(pl[idx]);
      double q = (double)v.x*v.x + (double)v.y*v.y;
      p += (idx < 63) ? q : 2.0*q;
      if (idx == 31) s += v.x;
    }
  }
  __shared__ double sh[TPB], sh2[TPB];
  sh[threadIdx.x] = s; sh2[threadIdx.x] = p;
  __syncthreads();
  for (int o = 128; o > 0; o >>= 1){
    if (threadIdx.x < o){ sh[threadIdx.x] += sh[threadIdx.x+o]; sh2[threadIdx.x] += sh2[threadIdx.x+o]; }
    __syncthreads();
  }
  if (threadIdx.x == 0){
    part[((size_t)bo*16 + zb)*2 + 0] = sh[0];
    part[((size_t)bo*16 + zb)*2 + 1] = sh2[0];
  }
}

__global__ void k_fstat(const double* __restrict__ part, const float* __restrict__ bias,
                        const float* __restrict__ g, const float* __restrict__ bsh,
                        float2* __restrict__ ss, int O){
  int o = threadIdx.x;
  if (o >= O) return;
  double S = 0.0, P = 0.0;
  for (int b = 0; b < 2; ++b)
    for (int zb = 0; zb < 16; ++zb){
      size_t base = ((size_t)(b*O + o)*16 + zb)*2;
      S += part[base]; P += part[base+1];
    }
  P *= (1.0/4096.0);
  double N = 524288.0;
  double bi = bias[o];
  double mean = S/N + bi;
  double var = P/N + 2.0*bi*S/N + bi*bi - mean*mean;
  double sc = (double)g[o] / sqrt(var + 1e-5);
  ss[o] = make_float2((float)sc, (float)((bi - mean)*sc + (double)bsh[o]));
}

// ---------------- fused ifft2 + BN + ReLU + mean over gamma ----------------
__global__ __launch_bounds__(TPB) void k_final(const uintT* __restrict__ Xt, const float2* __restrict__ ss,
                                               float* __restrict__ out, int O){
  __shared__ float2 W[64];
  __shared__ __attribute__((aligned(16))) float2 bufR[33*65];
  __shared__ float s4[4*64];
  int bo = blockIdx.x >> 6;
  int o = bo % O;
  init_W(W, 1.f);
  int tid = threadIdx.x, lane = tid & 63, wid = tid >> 6;
  int rl = (int)(__brev((uintT)lane) >> 26);
  const uintT* src = Xt + (size_t)blockIdx.x*2016;
  inv_stage_rows(src, bufR, W, lane, wid, rl);
  float2 sv = ss[o];
  float acc = 0.f;
  #pragma unroll 2
  for (int j = 0; j < 8; ++j){
    int pc = wid*8 + j;
    float2 w = inv_col_pack(bufR, lane, pc);
    float2 x = fft64_lane(w, W, lane);
    acc += fmaxf(fmaf(x.x*(1.f/4096.f), sv.x, sv.y), 0.f);
    acc += fmaxf(fmaf(x.y*(1.f/4096.f), sv.x, sv.y), 0.f);
  }
  s4[wid*64 + rl] = acc;
  __syncthreads();
  if (tid < 64)
    out[(size_t)blockIdx.x*64 + tid] = (s4[tid] + s4[64+tid] + s4[128+tid] + s4[192+tid]) * (1.f/64.f);
}

extern "C" void kernel_launch(void* const* d_in, const int* in_sizes, int n_in,
                              void* d_out, int out_size, void* d_ws, size_t ws_size,
                              hipStream_t stream){
  const float* x   = (const float*)d_in[0];
  const float* ks2 = (const float*)d_in[1];
  const float* bs2 = (const float*)d_in[2];
  const float* k1  = (const float*)d_in[3];
  const float* b1c = (const float*)d_in[4];
  const float* k2  = (const float*)d_in[5];
  const float* b2c = (const float*)d_in[6];
  const float* k3  = (const float*)d_in[7];
  const float* b3c = (const float*)d_in[8];
  const float* g1 = (const float*)d_in[9],  *bb1 = (const float*)d_in[10];
  const float* g2 = (const float*)d_in[11], *bb2 = (const float*)d_in[12];
  const float* g3 = (const float*)d_in[13], *bb3 = (const float*)d_in[14];
  const float* g4 = (const float*)d_in[15], *bb4 = (const float*)d_in[16];
  float* out = (float*)d_out;

  char* w = (char*)d_ws;
  size_t off = 0;
  auto take = [&](size_t bytes)->char*{
    char* p = w + off;
    off += (bytes + 255) & ~(size_t)255;
    return p;
  };
  float*  Dz2  = (float*) take(32ull*8*64*32*8*4);    // 16.8 MB tiled
  float*  D0   = (float*) take(64ull*32*32*4);
  float*  Deq  = (float*) take(32ull*63*63*4);
  double* lf   = (double*)take(65*8);
  double* qw   = (double*)take(64*8);
  double* part = (double*)take(75ull*64*2*8);
  float2* ss   = (float2*)take(75*8);
  float2* KhS2 = (float2*)take(63ull*25*3*8);
  float2* Kh1  = (float2*)take(63ull*25*25*8);
  float2* Kh2  = (float2*)take(63ull*25*50*8);
  float2* Kh3  = (float2*)take(63ull*36*75*8);
  float2* XH2  = (float2*)take(2ull*3*64*63*8);
  float2* F2   = (float2*)take(2ull*3*32*63*8);
  ushortT* X1  = (ushortT*)take(2ull*25*262144*2);
  ushortT* X2  = (ushortT*)take(2ull*25*262144*2);
  ushortT* X3  = (ushortT*)take(2ull*25*262144*2);
  uintT*  Ah   = (uintT*) take(150ull*32*2016*4);     // 38.7 MB bf16-packed
  uintT*  Bh   = (uintT*) take(150ull*32*2016*4);
  uintT*  P    = (uintT*) take(150ull*32*2016*4);     // 38.7 MB bf16-packed (F, C in-place)
  if (off > ws_size) return;

  dim3 tpb(TPB);
  auto cdiv = [](long long a, long long b){ return (int)((a + b - 1) / b); };

  k_tables<<<1, 64, 0, stream>>>(lf, qw);
  k_wigner<<<dim3(65,32), tpb, 0, stream>>>(lf, Dz2, D0, Deq);
  k_kh<<<cdiv(3ll*25*63,TPB),  tpb, 0, stream>>>(ks2, KhS2, 3, 25,  (float)(1.0/sqrt(196608.0)));
  k_kh<<<cdiv(25ll*25*63,TPB), tpb, 0, stream>>>(k1,  Kh1, 25, 25, (float)(1.0/sqrt(1600.0)));
  k_kh<<<cdiv(50ll*25*63,TPB), tpb, 0, stream>>>(k2,  Kh2, 50, 25, (float)(1.0/sqrt(3200.0)));
  k_kh<<<cdiv(75ll*36*63,TPB), tpb, 0, stream>>>(k3,  Kh3, 75, 36, (float)(1.0/sqrt(4800.0)));

  // ---- S2 conv ----
  k_s2_fft<<<cdiv(2ll*3*64*63,TPB), tpb, 0, stream>>>(x, XH2);
  k_s2_F<<<cdiv(2ll*3*32*63,TPB), tpb, 0, stream>>>(D0, qw, XH2, F2);
  k_s2_zhat<<<cdiv(2ll*25*32*2016,TPB), tpb, 0, stream>>>(Deq, F2, KhS2, Ah);
  k_wig_synth<<<dim3(32,8,2*cdiv(50,16)), tpb, 0, stream>>>(Dz2, Ah, Bh, 50);
  k_ifft2_sym<<<50*64, tpb, 0, stream>>>(Bh, X1, bs2, 25);
  k_bnstats<<<dim3(25,64), tpb, 0, stream>>>(X1, 0, part);

  // ---- generic SO3 conv ----
  auto so3 = [&](const ushortT* Xa, const ushortT* Xb, const ushortT* Xc, int Cin,
                 const float* g, const float* bb, const float2* Kh, int O,
                 const float* bias, ushortT* Xout, int isFinal){
    int BC = 2*Cin, BO = 2*O;
    k_bnfinal<<<1, 128, 0, stream>>>(part, g, bb, ss, Cin);
    k_fft2_fwd<<<dim3(BC,32), tpb, 0, stream>>>(Xa, Xb, Xc, ss, Ah, Cin, 0);
    k_fft2_fwd<<<dim3(BC,32), tpb, 0, stream>>>(Xa, Xb, Xc, ss, Bh, Cin, 32);
    k_wig_F<<<dim3(32,8,cdiv(BC,16)), tpb, 0, stream>>>(Dz2, qw, Ah, Bh, P, BC);
    k_deq_C<<<dim3(32,32,cdiv(BC,64)), tpb, 0, stream>>>(Deq, P, P, BC);        // C in-place (packed)
    k_kh_z<<<dim3(32,4,cdiv(O,KOC)), tpb, 0, stream>>>(P, Kh, Ah, Cin, O);      // Z packed -> Ah
    k_wig_synth<<<dim3(32,8,2*cdiv(BO,16)), tpb, 0, stream>>>(Dz2, Ah, Bh, BO); // Xt packed -> Bh
    if (!isFinal){
      k_ifft2_sym<<<BO*64, tpb, 0, stream>>>(Bh, Xout, bias, O);
    } else {
      k_stats3<<<dim3(BO,16), tpb, 0, stream>>>(Bh, part);
      k_fstat<<<1, 64, 0, stream>>>(part, bias, g4, bb4, ss, O);
      k_final<<<BO*64, tpb, 0, stream>>>(Bh, ss, out, O);
    }
  };

  so3(X1, X1, X1, 25, g1, bb1, Kh1, 25, b1c, X2, 0);
  k_bnstats<<<dim3(25,64), tpb, 0, stream>>>(X2, 25, part);
  so3(X1, X2, X2, 50, g2, bb2, Kh2, 25, b2c, X3, 0);
  k_bnstats<<<dim3(25,64), tpb, 0, stream>>>(X3, 50, part);
  so3(X1, X2, X3, 75, g3, bb3, Kh3, 36, b3c, nullptr, 1);
}

// Round 16
// 1280.276 us; speedup vs baseline: 1.8821x; 1.0850x over previous
//
#include <hip/hip_runtime.h>
#include <math.h>

#define PI_D 3.14159265358979323846
#define TPB 256
typedef unsigned short ushortT;
typedef unsigned int uintT;

__device__ __forceinline__ float2 cxmul(float2 a, float2 b){
  return make_float2(a.x*b.x - a.y*b.y, a.x*b.y + a.y*b.x);
}
__device__ __forceinline__ float bf2f(ushortT u){
  uintT x = ((uintT)u) << 16;
  return __uint_as_float(x);
}
__device__ __forceinline__ ushortT f2bf(float f){
  uintT x = __float_as_uint(f);
  x = x + 0x7FFFu + ((x >> 16) & 1u);
  return (ushortT)(x >> 16);
}
__device__ __forceinline__ uintT pk2(float2 v){
  return (uintT)f2bf(v.x) | ((uintT)f2bf(v.y) << 16);
}
__device__ __forceinline__ float2 up2(uintT u){
  return make_float2(bf2f((ushortT)(u & 0xffff)), bf2f((ushortT)(u >> 16)));
}

// ---------------- tables ----------------
__global__ void k_tables(double* lf, double* qw){
  if (threadIdx.x == 0){
    lf[0] = 0.0;
    for (int i = 1; i <= 64; ++i) lf[i] = lf[i-1] + log((double)i);
  }
  int j = threadIdx.x;
  if (j < 64){
    double s1 = sin(PI_D*(2*j+1)/128.0);
    double inner = 0.0;
    for (int k = 0; k < 32; ++k)
      inner += (1.0/(double)(2*k+1)) * sin((double)(2*j+1)*(double)(2*k+1)*PI_D/128.0);
    qw[j] = (2.0/32.0) * s1 * inner;
  }
}

__device__ double wigd(const double* lfs, int l, int mp, int m, double lc, double ls){
  if (mp < -l || mp > l || m < -l || m > l) return 0.0;
  int k0 = (m - mp > 0) ? (m - mp) : 0;
  int k1 = (l + m < l - mp) ? (l + m) : (l - mp);
  double base = 0.5*(lfs[l+mp] + lfs[l-mp] + lfs[l+m] + lfs[l-m]);
  double val = 0.0;
  for (int k = k0; k <= k1; ++k){
    double t = base - lfs[l+m-k] - lfs[k] - lfs[mp-m+k] - lfs[l-mp-k]
             + (double)(2*l + m - mp - 2*k)*lc + (double)(mp - m + 2*k)*ls;
    double e = exp(t);
    val += ((mp - m + k) & 1) ? -e : e;
  }
  return val;
}

// Dz2[mi][nt][z][l][nn] (n = nt*8+nn, zero pad n=63), D0[z][l][mi], Deq[l][r][c]
__global__ __launch_bounds__(TPB) void k_wigner(const double* __restrict__ lf,
                                                float* __restrict__ Dz2, float* __restrict__ D0,
                                                float* __restrict__ Deq){
  __shared__ double lfs[65];
  if (threadIdx.x < 65) lfs[threadIdx.x] = lf[threadIdx.x];
  __syncthreads();
  int zs = blockIdx.x, l = blockIdx.y;
  double beta = (zs < 64) ? ((double)zs + 0.5)*PI_D/64.0 : PI_D*0.5;
  double ch = cos(beta*0.5), sh = sin(beta*0.5);
  double lc = log(ch), ls = log(sh);
  if (zs < 64){
    for (int idx = threadIdx.x; idx < 2048; idx += TPB){
      int mi = idx >> 6, nf = idx & 63;
      float v = (nf < 63) ? (float)wigd(lfs, l, mi, nf-31, lc, ls) : 0.f;
      int nt = nf >> 3, nn = nf & 7;
      Dz2[(((size_t)(mi*8 + nt)*64 + zs)*32 + l)*8 + nn] = v;
      if (nf == 31) D0[((size_t)zs*32 + l)*32 + mi] = v;
    }
  } else {
    for (int idx = threadIdx.x; idx < 3969; idx += TPB){
      int r = idx/63, c = idx%63;
      Deq[((size_t)l*63 + r)*63 + c] = (float)wigd(lfs, l, r-31, c-31, lc, ls);
    }
  }
}

// Kh[o][i][n]
__global__ void k_kh(const float* __restrict__ K, float2* __restrict__ Kh, int I, int O, float scale){
  int idx = blockIdx.x*blockDim.x + threadIdx.x;
  if (idx >= I*O*63) return;
  int n = idx % 63, i = (idx/63) % I, o = idx/(63*I);
  float sr = 0.f, si = 0.f;
  for (int p = 0; p < 64; ++p){
    int t = (p * (n - 31)) & 63;
    float s, c;
    sincosf(-(float)PI_D/32.f * (float)t, &s, &c);
    float kv = K[(i*O + o)*64 + p];
    sr += kv * c; si += kv * s;
  }
  Kh[((size_t)o*I + i)*63 + n] = make_float2(sr*scale, si*scale);
}

// ---------------- S2 front ----------------
__global__ void k_s2_fft(const float* __restrict__ x, float2* __restrict__ XH2){
  int idx = blockIdx.x*blockDim.x + threadIdx.x;
  if (idx >= 2*3*64*63) return;
  int mi = idx % 63; int z = (idx/63) & 63; int bc = idx / (63*64);
  int f = (mi + 33) & 63;
  const float* row = x + ((size_t)bc*64 + z)*64;
  float sr = 0.f, si = 0.f;
  for (int a = 0; a < 64; ++a){
    int t = (f*a) & 63;
    float s, c;
    sincosf(-(float)PI_D/32.f * (float)t, &s, &c);
    sr += row[a]*c; si += row[a]*s;
  }
  XH2[idx] = make_float2(sr, si);
}

__global__ void k_s2_F(const float* __restrict__ D0, const double* __restrict__ qw,
                       const float2* __restrict__ XH2, float2* __restrict__ F2){
  int idx = blockIdx.x*blockDim.x + threadIdx.x;
  if (idx >= 2*3*32*63) return;
  int r = idx % 63; int l = (idx/63) & 31; int bc = idx / (63*32);
  float2 acc = make_float2(0,0);
  for (int z = 0; z < 64; ++z){
    float d;
    if (r >= 31) d = D0[((size_t)z*32 + l)*32 + (r-31)];
    else {
      d = D0[((size_t)z*32 + l)*32 + (31-r)];
      if ((31-r) & 1) d = -d;
    }
    float wv = (float)qw[z] * d;
    float2 v = XH2[((size_t)bc*64 + z)*63 + r];
    acc.x += wv*v.x; acc.y += wv*v.y;
  }
  F2[idx] = acc;
}

__global__ void k_s2_zhat(const float* __restrict__ Deq, const float2* __restrict__ F2,
                          const float2* __restrict__ Kh, uintT* __restrict__ Z){
  int idx = blockIdx.x*blockDim.x + threadIdx.x;
  if (idx >= 2*25*32*2016) return;
  int n = idx % 63; int mi = (idx/63) & 31; int l = (idx/2016) & 31;
  int o = (idx/(2016*32)) % 25; int b = idx/(2016*32*25);
  float deq0 = Deq[((size_t)l*63 + n)*63 + 31];
  float2 acc = make_float2(0,0);
  for (int i = 0; i < 3; ++i){
    float2 f = F2[((size_t)(b*3 + i)*32 + l)*63 + (mi+31)];
    float2 kh = Kh[((size_t)(o*3 + i))*63 + n];
    acc.x = fmaf(kh.x, f.x, acc.x); acc.x = fmaf(-kh.y, f.y, acc.x);
    acc.y = fmaf(kh.x, f.y, acc.y); acc.y = fmaf(kh.y, f.x, acc.y);
  }
  Z[((size_t)((b*25+o)*32) + l)*2016 + mi*63 + n] = pk2(make_float2(acc.x*deq0, acc.y*deq0));
}

// ---------------- BN stats over bf16 X buffers ----------------
__global__ __launch_bounds__(TPB) void k_bnstats(const ushortT* __restrict__ src, int slotBase,
                                                 double* __restrict__ part){
  int c = blockIdx.x, blk = blockIdx.y;
  const uint2* s4 = (const uint2*)src;
  double s = 0.0, q = 0.0;
  for (int k = 0; k < 8; ++k){
    int g4 = blk*2048 + k*256 + threadIdx.x;
    int b = g4 >> 16, pos4 = g4 & 65535;
    uint2 u = s4[((size_t)(b*25 + c))*65536 + pos4];
    float v0 = bf2f((ushortT)(u.x & 0xffff)), v1 = bf2f((ushortT)(u.x >> 16));
    float v2 = bf2f((ushortT)(u.y & 0xffff)), v3 = bf2f((ushortT)(u.y >> 16));
    s += (double)v0 + v1 + v2 + v3;
    q += (double)v0*v0 + (double)v1*v1 + (double)v2*v2 + (double)v3*v3;
  }
  __shared__ double sh[TPB], sh2[TPB];
  sh[threadIdx.x] = s; sh2[threadIdx.x] = q;
  __syncthreads();
  for (int o = 128; o > 0; o >>= 1){
    if (threadIdx.x < o){ sh[threadIdx.x] += sh[threadIdx.x+o]; sh2[threadIdx.x] += sh2[threadIdx.x+o]; }
    __syncthreads();
  }
  if (threadIdx.x == 0){
    part[((size_t)(slotBase + c)*64 + blk)*2 + 0] = sh[0];
    part[((size_t)(slotBase + c)*64 + blk)*2 + 1] = sh2[0];
  }
}

__global__ void k_bnfinal(const double* __restrict__ part, const float* __restrict__ g,
                          const float* __restrict__ b, float2* __restrict__ ss, int C){
  int c = blockIdx.x*blockDim.x + threadIdx.x;
  if (c >= C) return;
  double s = 0.0, q = 0.0;
  for (int k = 0; k < 64; ++k){
    s += part[((size_t)c*64 + k)*2 + 0];
    q += part[((size_t)c*64 + k)*2 + 1];
  }
  double N = 524288.0;
  double mu = s / N;
  double var = q / N - mu*mu;
  double sc = (double)g[c] / sqrt(var + 1e-5);
  ss[c] = make_float2((float)sc, (float)((double)b[c] - mu*sc));
}

// ---------------- 64-pt FFT across lanes ----------------
__device__ __forceinline__ float2 fft64_lane(float2 x, const float2* __restrict__ Wt, int lane){
  #pragma unroll
  for (int st = 0; st < 6; ++st){
    int h = 32 >> st;
    float2 p;
    p.x = __shfl_xor(x.x, h, 64);
    p.y = __shfl_xor(x.y, h, 64);
    if (lane & h){
      float2 s = make_float2(p.x - x.x, p.y - x.y);
      x = cxmul(s, Wt[(lane & (h-1)) << st]);
    } else {
      x = make_float2(x.x + p.x, x.y + p.y);
    }
  }
  return x;
}
__device__ __forceinline__ void init_W(float2* W, float sign){
  if (threadIdx.x < 64){
    float s, c;
    sincosf(sign*(float)(2.0*PI_D/64.0)*(float)threadIdx.x, &s, &c);
    W[threadIdx.x] = make_float2(c, s);
  }
}

// ---------------- fused BN+ReLU + packed real fft2 -> bf16-packed XH ----------------
__global__ __launch_bounds__(TPB) void k_fft2_fwd(const ushortT* __restrict__ X1, const ushortT* __restrict__ X2,
                                                  const ushortT* __restrict__ X3, const float2* __restrict__ ss,
                                                  uintT* __restrict__ XH, int Cin, int z0){
  __shared__ float2 W[64];
  __shared__ __attribute__((aligned(16))) float2 smem[4224];
  float2* bufP = smem;
  float2* bufW = smem + 2112;
  int bc = blockIdx.x, zz = blockIdx.y, z = z0 + zz;
  int b = bc / Cin, ci = bc % Cin;
  const ushortT* src; int cl;
  if (ci < 25){ src = X1; cl = ci; }
  else if (ci < 50){ src = X2; cl = ci - 25; }
  else { src = X3; cl = ci - 50; }
  src += ((size_t)(b*25 + cl)*64 + z)*4096;
  float2 sc = ss[ci];
  init_W(W, -1.f);
  int tid = threadIdx.x, lane = tid & 63, wid = tid >> 6;
  int rl = (int)(__brev((uintT)lane) >> 26);
  const uintT* s32 = (const uintT*)src;
  for (int i = tid; i < 2048; i += TPB){
    uintT u = s32[i];
    float v0 = fmaxf(bf2f((ushortT)(u & 0xffff))*sc.x + sc.y, 0.f);
    float v1 = fmaxf(bf2f((ushortT)(u >> 16))*sc.x + sc.y, 0.f);
    int a1 = i >> 5, c = i & 31;
    bufP[a1*33 + c] = make_float2(v0, v1);
  }
  __syncthreads();
  #pragma unroll 2
  for (int j = 0; j < 8; ++j){
    int c = wid*8 + j;
    float2 x = bufP[lane*33 + c];
    x = fft64_lane(x, W, lane);
    bufW[rl*33 + c] = x;
  }
  __syncthreads();
  for (int i = tid; i < 1024; i += TPB){
    int f1 = i >> 5, c = i & 31;
    float2 Wv = bufW[f1*33 + c];
    float2 Wm = bufW[((64-f1)&63)*33 + c];
    bufP[f1*65 + 2*c]     = make_float2(0.5f*(Wv.x + Wm.x), 0.5f*(Wv.y - Wm.y));
    bufP[f1*65 + 2*c + 1] = make_float2(0.5f*(Wv.y + Wm.y), 0.5f*(Wm.x - Wv.x));
  }
  __syncthreads();
  #pragma unroll 2
  for (int j = 0; j < 8; ++j){
    int r = wid*8 + j;
    float2 x = bufP[r*65 + lane];
    x = fft64_lane(x, W, lane);
    bufP[r*65 + rl] = x;
  }
  __syncthreads();
  uintT* dst = XH + ((size_t)bc*32 + zz)*2016;
  for (int idx = tid; idx < 2016; idx += TPB){
    int mi = idx / 63, n = idx % 63;
    dst[idx] = pk2(bufP[mi*65 + ((n+33)&63)]);
  }
}

// ---------------- F[bc,l,mi,n] = sum_z qw*Dz*XH — packed, reg-prefetch pipelined ----------------
#define SKEW(e) ((e) + ((e)>>4))
__global__ __launch_bounds__(TPB) void k_wig_F(const float* __restrict__ Dz2, const double* __restrict__ qw,
                                               const uintT* __restrict__ XHa, const uintT* __restrict__ XHb,
                                               uintT* __restrict__ F, int BC){
  __shared__ __attribute__((aligned(16))) float sm[9088];
  float* Dt = sm;                          // [z16][nn8][l 36pad]
  float2* Xt = (float2*)(sm + 4608);       // [bc16][130]
  int mi = blockIdx.x, nt = blockIdx.y, bcBase = blockIdx.z*16;
  int tid = threadIdx.x;
  int bg = tid & 3, lg = (tid>>2)&7, ng = tid>>5;
  const float* DzB = Dz2 + ((size_t)(mi*8 + nt)*64)*256;
  float2 acc[4][4];
  #pragma unroll
  for (int a = 0; a < 4; ++a)
    #pragma unroll
    for (int j = 0; j < 4; ++j) acc[a][j] = make_float2(0,0);

  float pd[16]; uintT px[8];
  auto fetch = [&](int chunk){
    const uintT* XH = (chunk < 2) ? XHa : XHb;
    int zq = (chunk & 1)*16, gz0 = chunk*16;
    #pragma unroll
    for (int t = 0; t < 16; ++t)
      pd[t] = DzB[(size_t)gz0*256 + tid + t*256];
    #pragma unroll
    for (int t = 0; t < 8; ++t){
      int idx = tid + t*256;
      int bc = idx >> 7, z = (idx>>3)&15, nn = idx&7;
      int gbc = bcBase + bc, n = nt*8 + nn;
      px[t] = (gbc < BC && n < 63) ? XH[((size_t)gbc*32 + zq + z)*2016 + mi*63 + n] : 0u;
    }
  };
  fetch(0);

  for (int chunk = 0; chunk < 4; ++chunk){
    int gz0 = chunk*16;
    __syncthreads();
    #pragma unroll
    for (int t = 0; t < 16; ++t){
      int idx = tid + t*256;
      int z = idx >> 8, l = (idx>>3)&31, nn = idx&7;
      Dt[(z*8+nn)*36 + l] = pd[t] * (float)qw[gz0+z];
    }
    #pragma unroll
    for (int t = 0; t < 8; ++t){
      int idx = tid + t*256;
      int bc = idx >> 7, z = (idx>>3)&15, nn = idx&7;
      Xt[bc*130 + z*8 + nn] = up2(px[t]);
    }
    __syncthreads();
    if (chunk + 1 < 4) fetch(chunk + 1);
    #pragma unroll 4
    for (int z = 0; z < 16; ++z){
      const float4 d = *(const float4*)&Dt[(z*8+ng)*36 + lg*4];
      float dd[4] = {d.x, d.y, d.z, d.w};
      float2 xv[4];
      #pragma unroll
      for (int j = 0; j < 4; ++j) xv[j] = Xt[(bg + 4*j)*130 + z*8 + ng];
      #pragma unroll
      for (int j = 0; j < 4; ++j)
        #pragma unroll
        for (int dl = 0; dl < 4; ++dl){
          acc[j][dl].x = fmaf(dd[dl], xv[j].x, acc[j][dl].x);
          acc[j][dl].y = fmaf(dd[dl], xv[j].y, acc[j][dl].y);
        }
    }
  }
  __syncthreads();
  float2* St = (float2*)sm;
  #pragma unroll
  for (int j = 0; j < 4; ++j)
    #pragma unroll
    for (int dl = 0; dl < 4; ++dl){
      int e = (bg + 4*j)*256 + (lg*4 + dl)*8 + ng;
      St[SKEW(e)] = acc[j][dl];
    }
  __syncthreads();
  for (int idx = tid; idx < 4096; idx += TPB){
    int bc = idx >> 8, l = (idx>>3)&31, nn = idx&7;
    int gbc = bcBase + bc, n = nt*8 + nn;
    if (gbc < BC && n < 63)
      F[((size_t)(gbc*32 + l))*2016 + mi*63 + n] = pk2(St[SKEW(idx)]);
  }
}

// ---------------- C[bi,l,mi,n] = sum_k F[bi,l,mi,k]*Deq[l,n,k] — packed in/out, in-place safe ----------------
__global__ __launch_bounds__(TPB) void k_deq_C(const float* __restrict__ Deq, const uintT* __restrict__ F,
                                               uintT* __restrict__ C, int BC){
  __shared__ __attribute__((aligned(16))) float sm[12604];
  float2* Fb = (float2*)sm;
  float* DeqT = sm + 8320;
  int l = blockIdx.x, mi = blockIdx.y, biBase = blockIdx.z*64;
  int tid = threadIdx.x;
  int ngr = tid & 15, big = tid >> 4;
  for (int idx = tid; idx < 3969; idx += TPB){
    int n = idx/63, k = idx - n*63;
    DeqT[k*68 + n] = Deq[((size_t)l*63 + n)*63 + k];
  }
  for (int idx = tid; idx < 4032; idx += TPB){
    int bi = idx/63, k = idx - bi*63;
    int gbi = biBase + bi;
    Fb[bi*65 + k] = (gbi < BC) ? up2(F[((size_t)(gbi*32 + l))*2016 + mi*63 + k]) : make_float2(0,0);
  }
  __syncthreads();
  float2 acc[4][4];
  #pragma unroll
  for (int a = 0; a < 4; ++a)
    #pragma unroll
    for (int j = 0; j < 4; ++j) acc[a][j] = make_float2(0,0);
  #pragma unroll 3
  for (int k = 0; k < 63; ++k){
    const float4 d = *(const float4*)&DeqT[k*68 + ngr*4];
    float dd[4] = {d.x, d.y, d.z, d.w};
    float2 fv[4];
    #pragma unroll
    for (int j = 0; j < 4; ++j) fv[j] = Fb[(big + 16*j)*65 + k];
    #pragma unroll
    for (int j = 0; j < 4; ++j)
      #pragma unroll
      for (int dn = 0; dn < 4; ++dn){
        acc[j][dn].x = fmaf(dd[dn], fv[j].x, acc[j][dn].x);
        acc[j][dn].y = fmaf(dd[dn], fv[j].y, acc[j][dn].y);
      }
  }
  __syncthreads();
  float2* St = (float2*)sm;
  #pragma unroll
  for (int j = 0; j < 4; ++j)
    #pragma unroll
    for (int dn = 0; dn < 4; ++dn){
      int n = ngr*4 + dn;
      if (n < 63) St[(big + 16*j)*63 + n] = acc[j][dn];
    }
  __syncthreads();
  for (int idx = tid; idx < 4032; idx += TPB){
    int bi = idx/63, n = idx - bi*63;
    int gbi = biBase + bi;
    if (gbi < BC) C[((size_t)(gbi*32 + l))*2016 + mi*63 + n] = pk2(St[idx]);
  }
}

// ---------------- Z[b,o,l,mi,n] = sum_i Kh[o,i,n]*C[b,i,l,mi,n] — packed C in, packed Z out ----------------
#define KOC 9
__global__ __launch_bounds__(TPB) void k_kh_z(const uintT* __restrict__ C, const float2* __restrict__ Kh,
                                              uintT* __restrict__ Z, int I, int O){
  __shared__ float2 Kt[KOC*5*64];
  const int nK = KOC*5*64;
  int l = blockIdx.x, mic = blockIdx.y, oc = blockIdx.z;
  int lane = threadIdx.x & 63, wid = threadIdx.x >> 6;
  int mi0 = mic*8 + wid*2;
  int n = lane;
  int o0 = oc*KOC;
  float2 acc[2][2][KOC];
  #pragma unroll
  for (int ml = 0; ml < 2; ++ml)
    #pragma unroll
    for (int b = 0; b < 2; ++b)
      #pragma unroll
      for (int oo = 0; oo < KOC; ++oo) acc[ml][b][oo] = make_float2(0,0);

  float2 pre[12];
  auto loadK = [&](int i0){
    #pragma unroll
    for (int t = 0; t < 12; ++t){
      int idx = threadIdx.x + t*256;
      float2 v = make_float2(0,0);
      if (idx < nK){
        int nn = idx & 63, rem = idx >> 6;
        int ic = rem % 5, oo = rem / 5;
        int o = o0 + oo;
        if (o < O && nn < 63) v = Kh[((size_t)o*I + (i0+ic))*63 + nn];
      }
      pre[t] = v;
    }
  };
  loadK(0);

  size_t cBase0 = ((size_t)l)*2016 + mi0*63 + n;
  size_t cBase1 = cBase0 + 63;
  int nch = I/5;
  for (int c = 0; c < nch; ++c){
    __syncthreads();
    #pragma unroll
    for (int t = 0; t < 12; ++t){
      int idx = threadIdx.x + t*256;
      if (idx < nK) Kt[idx] = pre[t];
    }
    __syncthreads();
    if (c+1 < nch) loadK((c+1)*5);
    if (n < 63){
      int i0 = c*5;
      float2 cv[5][4];
      #pragma unroll
      for (int ic = 0; ic < 5; ++ic){
        int i = i0 + ic;
        cv[ic][0] = up2(C[cBase0 + (size_t)i*64512]);
        cv[ic][1] = up2(C[cBase0 + (size_t)(I + i)*64512]);
        cv[ic][2] = up2(C[cBase1 + (size_t)i*64512]);
        cv[ic][3] = up2(C[cBase1 + (size_t)(I + i)*64512]);
      }
      #pragma unroll
      for (int ic = 0; ic < 5; ++ic){
        #pragma unroll
        for (int oo = 0; oo < KOC; ++oo){
          float2 kh = Kt[(oo*5 + ic)*64 + n];
          #pragma unroll
          for (int q = 0; q < 4; ++q){
            float2 cc = cv[ic][q];
            int ml = q >> 1, b = q & 1;
            acc[ml][b][oo].x = fmaf(kh.x, cc.x, acc[ml][b][oo].x);
            acc[ml][b][oo].x = fmaf(-kh.y, cc.y, acc[ml][b][oo].x);
            acc[ml][b][oo].y = fmaf(kh.x, cc.y, acc[ml][b][oo].y);
            acc[ml][b][oo].y = fmaf(kh.y, cc.x, acc[ml][b][oo].y);
          }
        }
      }
    }
  }
  if (n < 63){
    #pragma unroll
    for (int ml = 0; ml < 2; ++ml){
      size_t zBase = ((size_t)l)*2016 + (mi0 + ml)*63 + n;
      #pragma unroll
      for (int oo = 0; oo < KOC; ++oo){
        int o = o0 + oo;
        if (o < O){
          Z[zBase + (size_t)(0*O + o)*64512] = pk2(acc[ml][0][oo]);
          Z[zBase + (size_t)(1*O + o)*64512] = pk2(acc[ml][1][oo]);
        }
      }
    }
  }
}

// ---------------- Xt[bo,z,mi,n] = sum_l wl*Dz*Z — packed, reg-prefetch pipelined ----------------
__global__ __launch_bounds__(TPB) void k_wig_synth(const float* __restrict__ Dz2, const uintT* __restrict__ Z,
                                                   uintT* __restrict__ Xt_g, int BO){
  __shared__ __attribute__((aligned(16))) float sm[9088];
  float* Dt = sm;                          // [l16][nn8][z 36pad]
  float2* Zt = (float2*)(sm + 4608);       // [bo16][130]
  int mi = blockIdx.x, nt = blockIdx.y;
  int z0 = (blockIdx.z & 1)*32;
  int boBase = (blockIdx.z >> 1)*16;
  int tid = threadIdx.x;
  int bg = tid & 3, zg = (tid>>2)&7, ng = tid>>5;
  const float* DzB = Dz2 + ((size_t)(mi*8 + nt)*64)*256;
  float2 acc[4][4];
  #pragma unroll
  for (int a = 0; a < 4; ++a)
    #pragma unroll
    for (int j = 0; j < 4; ++j) acc[a][j] = make_float2(0,0);

  float pd[16]; uintT pz[8];
  auto fetch = [&](int lq){
    #pragma unroll
    for (int t = 0; t < 16; ++t){
      int idx = tid + t*256;
      int z = idx >> 7, ll = (idx>>3)&15, nn = idx&7;
      int lG = lq + ll;
      pd[t] = DzB[(size_t)(z0+z)*256 + lG*8 + nn];
    }
    #pragma unroll
    for (int t = 0; t < 8; ++t){
      int idx = tid + t*256;
      int bo = idx >> 7, ll = (idx>>3)&15, nn = idx&7;
      int gbo = boBase + bo, n = nt*8 + nn;
      pz[t] = (gbo < BO && n < 63) ? Z[((size_t)(gbo*32 + lq + ll))*2016 + mi*63 + n] : 0u;
    }
  };
  fetch(0);

  for (int lq = 0; lq < 32; lq += 16){
    __syncthreads();
    #pragma unroll
    for (int t = 0; t < 16; ++t){
      int idx = tid + t*256;
      int z = idx >> 7, ll = (idx>>3)&15, nn = idx&7;
      int lG = lq + ll;
      Dt[(ll*8+nn)*36 + z] = pd[t] * (0.5f*(float)(2*lG+1));
    }
    #pragma unroll
    for (int t = 0; t < 8; ++t){
      int idx = tid + t*256;
      int bo = idx >> 7, ll = (idx>>3)&15, nn = idx&7;
      Zt[bo*130 + ll*8 + nn] = up2(pz[t]);
    }
    __syncthreads();
    if (lq == 0) fetch(16);
    #pragma unroll 4
    for (int ll = 0; ll < 16; ++ll){
      const float4 d = *(const float4*)&Dt[(ll*8+ng)*36 + zg*4];
      float dd[4] = {d.x, d.y, d.z, d.w};
      float2 zv[4];
      #pragma unroll
      for (int j = 0; j < 4; ++j) zv[j] = Zt[(bg + 4*j)*130 + ll*8 + ng];
      #pragma unroll
      for (int j = 0; j < 4; ++j)
        #pragma unroll
        for (int dz = 0; dz < 4; ++dz){
          acc[j][dz].x = fmaf(dd[dz], zv[j].x, acc[j][dz].x);
          acc[j][dz].y = fmaf(dd[dz], zv[j].y, acc[j][dz].y);
        }
    }
  }
  __syncthreads();
  float2* St = (float2*)sm;
  #pragma unroll
  for (int j = 0; j < 4; ++j)
    #pragma unroll
    for (int dz = 0; dz < 4; ++dz){
      int e = (bg + 4*j)*256 + (zg*4 + dz)*8 + ng;
      St[SKEW(e)] = acc[j][dz];
    }
  __syncthreads();
  for (int idx = tid; idx < 4096; idx += TPB){
    int bo = idx >> 8, z = (idx>>3)&31, nn = idx&7;
    int gbo = boBase + bo, n = nt*8 + nn;
    if (gbo < BO && n < 63)
      Xt_g[((size_t)gbo*64 + z0 + z)*2016 + mi*63 + n] = pk2(St[SKEW(idx)]);
  }
}

// ---------------- inverse helpers (bf16-packed src) ----------------
__device__ __forceinline__ void inv_stage_rows(const uintT* __restrict__ src, float2* bufR,
                                               const float2* W, int lane, int wid, int rl){
  int tid = threadIdx.x;
  if (tid < 64) bufR[32*65 + tid] = make_float2(0,0);
  else if (tid < 96) bufR[(tid-64)*65 + 32] = make_float2(0,0);
  for (int idx = tid; idx < 2016; idx += TPB){
    int mi = idx / 63, ni = idx - mi*63;
    bufR[mi*65 + ((ni+33)&63)] = up2(src[idx]);
  }
  __syncthreads();
  #pragma unroll 2
  for (int j = 0; j < 8; ++j){
    int r = wid*8 + j;
    float2 x = bufR[r*65 + lane];
    x = fft64_lane(x, W, lane);
    bufR[r*65 + rl] = x;
  }
  __syncthreads();
}
__device__ __forceinline__ float2 inv_col_pack(const float2* bufR, int f, int pc){
  float2 r0, r1;
  if (f <= 32){
    r0 = bufR[f*65 + 2*pc];
    r1 = bufR[f*65 + 2*pc + 1];
  } else {
    int g = 64 - f;
    float2 a = bufR[g*65 + 2*pc];
    float2 b = bufR[g*65 + 2*pc + 1];
    r0 = make_float2(a.x, -a.y);
    r1 = make_float2(b.x, -b.y);
  }
  return make_float2(r0.x - r1.y, r0.y + r1.x);
}

// ---------------- ifft2 + real + bias -> bf16 X ----------------
__global__ __launch_bounds__(TPB) void k_ifft2_sym(const uintT* __restrict__ Xt, ushortT* __restrict__ Xo,
                                                   const float* __restrict__ bias, int O){
  __shared__ float2 W[64];
  __shared__ __attribute__((aligned(16))) float2 bufR[33*65];
  __shared__ uintT ldsOut[64*33];
  int bo = blockIdx.x >> 6;
  int o = bo % O;
  init_W(W, 1.f);
  int tid = threadIdx.x, lane = tid & 63, wid = tid >> 6;
  int rl = (int)(__brev((uintT)lane) >> 26);
  const uintT* src = Xt + (size_t)blockIdx.x*2016;
  inv_stage_rows(src, bufR, W, lane, wid, rl);
  float bb = bias[o];
  #pragma unroll 2
  for (int j = 0; j < 8; ++j){
    int pc = wid*8 + j;
    float2 w = inv_col_pack(bufR, lane, pc);
    float2 x = fft64_lane(w, W, lane);
    ushortT u0 = f2bf(x.x*(1.f/4096.f) + bb);
    ushortT u1 = f2bf(x.y*(1.f/4096.f) + bb);
    ldsOut[rl*33 + pc] = (uintT)u0 | ((uintT)u1 << 16);
  }
  __syncthreads();
  uintT* dst = (uintT*)(Xo + (size_t)blockIdx.x*4096);
  for (int i = tid; i < 2048; i += TPB){
    int a1 = i >> 5, pc = i & 31;
    dst[i] = ldsOut[a1*33 + pc];
  }
}

// ---------------- conv3 final stats from spectrum (Parseval, bf16-packed) ----------------
__global__ __launch_bounds__(TPB) void k_stats3(const uintT* __restrict__ Xt, double* __restrict__ part){
  int bo = blockIdx.x, zb = blockIdx.y;
  double s = 0.0, p = 0.0;
  for (int zz = 0; zz < 4; ++zz){
    const uintT* pl = Xt + ((size_t)bo*64 + zb*4 + zz)*2016;
    for (int idx = threadIdx.x; idx < 2016; idx += TPB){
      float2 v = up2(pl[idx]);
      double q = (double)v.x*v.x + (double)v.y*v.y;
      p += (idx < 63) ? q : 2.0*q;
      if (idx == 31) s += v.x;
    }
  }
  __shared__ double sh[TPB], sh2[TPB];
  sh[threadIdx.x] = s; sh2[threadIdx.x] = p;
  __syncthreads();
  for (int o = 128; o > 0; o >>= 1){
    if (threadIdx.x < o){ sh[threadIdx.x] += sh[threadIdx.x+o]; sh2[threadIdx.x] += sh2[threadIdx.x+o]; }
    __syncthreads();
  }
  if (threadIdx.x == 0){
    part[((size_t)bo*16 + zb)*2 + 0] = sh[0];
    part[((size_t)bo*16 + zb)*2 + 1] = sh2[0];
  }
}

__global__ void k_fstat(const double* __restrict__ part, const float* __restrict__ bias,
                        const float* __restrict__ g, const float* __restrict__ bsh,
                        float2* __restrict__ ss, int O){
  int o = threadIdx.x;
  if (o >= O) return;
  double S = 0.0, P = 0.0;
  for (int b = 0; b < 2; ++b)
    for (int zb = 0; zb < 16; ++zb){
      size_t base = ((size_t)(b*O + o)*16 + zb)*2;
      S += part[base]; P += part[base+1];
    }
  P *= (1.0/4096.0);
  double N = 524288.0;
  double bi = bias[o];
  double mean = S/N + bi;
  double var = P/N + 2.0*bi*S/N + bi*bi - mean*mean;
  double sc = (double)g[o] / sqrt(var + 1e-5);
  ss[o] = make_float2((float)sc, (float)((bi - mean)*sc + (double)bsh[o]));
}

// ---------------- fused ifft2 + BN + ReLU + mean over gamma ----------------
__global__ __launch_bounds__(TPB) void k_final(const uintT* __restrict__ Xt, const float2* __restrict__ ss,
                                               float* __restrict__ out, int O){
  __shared__ float2 W[64];
  __shared__ __attribute__((aligned(16))) float2 bufR[33*65];
  __shared__ float s4[4*64];
  int bo = blockIdx.x >> 6;
  int o = bo % O;
  init_W(W, 1.f);
  int tid = threadIdx.x, lane = tid & 63, wid = tid >> 6;
  int rl = (int)(__brev((uintT)lane) >> 26);
  const uintT* src = Xt + (size_t)blockIdx.x*2016;
  inv_stage_rows(src, bufR, W, lane, wid, rl);
  float2 sv = ss[o];
  float acc = 0.f;
  #pragma unroll 2
  for (int j = 0; j < 8; ++j){
    int pc = wid*8 + j;
    float2 w = inv_col_pack(bufR, lane, pc);
    float2 x = fft64_lane(w, W, lane);
    acc += fmaxf(fmaf(x.x*(1.f/4096.f), sv.x, sv.y), 0.f);
    acc += fmaxf(fmaf(x.y*(1.f/4096.f), sv.x, sv.y), 0.f);
  }
  s4[wid*64 + rl] = acc;
  __syncthreads();
  if (tid < 64)
    out[(size_t)blockIdx.x*64 + tid] = (s4[tid] + s4[64+tid] + s4[128+tid] + s4[192+tid]) * (1.f/64.f);
}

extern "C" void kernel_launch(void* const* d_in, const int* in_sizes, int n_in,
                              void* d_out, int out_size, void* d_ws, size_t ws_size,
                              hipStream_t stream){
  const float* x   = (const float*)d_in[0];
  const float* ks2 = (const float*)d_in[1];
  const float* bs2 = (const float*)d_in[2];
  const float* k1  = (const float*)d_in[3];
  const float* b1c = (const float*)d_in[4];
  const float* k2  = (const float*)d_in[5];
  const float* b2c = (const float*)d_in[6];
  const float* k3  = (const float*)d_in[7];
  const float* b3c = (const float*)d_in[8];
  const float* g1 = (const float*)d_in[9],  *bb1 = (const float*)d_in[10];
  const float* g2 = (const float*)d_in[11], *bb2 = (const float*)d_in[12];
  const float* g3 = (const float*)d_in[13], *bb3 = (const float*)d_in[14];
  const float* g4 = (const float*)d_in[15], *bb4 = (const float*)d_in[16];
  float* out = (float*)d_out;

  char* w = (char*)d_ws;
  size_t off = 0;
  auto take = [&](size_t bytes)->char*{
    char* p = w + off;
    off += (bytes + 255) & ~(size_t)255;
    return p;
  };
  float*  Dz2  = (float*) take(32ull*8*64*32*8*4);    // 16.8 MB tiled
  float*  D0   = (float*) take(64ull*32*32*4);
  float*  Deq  = (float*) take(32ull*63*63*4);
  double* lf   = (double*)take(65*8);
  double* qw   = (double*)take(64*8);
  double* part = (double*)take(75ull*64*2*8);
  float2* ss   = (float2*)take(75*8);
  float2* KhS2 = (float2*)take(63ull*25*3*8);
  float2* Kh1  = (float2*)take(63ull*25*25*8);
  float2* Kh2  = (float2*)take(63ull*25*50*8);
  float2* Kh3  = (float2*)take(63ull*36*75*8);
  float2* XH2  = (float2*)take(2ull*3*64*63*8);
  float2* F2   = (float2*)take(2ull*3*32*63*8);
  ushortT* X1  = (ushortT*)take(2ull*25*262144*2);
  ushortT* X2  = (ushortT*)take(2ull*25*262144*2);
  ushortT* X3  = (ushortT*)take(2ull*25*262144*2);
  uintT*  Ah   = (uintT*) take(150ull*32*2016*4);     // 38.7 MB bf16-packed
  uintT*  Bh   = (uintT*) take(150ull*32*2016*4);
  uintT*  P    = (uintT*) take(150ull*32*2016*4);     // 38.7 MB bf16-packed (F, C in-place)
  if (off > ws_size) return;

  dim3 tpb(TPB);
  auto cdiv = [](long long a, long long b){ return (int)((a + b - 1) / b); };

  k_tables<<<1, 64, 0, stream>>>(lf, qw);
  k_wigner<<<dim3(65,32), tpb, 0, stream>>>(lf, Dz2, D0, Deq);
  k_kh<<<cdiv(3ll*25*63,TPB),  tpb, 0, stream>>>(ks2, KhS2, 3, 25,  (float)(1.0/sqrt(196608.0)));
  k_kh<<<cdiv(25ll*25*63,TPB), tpb, 0, stream>>>(k1,  Kh1, 25, 25, (float)(1.0/sqrt(1600.0)));
  k_kh<<<cdiv(50ll*25*63,TPB), tpb, 0, stream>>>(k2,  Kh2, 50, 25, (float)(1.0/sqrt(3200.0)));
  k_kh<<<cdiv(75ll*36*63,TPB), tpb, 0, stream>>>(k3,  Kh3, 75, 36, (float)(1.0/sqrt(4800.0)));

  // ---- S2 conv ----
  k_s2_fft<<<cdiv(2ll*3*64*63,TPB), tpb, 0, stream>>>(x, XH2);
  k_s2_F<<<cdiv(2ll*3*32*63,TPB), tpb, 0, stream>>>(D0, qw, XH2, F2);
  k_s2_zhat<<<cdiv(2ll*25*32*2016,TPB), tpb, 0, stream>>>(Deq, F2, KhS2, Ah);
  k_wig_synth<<<dim3(32,8,2*cdiv(50,16)), tpb, 0, stream>>>(Dz2, Ah, Bh, 50);
  k_ifft2_sym<<<50*64, tpb, 0, stream>>>(Bh, X1, bs2, 25);
  k_bnstats<<<dim3(25,64), tpb, 0, stream>>>(X1, 0, part);

  // ---- generic SO3 conv ----
  auto so3 = [&](const ushortT* Xa, const ushortT* Xb, const ushortT* Xc, int Cin,
                 const float* g, const float* bb, const float2* Kh, int O,
                 const float* bias, ushortT* Xout, int isFinal){
    int BC = 2*Cin, BO = 2*O;
    k_bnfinal<<<1, 128, 0, stream>>>(part, g, bb, ss, Cin);
    k_fft2_fwd<<<dim3(BC,32), tpb, 0, stream>>>(Xa, Xb, Xc, ss, Ah, Cin, 0);
    k_fft2_fwd<<<dim3(BC,32), tpb, 0, stream>>>(Xa, Xb, Xc, ss, Bh, Cin, 32);
    k_wig_F<<<dim3(32,8,cdiv(BC,16)), tpb, 0, stream>>>(Dz2, qw, Ah, Bh, P, BC);
    k_deq_C<<<dim3(32,32,cdiv(BC,64)), tpb, 0, stream>>>(Deq, P, P, BC);        // C in-place (packed)
    k_kh_z<<<dim3(32,4,cdiv(O,KOC)), tpb, 0, stream>>>(P, Kh, Ah, Cin, O);      // Z packed -> Ah
    k_wig_synth<<<dim3(32,8,2*cdiv(BO,16)), tpb, 0, stream>>>(Dz2, Ah, Bh, BO); // Xt packed -> Bh
    if (!isFinal){
      k_ifft2_sym<<<BO*64, tpb, 0, stream>>>(Bh, Xout, bias, O);
    } else {
      k_stats3<<<dim3(BO,16), tpb, 0, stream>>>(Bh, part);
      k_fstat<<<1, 64, 0, stream>>>(part, bias, g4, bb4, ss, O);
      k_final<<<BO*64, tpb, 0, stream>>>(Bh, ss, out, O);
    }
  };

  so3(X1, X1, X1, 25, g1, bb1, Kh1, 25, b1c, X2, 0);
  k_bnstats<<<dim3(25,64), tpb, 0, stream>>>(X2, 25, part);
  so3(X1, X2, X2, 50, g2, bb2, Kh2, 25, b2c, X3, 0);
  k_bnstats<<<dim3(25,64), tpb, 0, stream>>>(X3, 50, part);
  so3(X1, X2, X3, 75, g3, bb3, Kh3, 36, b3c, nullptr, 1);
}

// Round 17
// 1231.794 us; speedup vs baseline: 1.9561x; 1.0394x over previous
//
#include <hip/hip_runtime.h>
#include <math.h>

#define PI_D 3.14159265358979323846
#define TPB 256
typedef unsigned short ushortT;
typedef unsigned int uintT;

__device__ __forceinline__ float2 cxmul(float2 a, float2 b){
  return make_float2(a.x*b.x - a.y*b.y, a.x*b.y + a.y*b.x);
}
__device__ __forceinline__ float bf2f(ushortT u){
  uintT x = ((uintT)u) << 16;
  return __uint_as_float(x);
}
__device__ __forceinline__ ushortT f2bf(float f){
  uintT x = __float_as_uint(f);
  x = x + 0x7FFFu + ((x >> 16) & 1u);
  return (ushortT)(x >> 16);
}
__device__ __forceinline__ uintT pk2(float2 v){
  return (uintT)f2bf(v.x) | ((uintT)f2bf(v.y) << 16);
}
__device__ __forceinline__ float2 up2(uintT u){
  return make_float2(bf2f((ushortT)(u & 0xffff)), bf2f((ushortT)(u >> 16)));
}

// ---------------- tables ----------------
__global__ void k_tables(double* lf, double* qw){
  if (threadIdx.x == 0){
    lf[0] = 0.0;
    for (int i = 1; i <= 64; ++i) lf[i] = lf[i-1] + log((double)i);
  }
  int j = threadIdx.x;
  if (j < 64){
    double s1 = sin(PI_D*(2*j+1)/128.0);
    double inner = 0.0;
    for (int k = 0; k < 32; ++k)
      inner += (1.0/(double)(2*k+1)) * sin((double)(2*j+1)*(double)(2*k+1)*PI_D/128.0);
    qw[j] = (2.0/32.0) * s1 * inner;
  }
}

// ratio-recurrence wigd: one exp per entry, exp-free inner loop
__device__ double wigd(const double* lfs, const double* dinv, int l, int mp, int m,
                       double lc, double ls, double tsq){
  if (mp < -l || mp > l || m < -l || m > l) return 0.0;
  int k0 = (m - mp > 0) ? (m - mp) : 0;
  int k1 = (l + m < l - mp) ? (l + m) : (l - mp);
  double base = 0.5*(lfs[l+mp] + lfs[l-mp] + lfs[l+m] + lfs[l-m]);
  double t0 = base - lfs[l+m-k0] - lfs[k0] - lfs[mp-m+k0] - lfs[l-mp-k0]
            + (double)(2*l + m - mp - 2*k0)*lc + (double)(mp - m + 2*k0)*ls;
  double t = exp(t0);
  if ((mp - m + k0) & 1) t = -t;
  double val = t;
  for (int k = k0; k < k1; ++k){
    t *= -((double)((l+m-k)*(l-mp-k))) * dinv[k+1] * dinv[mp-m+k+1] * tsq;
    val += t;
  }
  return val;
}

// Dz2[mi][nt][z][l][nn] (n = nt*8+nn, zero pad n=63), D0[z][l][mi], Deq[l][r][c]
__global__ __launch_bounds__(TPB) void k_wigner(const double* __restrict__ lf,
                                                float* __restrict__ Dz2, float* __restrict__ D0,
                                                float* __restrict__ Deq){
  __shared__ double lfs[65];
  __shared__ double dinv[65];
  if (threadIdx.x < 65){
    lfs[threadIdx.x] = lf[threadIdx.x];
    dinv[threadIdx.x] = (threadIdx.x > 0) ? 1.0/(double)threadIdx.x : 0.0;
  }
  __syncthreads();
  int zs = blockIdx.x, l = blockIdx.y;
  double beta = (zs < 64) ? ((double)zs + 0.5)*PI_D/64.0 : PI_D*0.5;
  double ch = cos(beta*0.5), sh = sin(beta*0.5);
  double lc = log(ch), ls = log(sh);
  double tsq = (sh/ch)*(sh/ch);
  if (zs < 64){
    for (int idx = threadIdx.x; idx < 2048; idx += TPB){
      int mi = idx >> 6, nf = idx & 63;
      float v = (nf < 63) ? (float)wigd(lfs, dinv, l, mi, nf-31, lc, ls, tsq) : 0.f;
      int nt = nf >> 3, nn = nf & 7;
      Dz2[(((size_t)(mi*8 + nt)*64 + zs)*32 + l)*8 + nn] = v;
      if (nf == 31) D0[((size_t)zs*32 + l)*32 + mi] = v;
    }
  } else {
    for (int idx = threadIdx.x; idx < 3969; idx += TPB){
      int r = idx/63, c = idx%63;
      Deq[((size_t)l*63 + r)*63 + c] = (float)wigd(lfs, dinv, l, r-31, c-31, lc, ls, tsq);
    }
  }
}

// Kh[o][i][n]
__global__ void k_kh(const float* __restrict__ K, float2* __restrict__ Kh, int I, int O, float scale){
  int idx = blockIdx.x*blockDim.x + threadIdx.x;
  if (idx >= I*O*63) return;
  int n = idx % 63, i = (idx/63) % I, o = idx/(63*I);
  float sr = 0.f, si = 0.f;
  for (int p = 0; p < 64; ++p){
    int t = (p * (n - 31)) & 63;
    float s, c;
    sincosf(-(float)PI_D/32.f * (float)t, &s, &c);
    float kv = K[(i*O + o)*64 + p];
    sr += kv * c; si += kv * s;
  }
  Kh[((size_t)o*I + i)*63 + n] = make_float2(sr*scale, si*scale);
}

// ---------------- S2 front ----------------
__global__ void k_s2_fft(const float* __restrict__ x, float2* __restrict__ XH2){
  int idx = blockIdx.x*blockDim.x + threadIdx.x;
  if (idx >= 2*3*64*63) return;
  int mi = idx % 63; int z = (idx/63) & 63; int bc = idx / (63*64);
  int f = (mi + 33) & 63;
  const float* row = x + ((size_t)bc*64 + z)*64;
  float sr = 0.f, si = 0.f;
  for (int a = 0; a < 64; ++a){
    int t = (f*a) & 63;
    float s, c;
    sincosf(-(float)PI_D/32.f * (float)t, &s, &c);
    sr += row[a]*c; si += row[a]*s;
  }
  XH2[idx] = make_float2(sr, si);
}

__global__ void k_s2_F(const float* __restrict__ D0, const double* __restrict__ qw,
                       const float2* __restrict__ XH2, float2* __restrict__ F2){
  int idx = blockIdx.x*blockDim.x + threadIdx.x;
  if (idx >= 2*3*32*63) return;
  int r = idx % 63; int l = (idx/63) & 31; int bc = idx / (63*32);
  float2 acc = make_float2(0,0);
  for (int z = 0; z < 64; ++z){
    float d;
    if (r >= 31) d = D0[((size_t)z*32 + l)*32 + (r-31)];
    else {
      d = D0[((size_t)z*32 + l)*32 + (31-r)];
      if ((31-r) & 1) d = -d;
    }
    float wv = (float)qw[z] * d;
    float2 v = XH2[((size_t)bc*64 + z)*63 + r];
    acc.x += wv*v.x; acc.y += wv*v.y;
  }
  F2[idx] = acc;
}

__global__ void k_s2_zhat(const float* __restrict__ Deq, const float2* __restrict__ F2,
                          const float2* __restrict__ Kh, uintT* __restrict__ Z){
  int idx = blockIdx.x*blockDim.x + threadIdx.x;
  if (idx >= 2*25*32*2016) return;
  int n = idx % 63; int mi = (idx/63) & 31; int l = (idx/2016) & 31;
  int o = (idx/(2016*32)) % 25; int b = idx/(2016*32*25);
  float deq0 = Deq[((size_t)l*63 + n)*63 + 31];
  float2 acc = make_float2(0,0);
  for (int i = 0; i < 3; ++i){
    float2 f = F2[((size_t)(b*3 + i)*32 + l)*63 + (mi+31)];
    float2 kh = Kh[((size_t)(o*3 + i))*63 + n];
    acc.x = fmaf(kh.x, f.x, acc.x); acc.x = fmaf(-kh.y, f.y, acc.x);
    acc.y = fmaf(kh.x, f.y, acc.y); acc.y = fmaf(kh.y, f.x, acc.y);
  }
  Z[((size_t)((b*25+o)*32) + l)*2016 + mi*63 + n] = pk2(make_float2(acc.x*deq0, acc.y*deq0));
}

// ---------------- BN stats over bf16 X buffers ----------------
__global__ __launch_bounds__(TPB) void k_bnstats(const ushortT* __restrict__ src, int slotBase,
                                                 double* __restrict__ part){
  int c = blockIdx.x, blk = blockIdx.y;
  const uint2* s4 = (const uint2*)src;
  double s = 0.0, q = 0.0;
  for (int k = 0; k < 8; ++k){
    int g4 = blk*2048 + k*256 + threadIdx.x;
    int b = g4 >> 16, pos4 = g4 & 65535;
    uint2 u = s4[((size_t)(b*25 + c))*65536 + pos4];
    float v0 = bf2f((ushortT)(u.x & 0xffff)), v1 = bf2f((ushortT)(u.x >> 16));
    float v2 = bf2f((ushortT)(u.y & 0xffff)), v3 = bf2f((ushortT)(u.y >> 16));
    s += (double)v0 + v1 + v2 + v3;
    q += (double)v0*v0 + (double)v1*v1 + (double)v2*v2 + (double)v3*v3;
  }
  __shared__ double sh[TPB], sh2[TPB];
  sh[threadIdx.x] = s; sh2[threadIdx.x] = q;
  __syncthreads();
  for (int o = 128; o > 0; o >>= 1){
    if (threadIdx.x < o){ sh[threadIdx.x] += sh[threadIdx.x+o]; sh2[threadIdx.x] += sh2[threadIdx.x+o]; }
    __syncthreads();
  }
  if (threadIdx.x == 0){
    part[((size_t)(slotBase + c)*64 + blk)*2 + 0] = sh[0];
    part[((size_t)(slotBase + c)*64 + blk)*2 + 1] = sh2[0];
  }
}

__global__ void k_bnfinal(const double* __restrict__ part, const float* __restrict__ g,
                          const float* __restrict__ b, float2* __restrict__ ss, int C){
  int c = blockIdx.x*blockDim.x + threadIdx.x;
  if (c >= C) return;
  double s = 0.0, q = 0.0;
  for (int k = 0; k < 64; ++k){
    s += part[((size_t)c*64 + k)*2 + 0];
    q += part[((size_t)c*64 + k)*2 + 1];
  }
  double N = 524288.0;
  double mu = s / N;
  double var = q / N - mu*mu;
  double sc = (double)g[c] / sqrt(var + 1e-5);
  ss[c] = make_float2((float)sc, (float)((double)b[c] - mu*sc));
}

// ---------------- 64-pt FFT across lanes ----------------
__device__ __forceinline__ float2 fft64_lane(float2 x, const float2* __restrict__ Wt, int lane){
  #pragma unroll
  for (int st = 0; st < 6; ++st){
    int h = 32 >> st;
    float2 p;
    p.x = __shfl_xor(x.x, h, 64);
    p.y = __shfl_xor(x.y, h, 64);
    if (lane & h){
      float2 s = make_float2(p.x - x.x, p.y - x.y);
      x = cxmul(s, Wt[(lane & (h-1)) << st]);
    } else {
      x = make_float2(x.x + p.x, x.y + p.y);
    }
  }
  return x;
}
__device__ __forceinline__ void init_W(float2* W, float sign){
  if (threadIdx.x < 64){
    float s, c;
    sincosf(sign*(float)(2.0*PI_D/64.0)*(float)threadIdx.x, &s, &c);
    W[threadIdx.x] = make_float2(c, s);
  }
}

// ---------------- fused BN+ReLU + packed real fft2 -> bf16-packed XH ----------------
__global__ __launch_bounds__(TPB) void k_fft2_fwd(const ushortT* __restrict__ X1, const ushortT* __restrict__ X2,
                                                  const ushortT* __restrict__ X3, const float2* __restrict__ ss,
                                                  uintT* __restrict__ XH, int Cin, int z0){
  __shared__ float2 W[64];
  __shared__ __attribute__((aligned(16))) float2 smem[4224];
  float2* bufP = smem;
  float2* bufW = smem + 2112;
  int bc = blockIdx.x, zz = blockIdx.y, z = z0 + zz;
  int b = bc / Cin, ci = bc % Cin;
  const ushortT* src; int cl;
  if (ci < 25){ src = X1; cl = ci; }
  else if (ci < 50){ src = X2; cl = ci - 25; }
  else { src = X3; cl = ci - 50; }
  src += ((size_t)(b*25 + cl)*64 + z)*4096;
  float2 sc = ss[ci];
  init_W(W, -1.f);
  int tid = threadIdx.x, lane = tid & 63, wid = tid >> 6;
  int rl = (int)(__brev((uintT)lane) >> 26);
  const uintT* s32 = (const uintT*)src;
  for (int i = tid; i < 2048; i += TPB){
    uintT u = s32[i];
    float v0 = fmaxf(bf2f((ushortT)(u & 0xffff))*sc.x + sc.y, 0.f);
    float v1 = fmaxf(bf2f((ushortT)(u >> 16))*sc.x + sc.y, 0.f);
    int a1 = i >> 5, c = i & 31;
    bufP[a1*33 + c] = make_float2(v0, v1);
  }
  __syncthreads();
  #pragma unroll 2
  for (int j = 0; j < 8; ++j){
    int c = wid*8 + j;
    float2 x = bufP[lane*33 + c];
    x = fft64_lane(x, W, lane);
    bufW[rl*33 + c] = x;
  }
  __syncthreads();
  for (int i = tid; i < 1024; i += TPB){
    int f1 = i >> 5, c = i & 31;
    float2 Wv = bufW[f1*33 + c];
    float2 Wm = bufW[((64-f1)&63)*33 + c];
    bufP[f1*65 + 2*c]     = make_float2(0.5f*(Wv.x + Wm.x), 0.5f*(Wv.y - Wm.y));
    bufP[f1*65 + 2*c + 1] = make_float2(0.5f*(Wv.y + Wm.y), 0.5f*(Wm.x - Wv.x));
  }
  __syncthreads();
  #pragma unroll 2
  for (int j = 0; j < 8; ++j){
    int r = wid*8 + j;
    float2 x = bufP[r*65 + lane];
    x = fft64_lane(x, W, lane);
    bufP[r*65 + rl] = x;
  }
  __syncthreads();
  uintT* dst = XH + ((size_t)bc*32 + zz)*2016;
  for (int idx = tid; idx < 2016; idx += TPB){
    int mi = idx / 63, n = idx % 63;
    dst[idx] = pk2(bufP[mi*65 + ((n+33)&63)]);
  }
}

// ---------------- F[bc,l,mi,n] = sum_z qw*Dz*XH — packed, reg-prefetch pipelined ----------------
#define SKEW(e) ((e) + ((e)>>4))
__global__ __launch_bounds__(TPB) void k_wig_F(const float* __restrict__ Dz2, const double* __restrict__ qw,
                                               const uintT* __restrict__ XHa, const uintT* __restrict__ XHb,
                                               uintT* __restrict__ F, int BC){
  __shared__ __attribute__((aligned(16))) float sm[9088];
  float* Dt = sm;                          // [z16][nn8][l 36pad]
  float2* Xt = (float2*)(sm + 4608);       // [bc16][130]
  int mi = blockIdx.x, nt = blockIdx.y, bcBase = blockIdx.z*16;
  int tid = threadIdx.x;
  int bg = tid & 3, lg = (tid>>2)&7, ng = tid>>5;
  const float* DzB = Dz2 + ((size_t)(mi*8 + nt)*64)*256;
  float2 acc[4][4];
  #pragma unroll
  for (int a = 0; a < 4; ++a)
    #pragma unroll
    for (int j = 0; j < 4; ++j) acc[a][j] = make_float2(0,0);

  float pd[16]; uintT px[8];
  auto fetch = [&](int chunk){
    const uintT* XH = (chunk < 2) ? XHa : XHb;
    int zq = (chunk & 1)*16, gz0 = chunk*16;
    #pragma unroll
    for (int t = 0; t < 16; ++t)
      pd[t] = DzB[(size_t)gz0*256 + tid + t*256];
    #pragma unroll
    for (int t = 0; t < 8; ++t){
      int idx = tid + t*256;
      int bc = idx >> 7, z = (idx>>3)&15, nn = idx&7;
      int gbc = bcBase + bc, n = nt*8 + nn;
      px[t] = (gbc < BC && n < 63) ? XH[((size_t)gbc*32 + zq + z)*2016 + mi*63 + n] : 0u;
    }
  };
  fetch(0);

  for (int chunk = 0; chunk < 4; ++chunk){
    int gz0 = chunk*16;
    __syncthreads();
    #pragma unroll
    for (int t = 0; t < 16; ++t){
      int idx = tid + t*256;
      int z = idx >> 8, l = (idx>>3)&31, nn = idx&7;
      Dt[(z*8+nn)*36 + l] = pd[t] * (float)qw[gz0+z];
    }
    #pragma unroll
    for (int t = 0; t < 8; ++t){
      int idx = tid + t*256;
      int bc = idx >> 7, z = (idx>>3)&15, nn = idx&7;
      Xt[bc*130 + z*8 + nn] = up2(px[t]);
    }
    __syncthreads();
    if (chunk + 1 < 4) fetch(chunk + 1);
    #pragma unroll 4
    for (int z = 0; z < 16; ++z){
      const float4 d = *(const float4*)&Dt[(z*8+ng)*36 + lg*4];
      float dd[4] = {d.x, d.y, d.z, d.w};
      float2 xv[4];
      #pragma unroll
      for (int j = 0; j < 4; ++j) xv[j] = Xt[(bg + 4*j)*130 + z*8 + ng];
      #pragma unroll
      for (int j = 0; j < 4; ++j)
        #pragma unroll
        for (int dl = 0; dl < 4; ++dl){
          acc[j][dl].x = fmaf(dd[dl], xv[j].x, acc[j][dl].x);
          acc[j][dl].y = fmaf(dd[dl], xv[j].y, acc[j][dl].y);
        }
    }
  }
  __syncthreads();
  float2* St = (float2*)sm;
  #pragma unroll
  for (int j = 0; j < 4; ++j)
    #pragma unroll
    for (int dl = 0; dl < 4; ++dl){
      int e = (bg + 4*j)*256 + (lg*4 + dl)*8 + ng;
      St[SKEW(e)] = acc[j][dl];
    }
  __syncthreads();
  for (int idx = tid; idx < 4096; idx += TPB){
    int bc = idx >> 8, l = (idx>>3)&31, nn = idx&7;
    int gbc = bcBase + bc, n = nt*8 + nn;
    if (gbc < BC && n < 63)
      F[((size_t)(gbc*32 + l))*2016 + mi*63 + n] = pk2(St[SKEW(idx)]);
  }
}

// ---------------- C[bi,l,mi,n] = sum_k F[bi,l,mi,k]*Deq[l,n,k] — packed in/out, in-place safe ----------------
__global__ __launch_bounds__(TPB) void k_deq_C(const float* __restrict__ Deq, const uintT* __restrict__ F,
                                               uintT* __restrict__ C, int BC){
  __shared__ __attribute__((aligned(16))) float sm[12604];
  float2* Fb = (float2*)sm;
  float* DeqT = sm + 8320;
  int l = blockIdx.x, mi = blockIdx.y, biBase = blockIdx.z*64;
  int tid = threadIdx.x;
  int ngr = tid & 15, big = tid >> 4;
  for (int idx = tid; idx < 3969; idx += TPB){
    int n = idx/63, k = idx - n*63;
    DeqT[k*68 + n] = Deq[((size_t)l*63 + n)*63 + k];
  }
  for (int idx = tid; idx < 4032; idx += TPB){
    int bi = idx/63, k = idx - bi*63;
    int gbi = biBase + bi;
    Fb[bi*65 + k] = (gbi < BC) ? up2(F[((size_t)(gbi*32 + l))*2016 + mi*63 + k]) : make_float2(0,0);
  }
  __syncthreads();
  float2 acc[4][4];
  #pragma unroll
  for (int a = 0; a < 4; ++a)
    #pragma unroll
    for (int j = 0; j < 4; ++j) acc[a][j] = make_float2(0,0);
  #pragma unroll 3
  for (int k = 0; k < 63; ++k){
    const float4 d = *(const float4*)&DeqT[k*68 + ngr*4];
    float dd[4] = {d.x, d.y, d.z, d.w};
    float2 fv[4];
    #pragma unroll
    for (int j = 0; j < 4; ++j) fv[j] = Fb[(big + 16*j)*65 + k];
    #pragma unroll
    for (int j = 0; j < 4; ++j)
      #pragma unroll
      for (int dn = 0; dn < 4; ++dn){
        acc[j][dn].x = fmaf(dd[dn], fv[j].x, acc[j][dn].x);
        acc[j][dn].y = fmaf(dd[dn], fv[j].y, acc[j][dn].y);
      }
  }
  __syncthreads();
  float2* St = (float2*)sm;
  #pragma unroll
  for (int j = 0; j < 4; ++j)
    #pragma unroll
    for (int dn = 0; dn < 4; ++dn){
      int n = ngr*4 + dn;
      if (n < 63) St[(big + 16*j)*63 + n] = acc[j][dn];
    }
  __syncthreads();
  for (int idx = tid; idx < 4032; idx += TPB){
    int bi = idx/63, n = idx - bi*63;
    int gbi = biBase + bi;
    if (gbi < BC) C[((size_t)(gbi*32 + l))*2016 + mi*63 + n] = pk2(St[idx]);
  }
}

// ---------------- Z[b,o,l,mi,n] = sum_i Kh[o,i,n]*C[b,i,l,mi,n] — packed C in, packed Z out ----------------
#define KOC 9
__global__ __launch_bounds__(TPB) void k_kh_z(const uintT* __restrict__ C, const float2* __restrict__ Kh,
                                              uintT* __restrict__ Z, int I, int O){
  __shared__ float2 Kt[KOC*5*64];
  const int nK = KOC*5*64;
  int l = blockIdx.x, mic = blockIdx.y, oc = blockIdx.z;
  int lane = threadIdx.x & 63, wid = threadIdx.x >> 6;
  int mi0 = mic*8 + wid*2;
  int n = lane;
  int o0 = oc*KOC;
  float2 acc[2][2][KOC];
  #pragma unroll
  for (int ml = 0; ml < 2; ++ml)
    #pragma unroll
    for (int b = 0; b < 2; ++b)
      #pragma unroll
      for (int oo = 0; oo < KOC; ++oo) acc[ml][b][oo] = make_float2(0,0);

  float2 pre[12];
  auto loadK = [&](int i0){
    #pragma unroll
    for (int t = 0; t < 12; ++t){
      int idx = threadIdx.x + t*256;
      float2 v = make_float2(0,0);
      if (idx < nK){
        int nn = idx & 63, rem = idx >> 6;
        int ic = rem % 5, oo = rem / 5;
        int o = o0 + oo;
        if (o < O && nn < 63) v = Kh[((size_t)o*I + (i0+ic))*63 + nn];
      }
      pre[t] = v;
    }
  };
  loadK(0);

  size_t cBase0 = ((size_t)l)*2016 + mi0*63 + n;
  size_t cBase1 = cBase0 + 63;
  int nch = I/5;
  for (int c = 0; c < nch; ++c){
    __syncthreads();
    #pragma unroll
    for (int t = 0; t < 12; ++t){
      int idx = threadIdx.x + t*256;
      if (idx < nK) Kt[idx] = pre[t];
    }
    __syncthreads();
    if (c+1 < nch) loadK((c+1)*5);
    if (n < 63){
      int i0 = c*5;
      float2 cv[5][4];
      #pragma unroll
      for (int ic = 0; ic < 5; ++ic){
        int i = i0 + ic;
        cv[ic][0] = up2(C[cBase0 + (size_t)i*64512]);
        cv[ic][1] = up2(C[cBase0 + (size_t)(I + i)*64512]);
        cv[ic][2] = up2(C[cBase1 + (size_t)i*64512]);
        cv[ic][3] = up2(C[cBase1 + (size_t)(I + i)*64512]);
      }
      #pragma unroll
      for (int ic = 0; ic < 5; ++ic){
        #pragma unroll
        for (int oo = 0; oo < KOC; ++oo){
          float2 kh = Kt[(oo*5 + ic)*64 + n];
          #pragma unroll
          for (int q = 0; q < 4; ++q){
            float2 cc = cv[ic][q];
            int ml = q >> 1, b = q & 1;
            acc[ml][b][oo].x = fmaf(kh.x, cc.x, acc[ml][b][oo].x);
            acc[ml][b][oo].x = fmaf(-kh.y, cc.y, acc[ml][b][oo].x);
            acc[ml][b][oo].y = fmaf(kh.x, cc.y, acc[ml][b][oo].y);
            acc[ml][b][oo].y = fmaf(kh.y, cc.x, acc[ml][b][oo].y);
          }
        }
      }
    }
  }
  if (n < 63){
    #pragma unroll
    for (int ml = 0; ml < 2; ++ml){
      size_t zBase = ((size_t)l)*2016 + (mi0 + ml)*63 + n;
      #pragma unroll
      for (int oo = 0; oo < KOC; ++oo){
        int o = o0 + oo;
        if (o < O){
          Z[zBase + (size_t)(0*O + o)*64512] = pk2(acc[ml][0][oo]);
          Z[zBase + (size_t)(1*O + o)*64512] = pk2(acc[ml][1][oo]);
        }
      }
    }
  }
}

// ---------------- Xt[bo,z,mi,n] = sum_l wl*Dz*Z — packed, reg-prefetch pipelined ----------------
__global__ __launch_bounds__(TPB) void k_wig_synth(const float* __restrict__ Dz2, const uintT* __restrict__ Z,
                                                   uintT* __restrict__ Xt_g, int BO){
  __shared__ __attribute__((aligned(16))) float sm[9088];
  float* Dt = sm;                          // [l16][nn8][z 36pad]
  float2* Zt = (float2*)(sm + 4608);       // [bo16][130]
  int mi = blockIdx.x, nt = blockIdx.y;
  int z0 = (blockIdx.z & 1)*32;
  int boBase = (blockIdx.z >> 1)*16;
  int tid = threadIdx.x;
  int bg = tid & 3, zg = (tid>>2)&7, ng = tid>>5;
  const float* DzB = Dz2 + ((size_t)(mi*8 + nt)*64)*256;
  float2 acc[4][4];
  #pragma unroll
  for (int a = 0; a < 4; ++a)
    #pragma unroll
    for (int j = 0; j < 4; ++j) acc[a][j] = make_float2(0,0);

  float pd[16]; uintT pz[8];
  auto fetch = [&](int lq){
    #pragma unroll
    for (int t = 0; t < 16; ++t){
      int idx = tid + t*256;
      int z = idx >> 7, ll = (idx>>3)&15, nn = idx&7;
      int lG = lq + ll;
      pd[t] = DzB[(size_t)(z0+z)*256 + lG*8 + nn];
    }
    #pragma unroll
    for (int t = 0; t < 8; ++t){
      int idx = tid + t*256;
      int bo = idx >> 7, ll = (idx>>3)&15, nn = idx&7;
      int gbo = boBase + bo, n = nt*8 + nn;
      pz[t] = (gbo < BO && n < 63) ? Z[((size_t)(gbo*32 + lq + ll))*2016 + mi*63 + n] : 0u;
    }
  };
  fetch(0);

  for (int lq = 0; lq < 32; lq += 16){
    __syncthreads();
    #pragma unroll
    for (int t = 0; t < 16; ++t){
      int idx = tid + t*256;
      int z = idx >> 7, ll = (idx>>3)&15, nn = idx&7;
      int lG = lq + ll;
      Dt[(ll*8+nn)*36 + z] = pd[t] * (0.5f*(float)(2*lG+1));
    }
    #pragma unroll
    for (int t = 0; t < 8; ++t){
      int idx = tid + t*256;
      int bo = idx >> 7, ll = (idx>>3)&15, nn = idx&7;
      Zt[bo*130 + ll*8 + nn] = up2(pz[t]);
    }
    __syncthreads();
    if (lq == 0) fetch(16);
    #pragma unroll 4
    for (int ll = 0; ll < 16; ++ll){
      const float4 d = *(const float4*)&Dt[(ll*8+ng)*36 + zg*4];
      float dd[4] = {d.x, d.y, d.z, d.w};
      float2 zv[4];
      #pragma unroll
      for (int j = 0; j < 4; ++j) zv[j] = Zt[(bg + 4*j)*130 + ll*8 + ng];
      #pragma unroll
      for (int j = 0; j < 4; ++j)
        #pragma unroll
        for (int dz = 0; dz < 4; ++dz){
          acc[j][dz].x = fmaf(dd[dz], zv[j].x, acc[j][dz].x);
          acc[j][dz].y = fmaf(dd[dz], zv[j].y, acc[j][dz].y);
        }
    }
  }
  __syncthreads();
  float2* St = (float2*)sm;
  #pragma unroll
  for (int j = 0; j < 4; ++j)
    #pragma unroll
    for (int dz = 0; dz < 4; ++dz){
      int e = (bg + 4*j)*256 + (zg*4 + dz)*8 + ng;
      St[SKEW(e)] = acc[j][dz];
    }
  __syncthreads();
  for (int idx = tid; idx < 4096; idx += TPB){
    int bo = idx >> 8, z = (idx>>3)&31, nn = idx&7;
    int gbo = boBase + bo, n = nt*8 + nn;
    if (gbo < BO && n < 63)
      Xt_g[((size_t)gbo*64 + z0 + z)*2016 + mi*63 + n] = pk2(St[SKEW(idx)]);
  }
}

// ---------------- inverse helpers (bf16-packed src) ----------------
__device__ __forceinline__ void inv_stage_rows(const uintT* __restrict__ src, float2* bufR,
                                               const float2* W, int lane, int wid, int rl){
  int tid = threadIdx.x;
  if (tid < 64) bufR[32*65 + tid] = make_float2(0,0);
  else if (tid < 96) bufR[(tid-64)*65 + 32] = make_float2(0,0);
  for (int idx = tid; idx < 2016; idx += TPB){
    int mi = idx / 63, ni = idx - mi*63;
    bufR[mi*65 + ((ni+33)&63)] = up2(src[idx]);
  }
  __syncthreads();
  #pragma unroll 2
  for (int j = 0; j < 8; ++j){
    int r = wid*8 + j;
    float2 x = bufR[r*65 + lane];
    x = fft64_lane(x, W, lane);
    bufR[r*65 + rl] = x;
  }
  __syncthreads();
}
__device__ __forceinline__ float2 inv_col_pack(const float2* bufR, int f, int pc){
  float2 r0, r1;
  if (f <= 32){
    r0 = bufR[f*65 + 2*pc];
    r1 = bufR[f*65 + 2*pc + 1];
  } else {
    int g = 64 - f;
    float2 a = bufR[g*65 + 2*pc];
    float2 b = bufR[g*65 + 2*pc + 1];
    r0 = make_float2(a.x, -a.y);
    r1 = make_float2(b.x, -b.y);
  }
  return make_float2(r0.x - r1.y, r0.y + r1.x);
}

// ---------------- ifft2 + real + bias -> bf16 X ----------------
__global__ __launch_bounds__(TPB) void k_ifft2_sym(const uintT* __restrict__ Xt, ushortT* __restrict__ Xo,
                                                   const float* __restrict__ bias, int O){
  __shared__ float2 W[64];
  __shared__ __attribute__((aligned(16))) float2 bufR[33*65];
  __shared__ uintT ldsOut[64*33];
  int bo = blockIdx.x >> 6;
  int o = bo % O;
  init_W(W, 1.f);
  int tid = threadIdx.x, lane = tid & 63, wid = tid >> 6;
  int rl = (int)(__brev((uintT)lane) >> 26);
  const uintT* src = Xt + (size_t)blockIdx.x*2016;
  inv_stage_rows(src, bufR, W, lane, wid, rl);
  float bb = bias[o];
  #pragma unroll 2
  for (int j = 0; j < 8; ++j){
    int pc = wid*8 + j;
    float2 w = inv_col_pack(bufR, lane, pc);
    float2 x = fft64_lane(w, W, lane);
    ushortT u0 = f2bf(x.x*(1.f/4096.f) + bb);
    ushortT u1 = f2bf(x.y*(1.f/4096.f) + bb);
    ldsOut[rl*33 + pc] = (uintT)u0 | ((uintT)u1 << 16);
  }
  __syncthreads();
  uintT* dst = (uintT*)(Xo + (size_t)blockIdx.x*4096);
  for (int i = tid; i < 2048; i += TPB){
    int a1 = i >> 5, pc = i & 31;
    dst[i] = ldsOut[a1*33 + pc];
  }
}

// ---------------- conv3 final stats from spectrum (Parseval, bf16-packed) ----------------
__global__ __launch_bounds__(TPB) void k_stats3(const uintT* __restrict__ Xt, double* __restrict__ part){
  int bo = blockIdx.x, zb = blockIdx.y;
  double s = 0.0, p = 0.0;
  for (int zz = 0; zz < 4; ++zz){
    const uintT* pl = Xt + ((size_t)bo*64 + zb*4 + zz)*2016;
    for (int idx = threadIdx.x; idx < 2016; idx += TPB){
      float2 v = up2(pl[idx]);
      double q = (double)v.x*v.x + (double)v.y*v.y;
      p += (idx < 63) ? q : 2.0*q;
      if (idx == 31) s += v.x;
    }
  }
  __shared__ double sh[TPB], sh2[TPB];
  sh[threadIdx.x] = s; sh2[threadIdx.x] = p;
  __syncthreads();
  for (int o = 128; o > 0; o >>= 1){
    if (threadIdx.x < o){ sh[threadIdx.x] += sh[threadIdx.x+o]; sh2[threadIdx.x] += sh2[threadIdx.x+o]; }
    __syncthreads();
  }
  if (threadIdx.x == 0){
    part[((size_t)bo*16 + zb)*2 + 0] = sh[0];
    part[((size_t)bo*16 + zb)*2 + 1] = sh2[0];
  }
}

__global__ void k_fstat(const double* __restrict__ part, const float* __restrict__ bias,
                        const float* __restrict__ g, const float* __restrict__ bsh,
                        float2* __restrict__ ss, int O){
  int o = threadIdx.x;
  if (o >= O) return;
  double S = 0.0, P = 0.0;
  for (int b = 0; b < 2; ++b)
    for (int zb = 0; zb < 16; ++zb){
      size_t base = ((size_t)(b*O + o)*16 + zb)*2;
      S += part[base]; P += part[base+1];
    }
  P *= (1.0/4096.0);
  double N = 524288.0;
  double bi = bias[o];
  double mean = S/N + bi;
  double var = P/N + 2.0*bi*S/N + bi*bi - mean*mean;
  double sc = (double)g[o] / sqrt(var + 1e-5);
  ss[o] = make_float2((float)sc, (float)((bi - mean)*sc + (double)bsh[o]));
}

// ---------------- fused ifft2 + BN + ReLU + mean over gamma ----------------
__global__ __launch_bounds__(TPB) void k_final(const uintT* __restrict__ Xt, const float2* __restrict__ ss,
                                               float* __restrict__ out, int O){
  __shared__ float2 W[64];
  __shared__ __attribute__((aligned(16))) float2 bufR[33*65];
  __shared__ float s4[4*64];
  int bo = blockIdx.x >> 6;
  int o = bo % O;
  init_W(W, 1.f);
  int tid = threadIdx.x, lane = tid & 63, wid = tid >> 6;
  int rl = (int)(__brev((uintT)lane) >> 26);
  const uintT* src = Xt + (size_t)blockIdx.x*2016;
  inv_stage_rows(src, bufR, W, lane, wid, rl);
  float2 sv = ss[o];
  float acc = 0.f;
  #pragma unroll 2
  for (int j = 0; j < 8; ++j){
    int pc = wid*8 + j;
    float2 w = inv_col_pack(bufR, lane, pc);
    float2 x = fft64_lane(w, W, lane);
    acc += fmaxf(fmaf(x.x*(1.f/4096.f), sv.x, sv.y), 0.f);
    acc += fmaxf(fmaf(x.y*(1.f/4096.f), sv.x, sv.y), 0.f);
  }
  s4[wid*64 + rl] = acc;
  __syncthreads();
  if (tid < 64)
    out[(size_t)blockIdx.x*64 + tid] = (s4[tid] + s4[64+tid] + s4[128+tid] + s4[192+tid]) * (1.f/64.f);
}

extern "C" void kernel_launch(void* const* d_in, const int* in_sizes, int n_in,
                              void* d_out, int out_size, void* d_ws, size_t ws_size,
                              hipStream_t stream){
  const float* x   = (const float*)d_in[0];
  const float* ks2 = (const float*)d_in[1];
  const float* bs2 = (const float*)d_in[2];
  const float* k1  = (const float*)d_in[3];
  const float* b1c = (const float*)d_in[4];
  const float* k2  = (const float*)d_in[5];
  const float* b2c = (const float*)d_in[6];
  const float* k3  = (const float*)d_in[7];
  const float* b3c = (const float*)d_in[8];
  const float* g1 = (const float*)d_in[9],  *bb1 = (const float*)d_in[10];
  const float* g2 = (const float*)d_in[11], *bb2 = (const float*)d_in[12];
  const float* g3 = (const float*)d_in[13], *bb3 = (const float*)d_in[14];
  const float* g4 = (const float*)d_in[15], *bb4 = (const float*)d_in[16];
  float* out = (float*)d_out;

  char* w = (char*)d_ws;
  size_t off = 0;
  auto take = [&](size_t bytes)->char*{
    char* p = w + off;
    off += (bytes + 255) & ~(size_t)255;
    return p;
  };
  float*  Dz2  = (float*) take(32ull*8*64*32*8*4);    // 16.8 MB tiled
  float*  D0   = (float*) take(64ull*32*32*4);
  float*  Deq  = (float*) take(32ull*63*63*4);
  double* lf   = (double*)take(65*8);
  double* qw   = (double*)take(64*8);
  double* part = (double*)take(75ull*64*2*8);
  float2* ss   = (float2*)take(75*8);
  float2* KhS2 = (float2*)take(63ull*25*3*8);
  float2* Kh1  = (float2*)take(63ull*25*25*8);
  float2* Kh2  = (float2*)take(63ull*25*50*8);
  float2* Kh3  = (float2*)take(63ull*36*75*8);
  float2* XH2  = (float2*)take(2ull*3*64*63*8);
  float2* F2   = (float2*)take(2ull*3*32*63*8);
  ushortT* X1  = (ushortT*)take(2ull*25*262144*2);
  ushortT* X2  = (ushortT*)take(2ull*25*262144*2);
  ushortT* X3  = (ushortT*)take(2ull*25*262144*2);
  uintT*  Ah   = (uintT*) take(150ull*32*2016*4);     // 38.7 MB bf16-packed
  uintT*  Bh   = (uintT*) take(150ull*32*2016*4);
  uintT*  P    = (uintT*) take(150ull*32*2016*4);     // 38.7 MB bf16-packed (F, C in-place)
  if (off > ws_size) return;

  dim3 tpb(TPB);
  auto cdiv = [](long long a, long long b){ return (int)((a + b - 1) / b); };

  k_tables<<<1, 64, 0, stream>>>(lf, qw);
  k_wigner<<<dim3(65,32), tpb, 0, stream>>>(lf, Dz2, D0, Deq);
  k_kh<<<cdiv(3ll*25*63,TPB),  tpb, 0, stream>>>(ks2, KhS2, 3, 25,  (float)(1.0/sqrt(196608.0)));
  k_kh<<<cdiv(25ll*25*63,TPB), tpb, 0, stream>>>(k1,  Kh1, 25, 25, (float)(1.0/sqrt(1600.0)));
  k_kh<<<cdiv(50ll*25*63,TPB), tpb, 0, stream>>>(k2,  Kh2, 50, 25, (float)(1.0/sqrt(3200.0)));
  k_kh<<<cdiv(75ll*36*63,TPB), tpb, 0, stream>>>(k3,  Kh3, 75, 36, (float)(1.0/sqrt(4800.0)));

  // ---- S2 conv ----
  k_s2_fft<<<cdiv(2ll*3*64*63,TPB), tpb, 0, stream>>>(x, XH2);
  k_s2_F<<<cdiv(2ll*3*32*63,TPB), tpb, 0, stream>>>(D0, qw, XH2, F2);
  k_s2_zhat<<<cdiv(2ll*25*32*2016,TPB), tpb, 0, stream>>>(Deq, F2, KhS2, Ah);
  k_wig_synth<<<dim3(32,8,2*cdiv(50,16)), tpb, 0, stream>>>(Dz2, Ah, Bh, 50);
  k_ifft2_sym<<<50*64, tpb, 0, stream>>>(Bh, X1, bs2, 25);
  k_bnstats<<<dim3(25,64), tpb, 0, stream>>>(X1, 0, part);

  // ---- generic SO3 conv ----
  auto so3 = [&](const ushortT* Xa, const ushortT* Xb, const ushortT* Xc, int Cin,
                 const float* g, const float* bb, const float2* Kh, int O,
                 const float* bias, ushortT* Xout, int isFinal){
    int BC = 2*Cin, BO = 2*O;
    k_bnfinal<<<1, 128, 0, stream>>>(part, g, bb, ss, Cin);
    k_fft2_fwd<<<dim3(BC,32), tpb, 0, stream>>>(Xa, Xb, Xc, ss, Ah, Cin, 0);
    k_fft2_fwd<<<dim3(BC,32), tpb, 0, stream>>>(Xa, Xb, Xc, ss, Bh, Cin, 32);
    k_wig_F<<<dim3(32,8,cdiv(BC,16)), tpb, 0, stream>>>(Dz2, qw, Ah, Bh, P, BC);
    k_deq_C<<<dim3(32,32,cdiv(BC,64)), tpb, 0, stream>>>(Deq, P, P, BC);        // C in-place (packed)
    k_kh_z<<<dim3(32,4,cdiv(O,KOC)), tpb, 0, stream>>>(P, Kh, Ah, Cin, O);      // Z packed -> Ah
    k_wig_synth<<<dim3(32,8,2*cdiv(BO,16)), tpb, 0, stream>>>(Dz2, Ah, Bh, BO); // Xt packed -> Bh
    if (!isFinal){
      k_ifft2_sym<<<BO*64, tpb, 0, stream>>>(Bh, Xout, bias, O);
    } else {
      k_stats3<<<dim3(BO,16), tpb, 0, stream>>>(Bh, part);
      k_fstat<<<1, 64, 0, stream>>>(part, bias, g4, bb4, ss, O);
      k_final<<<BO*64, tpb, 0, stream>>>(Bh, ss, out, O);
    }
  };

  so3(X1, X1, X1, 25, g1, bb1, Kh1, 25, b1c, X2, 0);
  k_bnstats<<<dim3(25,64), tpb, 0, stream>>>(X2, 25, part);
  so3(X1, X2, X2, 50, g2, bb2, Kh2, 25, b2c, X3, 0);
  k_bnstats<<<dim3(25,64), tpb, 0, stream>>>(X3, 50, part);
  so3(X1, X2, X3, 75, g3, bb3, Kh3, 36, b3c, nullptr, 1);
}

// Round 18
// 1164.454 us; speedup vs baseline: 2.0693x; 1.0578x over previous
//
#include <hip/hip_runtime.h>
#include <math.h>

#define PI_D 3.14159265358979323846
#define TPB 256
typedef unsigned short ushortT;
typedef unsigned int uintT;

__device__ __forceinline__ float2 cxmul(float2 a, float2 b){
  return make_float2(a.x*b.x - a.y*b.y, a.x*b.y + a.y*b.x);
}
__device__ __forceinline__ float bf2f(ushortT u){
  uintT x = ((uintT)u) << 16;
  return __uint_as_float(x);
}
__device__ __forceinline__ ushortT f2bf(float f){
  uintT x = __float_as_uint(f);
  x = x + 0x7FFFu + ((x >> 16) & 1u);
  return (ushortT)(x >> 16);
}
__device__ __forceinline__ uintT pk2(float2 v){
  return (uintT)f2bf(v.x) | ((uintT)f2bf(v.y) << 16);
}
__device__ __forceinline__ float2 up2(uintT u){
  return make_float2(bf2f((ushortT)(u & 0xffff)), bf2f((ushortT)(u >> 16)));
}

// ---------------- tables ----------------
__global__ void k_tables(double* lf, double* qw){
  if (threadIdx.x == 0){
    lf[0] = 0.0;
    for (int i = 1; i <= 64; ++i) lf[i] = lf[i-1] + log((double)i);
  }
  int j = threadIdx.x;
  if (j < 64){
    double s1 = sin(PI_D*(2*j+1)/128.0);
    double inner = 0.0;
    for (int k = 0; k < 32; ++k)
      inner += (1.0/(double)(2*k+1)) * sin((double)(2*j+1)*(double)(2*k+1)*PI_D/128.0);
    qw[j] = (2.0/32.0) * s1 * inner;
  }
}

// ratio-recurrence wigd: one exp per entry, exp-free inner loop
__device__ double wigd(const double* lfs, const double* dinv, int l, int mp, int m,
                       double lc, double ls, double tsq){
  if (mp < -l || mp > l || m < -l || m > l) return 0.0;
  int k0 = (m - mp > 0) ? (m - mp) : 0;
  int k1 = (l + m < l - mp) ? (l + m) : (l - mp);
  double base = 0.5*(lfs[l+mp] + lfs[l-mp] + lfs[l+m] + lfs[l-m]);
  double t0 = base - lfs[l+m-k0] - lfs[k0] - lfs[mp-m+k0] - lfs[l-mp-k0]
            + (double)(2*l + m - mp - 2*k0)*lc + (double)(mp - m + 2*k0)*ls;
  double t = exp(t0);
  if ((mp - m + k0) & 1) t = -t;
  double val = t;
  for (int k = k0; k < k1; ++k){
    t *= -((double)((l+m-k)*(l-mp-k))) * dinv[k+1] * dinv[mp-m+k+1] * tsq;
    val += t;
  }
  return val;
}

// Dz2[mi][nt][z][l][nn] (n = nt*8+nn, zero pad n=63), D0[z][l][mi], Deq[l][r][c]
__global__ __launch_bounds__(TPB) void k_wigner(const double* __restrict__ lf,
                                                float* __restrict__ Dz2, float* __restrict__ D0,
                                                float* __restrict__ Deq){
  __shared__ double lfs[65];
  __shared__ double dinv[65];
  if (threadIdx.x < 65){
    lfs[threadIdx.x] = lf[threadIdx.x];
    dinv[threadIdx.x] = (threadIdx.x > 0) ? 1.0/(double)threadIdx.x : 0.0;
  }
  __syncthreads();
  int zs = blockIdx.x, l = blockIdx.y;
  double beta = (zs < 64) ? ((double)zs + 0.5)*PI_D/64.0 : PI_D*0.5;
  double ch = cos(beta*0.5), sh = sin(beta*0.5);
  double lc = log(ch), ls = log(sh);
  double tsq = (sh/ch)*(sh/ch);
  if (zs < 64){
    for (int idx = threadIdx.x; idx < 2048; idx += TPB){
      int mi = idx >> 6, nf = idx & 63;
      float v = (nf < 63) ? (float)wigd(lfs, dinv, l, mi, nf-31, lc, ls, tsq) : 0.f;
      int nt = nf >> 3, nn = nf & 7;
      Dz2[(((size_t)(mi*8 + nt)*64 + zs)*32 + l)*8 + nn] = v;
      if (nf == 31) D0[((size_t)zs*32 + l)*32 + mi] = v;
    }
  } else {
    for (int idx = threadIdx.x; idx < 3969; idx += TPB){
      int r = idx/63, c = idx%63;
      Deq[((size_t)l*63 + r)*63 + c] = (float)wigd(lfs, dinv, l, r-31, c-31, lc, ls, tsq);
    }
  }
}

// Kh[o][i][n]
__global__ void k_kh(const float* __restrict__ K, float2* __restrict__ Kh, int I, int O, float scale){
  int idx = blockIdx.x*blockDim.x + threadIdx.x;
  if (idx >= I*O*63) return;
  int n = idx % 63, i = (idx/63) % I, o = idx/(63*I);
  float sr = 0.f, si = 0.f;
  for (int p = 0; p < 64; ++p){
    int t = (p * (n - 31)) & 63;
    float s, c;
    sincosf(-(float)PI_D/32.f * (float)t, &s, &c);
    float kv = K[(i*O + o)*64 + p];
    sr += kv * c; si += kv * s;
  }
  Kh[((size_t)o*I + i)*63 + n] = make_float2(sr*scale, si*scale);
}

// ---------------- S2 front ----------------
__global__ void k_s2_fft(const float* __restrict__ x, float2* __restrict__ XH2){
  int idx = blockIdx.x*blockDim.x + threadIdx.x;
  if (idx >= 2*3*64*63) return;
  int mi = idx % 63; int z = (idx/63) & 63; int bc = idx / (63*64);
  int f = (mi + 33) & 63;
  const float* row = x + ((size_t)bc*64 + z)*64;
  float sr = 0.f, si = 0.f;
  for (int a = 0; a < 64; ++a){
    int t = (f*a) & 63;
    float s, c;
    sincosf(-(float)PI_D/32.f * (float)t, &s, &c);
    sr += row[a]*c; si += row[a]*s;
  }
  XH2[idx] = make_float2(sr, si);
}

__global__ void k_s2_F(const float* __restrict__ D0, const double* __restrict__ qw,
                       const float2* __restrict__ XH2, float2* __restrict__ F2){
  int idx = blockIdx.x*blockDim.x + threadIdx.x;
  if (idx >= 2*3*32*63) return;
  int r = idx % 63; int l = (idx/63) & 31; int bc = idx / (63*32);
  float2 acc = make_float2(0,0);
  for (int z = 0; z < 64; ++z){
    float d;
    if (r >= 31) d = D0[((size_t)z*32 + l)*32 + (r-31)];
    else {
      d = D0[((size_t)z*32 + l)*32 + (31-r)];
      if ((31-r) & 1) d = -d;
    }
    float wv = (float)qw[z] * d;
    float2 v = XH2[((size_t)bc*64 + z)*63 + r];
    acc.x += wv*v.x; acc.y += wv*v.y;
  }
  F2[idx] = acc;
}

__global__ void k_s2_zhat(const float* __restrict__ Deq, const float2* __restrict__ F2,
                          const float2* __restrict__ Kh, uintT* __restrict__ Z){
  int idx = blockIdx.x*blockDim.x + threadIdx.x;
  if (idx >= 2*25*32*2016) return;
  int n = idx % 63; int mi = (idx/63) & 31; int l = (idx/2016) & 31;
  int o = (idx/(2016*32)) % 25; int b = idx/(2016*32*25);
  float deq0 = Deq[((size_t)l*63 + n)*63 + 31];
  float2 acc = make_float2(0,0);
  for (int i = 0; i < 3; ++i){
    float2 f = F2[((size_t)(b*3 + i)*32 + l)*63 + (mi+31)];
    float2 kh = Kh[((size_t)(o*3 + i))*63 + n];
    acc.x = fmaf(kh.x, f.x, acc.x); acc.x = fmaf(-kh.y, f.y, acc.x);
    acc.y = fmaf(kh.x, f.y, acc.y); acc.y = fmaf(kh.y, f.x, acc.y);
  }
  Z[((size_t)((b*25+o)*32) + l)*2016 + mi*63 + n] = pk2(make_float2(acc.x*deq0, acc.y*deq0));
}

// ---------------- BN stats over bf16 X buffers ----------------
__global__ __launch_bounds__(TPB) void k_bnstats(const ushortT* __restrict__ src, int slotBase,
                                                 double* __restrict__ part){
  int c = blockIdx.x, blk = blockIdx.y;
  const uint2* s4 = (const uint2*)src;
  double s = 0.0, q = 0.0;
  for (int k = 0; k < 8; ++k){
    int g4 = blk*2048 + k*256 + threadIdx.x;
    int b = g4 >> 16, pos4 = g4 & 65535;
    uint2 u = s4[((size_t)(b*25 + c))*65536 + pos4];
    float v0 = bf2f((ushortT)(u.x & 0xffff)), v1 = bf2f((ushortT)(u.x >> 16));
    float v2 = bf2f((ushortT)(u.y & 0xffff)), v3 = bf2f((ushortT)(u.y >> 16));
    s += (double)v0 + v1 + v2 + v3;
    q += (double)v0*v0 + (double)v1*v1 + (double)v2*v2 + (double)v3*v3;
  }
  __shared__ double sh[TPB], sh2[TPB];
  sh[threadIdx.x] = s; sh2[threadIdx.x] = q;
  __syncthreads();
  for (int o = 128; o > 0; o >>= 1){
    if (threadIdx.x < o){ sh[threadIdx.x] += sh[threadIdx.x+o]; sh2[threadIdx.x] += sh2[threadIdx.x+o]; }
    __syncthreads();
  }
  if (threadIdx.x == 0){
    part[((size_t)(slotBase + c)*64 + blk)*2 + 0] = sh[0];
    part[((size_t)(slotBase + c)*64 + blk)*2 + 1] = sh2[0];
  }
}

__global__ void k_bnfinal(const double* __restrict__ part, const float* __restrict__ g,
                          const float* __restrict__ b, float2* __restrict__ ss, int C){
  int c = blockIdx.x*blockDim.x + threadIdx.x;
  if (c >= C) return;
  double s = 0.0, q = 0.0;
  for (int k = 0; k < 64; ++k){
    s += part[((size_t)c*64 + k)*2 + 0];
    q += part[((size_t)c*64 + k)*2 + 1];
  }
  double N = 524288.0;
  double mu = s / N;
  double var = q / N - mu*mu;
  double sc = (double)g[c] / sqrt(var + 1e-5);
  ss[c] = make_float2((float)sc, (float)((double)b[c] - mu*sc));
}

// ---------------- 64-pt FFT across lanes — register twiddles, uniform butterfly ----------------
__device__ __forceinline__ void init_tw(float2* tw, float sign, int lane){
  #pragma unroll
  for (int st = 0; st < 6; ++st){
    int h = 32 >> st;
    int idx = (lane & (h-1)) << st;
    float s, c;
    sincosf(sign*(float)(2.0*PI_D/64.0)*(float)idx, &s, &c);
    tw[st] = make_float2(c, s);
  }
}
__device__ __forceinline__ float2 fft64_lane(float2 x, const float2* tw, int lane){
  #pragma unroll
  for (int st = 0; st < 6; ++st){
    int h = 32 >> st;
    float2 p;
    p.x = __shfl_xor(x.x, h, 64);
    p.y = __shfl_xor(x.y, h, 64);
    float sgn = (lane & h) ? -1.f : 1.f;
    float2 s = make_float2(fmaf(sgn, x.x, p.x), fmaf(sgn, x.y, p.y));
    float2 t = cxmul(s, tw[st]);
    x = (lane & h) ? t : s;
  }
  return x;
}

// ---------------- fused BN+ReLU + packed real fft2 -> bf16-packed XH ----------------
__global__ __launch_bounds__(TPB) void k_fft2_fwd(const ushortT* __restrict__ X1, const ushortT* __restrict__ X2,
                                                  const ushortT* __restrict__ X3, const float2* __restrict__ ss,
                                                  uintT* __restrict__ XH, int Cin, int z0){
  __shared__ __attribute__((aligned(16))) float2 smem[4224];
  float2* bufP = smem;          // packed input [a1][c33]; reused as row-FFT output [32][65]
  float2* bufW = smem + 2112;   // col-FFT result [f1][c33]
  int bc = blockIdx.x, zz = blockIdx.y, z = z0 + zz;
  int b = bc / Cin, ci = bc % Cin;
  const ushortT* src; int cl;
  if (ci < 25){ src = X1; cl = ci; }
  else if (ci < 50){ src = X2; cl = ci - 25; }
  else { src = X3; cl = ci - 50; }
  src += ((size_t)(b*25 + cl)*64 + z)*4096;
  float2 sc = ss[ci];
  int tid = threadIdx.x, lane = tid & 63, wid = tid >> 6;
  int rl = (int)(__brev((uintT)lane) >> 26);
  float2 tw[6];
  init_tw(tw, -1.f, lane);
  const uintT* s32 = (const uintT*)src;
  for (int i = tid; i < 2048; i += TPB){
    uintT u = s32[i];
    float v0 = fmaxf(bf2f((ushortT)(u & 0xffff))*sc.x + sc.y, 0.f);
    float v1 = fmaxf(bf2f((ushortT)(u >> 16))*sc.x + sc.y, 0.f);
    int a1 = i >> 5, c = i & 31;
    bufP[a1*33 + c] = make_float2(v0, v1);
  }
  __syncthreads();
  // step A: 32 packed FFTs over a1 (lane = a1)
  #pragma unroll 2
  for (int j = 0; j < 8; ++j){
    int c = wid*8 + j;
    float2 x = bufP[lane*33 + c];
    x = fft64_lane(x, tw, lane);
    bufW[rl*33 + c] = x;
  }
  __syncthreads();
  // step B: Hermitian unpack inline + 32 row FFTs (lane = a2)
  #pragma unroll 2
  for (int j = 0; j < 8; ++j){
    int r = wid*8 + j;
    int c = lane >> 1;
    float2 Wv = bufW[r*33 + c];
    float2 Wm = bufW[((64-r)&63)*33 + c];
    float2 x;
    if ((lane & 1) == 0) x = make_float2(0.5f*(Wv.x + Wm.x), 0.5f*(Wv.y - Wm.y));
    else                 x = make_float2(0.5f*(Wv.y + Wm.y), 0.5f*(Wm.x - Wv.x));
    x = fft64_lane(x, tw, lane);
    bufP[r*65 + rl] = x;
  }
  __syncthreads();
  uintT* dst = XH + ((size_t)bc*32 + zz)*2016;
  for (int idx = tid; idx < 2016; idx += TPB){
    int mi = idx / 63, n = idx % 63;
    dst[idx] = pk2(bufP[mi*65 + ((n+33)&63)]);
  }
}

// ---------------- F[bc,l,mi,n] = sum_z qw*Dz*XH — packed, reg-prefetch pipelined ----------------
#define SKEW(e) ((e) + ((e)>>4))
__global__ __launch_bounds__(TPB) void k_wig_F(const float* __restrict__ Dz2, const double* __restrict__ qw,
                                               const uintT* __restrict__ XHa, const uintT* __restrict__ XHb,
                                               uintT* __restrict__ F, int BC){
  __shared__ __attribute__((aligned(16))) float sm[9088];
  float* Dt = sm;                          // [z16][nn8][l 36pad]
  float2* Xt = (float2*)(sm + 4608);       // [bc16][130]
  int mi = blockIdx.x, nt = blockIdx.y, bcBase = blockIdx.z*16;
  int tid = threadIdx.x;
  int bg = tid & 3, lg = (tid>>2)&7, ng = tid>>5;
  const float* DzB = Dz2 + ((size_t)(mi*8 + nt)*64)*256;
  float2 acc[4][4];
  #pragma unroll
  for (int a = 0; a < 4; ++a)
    #pragma unroll
    for (int j = 0; j < 4; ++j) acc[a][j] = make_float2(0,0);

  float pd[16]; uintT px[8];
  auto fetch = [&](int chunk){
    const uintT* XH = (chunk < 2) ? XHa : XHb;
    int zq = (chunk & 1)*16, gz0 = chunk*16;
    #pragma unroll
    for (int t = 0; t < 16; ++t)
      pd[t] = DzB[(size_t)gz0*256 + tid + t*256];
    #pragma unroll
    for (int t = 0; t < 8; ++t){
      int idx = tid + t*256;
      int bc = idx >> 7, z = (idx>>3)&15, nn = idx&7;
      int gbc = bcBase + bc, n = nt*8 + nn;
      px[t] = (gbc < BC && n < 63) ? XH[((size_t)gbc*32 + zq + z)*2016 + mi*63 + n] : 0u;
    }
  };
  fetch(0);

  for (int chunk = 0; chunk < 4; ++chunk){
    int gz0 = chunk*16;
    __syncthreads();
    #pragma unroll
    for (int t = 0; t < 16; ++t){
      int idx = tid + t*256;
      int z = idx >> 8, l = (idx>>3)&31, nn = idx&7;
      Dt[(z*8+nn)*36 + l] = pd[t] * (float)qw[gz0+z];
    }
    #pragma unroll
    for (int t = 0; t < 8; ++t){
      int idx = tid + t*256;
      int bc = idx >> 7, z = (idx>>3)&15, nn = idx&7;
      Xt[bc*130 + z*8 + nn] = up2(px[t]);
    }
    __syncthreads();
    if (chunk + 1 < 4) fetch(chunk + 1);
    #pragma unroll 4
    for (int z = 0; z < 16; ++z){
      const float4 d = *(const float4*)&Dt[(z*8+ng)*36 + lg*4];
      float dd[4] = {d.x, d.y, d.z, d.w};
      float2 xv[4];
      #pragma unroll
      for (int j = 0; j < 4; ++j) xv[j] = Xt[(bg + 4*j)*130 + z*8 + ng];
      #pragma unroll
      for (int j = 0; j < 4; ++j)
        #pragma unroll
        for (int dl = 0; dl < 4; ++dl){
          acc[j][dl].x = fmaf(dd[dl], xv[j].x, acc[j][dl].x);
          acc[j][dl].y = fmaf(dd[dl], xv[j].y, acc[j][dl].y);
        }
    }
  }
  __syncthreads();
  float2* St = (float2*)sm;
  #pragma unroll
  for (int j = 0; j < 4; ++j)
    #pragma unroll
    for (int dl = 0; dl < 4; ++dl){
      int e = (bg + 4*j)*256 + (lg*4 + dl)*8 + ng;
      St[SKEW(e)] = acc[j][dl];
    }
  __syncthreads();
  for (int idx = tid; idx < 4096; idx += TPB){
    int bc = idx >> 8, l = (idx>>3)&31, nn = idx&7;
    int gbc = bcBase + bc, n = nt*8 + nn;
    if (gbc < BC && n < 63)
      F[((size_t)(gbc*32 + l))*2016 + mi*63 + n] = pk2(St[SKEW(idx)]);
  }
}

// ---------------- C[bi,l,mi,n] = sum_k F[bi,l,mi,k]*Deq[l,n,k] — packed in/out, in-place safe ----------------
__global__ __launch_bounds__(TPB) void k_deq_C(const float* __restrict__ Deq, const uintT* __restrict__ F,
                                               uintT* __restrict__ C, int BC){
  __shared__ __attribute__((aligned(16))) float sm[12604];
  float2* Fb = (float2*)sm;
  float* DeqT = sm + 8320;
  int l = blockIdx.x, mi = blockIdx.y, biBase = blockIdx.z*64;
  int tid = threadIdx.x;
  int ngr = tid & 15, big = tid >> 4;
  for (int idx = tid; idx < 3969; idx += TPB){
    int n = idx/63, k = idx - n*63;
    DeqT[k*68 + n] = Deq[((size_t)l*63 + n)*63 + k];
  }
  for (int idx = tid; idx < 4032; idx += TPB){
    int bi = idx/63, k = idx - bi*63;
    int gbi = biBase + bi;
    Fb[bi*65 + k] = (gbi < BC) ? up2(F[((size_t)(gbi*32 + l))*2016 + mi*63 + k]) : make_float2(0,0);
  }
  __syncthreads();
  float2 acc[4][4];
  #pragma unroll
  for (int a = 0; a < 4; ++a)
    #pragma unroll
    for (int j = 0; j < 4; ++j) acc[a][j] = make_float2(0,0);
  #pragma unroll 3
  for (int k = 0; k < 63; ++k){
    const float4 d = *(const float4*)&DeqT[k*68 + ngr*4];
    float dd[4] = {d.x, d.y, d.z, d.w};
    float2 fv[4];
    #pragma unroll
    for (int j = 0; j < 4; ++j) fv[j] = Fb[(big + 16*j)*65 + k];
    #pragma unroll
    for (int j = 0; j < 4; ++j)
      #pragma unroll
      for (int dn = 0; dn < 4; ++dn){
        acc[j][dn].x = fmaf(dd[dn], fv[j].x, acc[j][dn].x);
        acc[j][dn].y = fmaf(dd[dn], fv[j].y, acc[j][dn].y);
      }
  }
  __syncthreads();
  float2* St = (float2*)sm;
  #pragma unroll
  for (int j = 0; j < 4; ++j)
    #pragma unroll
    for (int dn = 0; dn < 4; ++dn){
      int n = ngr*4 + dn;
      if (n < 63) St[(big + 16*j)*63 + n] = acc[j][dn];
    }
  __syncthreads();
  for (int idx = tid; idx < 4032; idx += TPB){
    int bi = idx/63, n = idx - bi*63;
    int gbi = biBase + bi;
    if (gbi < BC) C[((size_t)(gbi*32 + l))*2016 + mi*63 + n] = pk2(St[idx]);
  }
}

// ---------------- Z[b,o,l,mi,n] = sum_i Kh[o,i,n]*C[b,i,l,mi,n] — packed C in, packed Z out ----------------
#define KOC 9
__global__ __launch_bounds__(TPB) void k_kh_z(const uintT* __restrict__ C, const float2* __restrict__ Kh,
                                              uintT* __restrict__ Z, int I, int O){
  __shared__ float2 Kt[KOC*5*64];
  const int nK = KOC*5*64;
  int l = blockIdx.x, mic = blockIdx.y, oc = blockIdx.z;
  int lane = threadIdx.x & 63, wid = threadIdx.x >> 6;
  int mi0 = mic*8 + wid*2;
  int n = lane;
  int o0 = oc*KOC;
  float2 acc[2][2][KOC];
  #pragma unroll
  for (int ml = 0; ml < 2; ++ml)
    #pragma unroll
    for (int b = 0; b < 2; ++b)
      #pragma unroll
      for (int oo = 0; oo < KOC; ++oo) acc[ml][b][oo] = make_float2(0,0);

  float2 pre[12];
  auto loadK = [&](int i0){
    #pragma unroll
    for (int t = 0; t < 12; ++t){
      int idx = threadIdx.x + t*256;
      float2 v = make_float2(0,0);
      if (idx < nK){
        int nn = idx & 63, rem = idx >> 6;
        int ic = rem % 5, oo = rem / 5;
        int o = o0 + oo;
        if (o < O && nn < 63) v = Kh[((size_t)o*I + (i0+ic))*63 + nn];
      }
      pre[t] = v;
    }
  };
  loadK(0);

  size_t cBase0 = ((size_t)l)*2016 + mi0*63 + n;
  size_t cBase1 = cBase0 + 63;
  int nch = I/5;
  for (int c = 0; c < nch; ++c){
    __syncthreads();
    #pragma unroll
    for (int t = 0; t < 12; ++t){
      int idx = threadIdx.x + t*256;
      if (idx < nK) Kt[idx] = pre[t];
    }
    __syncthreads();
    if (c+1 < nch) loadK((c+1)*5);
    if (n < 63){
      int i0 = c*5;
      float2 cv[5][4];
      #pragma unroll
      for (int ic = 0; ic < 5; ++ic){
        int i = i0 + ic;
        cv[ic][0] = up2(C[cBase0 + (size_t)i*64512]);
        cv[ic][1] = up2(C[cBase0 + (size_t)(I + i)*64512]);
        cv[ic][2] = up2(C[cBase1 + (size_t)i*64512]);
        cv[ic][3] = up2(C[cBase1 + (size_t)(I + i)*64512]);
      }
      #pragma unroll
      for (int ic = 0; ic < 5; ++ic){
        #pragma unroll
        for (int oo = 0; oo < KOC; ++oo){
          float2 kh = Kt[(oo*5 + ic)*64 + n];
          #pragma unroll
          for (int q = 0; q < 4; ++q){
            float2 cc = cv[ic][q];
            int ml = q >> 1, b = q & 1;
            acc[ml][b][oo].x = fmaf(kh.x, cc.x, acc[ml][b][oo].x);
            acc[ml][b][oo].x = fmaf(-kh.y, cc.y, acc[ml][b][oo].x);
            acc[ml][b][oo].y = fmaf(kh.x, cc.y, acc[ml][b][oo].y);
            acc[ml][b][oo].y = fmaf(kh.y, cc.x, acc[ml][b][oo].y);
          }
        }
      }
    }
  }
  if (n < 63){
    #pragma unroll
    for (int ml = 0; ml < 2; ++ml){
      size_t zBase = ((size_t)l)*2016 + (mi0 + ml)*63 + n;
      #pragma unroll
      for (int oo = 0; oo < KOC; ++oo){
        int o = o0 + oo;
        if (o < O){
          Z[zBase + (size_t)(0*O + o)*64512] = pk2(acc[ml][0][oo]);
          Z[zBase + (size_t)(1*O + o)*64512] = pk2(acc[ml][1][oo]);
        }
      }
    }
  }
}

// ---------------- Xt[bo,z,mi,n] = sum_l wl*Dz*Z — packed, reg-prefetch pipelined ----------------
__global__ __launch_bounds__(TPB) void k_wig_synth(const float* __restrict__ Dz2, const uintT* __restrict__ Z,
                                                   uintT* __restrict__ Xt_g, int BO){
  __shared__ __attribute__((aligned(16))) float sm[9088];
  float* Dt = sm;                          // [l16][nn8][z 36pad]
  float2* Zt = (float2*)(sm + 4608);       // [bo16][130]
  int mi = blockIdx.x, nt = blockIdx.y;
  int z0 = (blockIdx.z & 1)*32;
  int boBase = (blockIdx.z >> 1)*16;
  int tid = threadIdx.x;
  int bg = tid & 3, zg = (tid>>2)&7, ng = tid>>5;
  const float* DzB = Dz2 + ((size_t)(mi*8 + nt)*64)*256;
  float2 acc[4][4];
  #pragma unroll
  for (int a = 0; a < 4; ++a)
    #pragma unroll
    for (int j = 0; j < 4; ++j) acc[a][j] = make_float2(0,0);

  float pd[16]; uintT pz[8];
  auto fetch = [&](int lq){
    #pragma unroll
    for (int t = 0; t < 16; ++t){
      int idx = tid + t*256;
      int z = idx >> 7, ll = (idx>>3)&15, nn = idx&7;
      int lG = lq + ll;
      pd[t] = DzB[(size_t)(z0+z)*256 + lG*8 + nn];
    }
    #pragma unroll
    for (int t = 0; t < 8; ++t){
      int idx = tid + t*256;
      int bo = idx >> 7, ll = (idx>>3)&15, nn = idx&7;
      int gbo = boBase + bo, n = nt*8 + nn;
      pz[t] = (gbo < BO && n < 63) ? Z[((size_t)(gbo*32 + lq + ll))*2016 + mi*63 + n] : 0u;
    }
  };
  fetch(0);

  for (int lq = 0; lq < 32; lq += 16){
    __syncthreads();
    #pragma unroll
    for (int t = 0; t < 16; ++t){
      int idx = tid + t*256;
      int z = idx >> 7, ll = (idx>>3)&15, nn = idx&7;
      int lG = lq + ll;
      Dt[(ll*8+nn)*36 + z] = pd[t] * (0.5f*(float)(2*lG+1));
    }
    #pragma unroll
    for (int t = 0; t < 8; ++t){
      int idx = tid + t*256;
      int bo = idx >> 7, ll = (idx>>3)&15, nn = idx&7;
      Zt[bo*130 + ll*8 + nn] = up2(pz[t]);
    }
    __syncthreads();
    if (lq == 0) fetch(16);
    #pragma unroll 4
    for (int ll = 0; ll < 16; ++ll){
      const float4 d = *(const float4*)&Dt[(ll*8+ng)*36 + zg*4];
      float dd[4] = {d.x, d.y, d.z, d.w};
      float2 zv[4];
      #pragma unroll
      for (int j = 0; j < 4; ++j) zv[j] = Zt[(bg + 4*j)*130 + ll*8 + ng];
      #pragma unroll
      for (int j = 0; j < 4; ++j)
        #pragma unroll
        for (int dz = 0; dz < 4; ++dz){
          acc[j][dz].x = fmaf(dd[dz], zv[j].x, acc[j][dz].x);
          acc[j][dz].y = fmaf(dd[dz], zv[j].y, acc[j][dz].y);
        }
    }
  }
  __syncthreads();
  float2* St = (float2*)sm;
  #pragma unroll
  for (int j = 0; j < 4; ++j)
    #pragma unroll
    for (int dz = 0; dz < 4; ++dz){
      int e = (bg + 4*j)*256 + (zg*4 + dz)*8 + ng;
      St[SKEW(e)] = acc[j][dz];
    }
  __syncthreads();
  for (int idx = tid; idx < 4096; idx += TPB){
    int bo = idx >> 8, z = (idx>>3)&31, nn = idx&7;
    int gbo = boBase + bo, n = nt*8 + nn;
    if (gbo < BO && n < 63)
      Xt_g[((size_t)gbo*64 + z0 + z)*2016 + mi*63 + n] = pk2(St[SKEW(idx)]);
  }
}

// ---------------- inverse helpers (bf16-packed src) ----------------
__device__ __forceinline__ void inv_stage_rows(const uintT* __restrict__ src, float2* bufR,
                                               const float2* tw, int lane, int wid, int rl){
  int tid = threadIdx.x;
  if (tid < 64) bufR[32*65 + tid] = make_float2(0,0);
  else if (tid < 96) bufR[(tid-64)*65 + 32] = make_float2(0,0);
  for (int idx = tid; idx < 2016; idx += TPB){
    int mi = idx / 63, ni = idx - mi*63;
    bufR[mi*65 + ((ni+33)&63)] = up2(src[idx]);
  }
  __syncthreads();
  #pragma unroll 2
  for (int j = 0; j < 8; ++j){
    int r = wid*8 + j;
    float2 x = bufR[r*65 + lane];
    x = fft64_lane(x, tw, lane);
    bufR[r*65 + rl] = x;
  }
  __syncthreads();
}
__device__ __forceinline__ float2 inv_col_pack(const float2* bufR, int f, int pc){
  float2 r0, r1;
  if (f <= 32){
    r0 = bufR[f*65 + 2*pc];
    r1 = bufR[f*65 + 2*pc + 1];
  } else {
    int g = 64 - f;
    float2 a = bufR[g*65 + 2*pc];
    float2 b = bufR[g*65 + 2*pc + 1];
    r0 = make_float2(a.x, -a.y);
    r1 = make_float2(b.x, -b.y);
  }
  return make_float2(r0.x - r1.y, r0.y + r1.x);
}

// ---------------- ifft2 + real + bias -> bf16 X ----------------
__global__ __launch_bounds__(TPB) void k_ifft2_sym(const uintT* __restrict__ Xt, ushortT* __restrict__ Xo,
                                                   const float* __restrict__ bias, int O){
  __shared__ __attribute__((aligned(16))) float2 bufR[33*65];
  __shared__ uintT ldsOut[64*33];
  int bo = blockIdx.x >> 6;
  int o = bo % O;
  int tid = threadIdx.x, lane = tid & 63, wid = tid >> 6;
  int rl = (int)(__brev((uintT)lane) >> 26);
  float2 tw[6];
  init_tw(tw, 1.f, lane);
  const uintT* src = Xt + (size_t)blockIdx.x*2016;
  inv_stage_rows(src, bufR, tw, lane, wid, rl);
  float bb = bias[o];
  #pragma unroll 2
  for (int j = 0; j < 8; ++j){
    int pc = wid*8 + j;
    float2 w = inv_col_pack(bufR, lane, pc);
    float2 x = fft64_lane(w, tw, lane);
    ushortT u0 = f2bf(x.x*(1.f/4096.f) + bb);
    ushortT u1 = f2bf(x.y*(1.f/4096.f) + bb);
    ldsOut[rl*33 + pc] = (uintT)u0 | ((uintT)u1 << 16);
  }
  __syncthreads();
  uintT* dst = (uintT*)(Xo + (size_t)blockIdx.x*4096);
  for (int i = tid; i < 2048; i += TPB){
    int a1 = i >> 5, pc = i & 31;
    dst[i] = ldsOut[a1*33 + pc];
  }
}

// ---------------- conv3 final stats from spectrum (Parseval, bf16-packed) ----------------
__global__ __launch_bounds__(TPB) void k_stats3(const uintT* __restrict__ Xt, double* __restrict__ part){
  int bo = blockIdx.x, zb = blockIdx.y;
  double s = 0.0, p = 0.0;
  for (int zz = 0; zz < 4; ++zz){
    const uintT* pl = Xt + ((size_t)bo*64 + zb*4 + zz)*2016;
    for (int idx = threadIdx.x; idx < 2016; idx += TPB){
      float2 v = up2(pl[idx]);
      double q = (double)v.x*v.x + (double)v.y*v.y;
      p += (idx < 63) ? q : 2.0*q;
      if (idx == 31) s += v.x;
    }
  }
  __shared__ double sh[TPB], sh2[TPB];
  sh[threadIdx.x] = s; sh2[threadIdx.x] = p;
  __syncthreads();
  for (int o = 128; o > 0; o >>= 1){
    if (threadIdx.x < o){ sh[threadIdx.x] += sh[threadIdx.x+o]; sh2[threadIdx.x] += sh2[threadIdx.x+o]; }
    __syncthreads();
  }
  if (threadIdx.x == 0){
    part[((size_t)bo*16 + zb)*2 + 0] = sh[0];
    part[((size_t)bo*16 + zb)*2 + 1] = sh2[0];
  }
}

__global__ void k_fstat(const double* __restrict__ part, const float* __restrict__ bias,
                        const float* __restrict__ g, const float* __restrict__ bsh,
                        float2* __restrict__ ss, int O){
  int o = threadIdx.x;
  if (o >= O) return;
  double S = 0.0, P = 0.0;
  for (int b = 0; b < 2; ++b)
    for (int zb = 0; zb < 16; ++zb){
      size_t base = ((size_t)(b*O + o)*16 + zb)*2;
      S += part[base]; P += part[base+1];
    }
  P *= (1.0/4096.0);
  double N = 524288.0;
  double bi = bias[o];
  double mean = S/N + bi;
  double var = P/N + 2.0*bi*S/N + bi*bi - mean*mean;
  double sc = (double)g[o] / sqrt(var + 1e-5);
  ss[o] = make_float2((float)sc, (float)((bi - mean)*sc + (double)bsh[o]));
}

// ---------------- fused ifft2 + BN + ReLU + mean over gamma ----------------
__global__ __launch_bounds__(TPB) void k_final(const uintT* __restrict__ Xt, const float2* __restrict__ ss,
                                               float* __restrict__ out, int O){
  __shared__ __attribute__((aligned(16))) float2 bufR[33*65];
  __shared__ float s4[4*64];
  int bo = blockIdx.x >> 6;
  int o = bo % O;
  int tid = threadIdx.x, lane = tid & 63, wid = tid >> 6;
  int rl = (int)(__brev((uintT)lane) >> 26);
  float2 tw[6];
  init_tw(tw, 1.f, lane);
  const uintT* src = Xt + (size_t)blockIdx.x*2016;
  inv_stage_rows(src, bufR, tw, lane, wid, rl);
  float2 sv = ss[o];
  float acc = 0.f;
  #pragma unroll 2
  for (int j = 0; j < 8; ++j){
    int pc = wid*8 + j;
    float2 w = inv_col_pack(bufR, lane, pc);
    float2 x = fft64_lane(w, tw, lane);
    acc += fmaxf(fmaf(x.x*(1.f/4096.f), sv.x, sv.y), 0.f);
    acc += fmaxf(fmaf(x.y*(1.f/4096.f), sv.x, sv.y), 0.f);
  }
  s4[wid*64 + rl] = acc;
  __syncthreads();
  if (tid < 64)
    out[(size_t)blockIdx.x*64 + tid] = (s4[tid] + s4[64+tid] + s4[128+tid] + s4[192+tid]) * (1.f/64.f);
}

extern "C" void kernel_launch(void* const* d_in, const int* in_sizes, int n_in,
                              void* d_out, int out_size, void* d_ws, size_t ws_size,
                              hipStream_t stream){
  const float* x   = (const float*)d_in[0];
  const float* ks2 = (const float*)d_in[1];
  const float* bs2 = (const float*)d_in[2];
  const float* k1  = (const float*)d_in[3];
  const float* b1c = (const float*)d_in[4];
  const float* k2  = (const float*)d_in[5];
  const float* b2c = (const float*)d_in[6];
  const float* k3  = (const float*)d_in[7];
  const float* b3c = (const float*)d_in[8];
  const float* g1 = (const float*)d_in[9],  *bb1 = (const float*)d_in[10];
  const float* g2 = (const float*)d_in[11], *bb2 = (const float*)d_in[12];
  const float* g3 = (const float*)d_in[13], *bb3 = (const float*)d_in[14];
  const float* g4 = (const float*)d_in[15], *bb4 = (const float*)d_in[16];
  float* out = (float*)d_out;

  char* w = (char*)d_ws;
  size_t off = 0;
  auto take = [&](size_t bytes)->char*{
    char* p = w + off;
    off += (bytes + 255) & ~(size_t)255;
    return p;
  };
  float*  Dz2  = (float*) take(32ull*8*64*32*8*4);    // 16.8 MB tiled
  float*  D0   = (float*) take(64ull*32*32*4);
  float*  Deq  = (float*) take(32ull*63*63*4);
  double* lf   = (double*)take(65*8);
  double* qw   = (double*)take(64*8);
  double* part = (double*)take(75ull*64*2*8);
  float2* ss   = (float2*)take(75*8);
  float2* KhS2 = (float2*)take(63ull*25*3*8);
  float2* Kh1  = (float2*)take(63ull*25*25*8);
  float2* Kh2  = (float2*)take(63ull*25*50*8);
  float2* Kh3  = (float2*)take(63ull*36*75*8);
  float2* XH2  = (float2*)take(2ull*3*64*63*8);
  float2* F2   = (float2*)take(2ull*3*32*63*8);
  ushortT* X1  = (ushortT*)take(2ull*25*262144*2);
  ushortT* X2  = (ushortT*)take(2ull*25*262144*2);
  ushortT* X3  = (ushortT*)take(2ull*25*262144*2);
  uintT*  Ah   = (uintT*) take(150ull*32*2016*4);     // 38.7 MB bf16-packed
  uintT*  Bh   = (uintT*) take(150ull*32*2016*4);
  uintT*  P    = (uintT*) take(150ull*32*2016*4);     // 38.7 MB bf16-packed (F, C in-place)
  if (off > ws_size) return;

  dim3 tpb(TPB);
  auto cdiv = [](long long a, long long b){ return (int)((a + b - 1) / b); };

  k_tables<<<1, 64, 0, stream>>>(lf, qw);
  k_wigner<<<dim3(65,32), tpb, 0, stream>>>(lf, Dz2, D0, Deq);
  k_kh<<<cdiv(3ll*25*63,TPB),  tpb, 0, stream>>>(ks2, KhS2, 3, 25,  (float)(1.0/sqrt(196608.0)));
  k_kh<<<cdiv(25ll*25*63,TPB), tpb, 0, stream>>>(k1,  Kh1, 25, 25, (float)(1.0/sqrt(1600.0)));
  k_kh<<<cdiv(50ll*25*63,TPB), tpb, 0, stream>>>(k2,  Kh2, 50, 25, (float)(1.0/sqrt(3200.0)));
  k_kh<<<cdiv(75ll*36*63,TPB), tpb, 0, stream>>>(k3,  Kh3, 75, 36, (float)(1.0/sqrt(4800.0)));

  // ---- S2 conv ----
  k_s2_fft<<<cdiv(2ll*3*64*63,TPB), tpb, 0, stream>>>(x, XH2);
  k_s2_F<<<cdiv(2ll*3*32*63,TPB), tpb, 0, stream>>>(D0, qw, XH2, F2);
  k_s2_zhat<<<cdiv(2ll*25*32*2016,TPB), tpb, 0, stream>>>(Deq, F2, KhS2, Ah);
  k_wig_synth<<<dim3(32,8,2*cdiv(50,16)), tpb, 0, stream>>>(Dz2, Ah, Bh, 50);
  k_ifft2_sym<<<50*64, tpb, 0, stream>>>(Bh, X1, bs2, 25);
  k_bnstats<<<dim3(25,64), tpb, 0, stream>>>(X1, 0, part);

  // ---- generic SO3 conv ----
  auto so3 = [&](const ushortT* Xa, const ushortT* Xb, const ushortT* Xc, int Cin,
                 const float* g, const float* bb, const float2* Kh, int O,
                 const float* bias, ushortT* Xout, int isFinal){
    int BC = 2*Cin, BO = 2*O;
    k_bnfinal<<<1, 128, 0, stream>>>(part, g, bb, ss, Cin);
    k_fft2_fwd<<<dim3(BC,32), tpb, 0, stream>>>(Xa, Xb, Xc, ss, Ah, Cin, 0);
    k_fft2_fwd<<<dim3(BC,32), tpb, 0, stream>>>(Xa, Xb, Xc, ss, Bh, Cin, 32);
    k_wig_F<<<dim3(32,8,cdiv(BC,16)), tpb, 0, stream>>>(Dz2, qw, Ah, Bh, P, BC);
    k_deq_C<<<dim3(32,32,cdiv(BC,64)), tpb, 0, stream>>>(Deq, P, P, BC);        // C in-place (packed)
    k_kh_z<<<dim3(32,4,cdiv(O,KOC)), tpb, 0, stream>>>(P, Kh, Ah, Cin, O);      // Z packed -> Ah
    k_wig_synth<<<dim3(32,8,2*cdiv(BO,16)), tpb, 0, stream>>>(Dz2, Ah, Bh, BO); // Xt packed -> Bh
    if (!isFinal){
      k_ifft2_sym<<<BO*64, tpb, 0, stream>>>(Bh, Xout, bias, O);
    } else {
      k_stats3<<<dim3(BO,16), tpb, 0, stream>>>(Bh, part);
      k_fstat<<<1, 64, 0, stream>>>(part, bias, g4, bb4, ss, O);
      k_final<<<BO*64, tpb, 0, stream>>>(Bh, ss, out, O);
    }
  };

  so3(X1, X1, X1, 25, g1, bb1, Kh1, 25, b1c, X2, 0);
  k_bnstats<<<dim3(25,64), tpb, 0, stream>>>(X2, 25, part);
  so3(X1, X2, X2, 50, g2, bb2, Kh2, 25, b2c, X3, 0);
  k_bnstats<<<dim3(25,64), tpb, 0, stream>>>(X3, 50, part);
  so3(X1, X2, X3, 75, g3, bb3, Kh3, 36, b3c, nullptr, 1);
}